// Round 1
// baseline (2040.514 us; speedup 1.0000x reference)
//
#include <hip/hip_runtime.h>
#include <stdint.h>

#define DEVFN __device__ __forceinline__

constexpr int BB = 8, QQ = 300, CC = 300, NN = 300, DD = 256;
constexpr int WHX = 9216, BQ = 2400, SIMW = 600, ADJW = 38;

// ---------------- workspace layout (float units) ----------------
constexpr size_t F_SIMS   = 0;                                 // [2400][600]: c<300 sim, c>=300 scores2
constexpr size_t F_GTSIM  = F_SIMS   + (size_t)BQ*SIMW;        // [300][300]
constexpr size_t F_OM     = F_GTSIM  + (size_t)NN*CC;          // [300][9216]
constexpr size_t F_MM     = F_OM     + (size_t)NN*WHX;         // [300][300]
constexpr size_t F_SCORE  = F_MM     + (size_t)NN*NN;          // [2400]
constexpr size_t F_BBOX   = F_SCORE  + BQ;                     // [2400][4]
constexpr size_t F_TB     = F_BBOX   + (size_t)BQ*4;           // [300][4]
constexpr size_t F_SB     = F_TB     + (size_t)NN*4;           // sorted boxes [2400][4]
constexpr size_t F_SAREA  = F_SB     + (size_t)BQ*4;           // [2400]
constexpr size_t F_KB     = F_SAREA  + BQ;                     // kept boxes [<=2400][4]
constexpr size_t F_ROWSUM = F_KB     + (size_t)BQ*4;           // [300]
constexpr size_t F_OE     = F_ROWSUM + NN;                     // ---- zeroed zone: out_embs [300][256]
constexpr size_t F_GSEL   = F_OE     + (size_t)NN*DD;          // [300][4]
constexpr size_t F_MSUM   = F_GSEL   + (size_t)NN*4;           // [300]
constexpr size_t F_STGT   = F_MSUM   + NN;                     // [8]
constexpr size_t F_SINP   = F_STGT   + 8;                      // [8]
constexpr size_t F_SC     = F_SINP   + 8;                      // scalars: 0 t1,1 t2,2 oml,3 iouacc,4 l1,5 stot
constexpr size_t F_ACCEND = F_SC     + 16;                     // ---- end zeroed zone
constexpr size_t F_ORDER  = F_ACCEND;                          // int [2400]
constexpr size_t F_NMSIDX = F_ORDER  + BQ;                     // int [2400]
constexpr size_t F_SEL2   = F_NMSIDX + BQ;                     // int [300]
constexpr size_t F_BSTART = F_SEL2   + NN;                     // int [16]
constexpr size_t F_KINT   = F_BSTART + 16;                     // int [4]
constexpr size_t F_ADJ    = ((F_KINT + 4 + 1) & ~(size_t)1);   // u64 [2400][38]
constexpr size_t F_SUPW   = F_ADJ + (size_t)BQ*ADJW*2;         // u64 [38]
constexpr size_t F_TOTAL  = F_SUPW + ADJW*2;

// ---------------- JAX threefry2x32 (partitionable scheme) ----------------
DEVFN uint32_t rotl32(uint32_t v, int r){ return (v << r) | (v >> (32 - r)); }

DEVFN void tf2x32(uint32_t k0, uint32_t k1, uint32_t x0, uint32_t x1,
                  uint32_t& o0, uint32_t& o1){
  uint32_t ks2 = k0 ^ k1 ^ 0x1BD11BDAu;
  x0 += k0; x1 += k1;
#define TFR(r) x0 += x1; x1 = rotl32(x1, r); x1 ^= x0;
  TFR(13) TFR(15) TFR(26) TFR(6)   x0 += k1;  x1 += ks2 + 1u;
  TFR(17) TFR(29) TFR(16) TFR(24)  x0 += ks2; x1 += k0  + 2u;
  TFR(13) TFR(15) TFR(26) TFR(6)   x0 += k0;  x1 += k1  + 3u;
  TFR(17) TFR(29) TFR(16) TFR(24)  x0 += k1;  x1 += ks2 + 4u;
  TFR(13) TFR(15) TFR(26) TFR(6)   x0 += ks2; x1 += k0  + 5u;
#undef TFR
  o0 = x0; o1 = x1;
}

// split(key(42), 3) fold-like: key_i = threefry2x32((0,42),(0,i))
DEVFN void subkey(int i, uint32_t& k0, uint32_t& k1){
  tf2x32(0u, 42u, 0u, (uint32_t)i, k0, k1);
}

// partitionable 32-bit random bits for flat element idx: hi^lo of tf(key,(0,idx))
DEVFN float gumbel32(uint32_t k0, uint32_t k1, uint32_t idx){
  uint32_t h, l; tf2x32(k0, k1, 0u, idx, h, l);
  uint32_t bits = h ^ l;
  float f = __uint_as_float((bits >> 9) | 0x3F800000u) - 1.0f;
  const float tiny = 1.17549435e-38f;
  float u = fmaxf(tiny, f + tiny);
  return -logf(-logf(u));
}

DEVFN float iou_xyxy(float ax1,float ay1,float ax2,float ay2,
                     float bx1,float by1,float bx2,float by2){
  float aa = (ax2-ax1)*(ay2-ay1);
  float ab = (bx2-bx1)*(by2-by1);
  float lx = fmaxf(ax1,bx1), ly = fmaxf(ay1,by1);
  float rx = fminf(ax2,bx2), ry = fminf(ay2,by2);
  float iw = fmaxf(rx-lx,0.f), ih = fmaxf(ry-ly,0.f);
  float in_ = iw*ih;
  return in_/(aa+ab-in_);
}

// ---------------- K1: sims[2400][600] (sim | scores2) + gtsim[300][300] ----------------
__global__ __launch_bounds__(256) void k_gemm(
    const float* __restrict__ pl, const float* __restrict__ ce,
    const float* __restrict__ te, float* __restrict__ sims,
    float* __restrict__ gtsim){
  size_t idx = (size_t)blockIdx.x*256 + threadIdx.x;
  const float *a, *bp; float* o;
  if (idx < (size_t)BQ*SIMW){
    int r = (int)(idx / SIMW), c = (int)(idx % SIMW);
    a  = pl + (size_t)r*DD;
    bp = (c < CC) ? (ce + (size_t)c*DD) : (te + (size_t)(c-CC)*DD);
    o  = sims + idx;
  } else {
    size_t j = idx - (size_t)BQ*SIMW;
    if (j >= (size_t)NN*CC) return;
    int n = (int)(j / CC), c = (int)(j % CC);
    a = te + (size_t)n*DD; bp = ce + (size_t)c*DD;
    o = gtsim + j;
  }
  const float4* a4 = (const float4*)a;
  const float4* b4 = (const float4*)bp;
  float s = 0.f;
  #pragma unroll 8
  for (int t = 0; t < DD/4; t++){
    float4 x = a4[t], y = b4[t];
    s += x.x*y.x + x.y*y.y + x.z*y.z + x.w*y.w;
  }
  *o = s;
}

// ---------------- K2: per-bq scores/argmax(g0)/boxes; tb rows; gtsim rowsums ----------------
__global__ __launch_bounds__(512) void k_post(
    const float* __restrict__ sims, const float* __restrict__ pb,
    const float* __restrict__ tbb, const int* __restrict__ tids,
    const int* __restrict__ bidx, const float* __restrict__ gtsim,
    float* __restrict__ score, float* __restrict__ bbox,
    float* __restrict__ tb, float* __restrict__ rowsum){
  int bq = blockIdx.x, tid = threadIdx.x;
  __shared__ float sv[512];
  __shared__ int   si[512];
  float v = (tid < CC) ? sims[(size_t)bq*SIMW + tid] : -INFINITY;
  // phase A: out_scores = max_c sim
  sv[tid] = v; __syncthreads();
  for (int s = 256; s > 0; s >>= 1){ if (tid < s) sv[tid] = fmaxf(sv[tid], sv[tid+s]); __syncthreads(); }
  if (tid == 0) score[bq] = sv[0];
  __syncthreads();
  // phase B: argmax_c (sim + gumbel_k0)
  uint32_t gk0, gk1; subkey(0, gk0, gk1);
  float y = (tid < CC) ? v + gumbel32(gk0, gk1, (uint32_t)(bq*CC + tid)) : -INFINITY;
  sv[tid] = y; si[tid] = tid; __syncthreads();
  for (int s = 256; s > 0; s >>= 1){
    if (tid < s){
      float ov = sv[tid+s]; int oi = si[tid+s];
      if (ov > sv[tid] || (ov == sv[tid] && oi < si[tid])){ sv[tid] = ov; si[tid] = oi; }
    }
    __syncthreads();
  }
  if (tid == 0){
    int cls = si[0];
    float ox = 224.0f * (float)cls;
    float oy = 224.0f * (float)(bq / QQ);
    float cx = pb[bq*4+0], cy = pb[bq*4+1], ww = pb[bq*4+2], hh = pb[bq*4+3];
    bbox[bq*4+0] = cx - 0.5f*ww + ox;
    bbox[bq*4+1] = cy - 0.5f*hh + oy;
    bbox[bq*4+2] = cx + 0.5f*ww + ox;
    bbox[bq*4+3] = cy + 0.5f*hh + oy;
  }
  if (bq < NN){
    __syncthreads();
    float rs = (tid < CC) ? gtsim[(size_t)bq*CC + tid] : 0.f;
    sv[tid] = rs; __syncthreads();
    for (int s = 256; s > 0; s >>= 1){ if (tid < s) sv[tid] += sv[tid+s]; __syncthreads(); }
    if (tid == 0) rowsum[bq] = sv[0];
    if (tid == 1){
      float gx = 224.0f * (float)tids[bq], gy = 224.0f * (float)bidx[bq];
      float cx = tbb[bq*4+0], cy = tbb[bq*4+1], ww = tbb[bq*4+2], hh = tbb[bq*4+3];
      tb[bq*4+0] = cx - 0.5f*ww + gx;
      tb[bq*4+1] = cy - 0.5f*hh + gy;
      tb[bq*4+2] = cx + 0.5f*ww + gx;
      tb[bq*4+3] = cy + 0.5f*hh + gy;
    }
  }
}

// ---------------- K3: stable descending rank sort ----------------
__global__ __launch_bounds__(256) void k_rank(
    const float* __restrict__ score, int* __restrict__ order){
  __shared__ float s[BQ];
  int tid = threadIdx.x;
  for (int i = tid; i < BQ; i += 256) s[i] = score[i];
  __syncthreads();
  int t = blockIdx.x*256 + tid;
  if (t >= BQ) return;
  float st = s[t];
  int cnt = 0;
  for (int j = 0; j < BQ; j++){
    float sj = s[j];
    cnt += (sj > st) || (sj == st && j < t);
  }
  order[cnt] = t;
}

// ---------------- K4: gather sorted boxes/areas + batch segment starts ----------------
__global__ __launch_bounds__(256) void k_gather(
    const float* __restrict__ bbox, const int* __restrict__ order,
    const int* __restrict__ bidx, float* __restrict__ sb,
    float* __restrict__ sarea, int* __restrict__ bstart){
  int t = blockIdx.x*256 + threadIdx.x;
  if (t < BQ){
    int o = order[t];
    float x1 = bbox[o*4+0], y1 = bbox[o*4+1], x2 = bbox[o*4+2], y2 = bbox[o*4+3];
    sb[t*4+0] = x1; sb[t*4+1] = y1; sb[t*4+2] = x2; sb[t*4+3] = y2;
    sarea[t] = (x2-x1)*(y2-y1);
  }
  if (blockIdx.x == 0 && threadIdx.x < 9){
    int b = threadIdx.x, c = 0;
    for (int n = 0; n < NN; n++) c += (bidx[n] < b);
    bstart[b] = c;
  }
}

// ---------------- K5: adjacency bitmask (iou>0.5 && j>i) over sorted boxes ----------------
__global__ __launch_bounds__(256) void k_adj(
    const float* __restrict__ sb, const float* __restrict__ sarea,
    unsigned long long* __restrict__ adj){
  __shared__ float4 box[BQ];
  __shared__ float  ar[BQ];
  int tid = threadIdx.x, i = blockIdx.x;
  for (int t = tid; t < BQ; t += 256){ box[t] = ((const float4*)sb)[t]; ar[t] = sarea[t]; }
  __syncthreads();
  float4 bi = box[i]; float ai = ar[i];
  int lane = tid & 63, wv = tid >> 6;
  for (int w = wv; w < ADJW; w += 4){
    int j = w*64 + lane;
    bool pred = false;
    if (j < BQ && j > i){
      float4 bj = box[j];
      float lx = fmaxf(bi.x,bj.x), ly = fmaxf(bi.y,bj.y);
      float rx = fminf(bi.z,bj.z), ry = fminf(bi.w,bj.w);
      float iw = fmaxf(rx-lx,0.f), ih = fmaxf(ry-ly,0.f);
      float in_ = iw*ih;
      pred = (in_/(ai + ar[j] - in_)) > 0.5f;
    }
    unsigned long long m = __ballot(pred);
    if (lane == 0) adj[(size_t)i*ADJW + w] = m;
  }
}

// ---------------- K6: serial greedy suppress (1 wave, lane-per-word) ----------------
__global__ __launch_bounds__(64) void k_nms(
    const unsigned long long* __restrict__ adj,
    unsigned long long* __restrict__ supw){
  int lane = threadIdx.x;
  unsigned long long sup = 0ull;
  unsigned long long buf[8];
  #pragma unroll
  for (int d = 0; d < 8; d++)
    buf[d] = (lane < ADJW) ? adj[(size_t)d*ADJW + lane] : 0ull;
  for (int i0 = 0; i0 < BQ; i0 += 8){
    #pragma unroll
    for (int d = 0; d < 8; d++){
      int i = i0 + d;
      int wi = i >> 6;
      unsigned long long swi = __shfl(sup, wi);
      unsigned long long row = buf[d];
      int nx = i + 8;
      buf[d] = (nx < BQ && lane < ADJW) ? adj[(size_t)nx*ADJW + lane] : 0ull;
      if (!((swi >> (i & 63)) & 1ull)) sup |= row;
    }
  }
  if (lane < ADJW) supw[lane] = sup;
}

// ---------------- K7: compact kept -> nms_idx, kept boxes, K ----------------
__global__ __launch_bounds__(256) void k_compact(
    const unsigned long long* __restrict__ supw, const int* __restrict__ order,
    const float* __restrict__ sb, int* __restrict__ nmsidx,
    float* __restrict__ kb, int* __restrict__ kint){
  __shared__ int csum[256];
  int tid = threadIdx.x;
  int p0 = tid*10;
  int keepf[10];
  int cnt = 0;
  #pragma unroll
  for (int d = 0; d < 10; d++){
    int p = p0 + d;
    int k = 0;
    if (p < BQ) k = !((supw[p >> 6] >> (p & 63)) & 1ull);
    keepf[d] = k; cnt += k;
  }
  csum[tid] = cnt; __syncthreads();
  for (int s = 1; s < 256; s <<= 1){
    int add = (tid >= s) ? csum[tid - s] : 0;
    __syncthreads();
    csum[tid] += add;
    __syncthreads();
  }
  int pos = csum[tid] - cnt;
  #pragma unroll
  for (int d = 0; d < 10; d++){
    if (keepf[d]){
      int p = p0 + d;
      nmsidx[pos] = order[p];
      ((float4*)kb)[pos] = ((const float4*)sb)[p];
      pos++;
    }
  }
  if (tid == 255) kint[0] = csum[255];
}

// ---------------- K8: per-kept-box: softmax(iou)+g1 argmax -> scatter gt_sel/out_embs ----------------
__global__ __launch_bounds__(512) void k_gtsel(
    const float* __restrict__ kb, const float* __restrict__ tb,
    const int* __restrict__ nmsidx, const float* __restrict__ pl,
    const int* __restrict__ kint, float* __restrict__ gsel,
    float* __restrict__ oe){
  int k = blockIdx.x;
  if (k >= kint[0]) return;
  int tid = threadIdx.x;
  __shared__ float sv[512];
  __shared__ int   si[512];
  float4 a = ((const float4*)kb)[k];
  float iou = -INFINITY;
  if (tid < NN){
    float4 t = ((const float4*)tb)[tid];
    iou = iou_xyxy(a.x,a.y,a.z,a.w, t.x,t.y,t.z,t.w);
    if (iou != iou) iou = 0.f;
  }
  sv[tid] = iou; __syncthreads();
  for (int s = 256; s > 0; s >>= 1){ if (tid < s) sv[tid] = fmaxf(sv[tid], sv[tid+s]); __syncthreads(); }
  float m = sv[0]; __syncthreads();
  float e = (tid < NN) ? expf(iou - m) : 0.f;
  sv[tid] = e; __syncthreads();
  for (int s = 256; s > 0; s >>= 1){ if (tid < s) sv[tid] += sv[tid+s]; __syncthreads(); }
  float S = sv[0]; __syncthreads();
  uint32_t gk0, gk1; subkey(1, gk0, gk1);
  float y = (tid < NN) ? (e / S + gumbel32(gk0, gk1, (uint32_t)(k*NN + tid))) : -INFINITY;
  sv[tid] = y; si[tid] = tid; __syncthreads();
  for (int s = 256; s > 0; s >>= 1){
    if (tid < s){
      float ov = sv[tid+s]; int oi = si[tid+s];
      if (ov > sv[tid] || (ov == sv[tid] && oi < si[tid])){ sv[tid] = ov; si[tid] = oi; }
    }
    __syncthreads();
  }
  int sel = si[0];
  if (tid < 4) atomicAdd(&gsel[sel*4 + tid], ((const float*)&a)[tid]);
  if (tid < DD) atomicAdd(&oe[(size_t)sel*DD + tid], pl[(size_t)nmsidx[k]*DD + tid]);
}

// ---------------- K9: gt_ious sum(1-iou) and l1 ----------------
__global__ __launch_bounds__(512) void k_gtiou(
    const float* __restrict__ gsel, const float* __restrict__ tb,
    float* __restrict__ sc){
  int tid = threadIdx.x;
  __shared__ float s1[512], s2[512];
  float a1 = 0.f, a2 = 0.f;
  if (tid < NN){
    float4 g = ((const float4*)gsel)[tid];
    float4 t = ((const float4*)tb)[tid];
    float iou = iou_xyxy(g.x,g.y,g.z,g.w, t.x,t.y,t.z,t.w);
    a1 = 1.f - iou;
    a2 = fabsf(g.x-t.x) + fabsf(g.y-t.y) + fabsf(g.z-t.z) + fabsf(g.w-t.w);
  }
  s1[tid] = a1; s2[tid] = a2; __syncthreads();
  for (int s = 256; s > 0; s >>= 1){
    if (tid < s){ s1[tid] += s1[tid+s]; s2[tid] += s2[tid+s]; }
    __syncthreads();
  }
  if (tid == 0){ sc[3] = s1[0]; sc[4] = s2[0]; }
}

// ---------------- K10: M = tgt_embs @ out_embs^T ----------------
__global__ __launch_bounds__(256) void k_m(
    const float* __restrict__ te, const float* __restrict__ oe,
    float* __restrict__ M){
  int idx = blockIdx.x*256 + threadIdx.x;
  if (idx >= NN*NN) return;
  int i = idx / NN, j = idx % NN;
  const float4* a4 = (const float4*)(te + (size_t)i*DD);
  const float4* b4 = (const float4*)(oe + (size_t)j*DD);
  float s = 0.f;
  #pragma unroll 8
  for (int t = 0; t < DD/4; t++){
    float4 x = a4[t], y = b4[t];
    s += x.x*y.x + x.y*y.y + x.z*y.z + x.w*y.w;
  }
  M[idx] = s;
}

// ---------------- K11: both cross-entropies (row + col lse) ----------------
__global__ __launch_bounds__(64) void k_ce(
    const float* __restrict__ M, float* __restrict__ sc){
  int i = blockIdx.x, lane = threadIdx.x;
  float m = -INFINITY;
  for (int j = lane; j < NN; j += 64) m = fmaxf(m, M[(size_t)i*NN + j]);
  for (int o = 32; o > 0; o >>= 1) m = fmaxf(m, __shfl_xor(m, o));
  float s = 0.f;
  for (int j = lane; j < NN; j += 64) s += expf(M[(size_t)i*NN + j] - m);
  for (int o = 32; o > 0; o >>= 1) s += __shfl_xor(s, o);
  float lr = m + logf(s);
  float m2 = -INFINITY;
  for (int j = lane; j < NN; j += 64) m2 = fmaxf(m2, M[(size_t)j*NN + i]);
  for (int o = 32; o > 0; o >>= 1) m2 = fmaxf(m2, __shfl_xor(m2, o));
  float s2 = 0.f;
  for (int j = lane; j < NN; j += 64) s2 += expf(M[(size_t)j*NN + i] - m2);
  for (int o = 32; o > 0; o >>= 1) s2 += __shfl_xor(s2, o);
  float lc = m2 + logf(s2);
  if (lane == 0){
    float d = M[(size_t)i*NN + i];
    atomicAdd(&sc[0], lr - d);
    atomicAdd(&sc[1], lc - d);
  }
}

// ---------------- K12: sel2[n] = argmax_r (scores2[r,n] + g2) ----------------
__global__ __launch_bounds__(256) void k_sel2(
    const float* __restrict__ sims, int* __restrict__ sel2){
  int n = blockIdx.x, tid = threadIdx.x;
  uint32_t gk0, gk1; subkey(2, gk0, gk1);
  float best = -INFINITY; int bi = 0x7fffffff;
  for (int r = tid; r < BQ; r += 256){
    float v = sims[(size_t)r*SIMW + CC + n] + gumbel32(gk0, gk1, (uint32_t)(r*NN + n));
    if (v > best){ best = v; bi = r; }
  }
  __shared__ float sv[256];
  __shared__ int   si[256];
  sv[tid] = best; si[tid] = bi; __syncthreads();
  for (int s = 128; s > 0; s >>= 1){
    if (tid < s){
      float ov = sv[tid+s]; int oi = si[tid+s];
      if (ov > sv[tid] || (ov == sv[tid] && oi < si[tid])){ sv[tid] = ov; si[tid] = oi; }
    }
    __syncthreads();
  }
  if (tid == 0) sel2[n] = si[0];
}

// ---------------- K13: om gather + overall_mask_loss + masksum ----------------
__global__ __launch_bounds__(256) void k_om(
    const float* __restrict__ pm, const float* __restrict__ tm,
    const int* __restrict__ sel2, float* __restrict__ om,
    float* __restrict__ msum, float* __restrict__ sc){
  int nb = blockIdx.x;
  int n = nb / 9, ch = nb % 9;
  int c0 = ch*1024 + threadIdx.x*4;
  const float4 o4 = *(const float4*)(pm + (size_t)sel2[n]*WHX + c0);
  *(float4*)(om + (size_t)n*WHX + c0) = o4;
  const float4 t4 = *(const float4*)(tm + (size_t)n*WHX + c0);
  float dx = o4.x-t4.x, dy = o4.y-t4.y, dz = o4.z-t4.z, dw = o4.w-t4.w;
  float d2 = dx*dx + dy*dy + dz*dz + dw*dw;
  float ts = t4.x + t4.y + t4.z + t4.w;
  __shared__ float r1[256], r2[256];
  r1[threadIdx.x] = d2; r2[threadIdx.x] = ts; __syncthreads();
  for (int s = 128; s > 0; s >>= 1){
    if (threadIdx.x < s){ r1[threadIdx.x] += r1[threadIdx.x+s]; r2[threadIdx.x] += r2[threadIdx.x+s]; }
    __syncthreads();
  }
  if (threadIdx.x == 0){ atomicAdd(&sc[2], r1[0]); atomicAdd(&msum[n], r2[0]); }
}

// ---------------- K14: sum_tgt[b] ----------------
__global__ __launch_bounds__(512) void k_sumtgt(
    const int* __restrict__ bidx, const float* __restrict__ rowsum,
    const float* __restrict__ msum, float* __restrict__ stgt){
  int n = threadIdx.x;
  if (n >= NN) return;
  atomicAdd(&stgt[bidx[n]], rowsum[n] * msum[n]);
}

// ---------------- K15: fused z-GEMM + column softmax + dice contraction ----------------
__global__ __launch_bounds__(256) void k_zsoft(
    const float* __restrict__ sims, const float* __restrict__ om,
    const float* __restrict__ gtsim, const float* __restrict__ tm,
    const int* __restrict__ bstart, float* __restrict__ sinp,
    float* __restrict__ sc){
  extern __shared__ float lds[];
  float* omt  = lds;              // [300][32]
  float* simc = omt + 300*32;     // [304][32]
  float* red  = simc + 304*32;    // [256]
  float* rblk = red + 256;        // [256]
  const int tile = blockIdx.x, b = blockIdx.y;
  const int tid = threadIdx.x;
  const int col = tid & 31, rg = tid >> 5;
  const int wh0 = tile * 32;
  for (int idx = tid; idx < CC*32; idx += 256){
    int j = idx >> 5, cc = idx & 31;
    omt[idx] = om[(size_t)j*WHX + wh0 + cc];
  }
  float acc[38];
  #pragma unroll
  for (int ii = 0; ii < 38; ii++) acc[ii] = 0.f;
  const int i0 = rg * 38;
  const float* simb = sims + (size_t)b*QQ*SIMW;
  for (int jc = 0; jc < CC; jc += 32){
    const int len = (CC - jc < 32) ? (CC - jc) : 32;
    __syncthreads();
    for (int idx = tid; idx < 304*len; idx += 256){
      int i = idx / len, jj = idx - i*len;
      simc[i*32 + jj] = (i < CC) ? simb[(size_t)i*SIMW + jc + jj] : 0.f;
    }
    __syncthreads();
    for (int g = 0; g < len; g += 4){
      float o0 = omt[(jc+g+0)*32 + col];
      float o1 = omt[(jc+g+1)*32 + col];
      float o2 = omt[(jc+g+2)*32 + col];
      float o3 = omt[(jc+g+3)*32 + col];
      #pragma unroll
      for (int ii = 0; ii < 38; ii++){
        const float4 s4 = *(const float4*)(&simc[(i0+ii)*32 + g]);
        acc[ii] = fmaf(s4.x, o0, fmaf(s4.y, o1, fmaf(s4.z, o2, fmaf(s4.w, o3, acc[ii]))));
      }
    }
  }
  // z = acc/96, softmax over i per column (mask padded i>=300)
  float lm = -INFINITY;
  #pragma unroll
  for (int ii = 0; ii < 38; ii++){
    acc[ii] *= (1.0f/96.0f);
    if (i0 + ii < CC) lm = fmaxf(lm, acc[ii]);
  }
  __syncthreads();
  red[tid] = lm; __syncthreads();
  float m = -INFINITY;
  #pragma unroll
  for (int r = 0; r < 8; r++) m = fmaxf(m, red[r*32 + col]);
  __syncthreads();
  float ls = 0.f;
  #pragma unroll
  for (int ii = 0; ii < 38; ii++){
    float p = (i0 + ii < CC) ? expf(acc[ii] - m) : 0.f;
    acc[ii] = p; ls += p;
  }
  red[tid] = ls; __syncthreads();
  float S = 0.f;
  #pragma unroll
  for (int r = 0; r < 8; r++) S += red[r*32 + col];
  const float inv = 1.f / S;
  // contract with gt_sim rows of this batch and tgt_masks
  const int n0 = bstart[b], n1 = bstart[b+1];
  float sl = 0.f;
  for (int n = n0; n < n1; n++){
    const float tv = tm[(size_t)n*WHX + wh0 + col];
    const float* gr = gtsim + (size_t)n*CC + i0;
    float dv = 0.f;
    #pragma unroll
    for (int ii = 0; ii < 38; ii++){
      if (i0 + ii < CC) dv = fmaf(gr[ii], acc[ii], dv);
    }
    sl = fmaf(dv, tv, sl);
  }
  sl *= inv;
  float pi = ls * inv;
  rblk[tid] = sl; __syncthreads();
  for (int s = 128; s > 0; s >>= 1){ if (tid < s) rblk[tid] += rblk[tid+s]; __syncthreads(); }
  if (tid == 0) atomicAdd(&sc[5], rblk[0]);
  __syncthreads();
  rblk[tid] = pi; __syncthreads();
  for (int s = 128; s > 0; s >>= 1){ if (tid < s) rblk[tid] += rblk[tid+s]; __syncthreads(); }
  if (tid == 0) atomicAdd(&sinp[b], rblk[0]);
}

// ---------------- K16: finalize 5 outputs ----------------
__global__ __launch_bounds__(64) void k_final(
    const float* __restrict__ sc, const float* __restrict__ sinp,
    const float* __restrict__ stgt, const int* __restrict__ kint,
    float* __restrict__ out){
  if (threadIdx.x != 0) return;
  float K = (float)kint[0];
  float cls = sc[0]/300.f + sc[1]/300.f;
  float stot = sc[5];
  float dice = 0.f;
  for (int b = 0; b < 8; b++) dice += stot / (sinp[b] + stgt[b] + 1e-6f);
  dice *= (1.0f/8.0f);
  out[0] = cls;
  out[1] = dice;
  out[2] = (sc[2] / 2764800.0f) / K;
  out[3] = sc[3] / K;
  out[4] = sc[4] / K;
}

// ---------------- launch ----------------
extern "C" void kernel_launch(void* const* d_in, const int* in_sizes, int n_in,
                              void* d_out, int out_size, void* d_ws, size_t ws_size,
                              hipStream_t stream) {
  const float* ce  = (const float*)d_in[0];
  const float* pl  = (const float*)d_in[1];
  const float* pb  = (const float*)d_in[2];
  const float* pm  = (const float*)d_in[3];
  const float* tm  = (const float*)d_in[4];
  const float* te  = (const float*)d_in[5];
  const float* tbb = (const float*)d_in[6];
  const int*  tids = (const int*)d_in[8];
  const int*  bidx = (const int*)d_in[9];
  float* out = (float*)d_out;
  float* w = (float*)d_ws;

  if (ws_size < F_TOTAL * sizeof(float)) return;

  float* SIMS   = w + F_SIMS;
  float* GTSIM  = w + F_GTSIM;
  float* OM     = w + F_OM;
  float* MM     = w + F_MM;
  float* SCORE  = w + F_SCORE;
  float* BBOX   = w + F_BBOX;
  float* TBOX   = w + F_TB;
  float* SB     = w + F_SB;
  float* SAREA  = w + F_SAREA;
  float* KB     = w + F_KB;
  float* ROWSUM = w + F_ROWSUM;
  float* OE     = w + F_OE;
  float* GSEL   = w + F_GSEL;
  float* MSUM   = w + F_MSUM;
  float* STGT   = w + F_STGT;
  float* SINP   = w + F_SINP;
  float* SC     = w + F_SC;
  int*   ORDER  = (int*)(w + F_ORDER);
  int*   NMSIDX = (int*)(w + F_NMSIDX);
  int*   SEL2   = (int*)(w + F_SEL2);
  int*   BSTART = (int*)(w + F_BSTART);
  int*   KINT   = (int*)(w + F_KINT);
  unsigned long long* ADJ  = (unsigned long long*)(w + F_ADJ);
  unsigned long long* SUPW = (unsigned long long*)(w + F_SUPW);

  // zero accumulators (out_embs, gt_sel, masksum, sumtgt, suminp, scalars)
  hipMemsetAsync(w + F_OE, 0, (F_ACCEND - F_OE) * sizeof(float), stream);

  {
    int total = BQ*SIMW + NN*CC;
    k_gemm<<<(total + 255)/256, 256, 0, stream>>>(pl, ce, te, SIMS, GTSIM);
  }
  k_post<<<BQ, 512, 0, stream>>>(SIMS, pb, tbb, tids, bidx, GTSIM, SCORE, BBOX, TBOX, ROWSUM);
  k_rank<<<(BQ + 255)/256, 256, 0, stream>>>(SCORE, ORDER);
  k_gather<<<(BQ + 255)/256, 256, 0, stream>>>(BBOX, ORDER, bidx, SB, SAREA, BSTART);
  k_adj<<<BQ, 256, 0, stream>>>(SB, SAREA, ADJ);
  k_nms<<<1, 64, 0, stream>>>(ADJ, SUPW);
  k_compact<<<1, 256, 0, stream>>>(SUPW, ORDER, SB, NMSIDX, KB, KINT);
  k_gtsel<<<BQ, 512, 0, stream>>>(KB, TBOX, NMSIDX, pl, KINT, GSEL, OE);
  k_gtiou<<<1, 512, 0, stream>>>(GSEL, TBOX, SC);
  k_m<<<(NN*NN + 255)/256, 256, 0, stream>>>(te, OE, MM);
  k_ce<<<NN, 64, 0, stream>>>(MM, SC);
  k_sel2<<<NN, 256, 0, stream>>>(SIMS, SEL2);
  k_om<<<NN*9, 256, 0, stream>>>(pm, tm, SEL2, OM, MSUM, SC);
  k_sumtgt<<<1, 512, 0, stream>>>(bidx, ROWSUM, MSUM, STGT);
  {
    size_t shbytes = (300*32 + 304*32 + 256 + 256) * sizeof(float); // 79,360 B
    k_zsoft<<<dim3(WHX/32, BB), 256, shbytes, stream>>>(SIMS, OM, GTSIM, tm, BSTART, SINP, SC);
  }
  k_final<<<1, 64, 0, stream>>>(SC, SINP, STGT, KINT, out);
}

// Round 2
// 849.140 us; speedup vs baseline: 2.4030x; 2.4030x over previous
//
#include <hip/hip_runtime.h>
#include <stdint.h>

#define DEVFN __device__ __forceinline__

typedef unsigned short u16;
typedef short bf16x8 __attribute__((ext_vector_type(8)));
typedef float f32x4 __attribute__((ext_vector_type(4)));

constexpr int BB = 8, QQ = 300, CC = 300, NN = 300, DD = 256;
constexpr int WHX = 9216, BQ = 2400, SIMW = 600, ADJW = 38;
constexpr int QP = 320;   // padded Q for MFMA K-dim
constexpr int CP = 304;   // padded C rows
constexpr int KP = 96;    // per-batch n-window
constexpr int NP = 416;   // padded tmT n-dim

// ---------------- workspace layout (float units) ----------------
constexpr size_t F_SIMS   = 0;                                 // [2400][600]
constexpr size_t F_GTSIM  = F_SIMS   + (size_t)BQ*SIMW;        // [300][300]
constexpr size_t F_MM     = F_GTSIM  + (size_t)NN*CC;          // [300][300]
constexpr size_t F_SCORE  = F_MM     + (size_t)NN*NN;          // [2400]
constexpr size_t F_BBOX   = F_SCORE  + BQ;                     // [2400][4]
constexpr size_t F_TB     = F_BBOX   + (size_t)BQ*4;           // [300][4]
constexpr size_t F_SB     = F_TB     + (size_t)NN*4;           // [2400][4]
constexpr size_t F_SAREA  = F_SB     + (size_t)BQ*4;           // [2400]
constexpr size_t F_KB     = F_SAREA  + BQ;                     // [2400][4]
constexpr size_t F_ROWSUM = F_KB     + (size_t)BQ*4;           // [300]
constexpr size_t F_OE     = F_ROWSUM + NN;                     // ---- zeroed zone
constexpr size_t F_GSEL   = F_OE     + (size_t)NN*DD;          // [300][4]
constexpr size_t F_MSUM   = F_GSEL   + (size_t)NN*4;           // [300]
constexpr size_t F_STGT   = F_MSUM   + NN;                     // [8]
constexpr size_t F_SC     = F_STGT   + 8;                      // scalars
constexpr size_t F_ACCEND = F_SC     + 16;                     // ---- end zeroed zone
constexpr size_t F_ORDER  = F_ACCEND;                          // int [2400]
constexpr size_t F_NMSIDX = F_ORDER  + BQ;                     // int [2400]
constexpr size_t F_SEL2   = F_NMSIDX + BQ;                     // int [300]
constexpr size_t F_BSTART = F_SEL2   + NN;                     // int [16]
constexpr size_t F_KINT   = F_BSTART + 16;                     // int [4]
constexpr size_t F_ADJ    = ((F_KINT + 4 + 1) & ~(size_t)1);   // u64 [2400][38]
constexpr size_t F_SUPW   = F_ADJ + (size_t)BQ*ADJW*2;         // u64 [38]
// bf16 panels (sizes in floats = ushorts/2), 32B-align starts
constexpr size_t F_SIMTB  = ((F_SUPW + ADJW*2 + 7) & ~(size_t)7);   // u16[8][304][320]
constexpr size_t F_OMT    = F_SIMTB + (size_t)BB*CP*QP/2;           // u16[9216][320]
constexpr size_t F_TMT    = F_OMT   + (size_t)WHX*QP/2;             // u16[9216][416]
constexpr size_t F_GTP    = F_TMT   + (size_t)WHX*NP/2;             // u16[8][304][96]
constexpr size_t F_TOTAL  = F_GTP   + (size_t)BB*CP*KP/2;

// ---------------- JAX threefry2x32 (partitionable scheme) ----------------
DEVFN uint32_t rotl32(uint32_t v, int r){ return (v << r) | (v >> (32 - r)); }

DEVFN void tf2x32(uint32_t k0, uint32_t k1, uint32_t x0, uint32_t x1,
                  uint32_t& o0, uint32_t& o1){
  uint32_t ks2 = k0 ^ k1 ^ 0x1BD11BDAu;
  x0 += k0; x1 += k1;
#define TFR(r) x0 += x1; x1 = rotl32(x1, r); x1 ^= x0;
  TFR(13) TFR(15) TFR(26) TFR(6)   x0 += k1;  x1 += ks2 + 1u;
  TFR(17) TFR(29) TFR(16) TFR(24)  x0 += ks2; x1 += k0  + 2u;
  TFR(13) TFR(15) TFR(26) TFR(6)   x0 += k0;  x1 += k1  + 3u;
  TFR(17) TFR(29) TFR(16) TFR(24)  x0 += k1;  x1 += ks2 + 4u;
  TFR(13) TFR(15) TFR(26) TFR(6)   x0 += ks2; x1 += k0  + 5u;
#undef TFR
  o0 = x0; o1 = x1;
}

DEVFN void subkey(int i, uint32_t& k0, uint32_t& k1){
  tf2x32(0u, 42u, 0u, (uint32_t)i, k0, k1);
}

DEVFN float gumbel32(uint32_t k0, uint32_t k1, uint32_t idx){
  uint32_t h, l; tf2x32(k0, k1, 0u, idx, h, l);
  uint32_t bits = h ^ l;
  float f = __uint_as_float((bits >> 9) | 0x3F800000u) - 1.0f;
  const float tiny = 1.17549435e-38f;
  float u = fmaxf(tiny, f + tiny);
  return -logf(-logf(u));
}

DEVFN float iou_xyxy(float ax1,float ay1,float ax2,float ay2,
                     float bx1,float by1,float bx2,float by2){
  float aa = (ax2-ax1)*(ay2-ay1);
  float ab = (bx2-bx1)*(by2-by1);
  float lx = fmaxf(ax1,bx1), ly = fmaxf(ay1,by1);
  float rx = fminf(ax2,bx2), ry = fminf(ay2,by2);
  float iw = fmaxf(rx-lx,0.f), ih = fmaxf(ry-ly,0.f);
  float in_ = iw*ih;
  return in_/(aa+ab-in_);
}

DEVFN u16 f2bf(float x){
  uint32_t u = __float_as_uint(x);
  uint32_t r = u + 0x7FFFu + ((u >> 16) & 1u);
  return (u16)(r >> 16);
}

// ---------------- K1: sims[2400][600] + gtsim[300][300] ----------------
__global__ __launch_bounds__(256) void k_gemm(
    const float* __restrict__ pl, const float* __restrict__ ce,
    const float* __restrict__ te, float* __restrict__ sims,
    float* __restrict__ gtsim){
  size_t idx = (size_t)blockIdx.x*256 + threadIdx.x;
  const float *a, *bp; float* o;
  if (idx < (size_t)BQ*SIMW){
    int r = (int)(idx / SIMW), c = (int)(idx % SIMW);
    a  = pl + (size_t)r*DD;
    bp = (c < CC) ? (ce + (size_t)c*DD) : (te + (size_t)(c-CC)*DD);
    o  = sims + idx;
  } else {
    size_t j = idx - (size_t)BQ*SIMW;
    if (j >= (size_t)NN*CC) return;
    int n = (int)(j / CC), c = (int)(j % CC);
    a = te + (size_t)n*DD; bp = ce + (size_t)c*DD;
    o = gtsim + j;
  }
  const float4* a4 = (const float4*)a;
  const float4* b4 = (const float4*)bp;
  float s = 0.f;
  #pragma unroll 8
  for (int t = 0; t < DD/4; t++){
    float4 x = a4[t], y = b4[t];
    s += x.x*y.x + x.y*y.y + x.z*y.z + x.w*y.w;
  }
  *o = s;
}

// ---------------- K2: per-bq scores/argmax(g0)/boxes; tb rows; gtsim rowsums ----------------
__global__ __launch_bounds__(512) void k_post(
    const float* __restrict__ sims, const float* __restrict__ pb,
    const float* __restrict__ tbb, const int* __restrict__ tids,
    const int* __restrict__ bidx, const float* __restrict__ gtsim,
    float* __restrict__ score, float* __restrict__ bbox,
    float* __restrict__ tb, float* __restrict__ rowsum){
  int bq = blockIdx.x, tid = threadIdx.x;
  __shared__ float sv[512];
  __shared__ int   si[512];
  float v = (tid < CC) ? sims[(size_t)bq*SIMW + tid] : -INFINITY;
  sv[tid] = v; __syncthreads();
  for (int s = 256; s > 0; s >>= 1){ if (tid < s) sv[tid] = fmaxf(sv[tid], sv[tid+s]); __syncthreads(); }
  if (tid == 0) score[bq] = sv[0];
  __syncthreads();
  uint32_t gk0, gk1; subkey(0, gk0, gk1);
  float y = (tid < CC) ? v + gumbel32(gk0, gk1, (uint32_t)(bq*CC + tid)) : -INFINITY;
  sv[tid] = y; si[tid] = tid; __syncthreads();
  for (int s = 256; s > 0; s >>= 1){
    if (tid < s){
      float ov = sv[tid+s]; int oi = si[tid+s];
      if (ov > sv[tid] || (ov == sv[tid] && oi < si[tid])){ sv[tid] = ov; si[tid] = oi; }
    }
    __syncthreads();
  }
  if (tid == 0){
    int cls = si[0];
    float ox = 224.0f * (float)cls;
    float oy = 224.0f * (float)(bq / QQ);
    float cx = pb[bq*4+0], cy = pb[bq*4+1], ww = pb[bq*4+2], hh = pb[bq*4+3];
    bbox[bq*4+0] = cx - 0.5f*ww + ox;
    bbox[bq*4+1] = cy - 0.5f*hh + oy;
    bbox[bq*4+2] = cx + 0.5f*ww + ox;
    bbox[bq*4+3] = cy + 0.5f*hh + oy;
  }
  if (bq < NN){
    __syncthreads();
    float rs = (tid < CC) ? gtsim[(size_t)bq*CC + tid] : 0.f;
    sv[tid] = rs; __syncthreads();
    for (int s = 256; s > 0; s >>= 1){ if (tid < s) sv[tid] += sv[tid+s]; __syncthreads(); }
    if (tid == 0) rowsum[bq] = sv[0];
    if (tid == 1){
      float gx = 224.0f * (float)tids[bq], gy = 224.0f * (float)bidx[bq];
      float cx = tbb[bq*4+0], cy = tbb[bq*4+1], ww = tbb[bq*4+2], hh = tbb[bq*4+3];
      tb[bq*4+0] = cx - 0.5f*ww + gx;
      tb[bq*4+1] = cy - 0.5f*hh + gy;
      tb[bq*4+2] = cx + 0.5f*ww + gx;
      tb[bq*4+3] = cy + 0.5f*hh + gy;
    }
  }
}

// ---------------- K3: stable descending rank sort ----------------
__global__ __launch_bounds__(256) void k_rank(
    const float* __restrict__ score, int* __restrict__ order){
  __shared__ float s[BQ];
  int tid = threadIdx.x;
  for (int i = tid; i < BQ; i += 256) s[i] = score[i];
  __syncthreads();
  int t = blockIdx.x*256 + tid;
  if (t >= BQ) return;
  float st = s[t];
  int cnt = 0;
  for (int j = 0; j < BQ; j++){
    float sj = s[j];
    cnt += (sj > st) || (sj == st && j < t);
  }
  order[cnt] = t;
}

// ---------------- K4: gather sorted boxes/areas + batch segment starts ----------------
__global__ __launch_bounds__(256) void k_gather(
    const float* __restrict__ bbox, const int* __restrict__ order,
    const int* __restrict__ bidx, float* __restrict__ sb,
    float* __restrict__ sarea, int* __restrict__ bstart){
  int t = blockIdx.x*256 + threadIdx.x;
  if (t < BQ){
    int o = order[t];
    float x1 = bbox[o*4+0], y1 = bbox[o*4+1], x2 = bbox[o*4+2], y2 = bbox[o*4+3];
    sb[t*4+0] = x1; sb[t*4+1] = y1; sb[t*4+2] = x2; sb[t*4+3] = y2;
    sarea[t] = (x2-x1)*(y2-y1);
  }
  if (blockIdx.x == 0 && threadIdx.x < 9){
    int b = threadIdx.x, c = 0;
    for (int n = 0; n < NN; n++) c += (bidx[n] < b);
    bstart[b] = c;
  }
}

// ---------------- K5: adjacency bitmask ----------------
__global__ __launch_bounds__(256) void k_adj(
    const float* __restrict__ sb, const float* __restrict__ sarea,
    unsigned long long* __restrict__ adj){
  __shared__ float4 box[BQ];
  __shared__ float  ar[BQ];
  int tid = threadIdx.x, i = blockIdx.x;
  for (int t = tid; t < BQ; t += 256){ box[t] = ((const float4*)sb)[t]; ar[t] = sarea[t]; }
  __syncthreads();
  float4 bi = box[i]; float ai = ar[i];
  int lane = tid & 63, wv = tid >> 6;
  for (int w = wv; w < ADJW; w += 4){
    int j = w*64 + lane;
    bool pred = false;
    if (j < BQ && j > i){
      float4 bj = box[j];
      float lx = fmaxf(bi.x,bj.x), ly = fmaxf(bi.y,bj.y);
      float rx = fminf(bi.z,bj.z), ry = fminf(bi.w,bj.w);
      float iw = fmaxf(rx-lx,0.f), ih = fmaxf(ry-ly,0.f);
      float in_ = iw*ih;
      pred = (in_/(ai + ar[j] - in_)) > 0.5f;
    }
    unsigned long long m = __ballot(pred);
    if (lane == 0) adj[(size_t)i*ADJW + w] = m;
  }
}

// ---------------- K6: serial greedy suppress ----------------
__global__ __launch_bounds__(64) void k_nms(
    const unsigned long long* __restrict__ adj,
    unsigned long long* __restrict__ supw){
  int lane = threadIdx.x;
  unsigned long long sup = 0ull;
  unsigned long long buf[8];
  #pragma unroll
  for (int d = 0; d < 8; d++)
    buf[d] = (lane < ADJW) ? adj[(size_t)d*ADJW + lane] : 0ull;
  for (int i0 = 0; i0 < BQ; i0 += 8){
    #pragma unroll
    for (int d = 0; d < 8; d++){
      int i = i0 + d;
      int wi = i >> 6;
      unsigned long long swi = __shfl(sup, wi);
      unsigned long long row = buf[d];
      int nx = i + 8;
      buf[d] = (nx < BQ && lane < ADJW) ? adj[(size_t)nx*ADJW + lane] : 0ull;
      if (!((swi >> (i & 63)) & 1ull)) sup |= row;
    }
  }
  if (lane < ADJW) supw[lane] = sup;
}

// ---------------- K7: compact ----------------
__global__ __launch_bounds__(256) void k_compact(
    const unsigned long long* __restrict__ supw, const int* __restrict__ order,
    const float* __restrict__ sb, int* __restrict__ nmsidx,
    float* __restrict__ kb, int* __restrict__ kint){
  __shared__ int csum[256];
  int tid = threadIdx.x;
  int p0 = tid*10;
  int keepf[10];
  int cnt = 0;
  #pragma unroll
  for (int d = 0; d < 10; d++){
    int p = p0 + d;
    int k = 0;
    if (p < BQ) k = !((supw[p >> 6] >> (p & 63)) & 1ull);
    keepf[d] = k; cnt += k;
  }
  csum[tid] = cnt; __syncthreads();
  for (int s = 1; s < 256; s <<= 1){
    int add = (tid >= s) ? csum[tid - s] : 0;
    __syncthreads();
    csum[tid] += add;
    __syncthreads();
  }
  int pos = csum[tid] - cnt;
  #pragma unroll
  for (int d = 0; d < 10; d++){
    if (keepf[d]){
      int p = p0 + d;
      nmsidx[pos] = order[p];
      ((float4*)kb)[pos] = ((const float4*)sb)[p];
      pos++;
    }
  }
  if (tid == 255) kint[0] = csum[255];
}

// ---------------- K8: per-kept-box scatter ----------------
__global__ __launch_bounds__(512) void k_gtsel(
    const float* __restrict__ kb, const float* __restrict__ tb,
    const int* __restrict__ nmsidx, const float* __restrict__ pl,
    const int* __restrict__ kint, float* __restrict__ gsel,
    float* __restrict__ oe){
  int k = blockIdx.x;
  if (k >= kint[0]) return;
  int tid = threadIdx.x;
  __shared__ float sv[512];
  __shared__ int   si[512];
  float4 a = ((const float4*)kb)[k];
  float iou = -INFINITY;
  if (tid < NN){
    float4 t = ((const float4*)tb)[tid];
    iou = iou_xyxy(a.x,a.y,a.z,a.w, t.x,t.y,t.z,t.w);
    if (iou != iou) iou = 0.f;
  }
  sv[tid] = iou; __syncthreads();
  for (int s = 256; s > 0; s >>= 1){ if (tid < s) sv[tid] = fmaxf(sv[tid], sv[tid+s]); __syncthreads(); }
  float m = sv[0]; __syncthreads();
  float e = (tid < NN) ? expf(iou - m) : 0.f;
  sv[tid] = e; __syncthreads();
  for (int s = 256; s > 0; s >>= 1){ if (tid < s) sv[tid] += sv[tid+s]; __syncthreads(); }
  float S = sv[0]; __syncthreads();
  uint32_t gk0, gk1; subkey(1, gk0, gk1);
  float y = (tid < NN) ? (e / S + gumbel32(gk0, gk1, (uint32_t)(k*NN + tid))) : -INFINITY;
  sv[tid] = y; si[tid] = tid; __syncthreads();
  for (int s = 256; s > 0; s >>= 1){
    if (tid < s){
      float ov = sv[tid+s]; int oi = si[tid+s];
      if (ov > sv[tid] || (ov == sv[tid] && oi < si[tid])){ sv[tid] = ov; si[tid] = oi; }
    }
    __syncthreads();
  }
  int sel = si[0];
  if (tid < 4) atomicAdd(&gsel[sel*4 + tid], ((const float*)&a)[tid]);
  if (tid < DD) atomicAdd(&oe[(size_t)sel*DD + tid], pl[(size_t)nmsidx[k]*DD + tid]);
}

// ---------------- K9: gt_ious + l1 ----------------
__global__ __launch_bounds__(512) void k_gtiou(
    const float* __restrict__ gsel, const float* __restrict__ tb,
    float* __restrict__ sc){
  int tid = threadIdx.x;
  __shared__ float s1[512], s2[512];
  float a1 = 0.f, a2 = 0.f;
  if (tid < NN){
    float4 g = ((const float4*)gsel)[tid];
    float4 t = ((const float4*)tb)[tid];
    float iou = iou_xyxy(g.x,g.y,g.z,g.w, t.x,t.y,t.z,t.w);
    a1 = 1.f - iou;
    a2 = fabsf(g.x-t.x) + fabsf(g.y-t.y) + fabsf(g.z-t.z) + fabsf(g.w-t.w);
  }
  s1[tid] = a1; s2[tid] = a2; __syncthreads();
  for (int s = 256; s > 0; s >>= 1){
    if (tid < s){ s1[tid] += s1[tid+s]; s2[tid] += s2[tid+s]; }
    __syncthreads();
  }
  if (tid == 0){ sc[3] = s1[0]; sc[4] = s2[0]; }
}

// ---------------- K10: M = tgt_embs @ out_embs^T ----------------
__global__ __launch_bounds__(256) void k_m(
    const float* __restrict__ te, const float* __restrict__ oe,
    float* __restrict__ M){
  int idx = blockIdx.x*256 + threadIdx.x;
  if (idx >= NN*NN) return;
  int i = idx / NN, j = idx % NN;
  const float4* a4 = (const float4*)(te + (size_t)i*DD);
  const float4* b4 = (const float4*)(oe + (size_t)j*DD);
  float s = 0.f;
  #pragma unroll 8
  for (int t = 0; t < DD/4; t++){
    float4 x = a4[t], y = b4[t];
    s += x.x*y.x + x.y*y.y + x.z*y.z + x.w*y.w;
  }
  M[idx] = s;
}

// ---------------- K11: both cross-entropies ----------------
__global__ __launch_bounds__(64) void k_ce(
    const float* __restrict__ M, float* __restrict__ sc){
  int i = blockIdx.x, lane = threadIdx.x;
  float m = -INFINITY;
  for (int j = lane; j < NN; j += 64) m = fmaxf(m, M[(size_t)i*NN + j]);
  for (int o = 32; o > 0; o >>= 1) m = fmaxf(m, __shfl_xor(m, o));
  float s = 0.f;
  for (int j = lane; j < NN; j += 64) s += expf(M[(size_t)i*NN + j] - m);
  for (int o = 32; o > 0; o >>= 1) s += __shfl_xor(s, o);
  float lr = m + logf(s);
  float m2 = -INFINITY;
  for (int j = lane; j < NN; j += 64) m2 = fmaxf(m2, M[(size_t)j*NN + i]);
  for (int o = 32; o > 0; o >>= 1) m2 = fmaxf(m2, __shfl_xor(m2, o));
  float s2 = 0.f;
  for (int j = lane; j < NN; j += 64) s2 += expf(M[(size_t)j*NN + i] - m2);
  for (int o = 32; o > 0; o >>= 1) s2 += __shfl_xor(s2, o);
  float lc = m2 + logf(s2);
  if (lane == 0){
    float d = M[(size_t)i*NN + i];
    atomicAdd(&sc[0], lr - d);
    atomicAdd(&sc[1], lc - d);
  }
}

// ---------------- K12: sel2 ----------------
__global__ __launch_bounds__(256) void k_sel2(
    const float* __restrict__ sims, int* __restrict__ sel2){
  int n = blockIdx.x, tid = threadIdx.x;
  uint32_t gk0, gk1; subkey(2, gk0, gk1);
  float best = -INFINITY; int bi = 0x7fffffff;
  for (int r = tid; r < BQ; r += 256){
    float v = sims[(size_t)r*SIMW + CC + n] + gumbel32(gk0, gk1, (uint32_t)(r*NN + n));
    if (v > best){ best = v; bi = r; }
  }
  __shared__ float sv[256];
  __shared__ int   si[256];
  sv[tid] = best; si[tid] = bi; __syncthreads();
  for (int s = 128; s > 0; s >>= 1){
    if (tid < s){
      float ov = sv[tid+s]; int oi = si[tid+s];
      if (ov > sv[tid] || (ov == sv[tid] && oi < si[tid])){ sv[tid] = ov; si[tid] = oi; }
    }
    __syncthreads();
  }
  if (tid == 0) sel2[n] = si[0];
}

// ---------------- K13: overall_mask_loss + masksum ----------------
__global__ __launch_bounds__(256) void k_om(
    const float* __restrict__ pm, const float* __restrict__ tm,
    const int* __restrict__ sel2, float* __restrict__ msum,
    float* __restrict__ sc){
  int nb = blockIdx.x;
  int n = nb / 9, ch = nb % 9;
  int c0 = ch*1024 + threadIdx.x*4;
  const float4 o4 = *(const float4*)(pm + (size_t)sel2[n]*WHX + c0);
  const float4 t4 = *(const float4*)(tm + (size_t)n*WHX + c0);
  float dx = o4.x-t4.x, dy = o4.y-t4.y, dz = o4.z-t4.z, dw = o4.w-t4.w;
  float d2 = dx*dx + dy*dy + dz*dz + dw*dw;
  float ts = t4.x + t4.y + t4.z + t4.w;
  __shared__ float r1[256], r2[256];
  r1[threadIdx.x] = d2; r2[threadIdx.x] = ts; __syncthreads();
  for (int s = 128; s > 0; s >>= 1){
    if (threadIdx.x < s){ r1[threadIdx.x] += r1[threadIdx.x+s]; r2[threadIdx.x] += r2[threadIdx.x+s]; }
    __syncthreads();
  }
  if (threadIdx.x == 0){ atomicAdd(&sc[2], r1[0]); atomicAdd(&msum[n], r2[0]); }
}

// ---------------- K14: sum_tgt[b] ----------------
__global__ __launch_bounds__(512) void k_sumtgt(
    const int* __restrict__ bidx, const float* __restrict__ rowsum,
    const float* __restrict__ msum, float* __restrict__ stgt){
  int n = threadIdx.x;
  if (n >= NN) return;
  atomicAdd(&stgt[bidx[n]], rowsum[n] * msum[n]);
}

// ---------------- T1: sims f32 -> simTb bf16 [8][304][320] (transpose) ----------------
__global__ __launch_bounds__(256) void t_simT(
    const float* __restrict__ sims, u16* __restrict__ simTb){
  __shared__ float ld[32][65];
  int q0 = blockIdx.x*32, c0 = blockIdx.y*64, b = blockIdx.z;
  int tid = threadIdx.x;
  for (int i = tid; i < 32*64; i += 256){
    int qi = i >> 6, ci = i & 63;
    int q = q0 + qi, c = c0 + ci;
    ld[qi][ci] = (q < QQ && c < CC) ? sims[((size_t)b*QQ + q)*SIMW + c] : 0.f;
  }
  __syncthreads();
  int cloc = tid >> 2, j0 = (tid & 3)*8;
  int c = c0 + cloc;
  if (c < CP){
    u16 tmp[8];
    #pragma unroll
    for (int j = 0; j < 8; j++) tmp[j] = f2bf(ld[j0+j][cloc]);
    *(uint4*)(simTb + ((size_t)b*CP + c)*QP + q0 + j0) = *(const uint4*)tmp;
  }
}

// ---------------- T2: omT bf16 [9216][320] = pm[sel2[q]][wh]/96 (transpose) ----------------
__global__ __launch_bounds__(256) void t_omT(
    const float* __restrict__ pm, const int* __restrict__ sel2,
    u16* __restrict__ omT){
  __shared__ float ld[32][65];
  int q0 = blockIdx.x*32, wh0 = blockIdx.y*64;
  int tid = threadIdx.x;
  for (int i = tid; i < 32*64; i += 256){
    int qi = i >> 6, wi = i & 63;
    int q = q0 + qi;
    ld[qi][wi] = (q < QQ) ? pm[(size_t)sel2[q]*WHX + wh0 + wi] * (1.0f/96.0f) : 0.f;
  }
  __syncthreads();
  int wloc = tid >> 2, j0 = (tid & 3)*8;
  u16 tmp[8];
  #pragma unroll
  for (int j = 0; j < 8; j++) tmp[j] = f2bf(ld[j0+j][wloc]);
  *(uint4*)(omT + (size_t)(wh0+wloc)*QP + q0 + j0) = *(const uint4*)tmp;
}

// ---------------- T3: tmT bf16 [9216][416] (transpose, zero-padded) ----------------
__global__ __launch_bounds__(256) void t_tmT(
    const float* __restrict__ tm, u16* __restrict__ tmT){
  __shared__ float ld[32][65];
  int n0 = blockIdx.x*32, wh0 = blockIdx.y*64;
  int tid = threadIdx.x;
  for (int i = tid; i < 32*64; i += 256){
    int ni = i >> 6, wi = i & 63;
    int n = n0 + ni;
    ld[ni][wi] = (n < NN) ? tm[(size_t)n*WHX + wh0 + wi] : 0.f;
  }
  __syncthreads();
  int wloc = tid >> 2, j0 = (tid & 3)*8;
  u16 tmp[8];
  #pragma unroll
  for (int j = 0; j < 8; j++) tmp[j] = f2bf(ld[j0+j][wloc]);
  *(uint4*)(tmT + (size_t)(wh0+wloc)*NP + n0 + j0) = *(const uint4*)tmp;
}

// ---------------- T4: gtsimP bf16 [8][304][96] (per-batch zero-padded window) ----------------
__global__ __launch_bounds__(256) void t_gtp(
    const float* __restrict__ gtsim, const int* __restrict__ bstart,
    u16* __restrict__ gtp){
  int g = blockIdx.x*256 + threadIdx.x;
  if (g >= BB*CP*(KP/8)) return;
  int b = g / (CP*(KP/8));
  int rem = g - b*CP*(KP/8);
  int c = rem / (KP/8);
  int kg = rem % (KP/8);
  int n0 = bstart[b], n1 = bstart[b+1];
  int kst = n0 & ~7;
  u16 tmp[8];
  #pragma unroll
  for (int j = 0; j < 8; j++){
    int n = kst + kg*8 + j;
    float v = (n >= n0 && n < n1 && c < CC) ? gtsim[(size_t)n*CC + c] : 0.f;
    tmp[j] = f2bf(v);
  }
  *(uint4*)(gtp + ((size_t)b*CP + c)*KP + kg*8) = *(const uint4*)tmp;
}

// ---------------- K15: MFMA z-GEMM + column softmax + dice contraction ----------------
__global__ __launch_bounds__(256) void k_zsoft(
    const u16* __restrict__ simTb, const u16* __restrict__ omT,
    const u16* __restrict__ gtp, const u16* __restrict__ tmT,
    const int* __restrict__ bstart, float* __restrict__ sc){
  const int b = blockIdx.y;
  const int tid = threadIdx.x;
  const int w = tid >> 6, l = tid & 63;
  const int lrow = l & 15, lgrp = l >> 4;
  const int col = blockIdx.x*64 + w*16 + lrow;   // wh column owned by this lane

  f32x4 acc[19];
  #pragma unroll
  for (int t = 0; t < 19; t++) acc[t] = (f32x4){0.f,0.f,0.f,0.f};

  const u16* pA = simTb + (size_t)b*CP*QP + (size_t)lrow*QP + lgrp*8;
  const u16* pB = omT + (size_t)col*QP + lgrp*8;

  for (int ks = 0; ks < 10; ks++){
    bf16x8 bf = *(const bf16x8*)(pB + ks*32);
    #pragma unroll
    for (int t = 0; t < 19; t++){
      bf16x8 af = *(const bf16x8*)(pA + (size_t)t*16*QP + ks*32);
      acc[t] = __builtin_amdgcn_mfma_f32_16x16x32_bf16(af, bf, acc[t], 0, 0, 0);
    }
  }

  // column softmax over c (rows 300..303 are padding: tile 18, lane-group 3)
  float lmax = -INFINITY;
  #pragma unroll
  for (int t = 0; t < 19; t++){
    if (t == 18 && lgrp == 3) continue;
    lmax = fmaxf(lmax, fmaxf(fmaxf(acc[t][0], acc[t][1]), fmaxf(acc[t][2], acc[t][3])));
  }
  lmax = fmaxf(lmax, __shfl_xor(lmax, 16));
  lmax = fmaxf(lmax, __shfl_xor(lmax, 32));
  float ls = 0.f;
  #pragma unroll
  for (int t = 0; t < 19; t++){
    if (t == 18 && lgrp == 3){
      acc[t] = (f32x4){0.f,0.f,0.f,0.f};
      continue;
    }
    float p0 = __expf(acc[t][0] - lmax);
    float p1 = __expf(acc[t][1] - lmax);
    float p2 = __expf(acc[t][2] - lmax);
    float p3 = __expf(acc[t][3] - lmax);
    acc[t][0] = p0; acc[t][1] = p1; acc[t][2] = p2; acc[t][3] = p3;
    ls += p0 + p1 + p2 + p3;
  }
  float S = ls;
  S += __shfl_xor(S, 16);
  S += __shfl_xor(S, 32);
  float inv = 1.f / S;

  // dice: R[c][wh] = sum_n gtsim[n][c] tm[n][wh] via MFMA in same D-layout
  int n0 = bstart[b];
  int kst = n0 & ~7;
  const u16* tB = tmT + (size_t)col*NP + kst + lgrp*8;
  bf16x8 b2a = *(const bf16x8*)(tB);
  bf16x8 b2b = *(const bf16x8*)(tB + 32);
  bf16x8 b2c = *(const bf16x8*)(tB + 64);
  const u16* A2 = gtp + (size_t)b*CP*KP + lgrp*8;
  float dl = 0.f;
  #pragma unroll
  for (int t = 0; t < 19; t++){
    const u16* ar = A2 + (size_t)(t*16 + lrow)*KP;
    f32x4 rr = (f32x4){0.f,0.f,0.f,0.f};
    rr = __builtin_amdgcn_mfma_f32_16x16x32_bf16(*(const bf16x8*)(ar),      b2a, rr, 0, 0, 0);
    rr = __builtin_amdgcn_mfma_f32_16x16x32_bf16(*(const bf16x8*)(ar + 32), b2b, rr, 0, 0, 0);
    rr = __builtin_amdgcn_mfma_f32_16x16x32_bf16(*(const bf16x8*)(ar + 64), b2c, rr, 0, 0, 0);
    dl += acc[t][0]*rr[0] + acc[t][1]*rr[1] + acc[t][2]*rr[2] + acc[t][3]*rr[3];
  }
  dl *= inv;

  __shared__ float red[256];
  red[tid] = dl; __syncthreads();
  for (int s = 128; s > 0; s >>= 1){
    if (tid < s) red[tid] += red[tid+s];
    __syncthreads();
  }
  if (tid == 0) atomicAdd(&sc[5], red[0]);
}

// ---------------- K16: finalize ----------------
__global__ __launch_bounds__(64) void k_final(
    const float* __restrict__ sc, const float* __restrict__ stgt,
    const int* __restrict__ kint, float* __restrict__ out){
  if (threadIdx.x != 0) return;
  float K = (float)kint[0];
  float cls = sc[0]/300.f + sc[1]/300.f;
  float stot = sc[5];
  float dice = 0.f;
  for (int b = 0; b < 8; b++) dice += stot / (9216.0f + stgt[b] + 1e-6f);
  dice *= (1.0f/8.0f);
  out[0] = cls;
  out[1] = dice;
  out[2] = (sc[2] / 2764800.0f) / K;
  out[3] = sc[3] / K;
  out[4] = sc[4] / K;
}

// ---------------- launch ----------------
extern "C" void kernel_launch(void* const* d_in, const int* in_sizes, int n_in,
                              void* d_out, int out_size, void* d_ws, size_t ws_size,
                              hipStream_t stream) {
  const float* ce  = (const float*)d_in[0];
  const float* pl  = (const float*)d_in[1];
  const float* pb  = (const float*)d_in[2];
  const float* pm  = (const float*)d_in[3];
  const float* tm  = (const float*)d_in[4];
  const float* te  = (const float*)d_in[5];
  const float* tbb = (const float*)d_in[6];
  const int*  tids = (const int*)d_in[8];
  const int*  bidx = (const int*)d_in[9];
  float* out = (float*)d_out;
  float* w = (float*)d_ws;

  if (ws_size < F_TOTAL * sizeof(float)) return;

  float* SIMS   = w + F_SIMS;
  float* GTSIM  = w + F_GTSIM;
  float* MM     = w + F_MM;
  float* SCORE  = w + F_SCORE;
  float* BBOX   = w + F_BBOX;
  float* TBOX   = w + F_TB;
  float* SB     = w + F_SB;
  float* SAREA  = w + F_SAREA;
  float* KB     = w + F_KB;
  float* ROWSUM = w + F_ROWSUM;
  float* OE     = w + F_OE;
  float* GSEL   = w + F_GSEL;
  float* MSUM   = w + F_MSUM;
  float* STGT   = w + F_STGT;
  float* SC     = w + F_SC;
  int*   ORDER  = (int*)(w + F_ORDER);
  int*   NMSIDX = (int*)(w + F_NMSIDX);
  int*   SEL2   = (int*)(w + F_SEL2);
  int*   BSTART = (int*)(w + F_BSTART);
  int*   KINT   = (int*)(w + F_KINT);
  unsigned long long* ADJ  = (unsigned long long*)(w + F_ADJ);
  unsigned long long* SUPW = (unsigned long long*)(w + F_SUPW);
  u16* SIMTB = (u16*)(w + F_SIMTB);
  u16* OMT   = (u16*)(w + F_OMT);
  u16* TMT   = (u16*)(w + F_TMT);
  u16* GTP   = (u16*)(w + F_GTP);

  hipMemsetAsync(w + F_OE, 0, (F_ACCEND - F_OE) * sizeof(float), stream);

  {
    int total = BQ*SIMW + NN*CC;
    k_gemm<<<(total + 255)/256, 256, 0, stream>>>(pl, ce, te, SIMS, GTSIM);
  }
  k_post<<<BQ, 512, 0, stream>>>(SIMS, pb, tbb, tids, bidx, GTSIM, SCORE, BBOX, TBOX, ROWSUM);
  k_rank<<<(BQ + 255)/256, 256, 0, stream>>>(SCORE, ORDER);
  k_gather<<<(BQ + 255)/256, 256, 0, stream>>>(BBOX, ORDER, bidx, SB, SAREA, BSTART);
  k_adj<<<BQ, 256, 0, stream>>>(SB, SAREA, ADJ);
  k_nms<<<1, 64, 0, stream>>>(ADJ, SUPW);
  k_compact<<<1, 256, 0, stream>>>(SUPW, ORDER, SB, NMSIDX, KB, KINT);
  k_gtsel<<<BQ, 512, 0, stream>>>(KB, TBOX, NMSIDX, pl, KINT, GSEL, OE);
  k_gtiou<<<1, 512, 0, stream>>>(GSEL, TBOX, SC);
  k_m<<<(NN*NN + 255)/256, 256, 0, stream>>>(te, OE, MM);
  k_ce<<<NN, 64, 0, stream>>>(MM, SC);
  k_sel2<<<NN, 256, 0, stream>>>(SIMS, SEL2);
  k_om<<<NN*9, 256, 0, stream>>>(pm, tm, SEL2, MSUM, SC);
  k_sumtgt<<<1, 512, 0, stream>>>(bidx, ROWSUM, MSUM, STGT);

  t_simT<<<dim3(QP/32, 5, BB), 256, 0, stream>>>(SIMS, SIMTB);
  t_omT<<<dim3(QP/32, WHX/64), 256, 0, stream>>>(pm, SEL2, OMT);
  t_tmT<<<dim3(NP/32, WHX/64), 256, 0, stream>>>(tm, TMT);
  t_gtp<<<(BB*CP*(KP/8) + 255)/256, 256, 0, stream>>>(GTSIM, BSTART, GTP);

  k_zsoft<<<dim3(WHX/64, BB), 256, 0, stream>>>(SIMTB, OMT, GTP, TMT, BSTART, SC);
  k_final<<<1, 64, 0, stream>>>(SC, STGT, KINT, out);
}

// Round 3
// 742.901 us; speedup vs baseline: 2.7467x; 1.1430x over previous
//
#include <hip/hip_runtime.h>
#include <stdint.h>

#define DEVFN __device__ __forceinline__

typedef unsigned short u16;
typedef short bf16x8 __attribute__((ext_vector_type(8)));
typedef float f32x4 __attribute__((ext_vector_type(4)));

constexpr int BB = 8, QQ = 300, CC = 300, NN = 300, DD = 256;
constexpr int WHX = 9216, BQ = 2400, SIMW = 600, ADJW = 38;
constexpr int QP = 320;   // padded Q for MFMA K-dim
constexpr int CP = 304;   // padded C rows
constexpr int KP = 96;    // per-batch n-window
constexpr int NP = 416;   // padded tmT n-dim

// ---------------- workspace layout (float units) ----------------
constexpr size_t F_SIMS   = 0;                                 // [2400][600]
constexpr size_t F_GTSIM  = F_SIMS   + (size_t)BQ*SIMW;        // [300][300]
constexpr size_t F_MM     = F_GTSIM  + (size_t)NN*CC;          // [300][300]
constexpr size_t F_SCORE  = F_MM     + (size_t)NN*NN;          // [2400]
constexpr size_t F_BBOX   = F_SCORE  + BQ;                     // [2400][4]
constexpr size_t F_TB     = F_BBOX   + (size_t)BQ*4;           // [300][4]
constexpr size_t F_SB     = F_TB     + (size_t)NN*4;           // [2400][4]
constexpr size_t F_SAREA  = F_SB     + (size_t)BQ*4;           // [2400]
constexpr size_t F_KB     = F_SAREA  + BQ;                     // [2400][4]
constexpr size_t F_ROWSUM = F_KB     + (size_t)BQ*4;           // [300]
constexpr size_t F_OE     = F_ROWSUM + NN;                     // ---- zeroed zone
constexpr size_t F_GSEL   = F_OE     + (size_t)NN*DD;          // [300][4]
constexpr size_t F_MSUM   = F_GSEL   + (size_t)NN*4;           // [300]
constexpr size_t F_STGT   = F_MSUM   + NN;                     // [8]
constexpr size_t F_SC     = F_STGT   + 8;                      // scalars
constexpr size_t F_ACCEND = F_SC     + 16;                     // ---- end zeroed zone
constexpr size_t F_ORDER  = F_ACCEND;                          // int [2400]
constexpr size_t F_NMSIDX = F_ORDER  + BQ;                     // int [2400]
constexpr size_t F_SEL2   = F_NMSIDX + BQ;                     // int [300]
constexpr size_t F_BSTART = F_SEL2   + NN;                     // int [16]
constexpr size_t F_KINT   = F_BSTART + 16;                     // int [4]
constexpr size_t F_ADJ    = ((F_KINT + 4 + 1) & ~(size_t)1);   // u64 [2400][38]
constexpr size_t F_SUPW   = F_ADJ + (size_t)BQ*ADJW*2;         // u64 [38]
// bf16 panels (sizes in floats = ushorts/2), 32B-align starts
constexpr size_t F_SIMTB  = ((F_SUPW + ADJW*2 + 7) & ~(size_t)7);   // u16[8][304][320]
constexpr size_t F_OMT    = F_SIMTB + (size_t)BB*CP*QP/2;           // u16[9216][320]
constexpr size_t F_TMT    = F_OMT   + (size_t)WHX*QP/2;             // u16[9216][416]
constexpr size_t F_GTP    = F_TMT   + (size_t)WHX*NP/2;             // u16[8][304][96]
constexpr size_t F_TOTAL  = F_GTP   + (size_t)BB*CP*KP/2;

// ---------------- JAX threefry2x32 (partitionable scheme) ----------------
DEVFN uint32_t rotl32(uint32_t v, int r){ return (v << r) | (v >> (32 - r)); }

DEVFN void tf2x32(uint32_t k0, uint32_t k1, uint32_t x0, uint32_t x1,
                  uint32_t& o0, uint32_t& o1){
  uint32_t ks2 = k0 ^ k1 ^ 0x1BD11BDAu;
  x0 += k0; x1 += k1;
#define TFR(r) x0 += x1; x1 = rotl32(x1, r); x1 ^= x0;
  TFR(13) TFR(15) TFR(26) TFR(6)   x0 += k1;  x1 += ks2 + 1u;
  TFR(17) TFR(29) TFR(16) TFR(24)  x0 += ks2; x1 += k0  + 2u;
  TFR(13) TFR(15) TFR(26) TFR(6)   x0 += k0;  x1 += k1  + 3u;
  TFR(17) TFR(29) TFR(16) TFR(24)  x0 += k1;  x1 += ks2 + 4u;
  TFR(13) TFR(15) TFR(26) TFR(6)   x0 += ks2; x1 += k0  + 5u;
#undef TFR
  o0 = x0; o1 = x1;
}

DEVFN void subkey(int i, uint32_t& k0, uint32_t& k1){
  tf2x32(0u, 42u, 0u, (uint32_t)i, k0, k1);
}

DEVFN float gumbel32(uint32_t k0, uint32_t k1, uint32_t idx){
  uint32_t h, l; tf2x32(k0, k1, 0u, idx, h, l);
  uint32_t bits = h ^ l;
  float f = __uint_as_float((bits >> 9) | 0x3F800000u) - 1.0f;
  const float tiny = 1.17549435e-38f;
  float u = fmaxf(tiny, f + tiny);
  return -logf(-logf(u));
}

DEVFN float iou_xyxy(float ax1,float ay1,float ax2,float ay2,
                     float bx1,float by1,float bx2,float by2){
  float aa = (ax2-ax1)*(ay2-ay1);
  float ab = (bx2-bx1)*(by2-by1);
  float lx = fmaxf(ax1,bx1), ly = fmaxf(ay1,by1);
  float rx = fminf(ax2,bx2), ry = fminf(ay2,by2);
  float iw = fmaxf(rx-lx,0.f), ih = fmaxf(ry-ly,0.f);
  float in_ = iw*ih;
  return in_/(aa+ab-in_);
}

DEVFN u16 f2bf(float x){
  uint32_t u = __float_as_uint(x);
  uint32_t r = u + 0x7FFFu + ((u >> 16) & 1u);
  return (u16)(r >> 16);
}

// ---------------- K1: sims[2400][600] + gtsim[300][300] ----------------
__global__ __launch_bounds__(256) void k_gemm(
    const float* __restrict__ pl, const float* __restrict__ ce,
    const float* __restrict__ te, float* __restrict__ sims,
    float* __restrict__ gtsim){
  size_t idx = (size_t)blockIdx.x*256 + threadIdx.x;
  const float *a, *bp; float* o;
  if (idx < (size_t)BQ*SIMW){
    int r = (int)(idx / SIMW), c = (int)(idx % SIMW);
    a  = pl + (size_t)r*DD;
    bp = (c < CC) ? (ce + (size_t)c*DD) : (te + (size_t)(c-CC)*DD);
    o  = sims + idx;
  } else {
    size_t j = idx - (size_t)BQ*SIMW;
    if (j >= (size_t)NN*CC) return;
    int n = (int)(j / CC), c = (int)(j % CC);
    a = te + (size_t)n*DD; bp = ce + (size_t)c*DD;
    o = gtsim + j;
  }
  const float4* a4 = (const float4*)a;
  const float4* b4 = (const float4*)bp;
  float s = 0.f;
  #pragma unroll 8
  for (int t = 0; t < DD/4; t++){
    float4 x = a4[t], y = b4[t];
    s += x.x*y.x + x.y*y.y + x.z*y.z + x.w*y.w;
  }
  *o = s;
}

// ---------------- K2: per-bq scores/argmax(g0)/boxes; tb rows; gtsim rowsums ----------------
__global__ __launch_bounds__(512) void k_post(
    const float* __restrict__ sims, const float* __restrict__ pb,
    const float* __restrict__ tbb, const int* __restrict__ tids,
    const int* __restrict__ bidx, const float* __restrict__ gtsim,
    float* __restrict__ score, float* __restrict__ bbox,
    float* __restrict__ tb, float* __restrict__ rowsum){
  int bq = blockIdx.x, tid = threadIdx.x;
  __shared__ float sv[512];
  __shared__ int   si[512];
  float v = (tid < CC) ? sims[(size_t)bq*SIMW + tid] : -INFINITY;
  sv[tid] = v; __syncthreads();
  for (int s = 256; s > 0; s >>= 1){ if (tid < s) sv[tid] = fmaxf(sv[tid], sv[tid+s]); __syncthreads(); }
  if (tid == 0) score[bq] = sv[0];
  __syncthreads();
  uint32_t gk0, gk1; subkey(0, gk0, gk1);
  float y = (tid < CC) ? v + gumbel32(gk0, gk1, (uint32_t)(bq*CC + tid)) : -INFINITY;
  sv[tid] = y; si[tid] = tid; __syncthreads();
  for (int s = 256; s > 0; s >>= 1){
    if (tid < s){
      float ov = sv[tid+s]; int oi = si[tid+s];
      if (ov > sv[tid] || (ov == sv[tid] && oi < si[tid])){ sv[tid] = ov; si[tid] = oi; }
    }
    __syncthreads();
  }
  if (tid == 0){
    int cls = si[0];
    float ox = 224.0f * (float)cls;
    float oy = 224.0f * (float)(bq / QQ);
    float cx = pb[bq*4+0], cy = pb[bq*4+1], ww = pb[bq*4+2], hh = pb[bq*4+3];
    bbox[bq*4+0] = cx - 0.5f*ww + ox;
    bbox[bq*4+1] = cy - 0.5f*hh + oy;
    bbox[bq*4+2] = cx + 0.5f*ww + ox;
    bbox[bq*4+3] = cy + 0.5f*hh + oy;
  }
  if (bq < NN){
    __syncthreads();
    float rs = (tid < CC) ? gtsim[(size_t)bq*CC + tid] : 0.f;
    sv[tid] = rs; __syncthreads();
    for (int s = 256; s > 0; s >>= 1){ if (tid < s) sv[tid] += sv[tid+s]; __syncthreads(); }
    if (tid == 0) rowsum[bq] = sv[0];
    if (tid == 1){
      float gx = 224.0f * (float)tids[bq], gy = 224.0f * (float)bidx[bq];
      float cx = tbb[bq*4+0], cy = tbb[bq*4+1], ww = tbb[bq*4+2], hh = tbb[bq*4+3];
      tb[bq*4+0] = cx - 0.5f*ww + gx;
      tb[bq*4+1] = cy - 0.5f*hh + gy;
      tb[bq*4+2] = cx + 0.5f*ww + gx;
      tb[bq*4+3] = cy + 0.5f*hh + gy;
    }
  }
}

// ---------------- K3: stable descending rank sort ----------------
__global__ __launch_bounds__(256) void k_rank(
    const float* __restrict__ score, int* __restrict__ order){
  __shared__ float s[BQ];
  int tid = threadIdx.x;
  for (int i = tid; i < BQ; i += 256) s[i] = score[i];
  __syncthreads();
  int t = blockIdx.x*256 + tid;
  if (t >= BQ) return;
  float st = s[t];
  int cnt = 0;
  for (int j = 0; j < BQ; j++){
    float sj = s[j];
    cnt += (sj > st) || (sj == st && j < t);
  }
  order[cnt] = t;
}

// ---------------- K4: gather sorted boxes/areas + batch segment starts ----------------
__global__ __launch_bounds__(256) void k_gather(
    const float* __restrict__ bbox, const int* __restrict__ order,
    const int* __restrict__ bidx, float* __restrict__ sb,
    float* __restrict__ sarea, int* __restrict__ bstart){
  int t = blockIdx.x*256 + threadIdx.x;
  if (t < BQ){
    int o = order[t];
    float x1 = bbox[o*4+0], y1 = bbox[o*4+1], x2 = bbox[o*4+2], y2 = bbox[o*4+3];
    sb[t*4+0] = x1; sb[t*4+1] = y1; sb[t*4+2] = x2; sb[t*4+3] = y2;
    sarea[t] = (x2-x1)*(y2-y1);
  }
  if (blockIdx.x == 0 && threadIdx.x < 9){
    int b = threadIdx.x, c = 0;
    for (int n = 0; n < NN; n++) c += (bidx[n] < b);
    bstart[b] = c;
  }
}

// ---------------- K5: adjacency bitmask ----------------
__global__ __launch_bounds__(256) void k_adj(
    const float* __restrict__ sb, const float* __restrict__ sarea,
    unsigned long long* __restrict__ adj){
  __shared__ float4 box[BQ];
  __shared__ float  ar[BQ];
  int tid = threadIdx.x, i = blockIdx.x;
  for (int t = tid; t < BQ; t += 256){ box[t] = ((const float4*)sb)[t]; ar[t] = sarea[t]; }
  __syncthreads();
  float4 bi = box[i]; float ai = ar[i];
  int lane = tid & 63, wv = tid >> 6;
  for (int w = wv; w < ADJW; w += 4){
    int j = w*64 + lane;
    bool pred = false;
    if (j < BQ && j > i){
      float4 bj = box[j];
      float lx = fmaxf(bi.x,bj.x), ly = fmaxf(bi.y,bj.y);
      float rx = fminf(bi.z,bj.z), ry = fminf(bi.w,bj.w);
      float iw = fmaxf(rx-lx,0.f), ih = fmaxf(ry-ly,0.f);
      float in_ = iw*ih;
      pred = (in_/(ai + ar[j] - in_)) > 0.5f;
    }
    unsigned long long m = __ballot(pred);
    if (lane == 0) adj[(size_t)i*ADJW + w] = m;
  }
}

// ---------------- K6: blocked greedy suppress (4 waves: 1 process + 3 prefetch) ----------------
// groups of 64 rows; LDS double-buffer holds one group's 64x38 u64 adjacency.
constexpr int GRP = 38;       // ceil(2400/64)
constexpr int GWORDS = 2432;  // 64*38
__global__ __launch_bounds__(256) void k_nms(
    const unsigned long long* __restrict__ adj,
    unsigned long long* __restrict__ supw){
  __shared__ unsigned long long nb[2][2496];  // 64 extra u64 pad for branchless lane reads
  const int tid = threadIdx.x;
  const int lane = tid & 63;
  const int wv = tid >> 6;
  unsigned long long sup = 0ull;

  // prologue: waves 1-3 load group 0
  if (wv > 0){
    for (int s = 0; s < 13; s++){
      int idx = (tid - 64) + s*192;
      if (idx < GWORDS) nb[0][idx] = adj[idx];
    }
  }
  __syncthreads();

  for (int g = 0; g < GRP; g++){
    const int cur = g & 1, nxt = cur ^ 1;
    if (wv > 0){
      if (g + 1 < GRP){
        int base = (g+1)*GWORDS;
        int lim = BQ*ADJW - base; if (lim > GWORDS) lim = GWORDS;
        for (int s = 0; s < 13; s++){
          int idx = (tid - 64) + s*192;
          if (idx < lim) nb[nxt][idx] = adj[base + idx];
        }
      }
    } else {
      const int rows = (BQ - g*64 < 64) ? (BQ - g*64) : 64;
      unsigned long long mg = __shfl(sup, g);   // suppressed bits for this group's rows
      unsigned long long keep = 0ull;
      // serial within-group greedy via uniform LDS broadcast reads, 8-chunked
      for (int i0 = 0; i0 < rows; i0 += 8){
        unsigned long long wreg[8];
        #pragma unroll
        for (int j = 0; j < 8; j++) wreg[j] = nb[cur][(i0+j)*38 + g];
        #pragma unroll
        for (int j = 0; j < 8; j++){
          int i = i0 + j;
          if (!((mg >> i) & 1ull)){ keep |= (1ull << i); mg |= wreg[j]; }
        }
      }
      // parallel: OR kept rows' words into per-lane sup
      unsigned long long acc = 0ull;
      for (int i0 = 0; i0 < rows; i0 += 8){
        #pragma unroll
        for (int j = 0; j < 8; j++){
          int i = i0 + j;
          unsigned long long v = nb[cur][i*38 + lane];
          unsigned long long msk = (unsigned long long)0 - ((keep >> i) & 1ull);
          acc |= (v & msk);
        }
      }
      sup |= acc;
    }
    __syncthreads();
  }
  if (wv == 0 && lane < ADJW) supw[lane] = sup;
}

// ---------------- K7: compact ----------------
__global__ __launch_bounds__(256) void k_compact(
    const unsigned long long* __restrict__ supw, const int* __restrict__ order,
    const float* __restrict__ sb, int* __restrict__ nmsidx,
    float* __restrict__ kb, int* __restrict__ kint){
  __shared__ int csum[256];
  int tid = threadIdx.x;
  int p0 = tid*10;
  int keepf[10];
  int cnt = 0;
  #pragma unroll
  for (int d = 0; d < 10; d++){
    int p = p0 + d;
    int k = 0;
    if (p < BQ) k = !((supw[p >> 6] >> (p & 63)) & 1ull);
    keepf[d] = k; cnt += k;
  }
  csum[tid] = cnt; __syncthreads();
  for (int s = 1; s < 256; s <<= 1){
    int add = (tid >= s) ? csum[tid - s] : 0;
    __syncthreads();
    csum[tid] += add;
    __syncthreads();
  }
  int pos = csum[tid] - cnt;
  #pragma unroll
  for (int d = 0; d < 10; d++){
    if (keepf[d]){
      int p = p0 + d;
      nmsidx[pos] = order[p];
      ((float4*)kb)[pos] = ((const float4*)sb)[p];
      pos++;
    }
  }
  if (tid == 255) kint[0] = csum[255];
}

// ---------------- K8: per-kept-box scatter ----------------
__global__ __launch_bounds__(512) void k_gtsel(
    const float* __restrict__ kb, const float* __restrict__ tb,
    const int* __restrict__ nmsidx, const float* __restrict__ pl,
    const int* __restrict__ kint, float* __restrict__ gsel,
    float* __restrict__ oe){
  int k = blockIdx.x;
  if (k >= kint[0]) return;
  int tid = threadIdx.x;
  __shared__ float sv[512];
  __shared__ int   si[512];
  float4 a = ((const float4*)kb)[k];
  float iou = -INFINITY;
  if (tid < NN){
    float4 t = ((const float4*)tb)[tid];
    iou = iou_xyxy(a.x,a.y,a.z,a.w, t.x,t.y,t.z,t.w);
    if (iou != iou) iou = 0.f;
  }
  sv[tid] = iou; __syncthreads();
  for (int s = 256; s > 0; s >>= 1){ if (tid < s) sv[tid] = fmaxf(sv[tid], sv[tid+s]); __syncthreads(); }
  float m = sv[0]; __syncthreads();
  float e = (tid < NN) ? expf(iou - m) : 0.f;
  sv[tid] = e; __syncthreads();
  for (int s = 256; s > 0; s >>= 1){ if (tid < s) sv[tid] += sv[tid+s]; __syncthreads(); }
  float S = sv[0]; __syncthreads();
  uint32_t gk0, gk1; subkey(1, gk0, gk1);
  float y = (tid < NN) ? (e / S + gumbel32(gk0, gk1, (uint32_t)(k*NN + tid))) : -INFINITY;
  sv[tid] = y; si[tid] = tid; __syncthreads();
  for (int s = 256; s > 0; s >>= 1){
    if (tid < s){
      float ov = sv[tid+s]; int oi = si[tid+s];
      if (ov > sv[tid] || (ov == sv[tid] && oi < si[tid])){ sv[tid] = ov; si[tid] = oi; }
    }
    __syncthreads();
  }
  int sel = si[0];
  if (tid < 4) atomicAdd(&gsel[sel*4 + tid], ((const float*)&a)[tid]);
  if (tid < DD) atomicAdd(&oe[(size_t)sel*DD + tid], pl[(size_t)nmsidx[k]*DD + tid]);
}

// ---------------- K9: gt_ious + l1 ----------------
__global__ __launch_bounds__(512) void k_gtiou(
    const float* __restrict__ gsel, const float* __restrict__ tb,
    float* __restrict__ sc){
  int tid = threadIdx.x;
  __shared__ float s1[512], s2[512];
  float a1 = 0.f, a2 = 0.f;
  if (tid < NN){
    float4 g = ((const float4*)gsel)[tid];
    float4 t = ((const float4*)tb)[tid];
    float iou = iou_xyxy(g.x,g.y,g.z,g.w, t.x,t.y,t.z,t.w);
    a1 = 1.f - iou;
    a2 = fabsf(g.x-t.x) + fabsf(g.y-t.y) + fabsf(g.z-t.z) + fabsf(g.w-t.w);
  }
  s1[tid] = a1; s2[tid] = a2; __syncthreads();
  for (int s = 256; s > 0; s >>= 1){
    if (tid < s){ s1[tid] += s1[tid+s]; s2[tid] += s2[tid+s]; }
    __syncthreads();
  }
  if (tid == 0){ sc[3] = s1[0]; sc[4] = s2[0]; }
}

// ---------------- K10: M = tgt_embs @ out_embs^T ----------------
__global__ __launch_bounds__(256) void k_m(
    const float* __restrict__ te, const float* __restrict__ oe,
    float* __restrict__ M){
  int idx = blockIdx.x*256 + threadIdx.x;
  if (idx >= NN*NN) return;
  int i = idx / NN, j = idx % NN;
  const float4* a4 = (const float4*)(te + (size_t)i*DD);
  const float4* b4 = (const float4*)(oe + (size_t)j*DD);
  float s = 0.f;
  #pragma unroll 8
  for (int t = 0; t < DD/4; t++){
    float4 x = a4[t], y = b4[t];
    s += x.x*y.x + x.y*y.y + x.z*y.z + x.w*y.w;
  }
  M[idx] = s;
}

// ---------------- K11: both cross-entropies ----------------
__global__ __launch_bounds__(64) void k_ce(
    const float* __restrict__ M, float* __restrict__ sc){
  int i = blockIdx.x, lane = threadIdx.x;
  float m = -INFINITY;
  for (int j = lane; j < NN; j += 64) m = fmaxf(m, M[(size_t)i*NN + j]);
  for (int o = 32; o > 0; o >>= 1) m = fmaxf(m, __shfl_xor(m, o));
  float s = 0.f;
  for (int j = lane; j < NN; j += 64) s += expf(M[(size_t)i*NN + j] - m);
  for (int o = 32; o > 0; o >>= 1) s += __shfl_xor(s, o);
  float lr = m + logf(s);
  float m2 = -INFINITY;
  for (int j = lane; j < NN; j += 64) m2 = fmaxf(m2, M[(size_t)j*NN + i]);
  for (int o = 32; o > 0; o >>= 1) m2 = fmaxf(m2, __shfl_xor(m2, o));
  float s2 = 0.f;
  for (int j = lane; j < NN; j += 64) s2 += expf(M[(size_t)j*NN + i] - m2);
  for (int o = 32; o > 0; o >>= 1) s2 += __shfl_xor(s2, o);
  float lc = m2 + logf(s2);
  if (lane == 0){
    float d = M[(size_t)i*NN + i];
    atomicAdd(&sc[0], lr - d);
    atomicAdd(&sc[1], lc - d);
  }
}

// ---------------- K12: sel2 ----------------
__global__ __launch_bounds__(256) void k_sel2(
    const float* __restrict__ sims, int* __restrict__ sel2){
  int n = blockIdx.x, tid = threadIdx.x;
  uint32_t gk0, gk1; subkey(2, gk0, gk1);
  float best = -INFINITY; int bi = 0x7fffffff;
  for (int r = tid; r < BQ; r += 256){
    float v = sims[(size_t)r*SIMW + CC + n] + gumbel32(gk0, gk1, (uint32_t)(r*NN + n));
    if (v > best){ best = v; bi = r; }
  }
  __shared__ float sv[256];
  __shared__ int   si[256];
  sv[tid] = best; si[tid] = bi; __syncthreads();
  for (int s = 128; s > 0; s >>= 1){
    if (tid < s){
      float ov = sv[tid+s]; int oi = si[tid+s];
      if (ov > sv[tid] || (ov == sv[tid] && oi < si[tid])){ sv[tid] = ov; si[tid] = oi; }
    }
    __syncthreads();
  }
  if (tid == 0) sel2[n] = si[0];
}

// ---------------- K13: overall_mask_loss + masksum ----------------
__global__ __launch_bounds__(256) void k_om(
    const float* __restrict__ pm, const float* __restrict__ tm,
    const int* __restrict__ sel2, float* __restrict__ msum,
    float* __restrict__ sc){
  int nb = blockIdx.x;
  int n = nb / 9, ch = nb % 9;
  int c0 = ch*1024 + threadIdx.x*4;
  const float4 o4 = *(const float4*)(pm + (size_t)sel2[n]*WHX + c0);
  const float4 t4 = *(const float4*)(tm + (size_t)n*WHX + c0);
  float dx = o4.x-t4.x, dy = o4.y-t4.y, dz = o4.z-t4.z, dw = o4.w-t4.w;
  float d2 = dx*dx + dy*dy + dz*dz + dw*dw;
  float ts = t4.x + t4.y + t4.z + t4.w;
  __shared__ float r1[256], r2[256];
  r1[threadIdx.x] = d2; r2[threadIdx.x] = ts; __syncthreads();
  for (int s = 128; s > 0; s >>= 1){
    if (threadIdx.x < s){ r1[threadIdx.x] += r1[threadIdx.x+s]; r2[threadIdx.x] += r2[threadIdx.x+s]; }
    __syncthreads();
  }
  if (threadIdx.x == 0){ atomicAdd(&sc[2], r1[0]); atomicAdd(&msum[n], r2[0]); }
}

// ---------------- K14: sum_tgt[b] ----------------
__global__ __launch_bounds__(512) void k_sumtgt(
    const int* __restrict__ bidx, const float* __restrict__ rowsum,
    const float* __restrict__ msum, float* __restrict__ stgt){
  int n = threadIdx.x;
  if (n >= NN) return;
  atomicAdd(&stgt[bidx[n]], rowsum[n] * msum[n]);
}

// ---------------- T1: sims f32 -> simTb bf16 [8][304][320] (transpose) ----------------
__global__ __launch_bounds__(256) void t_simT(
    const float* __restrict__ sims, u16* __restrict__ simTb){
  __shared__ float ld[32][65];
  int q0 = blockIdx.x*32, c0 = blockIdx.y*64, b = blockIdx.z;
  int tid = threadIdx.x;
  for (int i = tid; i < 32*64; i += 256){
    int qi = i >> 6, ci = i & 63;
    int q = q0 + qi, c = c0 + ci;
    ld[qi][ci] = (q < QQ && c < CC) ? sims[((size_t)b*QQ + q)*SIMW + c] : 0.f;
  }
  __syncthreads();
  int cloc = tid >> 2, j0 = (tid & 3)*8;
  int c = c0 + cloc;
  if (c < CP){
    u16 tmp[8];
    #pragma unroll
    for (int j = 0; j < 8; j++) tmp[j] = f2bf(ld[j0+j][cloc]);
    *(uint4*)(simTb + ((size_t)b*CP + c)*QP + q0 + j0) = *(const uint4*)tmp;
  }
}

// ---------------- T2: omT bf16 [9216][320] = pm[sel2[q]][wh]/96 (transpose) ----------------
__global__ __launch_bounds__(256) void t_omT(
    const float* __restrict__ pm, const int* __restrict__ sel2,
    u16* __restrict__ omT){
  __shared__ float ld[32][65];
  int q0 = blockIdx.x*32, wh0 = blockIdx.y*64;
  int tid = threadIdx.x;
  for (int i = tid; i < 32*64; i += 256){
    int qi = i >> 6, wi = i & 63;
    int q = q0 + qi;
    ld[qi][wi] = (q < QQ) ? pm[(size_t)sel2[q]*WHX + wh0 + wi] * (1.0f/96.0f) : 0.f;
  }
  __syncthreads();
  int wloc = tid >> 2, j0 = (tid & 3)*8;
  u16 tmp[8];
  #pragma unroll
  for (int j = 0; j < 8; j++) tmp[j] = f2bf(ld[j0+j][wloc]);
  *(uint4*)(omT + (size_t)(wh0+wloc)*QP + q0 + j0) = *(const uint4*)tmp;
}

// ---------------- T3: tmT bf16 [9216][416] (transpose, zero-padded) ----------------
__global__ __launch_bounds__(256) void t_tmT(
    const float* __restrict__ tm, u16* __restrict__ tmT){
  __shared__ float ld[32][65];
  int n0 = blockIdx.x*32, wh0 = blockIdx.y*64;
  int tid = threadIdx.x;
  for (int i = tid; i < 32*64; i += 256){
    int ni = i >> 6, wi = i & 63;
    int n = n0 + ni;
    ld[ni][wi] = (n < NN) ? tm[(size_t)n*WHX + wh0 + wi] : 0.f;
  }
  __syncthreads();
  int wloc = tid >> 2, j0 = (tid & 3)*8;
  u16 tmp[8];
  #pragma unroll
  for (int j = 0; j < 8; j++) tmp[j] = f2bf(ld[j0+j][wloc]);
  *(uint4*)(tmT + (size_t)(wh0+wloc)*NP + n0 + j0) = *(const uint4*)tmp;
}

// ---------------- T4: gtsimP bf16 [8][304][96] (per-batch zero-padded window) ----------------
__global__ __launch_bounds__(256) void t_gtp(
    const float* __restrict__ gtsim, const int* __restrict__ bstart,
    u16* __restrict__ gtp){
  int g = blockIdx.x*256 + threadIdx.x;
  if (g >= BB*CP*(KP/8)) return;
  int b = g / (CP*(KP/8));
  int rem = g - b*CP*(KP/8);
  int c = rem / (KP/8);
  int kg = rem % (KP/8);
  int n0 = bstart[b], n1 = bstart[b+1];
  int kst = n0 & ~7;
  u16 tmp[8];
  #pragma unroll
  for (int j = 0; j < 8; j++){
    int n = kst + kg*8 + j;
    float v = (n >= n0 && n < n1 && c < CC) ? gtsim[(size_t)n*CC + c] : 0.f;
    tmp[j] = f2bf(v);
  }
  *(uint4*)(gtp + ((size_t)b*CP + c)*KP + kg*8) = *(const uint4*)tmp;
}

// ---------------- K15: MFMA z-GEMM + column softmax + dice contraction ----------------
__global__ __launch_bounds__(256) void k_zsoft(
    const u16* __restrict__ simTb, const u16* __restrict__ omT,
    const u16* __restrict__ gtp, const u16* __restrict__ tmT,
    const int* __restrict__ bstart, float* __restrict__ sc){
  const int b = blockIdx.y;
  const int tid = threadIdx.x;
  const int w = tid >> 6, l = tid & 63;
  const int lrow = l & 15, lgrp = l >> 4;
  const int col = blockIdx.x*64 + w*16 + lrow;   // wh column owned by this lane

  f32x4 acc[19];
  #pragma unroll
  for (int t = 0; t < 19; t++) acc[t] = (f32x4){0.f,0.f,0.f,0.f};

  const u16* pA = simTb + (size_t)b*CP*QP + (size_t)lrow*QP + lgrp*8;
  const u16* pB = omT + (size_t)col*QP + lgrp*8;

  for (int ks = 0; ks < 10; ks++){
    bf16x8 bf = *(const bf16x8*)(pB + ks*32);
    #pragma unroll
    for (int t = 0; t < 19; t++){
      bf16x8 af = *(const bf16x8*)(pA + (size_t)t*16*QP + ks*32);
      acc[t] = __builtin_amdgcn_mfma_f32_16x16x32_bf16(af, bf, acc[t], 0, 0, 0);
    }
  }

  // column softmax over c (rows 300..303 are padding: tile 18, lane-group 3)
  float lmax = -INFINITY;
  #pragma unroll
  for (int t = 0; t < 19; t++){
    if (t == 18 && lgrp == 3) continue;
    lmax = fmaxf(lmax, fmaxf(fmaxf(acc[t][0], acc[t][1]), fmaxf(acc[t][2], acc[t][3])));
  }
  lmax = fmaxf(lmax, __shfl_xor(lmax, 16));
  lmax = fmaxf(lmax, __shfl_xor(lmax, 32));
  float ls = 0.f;
  #pragma unroll
  for (int t = 0; t < 19; t++){
    if (t == 18 && lgrp == 3){
      acc[t] = (f32x4){0.f,0.f,0.f,0.f};
      continue;
    }
    float p0 = __expf(acc[t][0] - lmax);
    float p1 = __expf(acc[t][1] - lmax);
    float p2 = __expf(acc[t][2] - lmax);
    float p3 = __expf(acc[t][3] - lmax);
    acc[t][0] = p0; acc[t][1] = p1; acc[t][2] = p2; acc[t][3] = p3;
    ls += p0 + p1 + p2 + p3;
  }
  float S = ls;
  S += __shfl_xor(S, 16);
  S += __shfl_xor(S, 32);
  float inv = 1.f / S;

  // dice: R[c][wh] = sum_n gtsim[n][c] tm[n][wh] via MFMA in same D-layout
  int n0 = bstart[b];
  int kst = n0 & ~7;
  const u16* tB = tmT + (size_t)col*NP + kst + lgrp*8;
  bf16x8 b2a = *(const bf16x8*)(tB);
  bf16x8 b2b = *(const bf16x8*)(tB + 32);
  bf16x8 b2c = *(const bf16x8*)(tB + 64);
  const u16* A2 = gtp + (size_t)b*CP*KP + lgrp*8;
  float dl = 0.f;
  #pragma unroll
  for (int t = 0; t < 19; t++){
    const u16* ar = A2 + (size_t)(t*16 + lrow)*KP;
    f32x4 rr = (f32x4){0.f,0.f,0.f,0.f};
    rr = __builtin_amdgcn_mfma_f32_16x16x32_bf16(*(const bf16x8*)(ar),      b2a, rr, 0, 0, 0);
    rr = __builtin_amdgcn_mfma_f32_16x16x32_bf16(*(const bf16x8*)(ar + 32), b2b, rr, 0, 0, 0);
    rr = __builtin_amdgcn_mfma_f32_16x16x32_bf16(*(const bf16x8*)(ar + 64), b2c, rr, 0, 0, 0);
    dl += acc[t][0]*rr[0] + acc[t][1]*rr[1] + acc[t][2]*rr[2] + acc[t][3]*rr[3];
  }
  dl *= inv;

  __shared__ float red[256];
  red[tid] = dl; __syncthreads();
  for (int s = 128; s > 0; s >>= 1){
    if (tid < s) red[tid] += red[tid+s];
    __syncthreads();
  }
  if (tid == 0) atomicAdd(&sc[5], red[0]);
}

// ---------------- K16: finalize ----------------
__global__ __launch_bounds__(64) void k_final(
    const float* __restrict__ sc, const float* __restrict__ stgt,
    const int* __restrict__ kint, float* __restrict__ out){
  if (threadIdx.x != 0) return;
  float K = (float)kint[0];
  float cls = sc[0]/300.f + sc[1]/300.f;
  float stot = sc[5];
  float dice = 0.f;
  for (int b = 0; b < 8; b++) dice += stot / (9216.0f + stgt[b] + 1e-6f);
  dice *= (1.0f/8.0f);
  out[0] = cls;
  out[1] = dice;
  out[2] = (sc[2] / 2764800.0f) / K;
  out[3] = sc[3] / K;
  out[4] = sc[4] / K;
}

// ---------------- launch ----------------
extern "C" void kernel_launch(void* const* d_in, const int* in_sizes, int n_in,
                              void* d_out, int out_size, void* d_ws, size_t ws_size,
                              hipStream_t stream) {
  const float* ce  = (const float*)d_in[0];
  const float* pl  = (const float*)d_in[1];
  const float* pb  = (const float*)d_in[2];
  const float* pm  = (const float*)d_in[3];
  const float* tm  = (const float*)d_in[4];
  const float* te  = (const float*)d_in[5];
  const float* tbb = (const float*)d_in[6];
  const int*  tids = (const int*)d_in[8];
  const int*  bidx = (const int*)d_in[9];
  float* out = (float*)d_out;
  float* w = (float*)d_ws;

  if (ws_size < F_TOTAL * sizeof(float)) return;

  float* SIMS   = w + F_SIMS;
  float* GTSIM  = w + F_GTSIM;
  float* MM     = w + F_MM;
  float* SCORE  = w + F_SCORE;
  float* BBOX   = w + F_BBOX;
  float* TBOX   = w + F_TB;
  float* SB     = w + F_SB;
  float* SAREA  = w + F_SAREA;
  float* KB     = w + F_KB;
  float* ROWSUM = w + F_ROWSUM;
  float* OE     = w + F_OE;
  float* GSEL   = w + F_GSEL;
  float* MSUM   = w + F_MSUM;
  float* STGT   = w + F_STGT;
  float* SC     = w + F_SC;
  int*   ORDER  = (int*)(w + F_ORDER);
  int*   NMSIDX = (int*)(w + F_NMSIDX);
  int*   SEL2   = (int*)(w + F_SEL2);
  int*   BSTART = (int*)(w + F_BSTART);
  int*   KINT   = (int*)(w + F_KINT);
  unsigned long long* ADJ  = (unsigned long long*)(w + F_ADJ);
  unsigned long long* SUPW = (unsigned long long*)(w + F_SUPW);
  u16* SIMTB = (u16*)(w + F_SIMTB);
  u16* OMT   = (u16*)(w + F_OMT);
  u16* TMT   = (u16*)(w + F_TMT);
  u16* GTP   = (u16*)(w + F_GTP);

  hipMemsetAsync(w + F_OE, 0, (F_ACCEND - F_OE) * sizeof(float), stream);

  {
    int total = BQ*SIMW + NN*CC;
    k_gemm<<<(total + 255)/256, 256, 0, stream>>>(pl, ce, te, SIMS, GTSIM);
  }
  k_post<<<BQ, 512, 0, stream>>>(SIMS, pb, tbb, tids, bidx, GTSIM, SCORE, BBOX, TBOX, ROWSUM);
  k_rank<<<(BQ + 255)/256, 256, 0, stream>>>(SCORE, ORDER);
  k_gather<<<(BQ + 255)/256, 256, 0, stream>>>(BBOX, ORDER, bidx, SB, SAREA, BSTART);
  k_adj<<<BQ, 256, 0, stream>>>(SB, SAREA, ADJ);
  k_nms<<<1, 256, 0, stream>>>(ADJ, SUPW);
  k_compact<<<1, 256, 0, stream>>>(SUPW, ORDER, SB, NMSIDX, KB, KINT);
  k_gtsel<<<BQ, 512, 0, stream>>>(KB, TBOX, NMSIDX, pl, KINT, GSEL, OE);
  k_gtiou<<<1, 512, 0, stream>>>(GSEL, TBOX, SC);
  k_m<<<(NN*NN + 255)/256, 256, 0, stream>>>(te, OE, MM);
  k_ce<<<NN, 64, 0, stream>>>(MM, SC);
  k_sel2<<<NN, 256, 0, stream>>>(SIMS, SEL2);
  k_om<<<NN*9, 256, 0, stream>>>(pm, tm, SEL2, MSUM, SC);
  k_sumtgt<<<1, 512, 0, stream>>>(bidx, ROWSUM, MSUM, STGT);

  t_simT<<<dim3(QP/32, 5, BB), 256, 0, stream>>>(SIMS, SIMTB);
  t_omT<<<dim3(QP/32, WHX/64), 256, 0, stream>>>(pm, SEL2, OMT);
  t_tmT<<<dim3(NP/32, WHX/64), 256, 0, stream>>>(tm, TMT);
  t_gtp<<<(BB*CP*(KP/8) + 255)/256, 256, 0, stream>>>(GTSIM, BSTART, GTP);

  k_zsoft<<<dim3(WHX/64, BB), 256, 0, stream>>>(SIMTB, OMT, GTP, TMT, BSTART, SC);
  k_final<<<1, 64, 0, stream>>>(SC, STGT, KINT, out);
}

// Round 4
// 574.628 us; speedup vs baseline: 3.5510x; 1.2928x over previous
//
#include <hip/hip_runtime.h>
#include <stdint.h>

#define DEVFN __device__ __forceinline__

typedef unsigned short u16;
typedef short bf16x8 __attribute__((ext_vector_type(8)));
typedef float f32x4 __attribute__((ext_vector_type(4)));

constexpr int BB = 8, QQ = 300, CC = 300, NN = 300, DD = 256;
constexpr int WHX = 9216, BQ = 2400, SIMW = 600, ADJW = 38;
constexpr int QP = 320;   // padded Q for MFMA K-dim
constexpr int CP = 304;   // padded C rows
constexpr int KP = 96;    // per-batch n-window
constexpr int NP = 416;   // padded tmT n-dim

// ---------------- workspace layout (float units) ----------------
constexpr size_t F_SIMS   = 0;                                 // [2400][600]
constexpr size_t F_GTSIM  = F_SIMS   + (size_t)BQ*SIMW;        // [300][300]
constexpr size_t F_MM     = F_GTSIM  + (size_t)NN*CC;          // [300][300]
constexpr size_t F_SCORE  = F_MM     + (size_t)NN*NN;          // [2400]
constexpr size_t F_BBOX   = F_SCORE  + BQ;                     // [2400][4]
constexpr size_t F_TB     = F_BBOX   + (size_t)BQ*4;           // [300][4]
constexpr size_t F_SB     = F_TB     + (size_t)NN*4;           // [2400][4]
constexpr size_t F_SAREA  = F_SB     + (size_t)BQ*4;           // [2400]
constexpr size_t F_KB     = F_SAREA  + BQ;                     // [2400][4]
constexpr size_t F_ROWSUM = F_KB     + (size_t)BQ*4;           // [300]
constexpr size_t F_OE     = F_ROWSUM + NN;                     // ---- zeroed zone
constexpr size_t F_GSEL   = F_OE     + (size_t)NN*DD;          // [300][4]
constexpr size_t F_MSUM   = F_GSEL   + (size_t)NN*4;           // [300]
constexpr size_t F_STGT   = F_MSUM   + NN;                     // [8]
constexpr size_t F_SC     = F_STGT   + 8;                      // scalars
constexpr size_t F_ACCEND = F_SC     + 16;                     // ---- end zeroed zone
constexpr size_t F_ORDER  = F_ACCEND;                          // int [2400]
constexpr size_t F_NMSIDX = F_ORDER  + BQ;                     // int [2400]
constexpr size_t F_SEL2   = F_NMSIDX + BQ;                     // int [300]
constexpr size_t F_BSTART = F_SEL2   + NN;                     // int [16]
constexpr size_t F_KINT   = F_BSTART + 16;                     // int [4]
constexpr size_t F_ADJ    = ((F_KINT + 4 + 1) & ~(size_t)1);   // u64 [2400][38]
constexpr size_t F_SUPW   = F_ADJ + (size_t)BQ*ADJW*2;         // u64 [38]
// bf16 panels (sizes in floats = ushorts/2), 32B-align starts
constexpr size_t F_SIMTB  = ((F_SUPW + ADJW*2 + 7) & ~(size_t)7);   // u16[8][304][320]
constexpr size_t F_OMT    = F_SIMTB + (size_t)BB*CP*QP/2;           // u16[9216][320]
constexpr size_t F_TMT    = F_OMT   + (size_t)WHX*QP/2;             // u16[9216][416]
constexpr size_t F_GTP    = F_TMT   + (size_t)WHX*NP/2;             // u16[8][304][96]
constexpr size_t F_TOTAL  = F_GTP   + (size_t)BB*CP*KP/2;

// ---------------- JAX threefry2x32 (partitionable scheme) ----------------
DEVFN uint32_t rotl32(uint32_t v, int r){ return (v << r) | (v >> (32 - r)); }

DEVFN void tf2x32(uint32_t k0, uint32_t k1, uint32_t x0, uint32_t x1,
                  uint32_t& o0, uint32_t& o1){
  uint32_t ks2 = k0 ^ k1 ^ 0x1BD11BDAu;
  x0 += k0; x1 += k1;
#define TFR(r) x0 += x1; x1 = rotl32(x1, r); x1 ^= x0;
  TFR(13) TFR(15) TFR(26) TFR(6)   x0 += k1;  x1 += ks2 + 1u;
  TFR(17) TFR(29) TFR(16) TFR(24)  x0 += ks2; x1 += k0  + 2u;
  TFR(13) TFR(15) TFR(26) TFR(6)   x0 += k0;  x1 += k1  + 3u;
  TFR(17) TFR(29) TFR(16) TFR(24)  x0 += k1;  x1 += ks2 + 4u;
  TFR(13) TFR(15) TFR(26) TFR(6)   x0 += ks2; x1 += k0  + 5u;
#undef TFR
  o0 = x0; o1 = x1;
}

DEVFN void subkey(int i, uint32_t& k0, uint32_t& k1){
  tf2x32(0u, 42u, 0u, (uint32_t)i, k0, k1);
}

DEVFN float gumbel32(uint32_t k0, uint32_t k1, uint32_t idx){
  uint32_t h, l; tf2x32(k0, k1, 0u, idx, h, l);
  uint32_t bits = h ^ l;
  float f = __uint_as_float((bits >> 9) | 0x3F800000u) - 1.0f;
  const float tiny = 1.17549435e-38f;
  float u = fmaxf(tiny, f + tiny);
  return -logf(-logf(u));
}

DEVFN float iou_xyxy(float ax1,float ay1,float ax2,float ay2,
                     float bx1,float by1,float bx2,float by2){
  float aa = (ax2-ax1)*(ay2-ay1);
  float ab = (bx2-bx1)*(by2-by1);
  float lx = fmaxf(ax1,bx1), ly = fmaxf(ay1,by1);
  float rx = fminf(ax2,bx2), ry = fminf(ay2,by2);
  float iw = fmaxf(rx-lx,0.f), ih = fmaxf(ry-ly,0.f);
  float in_ = iw*ih;
  return in_/(aa+ab-in_);
}

DEVFN u16 f2bf(float x){
  uint32_t u = __float_as_uint(x);
  uint32_t r = u + 0x7FFFu + ((u >> 16) & 1u);
  return (u16)(r >> 16);
}

// ---------------- K1: tiled f32 GEMM: [pl;te](2700x256) x [ce;te]^T(256x600) ----------------
// rows<2400 -> sims, rows>=2400 & cols<300 -> gtsim. Ascending-k fmaf order (matches prior).
__global__ __launch_bounds__(256) void k_gemm_t(
    const float* __restrict__ pl, const float* __restrict__ ce,
    const float* __restrict__ te, float* __restrict__ sims,
    float* __restrict__ gtsim){
  __shared__ float As[16][128];
  __shared__ float Bs[16][128];
  const int row0 = blockIdx.x * 128, col0 = blockIdx.y * 128;
  const int tid = threadIdx.x;
  const int lrow = tid >> 1, lk0 = (tid & 1) * 8;   // load map: 128 rows x 16 k
  const int tr = tid >> 4, tc = tid & 15;            // compute map: 16x16 threads

  float acc[8][8];
  #pragma unroll
  for (int i = 0; i < 8; i++)
    #pragma unroll
    for (int j = 0; j < 8; j++) acc[i][j] = 0.f;

  const float4 z4 = {0.f,0.f,0.f,0.f};
  const int grow = row0 + lrow;
  const int gcol = col0 + lrow;
  const float* arow = nullptr;
  if (grow < 2400) arow = pl + (size_t)grow * DD;
  else if (grow < 2700) arow = te + (size_t)(grow - 2400) * DD;
  const float* brow = nullptr;
  if (gcol < 300) brow = ce + (size_t)gcol * DD;
  else if (gcol < 600) brow = te + (size_t)(gcol - 300) * DD;

  float4 av0 = arow ? *(const float4*)(arow + lk0)     : z4;
  float4 av1 = arow ? *(const float4*)(arow + lk0 + 4) : z4;
  float4 bv0 = brow ? *(const float4*)(brow + lk0)     : z4;
  float4 bv1 = brow ? *(const float4*)(brow + lk0 + 4) : z4;

  for (int step = 0; step < 16; step++){
    __syncthreads();
    #pragma unroll
    for (int j = 0; j < 4; j++){
      As[lk0 + j][lrow]     = ((const float*)&av0)[j];
      As[lk0 + 4 + j][lrow] = ((const float*)&av1)[j];
      Bs[lk0 + j][lrow]     = ((const float*)&bv0)[j];
      Bs[lk0 + 4 + j][lrow] = ((const float*)&bv1)[j];
    }
    __syncthreads();
    if (step + 1 < 16){
      const int k0 = (step + 1) * 16;
      av0 = arow ? *(const float4*)(arow + k0 + lk0)     : z4;
      av1 = arow ? *(const float4*)(arow + k0 + lk0 + 4) : z4;
      bv0 = brow ? *(const float4*)(brow + k0 + lk0)     : z4;
      bv1 = brow ? *(const float4*)(brow + k0 + lk0 + 4) : z4;
    }
    #pragma unroll
    for (int kk = 0; kk < 16; kk++){
      float4 a0 = *(const float4*)&As[kk][tr*8];
      float4 a1 = *(const float4*)&As[kk][tr*8 + 4];
      float4 b0 = *(const float4*)&Bs[kk][tc*8];
      float4 b1 = *(const float4*)&Bs[kk][tc*8 + 4];
      float a[8] = {a0.x,a0.y,a0.z,a0.w,a1.x,a1.y,a1.z,a1.w};
      float b[8] = {b0.x,b0.y,b0.z,b0.w,b1.x,b1.y,b1.z,b1.w};
      #pragma unroll
      for (int i = 0; i < 8; i++)
        #pragma unroll
        for (int j = 0; j < 8; j++)
          acc[i][j] = fmaf(a[i], b[j], acc[i][j]);
    }
  }

  #pragma unroll
  for (int i = 0; i < 8; i++){
    const int r = row0 + tr*8 + i;
    const int c0 = col0 + tc*8;
    if (r < 2400){
      if (c0 < 600){
        float4 o0 = {acc[i][0],acc[i][1],acc[i][2],acc[i][3]};
        float4 o1 = {acc[i][4],acc[i][5],acc[i][6],acc[i][7]};
        *(float4*)(sims + (size_t)r*SIMW + c0)     = o0;
        *(float4*)(sims + (size_t)r*SIMW + c0 + 4) = o1;
      }
    } else if (r < 2700){
      const int n = r - 2400;
      #pragma unroll
      for (int j = 0; j < 8; j++){
        int c = c0 + j;
        if (c < 300) gtsim[(size_t)n*CC + c] = acc[i][j];
      }
    }
  }
}

// ---------------- K2: per-bq scores/argmax(g0)/boxes; tb rows; gtsim rowsums ----------------
__global__ __launch_bounds__(512) void k_post(
    const float* __restrict__ sims, const float* __restrict__ pb,
    const float* __restrict__ tbb, const int* __restrict__ tids,
    const int* __restrict__ bidx, const float* __restrict__ gtsim,
    float* __restrict__ score, float* __restrict__ bbox,
    float* __restrict__ tb, float* __restrict__ rowsum){
  int bq = blockIdx.x, tid = threadIdx.x;
  __shared__ float sv[512];
  __shared__ int   si[512];
  float v = (tid < CC) ? sims[(size_t)bq*SIMW + tid] : -INFINITY;
  sv[tid] = v; __syncthreads();
  for (int s = 256; s > 0; s >>= 1){ if (tid < s) sv[tid] = fmaxf(sv[tid], sv[tid+s]); __syncthreads(); }
  if (tid == 0) score[bq] = sv[0];
  __syncthreads();
  uint32_t gk0, gk1; subkey(0, gk0, gk1);
  float y = (tid < CC) ? v + gumbel32(gk0, gk1, (uint32_t)(bq*CC + tid)) : -INFINITY;
  sv[tid] = y; si[tid] = tid; __syncthreads();
  for (int s = 256; s > 0; s >>= 1){
    if (tid < s){
      float ov = sv[tid+s]; int oi = si[tid+s];
      if (ov > sv[tid] || (ov == sv[tid] && oi < si[tid])){ sv[tid] = ov; si[tid] = oi; }
    }
    __syncthreads();
  }
  if (tid == 0){
    int cls = si[0];
    float ox = 224.0f * (float)cls;
    float oy = 224.0f * (float)(bq / QQ);
    float cx = pb[bq*4+0], cy = pb[bq*4+1], ww = pb[bq*4+2], hh = pb[bq*4+3];
    bbox[bq*4+0] = cx - 0.5f*ww + ox;
    bbox[bq*4+1] = cy - 0.5f*hh + oy;
    bbox[bq*4+2] = cx + 0.5f*ww + ox;
    bbox[bq*4+3] = cy + 0.5f*hh + oy;
  }
  if (bq < NN){
    __syncthreads();
    float rs = (tid < CC) ? gtsim[(size_t)bq*CC + tid] : 0.f;
    sv[tid] = rs; __syncthreads();
    for (int s = 256; s > 0; s >>= 1){ if (tid < s) sv[tid] += sv[tid+s]; __syncthreads(); }
    if (tid == 0) rowsum[bq] = sv[0];
    if (tid == 1){
      float gx = 224.0f * (float)tids[bq], gy = 224.0f * (float)bidx[bq];
      float cx = tbb[bq*4+0], cy = tbb[bq*4+1], ww = tbb[bq*4+2], hh = tbb[bq*4+3];
      tb[bq*4+0] = cx - 0.5f*ww + gx;
      tb[bq*4+1] = cy - 0.5f*hh + gy;
      tb[bq*4+2] = cx + 0.5f*ww + gx;
      tb[bq*4+3] = cy + 0.5f*hh + gy;
    }
  }
}

// ---------------- K3: stable descending rank sort ----------------
__global__ __launch_bounds__(256) void k_rank(
    const float* __restrict__ score, int* __restrict__ order){
  __shared__ float s[BQ];
  int tid = threadIdx.x;
  for (int i = tid; i < BQ; i += 256) s[i] = score[i];
  __syncthreads();
  int t = blockIdx.x*256 + tid;
  if (t >= BQ) return;
  float st = s[t];
  int cnt = 0;
  for (int j = 0; j < BQ; j++){
    float sj = s[j];
    cnt += (sj > st) || (sj == st && j < t);
  }
  order[cnt] = t;
}

// ---------------- K4: gather sorted boxes/areas + batch segment starts ----------------
__global__ __launch_bounds__(256) void k_gather(
    const float* __restrict__ bbox, const int* __restrict__ order,
    const int* __restrict__ bidx, float* __restrict__ sb,
    float* __restrict__ sarea, int* __restrict__ bstart){
  int t = blockIdx.x*256 + threadIdx.x;
  if (t < BQ){
    int o = order[t];
    float x1 = bbox[o*4+0], y1 = bbox[o*4+1], x2 = bbox[o*4+2], y2 = bbox[o*4+3];
    sb[t*4+0] = x1; sb[t*4+1] = y1; sb[t*4+2] = x2; sb[t*4+3] = y2;
    sarea[t] = (x2-x1)*(y2-y1);
  }
  if (blockIdx.x == 0 && threadIdx.x < 9){
    int b = threadIdx.x, c = 0;
    for (int n = 0; n < NN; n++) c += (bidx[n] < b);
    bstart[b] = c;
  }
}

// ---------------- K5: adjacency bitmask ----------------
__global__ __launch_bounds__(256) void k_adj(
    const float* __restrict__ sb, const float* __restrict__ sarea,
    unsigned long long* __restrict__ adj){
  __shared__ float4 box[BQ];
  __shared__ float  ar[BQ];
  int tid = threadIdx.x, i = blockIdx.x;
  for (int t = tid; t < BQ; t += 256){ box[t] = ((const float4*)sb)[t]; ar[t] = sarea[t]; }
  __syncthreads();
  float4 bi = box[i]; float ai = ar[i];
  int lane = tid & 63, wv = tid >> 6;
  for (int w = wv; w < ADJW; w += 4){
    int j = w*64 + lane;
    bool pred = false;
    if (j < BQ && j > i){
      float4 bj = box[j];
      float lx = fmaxf(bi.x,bj.x), ly = fmaxf(bi.y,bj.y);
      float rx = fminf(bi.z,bj.z), ry = fminf(bi.w,bj.w);
      float iw = fmaxf(rx-lx,0.f), ih = fmaxf(ry-ly,0.f);
      float in_ = iw*ih;
      pred = (in_/(ai + ar[j] - in_)) > 0.5f;
    }
    unsigned long long m = __ballot(pred);
    if (lane == 0) adj[(size_t)i*ADJW + w] = m;
  }
}

// ---------------- K6: blocked greedy suppress (4 waves: 1 process + 3 prefetch) ----------------
constexpr int GRP = 38;       // ceil(2400/64)
constexpr int GWORDS = 2432;  // 64*38
__global__ __launch_bounds__(256) void k_nms(
    const unsigned long long* __restrict__ adj,
    unsigned long long* __restrict__ supw){
  __shared__ unsigned long long nb[2][2496];
  const int tid = threadIdx.x;
  const int lane = tid & 63;
  const int wv = tid >> 6;
  unsigned long long sup = 0ull;

  if (wv > 0){
    for (int s = 0; s < 13; s++){
      int idx = (tid - 64) + s*192;
      if (idx < GWORDS) nb[0][idx] = adj[idx];
    }
  }
  __syncthreads();

  for (int g = 0; g < GRP; g++){
    const int cur = g & 1, nxt = cur ^ 1;
    if (wv > 0){
      if (g + 1 < GRP){
        int base = (g+1)*GWORDS;
        int lim = BQ*ADJW - base; if (lim > GWORDS) lim = GWORDS;
        for (int s = 0; s < 13; s++){
          int idx = (tid - 64) + s*192;
          if (idx < lim) nb[nxt][idx] = adj[base + idx];
        }
      }
    } else {
      const int rows = (BQ - g*64 < 64) ? (BQ - g*64) : 64;
      unsigned long long mg = __shfl(sup, g);
      unsigned long long keep = 0ull;
      for (int i0 = 0; i0 < rows; i0 += 8){
        unsigned long long wreg[8];
        #pragma unroll
        for (int j = 0; j < 8; j++) wreg[j] = nb[cur][(i0+j)*38 + g];
        #pragma unroll
        for (int j = 0; j < 8; j++){
          int i = i0 + j;
          if (!((mg >> i) & 1ull)){ keep |= (1ull << i); mg |= wreg[j]; }
        }
      }
      unsigned long long acc = 0ull;
      for (int i0 = 0; i0 < rows; i0 += 8){
        #pragma unroll
        for (int j = 0; j < 8; j++){
          int i = i0 + j;
          unsigned long long v = nb[cur][i*38 + lane];
          unsigned long long msk = (unsigned long long)0 - ((keep >> i) & 1ull);
          acc |= (v & msk);
        }
      }
      sup |= acc;
    }
    __syncthreads();
  }
  if (wv == 0 && lane < ADJW) supw[lane] = sup;
}

// ---------------- K7: compact ----------------
__global__ __launch_bounds__(256) void k_compact(
    const unsigned long long* __restrict__ supw, const int* __restrict__ order,
    const float* __restrict__ sb, int* __restrict__ nmsidx,
    float* __restrict__ kb, int* __restrict__ kint){
  __shared__ int csum[256];
  int tid = threadIdx.x;
  int p0 = tid*10;
  int keepf[10];
  int cnt = 0;
  #pragma unroll
  for (int d = 0; d < 10; d++){
    int p = p0 + d;
    int k = 0;
    if (p < BQ) k = !((supw[p >> 6] >> (p & 63)) & 1ull);
    keepf[d] = k; cnt += k;
  }
  csum[tid] = cnt; __syncthreads();
  for (int s = 1; s < 256; s <<= 1){
    int add = (tid >= s) ? csum[tid - s] : 0;
    __syncthreads();
    csum[tid] += add;
    __syncthreads();
  }
  int pos = csum[tid] - cnt;
  #pragma unroll
  for (int d = 0; d < 10; d++){
    if (keepf[d]){
      int p = p0 + d;
      nmsidx[pos] = order[p];
      ((float4*)kb)[pos] = ((const float4*)sb)[p];
      pos++;
    }
  }
  if (tid == 255) kint[0] = csum[255];
}

// ---------------- K8: per-kept-box scatter ----------------
__global__ __launch_bounds__(512) void k_gtsel(
    const float* __restrict__ kb, const float* __restrict__ tb,
    const int* __restrict__ nmsidx, const float* __restrict__ pl,
    const int* __restrict__ kint, float* __restrict__ gsel,
    float* __restrict__ oe){
  int k = blockIdx.x;
  if (k >= kint[0]) return;
  int tid = threadIdx.x;
  __shared__ float sv[512];
  __shared__ int   si[512];
  float4 a = ((const float4*)kb)[k];
  float iou = -INFINITY;
  if (tid < NN){
    float4 t = ((const float4*)tb)[tid];
    iou = iou_xyxy(a.x,a.y,a.z,a.w, t.x,t.y,t.z,t.w);
    if (iou != iou) iou = 0.f;
  }
  sv[tid] = iou; __syncthreads();
  for (int s = 256; s > 0; s >>= 1){ if (tid < s) sv[tid] = fmaxf(sv[tid], sv[tid+s]); __syncthreads(); }
  float m = sv[0]; __syncthreads();
  float e = (tid < NN) ? expf(iou - m) : 0.f;
  sv[tid] = e; __syncthreads();
  for (int s = 256; s > 0; s >>= 1){ if (tid < s) sv[tid] += sv[tid+s]; __syncthreads(); }
  float S = sv[0]; __syncthreads();
  uint32_t gk0, gk1; subkey(1, gk0, gk1);
  float y = (tid < NN) ? (e / S + gumbel32(gk0, gk1, (uint32_t)(k*NN + tid))) : -INFINITY;
  sv[tid] = y; si[tid] = tid; __syncthreads();
  for (int s = 256; s > 0; s >>= 1){
    if (tid < s){
      float ov = sv[tid+s]; int oi = si[tid+s];
      if (ov > sv[tid] || (ov == sv[tid] && oi < si[tid])){ sv[tid] = ov; si[tid] = oi; }
    }
    __syncthreads();
  }
  int sel = si[0];
  if (tid < 4) atomicAdd(&gsel[sel*4 + tid], ((const float*)&a)[tid]);
  if (tid < DD) atomicAdd(&oe[(size_t)sel*DD + tid], pl[(size_t)nmsidx[k]*DD + tid]);
}

// ---------------- K9: gt_ious + l1 ----------------
__global__ __launch_bounds__(512) void k_gtiou(
    const float* __restrict__ gsel, const float* __restrict__ tb,
    float* __restrict__ sc){
  int tid = threadIdx.x;
  __shared__ float s1[512], s2[512];
  float a1 = 0.f, a2 = 0.f;
  if (tid < NN){
    float4 g = ((const float4*)gsel)[tid];
    float4 t = ((const float4*)tb)[tid];
    float iou = iou_xyxy(g.x,g.y,g.z,g.w, t.x,t.y,t.z,t.w);
    a1 = 1.f - iou;
    a2 = fabsf(g.x-t.x) + fabsf(g.y-t.y) + fabsf(g.z-t.z) + fabsf(g.w-t.w);
  }
  s1[tid] = a1; s2[tid] = a2; __syncthreads();
  for (int s = 256; s > 0; s >>= 1){
    if (tid < s){ s1[tid] += s1[tid+s]; s2[tid] += s2[tid+s]; }
    __syncthreads();
  }
  if (tid == 0){ sc[3] = s1[0]; sc[4] = s2[0]; }
}

// ---------------- K10: M = tgt_embs @ out_embs^T ----------------
__global__ __launch_bounds__(256) void k_m(
    const float* __restrict__ te, const float* __restrict__ oe,
    float* __restrict__ M){
  int idx = blockIdx.x*256 + threadIdx.x;
  if (idx >= NN*NN) return;
  int i = idx / NN, j = idx % NN;
  const float4* a4 = (const float4*)(te + (size_t)i*DD);
  const float4* b4 = (const float4*)(oe + (size_t)j*DD);
  float s = 0.f;
  #pragma unroll 8
  for (int t = 0; t < DD/4; t++){
    float4 x = a4[t], y = b4[t];
    s += x.x*y.x + x.y*y.y + x.z*y.z + x.w*y.w;
  }
  M[idx] = s;
}

// ---------------- K11: both cross-entropies ----------------
__global__ __launch_bounds__(64) void k_ce(
    const float* __restrict__ M, float* __restrict__ sc){
  int i = blockIdx.x, lane = threadIdx.x;
  float m = -INFINITY;
  for (int j = lane; j < NN; j += 64) m = fmaxf(m, M[(size_t)i*NN + j]);
  for (int o = 32; o > 0; o >>= 1) m = fmaxf(m, __shfl_xor(m, o));
  float s = 0.f;
  for (int j = lane; j < NN; j += 64) s += expf(M[(size_t)i*NN + j] - m);
  for (int o = 32; o > 0; o >>= 1) s += __shfl_xor(s, o);
  float lr = m + logf(s);
  float m2 = -INFINITY;
  for (int j = lane; j < NN; j += 64) m2 = fmaxf(m2, M[(size_t)j*NN + i]);
  for (int o = 32; o > 0; o >>= 1) m2 = fmaxf(m2, __shfl_xor(m2, o));
  float s2 = 0.f;
  for (int j = lane; j < NN; j += 64) s2 += expf(M[(size_t)j*NN + i] - m2);
  for (int o = 32; o > 0; o >>= 1) s2 += __shfl_xor(s2, o);
  float lc = m2 + logf(s2);
  if (lane == 0){
    float d = M[(size_t)i*NN + i];
    atomicAdd(&sc[0], lr - d);
    atomicAdd(&sc[1], lc - d);
  }
}

// ---------------- K12: sel2 ----------------
__global__ __launch_bounds__(256) void k_sel2(
    const float* __restrict__ sims, int* __restrict__ sel2){
  int n = blockIdx.x, tid = threadIdx.x;
  uint32_t gk0, gk1; subkey(2, gk0, gk1);
  float best = -INFINITY; int bi = 0x7fffffff;
  for (int r = tid; r < BQ; r += 256){
    float v = sims[(size_t)r*SIMW + CC + n] + gumbel32(gk0, gk1, (uint32_t)(r*NN + n));
    if (v > best){ best = v; bi = r; }
  }
  __shared__ float sv[256];
  __shared__ int   si[256];
  sv[tid] = best; si[tid] = bi; __syncthreads();
  for (int s = 128; s > 0; s >>= 1){
    if (tid < s){
      float ov = sv[tid+s]; int oi = si[tid+s];
      if (ov > sv[tid] || (ov == sv[tid] && oi < si[tid])){ sv[tid] = ov; si[tid] = oi; }
    }
    __syncthreads();
  }
  if (tid == 0) sel2[n] = si[0];
}

// ---------------- K13: overall_mask_loss + masksum ----------------
__global__ __launch_bounds__(256) void k_om(
    const float* __restrict__ pm, const float* __restrict__ tm,
    const int* __restrict__ sel2, float* __restrict__ msum,
    float* __restrict__ sc){
  int nb = blockIdx.x;
  int n = nb / 9, ch = nb % 9;
  int c0 = ch*1024 + threadIdx.x*4;
  const float4 o4 = *(const float4*)(pm + (size_t)sel2[n]*WHX + c0);
  const float4 t4 = *(const float4*)(tm + (size_t)n*WHX + c0);
  float dx = o4.x-t4.x, dy = o4.y-t4.y, dz = o4.z-t4.z, dw = o4.w-t4.w;
  float d2 = dx*dx + dy*dy + dz*dz + dw*dw;
  float ts = t4.x + t4.y + t4.z + t4.w;
  __shared__ float r1[256], r2[256];
  r1[threadIdx.x] = d2; r2[threadIdx.x] = ts; __syncthreads();
  for (int s = 128; s > 0; s >>= 1){
    if (threadIdx.x < s){ r1[threadIdx.x] += r1[threadIdx.x+s]; r2[threadIdx.x] += r2[threadIdx.x+s]; }
    __syncthreads();
  }
  if (threadIdx.x == 0){ atomicAdd(&sc[2], r1[0]); atomicAdd(&msum[n], r2[0]); }
}

// ---------------- K14: sum_tgt[b] ----------------
__global__ __launch_bounds__(512) void k_sumtgt(
    const int* __restrict__ bidx, const float* __restrict__ rowsum,
    const float* __restrict__ msum, float* __restrict__ stgt){
  int n = threadIdx.x;
  if (n >= NN) return;
  atomicAdd(&stgt[bidx[n]], rowsum[n] * msum[n]);
}

// ---------------- T1: sims f32 -> simTb bf16 [8][304][320] (transpose) ----------------
__global__ __launch_bounds__(256) void t_simT(
    const float* __restrict__ sims, u16* __restrict__ simTb){
  __shared__ float ld[32][65];
  int q0 = blockIdx.x*32, c0 = blockIdx.y*64, b = blockIdx.z;
  int tid = threadIdx.x;
  for (int i = tid; i < 32*64; i += 256){
    int qi = i >> 6, ci = i & 63;
    int q = q0 + qi, c = c0 + ci;
    ld[qi][ci] = (q < QQ && c < CC) ? sims[((size_t)b*QQ + q)*SIMW + c] : 0.f;
  }
  __syncthreads();
  int cloc = tid >> 2, j0 = (tid & 3)*8;
  int c = c0 + cloc;
  if (c < CP){
    u16 tmp[8];
    #pragma unroll
    for (int j = 0; j < 8; j++) tmp[j] = f2bf(ld[j0+j][cloc]);
    *(uint4*)(simTb + ((size_t)b*CP + c)*QP + q0 + j0) = *(const uint4*)tmp;
  }
}

// ---------------- T2: omT bf16 [9216][320] = pm[sel2[q]][wh]/96 (transpose) ----------------
__global__ __launch_bounds__(256) void t_omT(
    const float* __restrict__ pm, const int* __restrict__ sel2,
    u16* __restrict__ omT){
  __shared__ float ld[32][65];
  int q0 = blockIdx.x*32, wh0 = blockIdx.y*64;
  int tid = threadIdx.x;
  for (int i = tid; i < 32*64; i += 256){
    int qi = i >> 6, wi = i & 63;
    int q = q0 + qi;
    ld[qi][wi] = (q < QQ) ? pm[(size_t)sel2[q]*WHX + wh0 + wi] * (1.0f/96.0f) : 0.f;
  }
  __syncthreads();
  int wloc = tid >> 2, j0 = (tid & 3)*8;
  u16 tmp[8];
  #pragma unroll
  for (int j = 0; j < 8; j++) tmp[j] = f2bf(ld[j0+j][wloc]);
  *(uint4*)(omT + (size_t)(wh0+wloc)*QP + q0 + j0) = *(const uint4*)tmp;
}

// ---------------- T3: tmT bf16 [9216][416] (transpose, zero-padded) ----------------
__global__ __launch_bounds__(256) void t_tmT(
    const float* __restrict__ tm, u16* __restrict__ tmT){
  __shared__ float ld[32][65];
  int n0 = blockIdx.x*32, wh0 = blockIdx.y*64;
  int tid = threadIdx.x;
  for (int i = tid; i < 32*64; i += 256){
    int ni = i >> 6, wi = i & 63;
    int n = n0 + ni;
    ld[ni][wi] = (n < NN) ? tm[(size_t)n*WHX + wh0 + wi] : 0.f;
  }
  __syncthreads();
  int wloc = tid >> 2, j0 = (tid & 3)*8;
  u16 tmp[8];
  #pragma unroll
  for (int j = 0; j < 8; j++) tmp[j] = f2bf(ld[j0+j][wloc]);
  *(uint4*)(tmT + (size_t)(wh0+wloc)*NP + n0 + j0) = *(const uint4*)tmp;
}

// ---------------- T4: gtsimP bf16 [8][304][96] (per-batch zero-padded window) ----------------
__global__ __launch_bounds__(256) void t_gtp(
    const float* __restrict__ gtsim, const int* __restrict__ bstart,
    u16* __restrict__ gtp){
  int g = blockIdx.x*256 + threadIdx.x;
  if (g >= BB*CP*(KP/8)) return;
  int b = g / (CP*(KP/8));
  int rem = g - b*CP*(KP/8);
  int c = rem / (KP/8);
  int kg = rem % (KP/8);
  int n0 = bstart[b], n1 = bstart[b+1];
  int kst = n0 & ~7;
  u16 tmp[8];
  #pragma unroll
  for (int j = 0; j < 8; j++){
    int n = kst + kg*8 + j;
    float v = (n >= n0 && n < n1 && c < CC) ? gtsim[(size_t)n*CC + c] : 0.f;
    tmp[j] = f2bf(v);
  }
  *(uint4*)(gtp + ((size_t)b*CP + c)*KP + kg*8) = *(const uint4*)tmp;
}

// ---------------- K15: MFMA z-GEMM + column softmax + dice contraction ----------------
__global__ __launch_bounds__(256) void k_zsoft(
    const u16* __restrict__ simTb, const u16* __restrict__ omT,
    const u16* __restrict__ gtp, const u16* __restrict__ tmT,
    const int* __restrict__ bstart, float* __restrict__ sc){
  const int b = blockIdx.y;
  const int tid = threadIdx.x;
  const int w = tid >> 6, l = tid & 63;
  const int lrow = l & 15, lgrp = l >> 4;
  const int col = blockIdx.x*64 + w*16 + lrow;   // wh column owned by this lane

  f32x4 acc[19];
  #pragma unroll
  for (int t = 0; t < 19; t++) acc[t] = (f32x4){0.f,0.f,0.f,0.f};

  const u16* pA = simTb + (size_t)b*CP*QP + (size_t)lrow*QP + lgrp*8;
  const u16* pB = omT + (size_t)col*QP + lgrp*8;

  for (int ks = 0; ks < 10; ks++){
    bf16x8 bf = *(const bf16x8*)(pB + ks*32);
    #pragma unroll
    for (int t = 0; t < 19; t++){
      bf16x8 af = *(const bf16x8*)(pA + (size_t)t*16*QP + ks*32);
      acc[t] = __builtin_amdgcn_mfma_f32_16x16x32_bf16(af, bf, acc[t], 0, 0, 0);
    }
  }

  float lmax = -INFINITY;
  #pragma unroll
  for (int t = 0; t < 19; t++){
    if (t == 18 && lgrp == 3) continue;
    lmax = fmaxf(lmax, fmaxf(fmaxf(acc[t][0], acc[t][1]), fmaxf(acc[t][2], acc[t][3])));
  }
  lmax = fmaxf(lmax, __shfl_xor(lmax, 16));
  lmax = fmaxf(lmax, __shfl_xor(lmax, 32));
  float ls = 0.f;
  #pragma unroll
  for (int t = 0; t < 19; t++){
    if (t == 18 && lgrp == 3){
      acc[t] = (f32x4){0.f,0.f,0.f,0.f};
      continue;
    }
    float p0 = __expf(acc[t][0] - lmax);
    float p1 = __expf(acc[t][1] - lmax);
    float p2 = __expf(acc[t][2] - lmax);
    float p3 = __expf(acc[t][3] - lmax);
    acc[t][0] = p0; acc[t][1] = p1; acc[t][2] = p2; acc[t][3] = p3;
    ls += p0 + p1 + p2 + p3;
  }
  float S = ls;
  S += __shfl_xor(S, 16);
  S += __shfl_xor(S, 32);
  float inv = 1.f / S;

  int n0 = bstart[b];
  int kst = n0 & ~7;
  const u16* tB = tmT + (size_t)col*NP + kst + lgrp*8;
  bf16x8 b2a = *(const bf16x8*)(tB);
  bf16x8 b2b = *(const bf16x8*)(tB + 32);
  bf16x8 b2c = *(const bf16x8*)(tB + 64);
  const u16* A2 = gtp + (size_t)b*CP*KP + lgrp*8;
  float dl = 0.f;
  #pragma unroll
  for (int t = 0; t < 19; t++){
    const u16* ar = A2 + (size_t)(t*16 + lrow)*KP;
    f32x4 rr = (f32x4){0.f,0.f,0.f,0.f};
    rr = __builtin_amdgcn_mfma_f32_16x16x32_bf16(*(const bf16x8*)(ar),      b2a, rr, 0, 0, 0);
    rr = __builtin_amdgcn_mfma_f32_16x16x32_bf16(*(const bf16x8*)(ar + 32), b2b, rr, 0, 0, 0);
    rr = __builtin_amdgcn_mfma_f32_16x16x32_bf16(*(const bf16x8*)(ar + 64), b2c, rr, 0, 0, 0);
    dl += acc[t][0]*rr[0] + acc[t][1]*rr[1] + acc[t][2]*rr[2] + acc[t][3]*rr[3];
  }
  dl *= inv;

  __shared__ float red[256];
  red[tid] = dl; __syncthreads();
  for (int s = 128; s > 0; s >>= 1){
    if (tid < s) red[tid] += red[tid+s];
    __syncthreads();
  }
  if (tid == 0) atomicAdd(&sc[5], red[0]);
}

// ---------------- K16: finalize ----------------
__global__ __launch_bounds__(64) void k_final(
    const float* __restrict__ sc, const float* __restrict__ stgt,
    const int* __restrict__ kint, float* __restrict__ out){
  if (threadIdx.x != 0) return;
  float K = (float)kint[0];
  float cls = sc[0]/300.f + sc[1]/300.f;
  float stot = sc[5];
  float dice = 0.f;
  for (int b = 0; b < 8; b++) dice += stot / (9216.0f + stgt[b] + 1e-6f);
  dice *= (1.0f/8.0f);
  out[0] = cls;
  out[1] = dice;
  out[2] = (sc[2] / 2764800.0f) / K;
  out[3] = sc[3] / K;
  out[4] = sc[4] / K;
}

// ---------------- launch ----------------
extern "C" void kernel_launch(void* const* d_in, const int* in_sizes, int n_in,
                              void* d_out, int out_size, void* d_ws, size_t ws_size,
                              hipStream_t stream) {
  const float* ce  = (const float*)d_in[0];
  const float* pl  = (const float*)d_in[1];
  const float* pb  = (const float*)d_in[2];
  const float* pm  = (const float*)d_in[3];
  const float* tm  = (const float*)d_in[4];
  const float* te  = (const float*)d_in[5];
  const float* tbb = (const float*)d_in[6];
  const int*  tids = (const int*)d_in[8];
  const int*  bidx = (const int*)d_in[9];
  float* out = (float*)d_out;
  float* w = (float*)d_ws;

  if (ws_size < F_TOTAL * sizeof(float)) return;

  float* SIMS   = w + F_SIMS;
  float* GTSIM  = w + F_GTSIM;
  float* MM     = w + F_MM;
  float* SCORE  = w + F_SCORE;
  float* BBOX   = w + F_BBOX;
  float* TBOX   = w + F_TB;
  float* SB     = w + F_SB;
  float* SAREA  = w + F_SAREA;
  float* KB     = w + F_KB;
  float* ROWSUM = w + F_ROWSUM;
  float* OE     = w + F_OE;
  float* GSEL   = w + F_GSEL;
  float* MSUM   = w + F_MSUM;
  float* STGT   = w + F_STGT;
  float* SC     = w + F_SC;
  int*   ORDER  = (int*)(w + F_ORDER);
  int*   NMSIDX = (int*)(w + F_NMSIDX);
  int*   SEL2   = (int*)(w + F_SEL2);
  int*   BSTART = (int*)(w + F_BSTART);
  int*   KINT   = (int*)(w + F_KINT);
  unsigned long long* ADJ  = (unsigned long long*)(w + F_ADJ);
  unsigned long long* SUPW = (unsigned long long*)(w + F_SUPW);
  u16* SIMTB = (u16*)(w + F_SIMTB);
  u16* OMT   = (u16*)(w + F_OMT);
  u16* TMT   = (u16*)(w + F_TMT);
  u16* GTP   = (u16*)(w + F_GTP);

  hipMemsetAsync(w + F_OE, 0, (F_ACCEND - F_OE) * sizeof(float), stream);

  k_gemm_t<<<dim3(22, 5), 256, 0, stream>>>(pl, ce, te, SIMS, GTSIM);
  k_post<<<BQ, 512, 0, stream>>>(SIMS, pb, tbb, tids, bidx, GTSIM, SCORE, BBOX, TBOX, ROWSUM);
  k_rank<<<(BQ + 255)/256, 256, 0, stream>>>(SCORE, ORDER);
  k_gather<<<(BQ + 255)/256, 256, 0, stream>>>(BBOX, ORDER, bidx, SB, SAREA, BSTART);
  k_adj<<<BQ, 256, 0, stream>>>(SB, SAREA, ADJ);
  k_nms<<<1, 256, 0, stream>>>(ADJ, SUPW);
  k_compact<<<1, 256, 0, stream>>>(SUPW, ORDER, SB, NMSIDX, KB, KINT);
  k_gtsel<<<BQ, 512, 0, stream>>>(KB, TBOX, NMSIDX, pl, KINT, GSEL, OE);
  k_gtiou<<<1, 512, 0, stream>>>(GSEL, TBOX, SC);
  k_m<<<(NN*NN + 255)/256, 256, 0, stream>>>(te, OE, MM);
  k_ce<<<NN, 64, 0, stream>>>(MM, SC);
  k_sel2<<<NN, 256, 0, stream>>>(SIMS, SEL2);
  k_om<<<NN*9, 256, 0, stream>>>(pm, tm, SEL2, MSUM, SC);
  k_sumtgt<<<1, 512, 0, stream>>>(bidx, ROWSUM, MSUM, STGT);

  t_simT<<<dim3(QP/32, 5, BB), 256, 0, stream>>>(SIMS, SIMTB);
  t_omT<<<dim3(QP/32, WHX/64), 256, 0, stream>>>(pm, SEL2, OMT);
  t_tmT<<<dim3(NP/32, WHX/64), 256, 0, stream>>>(tm, TMT);
  t_gtp<<<(BB*CP*(KP/8) + 255)/256, 256, 0, stream>>>(GTSIM, BSTART, GTP);

  k_zsoft<<<dim3(WHX/64, BB), 256, 0, stream>>>(SIMTB, OMT, GTP, TMT, BSTART, SC);
  k_final<<<1, 64, 0, stream>>>(SC, STGT, KINT, out);
}

// Round 5
// 491.344 us; speedup vs baseline: 4.1529x; 1.1695x over previous
//
#include <hip/hip_runtime.h>
#include <stdint.h>

#define DEVFN __device__ __forceinline__

typedef unsigned short u16;
typedef short bf16x8 __attribute__((ext_vector_type(8)));
typedef float f32x4 __attribute__((ext_vector_type(4)));

constexpr int BB = 8, QQ = 300, CC = 300, NN = 300, DD = 256;
constexpr int WHX = 9216, BQ = 2400, SIMW = 600, ADJW = 38;
constexpr int QP = 320;   // padded Q for MFMA K-dim
constexpr int CP = 304;   // padded C rows
constexpr int KP = 96;    // per-batch n-window
constexpr int NP = 416;   // padded tmT n-dim

// ---------------- workspace layout (float units) ----------------
constexpr size_t F_SIMS   = 0;                                 // [2400][600]
constexpr size_t F_GTSIM  = F_SIMS   + (size_t)BQ*SIMW;        // [300][300]
constexpr size_t F_MM     = F_GTSIM  + (size_t)NN*CC;          // [300][300]
constexpr size_t F_SCORE  = F_MM     + (size_t)NN*NN;          // [2400]
constexpr size_t F_BBOX   = F_SCORE  + BQ;                     // [2400][4]
constexpr size_t F_TB     = F_BBOX   + (size_t)BQ*4;           // [300][4]
constexpr size_t F_SB     = F_TB     + (size_t)NN*4;           // [2400][4]
constexpr size_t F_SAREA  = F_SB     + (size_t)BQ*4;           // [2400]
constexpr size_t F_KB     = F_SAREA  + BQ;                     // [2400][4]
constexpr size_t F_ROWSUM = F_KB     + (size_t)BQ*4;           // [300]
constexpr size_t F_OE     = F_ROWSUM + NN;                     // ---- zeroed zone
constexpr size_t F_GSEL   = F_OE     + (size_t)NN*DD;          // [300][4]
constexpr size_t F_MSUM   = F_GSEL   + (size_t)NN*4;           // [300]
constexpr size_t F_STGT   = F_MSUM   + NN;                     // [8]
constexpr size_t F_SC     = F_STGT   + 8;                      // scalars
constexpr size_t F_ACCEND = F_SC     + 16;                     // ---- end zeroed zone
constexpr size_t F_ORDER  = F_ACCEND;                          // int [2400]
constexpr size_t F_NMSIDX = F_ORDER  + BQ;                     // int [2400]
constexpr size_t F_SEL2   = F_NMSIDX + BQ;                     // int [300]
constexpr size_t F_BSTART = F_SEL2   + NN;                     // int [16]
constexpr size_t F_KINT   = F_BSTART + 16;                     // int [4]
constexpr size_t F_ADJ    = ((F_KINT + 4 + 1) & ~(size_t)1);   // u64 [2400][38]
constexpr size_t F_SUPW   = F_ADJ + (size_t)BQ*ADJW*2;         // u64 [38]
// bf16 panels (sizes in floats = ushorts/2), 32B-align starts
constexpr size_t F_SIMTB  = ((F_SUPW + ADJW*2 + 7) & ~(size_t)7);   // u16[8][304][320]
constexpr size_t F_OMT    = F_SIMTB + (size_t)BB*CP*QP/2;           // u16[9216][320]
constexpr size_t F_TMT    = F_OMT   + (size_t)WHX*QP/2;             // u16[9216][416]
constexpr size_t F_GTP    = F_TMT   + (size_t)WHX*NP/2;             // u16[8][304][96]
constexpr size_t F_TOTAL  = F_GTP   + (size_t)BB*CP*KP/2;

// ---------------- JAX threefry2x32 (partitionable scheme) ----------------
DEVFN uint32_t rotl32(uint32_t v, int r){ return (v << r) | (v >> (32 - r)); }

DEVFN void tf2x32(uint32_t k0, uint32_t k1, uint32_t x0, uint32_t x1,
                  uint32_t& o0, uint32_t& o1){
  uint32_t ks2 = k0 ^ k1 ^ 0x1BD11BDAu;
  x0 += k0; x1 += k1;
#define TFR(r) x0 += x1; x1 = rotl32(x1, r); x1 ^= x0;
  TFR(13) TFR(15) TFR(26) TFR(6)   x0 += k1;  x1 += ks2 + 1u;
  TFR(17) TFR(29) TFR(16) TFR(24)  x0 += ks2; x1 += k0  + 2u;
  TFR(13) TFR(15) TFR(26) TFR(6)   x0 += k0;  x1 += k1  + 3u;
  TFR(17) TFR(29) TFR(16) TFR(24)  x0 += k1;  x1 += ks2 + 4u;
  TFR(13) TFR(15) TFR(26) TFR(6)   x0 += ks2; x1 += k0  + 5u;
#undef TFR
  o0 = x0; o1 = x1;
}

DEVFN void subkey(int i, uint32_t& k0, uint32_t& k1){
  tf2x32(0u, 42u, 0u, (uint32_t)i, k0, k1);
}

DEVFN float gumbel32(uint32_t k0, uint32_t k1, uint32_t idx){
  uint32_t h, l; tf2x32(k0, k1, 0u, idx, h, l);
  uint32_t bits = h ^ l;
  float f = __uint_as_float((bits >> 9) | 0x3F800000u) - 1.0f;
  const float tiny = 1.17549435e-38f;
  float u = fmaxf(tiny, f + tiny);
  return -logf(-logf(u));
}

DEVFN float iou_xyxy(float ax1,float ay1,float ax2,float ay2,
                     float bx1,float by1,float bx2,float by2){
  float aa = (ax2-ax1)*(ay2-ay1);
  float ab = (bx2-bx1)*(by2-by1);
  float lx = fmaxf(ax1,bx1), ly = fmaxf(ay1,by1);
  float rx = fminf(ax2,bx2), ry = fminf(ay2,by2);
  float iw = fmaxf(rx-lx,0.f), ih = fmaxf(ry-ly,0.f);
  float in_ = iw*ih;
  return in_/(aa+ab-in_);
}

DEVFN u16 f2bf(float x){
  uint32_t u = __float_as_uint(x);
  uint32_t r = u + 0x7FFFu + ((u >> 16) & 1u);
  return (u16)(r >> 16);
}

// ---------------- K1: tiled f32 GEMM: [pl;te](2700x256) x [ce;te]^T(256x600) ----------------
__global__ __launch_bounds__(256) void k_gemm_t(
    const float* __restrict__ pl, const float* __restrict__ ce,
    const float* __restrict__ te, float* __restrict__ sims,
    float* __restrict__ gtsim){
  __shared__ float As[16][128];
  __shared__ float Bs[16][128];
  const int row0 = blockIdx.x * 128, col0 = blockIdx.y * 128;
  const int tid = threadIdx.x;
  const int lrow = tid >> 1, lk0 = (tid & 1) * 8;
  const int tr = tid >> 4, tc = tid & 15;

  float acc[8][8];
  #pragma unroll
  for (int i = 0; i < 8; i++)
    #pragma unroll
    for (int j = 0; j < 8; j++) acc[i][j] = 0.f;

  const float4 z4 = {0.f,0.f,0.f,0.f};
  const int grow = row0 + lrow;
  const int gcol = col0 + lrow;
  const float* arow = nullptr;
  if (grow < 2400) arow = pl + (size_t)grow * DD;
  else if (grow < 2700) arow = te + (size_t)(grow - 2400) * DD;
  const float* brow = nullptr;
  if (gcol < 300) brow = ce + (size_t)gcol * DD;
  else if (gcol < 600) brow = te + (size_t)(gcol - 300) * DD;

  float4 av0 = arow ? *(const float4*)(arow + lk0)     : z4;
  float4 av1 = arow ? *(const float4*)(arow + lk0 + 4) : z4;
  float4 bv0 = brow ? *(const float4*)(brow + lk0)     : z4;
  float4 bv1 = brow ? *(const float4*)(brow + lk0 + 4) : z4;

  for (int step = 0; step < 16; step++){
    __syncthreads();
    #pragma unroll
    for (int j = 0; j < 4; j++){
      As[lk0 + j][lrow]     = ((const float*)&av0)[j];
      As[lk0 + 4 + j][lrow] = ((const float*)&av1)[j];
      Bs[lk0 + j][lrow]     = ((const float*)&bv0)[j];
      Bs[lk0 + 4 + j][lrow] = ((const float*)&bv1)[j];
    }
    __syncthreads();
    if (step + 1 < 16){
      const int k0 = (step + 1) * 16;
      av0 = arow ? *(const float4*)(arow + k0 + lk0)     : z4;
      av1 = arow ? *(const float4*)(arow + k0 + lk0 + 4) : z4;
      bv0 = brow ? *(const float4*)(brow + k0 + lk0)     : z4;
      bv1 = brow ? *(const float4*)(brow + k0 + lk0 + 4) : z4;
    }
    #pragma unroll
    for (int kk = 0; kk < 16; kk++){
      float4 a0 = *(const float4*)&As[kk][tr*8];
      float4 a1 = *(const float4*)&As[kk][tr*8 + 4];
      float4 b0 = *(const float4*)&Bs[kk][tc*8];
      float4 b1 = *(const float4*)&Bs[kk][tc*8 + 4];
      float a[8] = {a0.x,a0.y,a0.z,a0.w,a1.x,a1.y,a1.z,a1.w};
      float b[8] = {b0.x,b0.y,b0.z,b0.w,b1.x,b1.y,b1.z,b1.w};
      #pragma unroll
      for (int i = 0; i < 8; i++)
        #pragma unroll
        for (int j = 0; j < 8; j++)
          acc[i][j] = fmaf(a[i], b[j], acc[i][j]);
    }
  }

  #pragma unroll
  for (int i = 0; i < 8; i++){
    const int r = row0 + tr*8 + i;
    const int c0 = col0 + tc*8;
    if (r < 2400){
      if (c0 < 600){
        float4 o0 = {acc[i][0],acc[i][1],acc[i][2],acc[i][3]};
        float4 o1 = {acc[i][4],acc[i][5],acc[i][6],acc[i][7]};
        *(float4*)(sims + (size_t)r*SIMW + c0)     = o0;
        *(float4*)(sims + (size_t)r*SIMW + c0 + 4) = o1;
      }
    } else if (r < 2700){
      const int n = r - 2400;
      #pragma unroll
      for (int j = 0; j < 8; j++){
        int c = c0 + j;
        if (c < 300) gtsim[(size_t)n*CC + c] = acc[i][j];
      }
    }
  }
}

// ---------------- K2: per-bq scores/argmax(g0)/boxes; tb rows; gtsim rowsums ----------------
__global__ __launch_bounds__(512) void k_post(
    const float* __restrict__ sims, const float* __restrict__ pb,
    const float* __restrict__ tbb, const int* __restrict__ tids,
    const int* __restrict__ bidx, const float* __restrict__ gtsim,
    float* __restrict__ score, float* __restrict__ bbox,
    float* __restrict__ tb, float* __restrict__ rowsum){
  int bq = blockIdx.x, tid = threadIdx.x;
  __shared__ float sv[512];
  __shared__ int   si[512];
  float v = (tid < CC) ? sims[(size_t)bq*SIMW + tid] : -INFINITY;
  sv[tid] = v; __syncthreads();
  for (int s = 256; s > 0; s >>= 1){ if (tid < s) sv[tid] = fmaxf(sv[tid], sv[tid+s]); __syncthreads(); }
  if (tid == 0) score[bq] = sv[0];
  __syncthreads();
  uint32_t gk0, gk1; subkey(0, gk0, gk1);
  float y = (tid < CC) ? v + gumbel32(gk0, gk1, (uint32_t)(bq*CC + tid)) : -INFINITY;
  sv[tid] = y; si[tid] = tid; __syncthreads();
  for (int s = 256; s > 0; s >>= 1){
    if (tid < s){
      float ov = sv[tid+s]; int oi = si[tid+s];
      if (ov > sv[tid] || (ov == sv[tid] && oi < si[tid])){ sv[tid] = ov; si[tid] = oi; }
    }
    __syncthreads();
  }
  if (tid == 0){
    int cls = si[0];
    float ox = 224.0f * (float)cls;
    float oy = 224.0f * (float)(bq / QQ);
    float cx = pb[bq*4+0], cy = pb[bq*4+1], ww = pb[bq*4+2], hh = pb[bq*4+3];
    bbox[bq*4+0] = cx - 0.5f*ww + ox;
    bbox[bq*4+1] = cy - 0.5f*hh + oy;
    bbox[bq*4+2] = cx + 0.5f*ww + ox;
    bbox[bq*4+3] = cy + 0.5f*hh + oy;
  }
  if (bq < NN){
    __syncthreads();
    float rs = (tid < CC) ? gtsim[(size_t)bq*CC + tid] : 0.f;
    sv[tid] = rs; __syncthreads();
    for (int s = 256; s > 0; s >>= 1){ if (tid < s) sv[tid] += sv[tid+s]; __syncthreads(); }
    if (tid == 0) rowsum[bq] = sv[0];
    if (tid == 1){
      float gx = 224.0f * (float)tids[bq], gy = 224.0f * (float)bidx[bq];
      float cx = tbb[bq*4+0], cy = tbb[bq*4+1], ww = tbb[bq*4+2], hh = tbb[bq*4+3];
      tb[bq*4+0] = cx - 0.5f*ww + gx;
      tb[bq*4+1] = cy - 0.5f*hh + gy;
      tb[bq*4+2] = cx + 0.5f*ww + gx;
      tb[bq*4+3] = cy + 0.5f*hh + gy;
    }
  }
}

// ---------------- K3: stable descending rank sort ----------------
__global__ __launch_bounds__(256) void k_rank(
    const float* __restrict__ score, int* __restrict__ order){
  __shared__ float s[BQ];
  int tid = threadIdx.x;
  for (int i = tid; i < BQ; i += 256) s[i] = score[i];
  __syncthreads();
  int t = blockIdx.x*256 + tid;
  if (t >= BQ) return;
  float st = s[t];
  int cnt = 0;
  for (int j = 0; j < BQ; j++){
    float sj = s[j];
    cnt += (sj > st) || (sj == st && j < t);
  }
  order[cnt] = t;
}

// ---------------- K4: gather sorted boxes/areas + batch segment starts ----------------
__global__ __launch_bounds__(256) void k_gather(
    const float* __restrict__ bbox, const int* __restrict__ order,
    const int* __restrict__ bidx, float* __restrict__ sb,
    float* __restrict__ sarea, int* __restrict__ bstart){
  int t = blockIdx.x*256 + threadIdx.x;
  if (t < BQ){
    int o = order[t];
    float x1 = bbox[o*4+0], y1 = bbox[o*4+1], x2 = bbox[o*4+2], y2 = bbox[o*4+3];
    sb[t*4+0] = x1; sb[t*4+1] = y1; sb[t*4+2] = x2; sb[t*4+3] = y2;
    sarea[t] = (x2-x1)*(y2-y1);
  }
  if (blockIdx.x == 0 && threadIdx.x < 9){
    int b = threadIdx.x, c = 0;
    for (int n = 0; n < NN; n++) c += (bidx[n] < b);
    bstart[b] = c;
  }
}

// ---------------- K5: adjacency bitmask ----------------
__global__ __launch_bounds__(256) void k_adj(
    const float* __restrict__ sb, const float* __restrict__ sarea,
    unsigned long long* __restrict__ adj){
  __shared__ float4 box[BQ];
  __shared__ float  ar[BQ];
  int tid = threadIdx.x, i = blockIdx.x;
  for (int t = tid; t < BQ; t += 256){ box[t] = ((const float4*)sb)[t]; ar[t] = sarea[t]; }
  __syncthreads();
  float4 bi = box[i]; float ai = ar[i];
  int lane = tid & 63, wv = tid >> 6;
  for (int w = wv; w < ADJW; w += 4){
    int j = w*64 + lane;
    bool pred = false;
    if (j < BQ && j > i){
      float4 bj = box[j];
      float lx = fmaxf(bi.x,bj.x), ly = fmaxf(bi.y,bj.y);
      float rx = fminf(bi.z,bj.z), ry = fminf(bi.w,bj.w);
      float iw = fmaxf(rx-lx,0.f), ih = fmaxf(ry-ly,0.f);
      float in_ = iw*ih;
      pred = (in_/(ai + ar[j] - in_)) > 0.5f;
    }
    unsigned long long m = __ballot(pred);
    if (lane == 0) adj[(size_t)i*ADJW + w] = m;
  }
}

// ---------------- K6: blocked greedy suppress ----------------
constexpr int GRP = 38;
constexpr int GWORDS = 2432;
__global__ __launch_bounds__(256) void k_nms(
    const unsigned long long* __restrict__ adj,
    unsigned long long* __restrict__ supw){
  __shared__ unsigned long long nb[2][2496];
  const int tid = threadIdx.x;
  const int lane = tid & 63;
  const int wv = tid >> 6;
  unsigned long long sup = 0ull;

  if (wv > 0){
    for (int s = 0; s < 13; s++){
      int idx = (tid - 64) + s*192;
      if (idx < GWORDS) nb[0][idx] = adj[idx];
    }
  }
  __syncthreads();

  for (int g = 0; g < GRP; g++){
    const int cur = g & 1, nxt = cur ^ 1;
    if (wv > 0){
      if (g + 1 < GRP){
        int base = (g+1)*GWORDS;
        int lim = BQ*ADJW - base; if (lim > GWORDS) lim = GWORDS;
        for (int s = 0; s < 13; s++){
          int idx = (tid - 64) + s*192;
          if (idx < lim) nb[nxt][idx] = adj[base + idx];
        }
      }
    } else {
      const int rows = (BQ - g*64 < 64) ? (BQ - g*64) : 64;
      unsigned long long mg = __shfl(sup, g);
      unsigned long long keep = 0ull;
      for (int i0 = 0; i0 < rows; i0 += 8){
        unsigned long long wreg[8];
        #pragma unroll
        for (int j = 0; j < 8; j++) wreg[j] = nb[cur][(i0+j)*38 + g];
        #pragma unroll
        for (int j = 0; j < 8; j++){
          int i = i0 + j;
          if (!((mg >> i) & 1ull)){ keep |= (1ull << i); mg |= wreg[j]; }
        }
      }
      unsigned long long acc = 0ull;
      for (int i0 = 0; i0 < rows; i0 += 8){
        #pragma unroll
        for (int j = 0; j < 8; j++){
          int i = i0 + j;
          unsigned long long v = nb[cur][i*38 + lane];
          unsigned long long msk = (unsigned long long)0 - ((keep >> i) & 1ull);
          acc |= (v & msk);
        }
      }
      sup |= acc;
    }
    __syncthreads();
  }
  if (wv == 0 && lane < ADJW) supw[lane] = sup;
}

// ---------------- K7: compact ----------------
__global__ __launch_bounds__(256) void k_compact(
    const unsigned long long* __restrict__ supw, const int* __restrict__ order,
    const float* __restrict__ sb, int* __restrict__ nmsidx,
    float* __restrict__ kb, int* __restrict__ kint){
  __shared__ int csum[256];
  int tid = threadIdx.x;
  int p0 = tid*10;
  int keepf[10];
  int cnt = 0;
  #pragma unroll
  for (int d = 0; d < 10; d++){
    int p = p0 + d;
    int k = 0;
    if (p < BQ) k = !((supw[p >> 6] >> (p & 63)) & 1ull);
    keepf[d] = k; cnt += k;
  }
  csum[tid] = cnt; __syncthreads();
  for (int s = 1; s < 256; s <<= 1){
    int add = (tid >= s) ? csum[tid - s] : 0;
    __syncthreads();
    csum[tid] += add;
    __syncthreads();
  }
  int pos = csum[tid] - cnt;
  #pragma unroll
  for (int d = 0; d < 10; d++){
    if (keepf[d]){
      int p = p0 + d;
      nmsidx[pos] = order[p];
      ((float4*)kb)[pos] = ((const float4*)sb)[p];
      pos++;
    }
  }
  if (tid == 255) kint[0] = csum[255];
}

// ---------------- K8: per-kept-box scatter ----------------
__global__ __launch_bounds__(512) void k_gtsel(
    const float* __restrict__ kb, const float* __restrict__ tb,
    const int* __restrict__ nmsidx, const float* __restrict__ pl,
    const int* __restrict__ kint, float* __restrict__ gsel,
    float* __restrict__ oe){
  int k = blockIdx.x;
  if (k >= kint[0]) return;
  int tid = threadIdx.x;
  __shared__ float sv[512];
  __shared__ int   si[512];
  float4 a = ((const float4*)kb)[k];
  float iou = -INFINITY;
  if (tid < NN){
    float4 t = ((const float4*)tb)[tid];
    iou = iou_xyxy(a.x,a.y,a.z,a.w, t.x,t.y,t.z,t.w);
    if (iou != iou) iou = 0.f;
  }
  sv[tid] = iou; __syncthreads();
  for (int s = 256; s > 0; s >>= 1){ if (tid < s) sv[tid] = fmaxf(sv[tid], sv[tid+s]); __syncthreads(); }
  float m = sv[0]; __syncthreads();
  float e = (tid < NN) ? expf(iou - m) : 0.f;
  sv[tid] = e; __syncthreads();
  for (int s = 256; s > 0; s >>= 1){ if (tid < s) sv[tid] += sv[tid+s]; __syncthreads(); }
  float S = sv[0]; __syncthreads();
  uint32_t gk0, gk1; subkey(1, gk0, gk1);
  float y = (tid < NN) ? (e / S + gumbel32(gk0, gk1, (uint32_t)(k*NN + tid))) : -INFINITY;
  sv[tid] = y; si[tid] = tid; __syncthreads();
  for (int s = 256; s > 0; s >>= 1){
    if (tid < s){
      float ov = sv[tid+s]; int oi = si[tid+s];
      if (ov > sv[tid] || (ov == sv[tid] && oi < si[tid])){ sv[tid] = ov; si[tid] = oi; }
    }
    __syncthreads();
  }
  int sel = si[0];
  if (tid < 4) atomicAdd(&gsel[sel*4 + tid], ((const float*)&a)[tid]);
  if (tid < DD) atomicAdd(&oe[(size_t)sel*DD + tid], pl[(size_t)nmsidx[k]*DD + tid]);
}

// ---------------- K9: gt_ious + l1 ----------------
__global__ __launch_bounds__(512) void k_gtiou(
    const float* __restrict__ gsel, const float* __restrict__ tb,
    float* __restrict__ sc){
  int tid = threadIdx.x;
  __shared__ float s1[512], s2[512];
  float a1 = 0.f, a2 = 0.f;
  if (tid < NN){
    float4 g = ((const float4*)gsel)[tid];
    float4 t = ((const float4*)tb)[tid];
    float iou = iou_xyxy(g.x,g.y,g.z,g.w, t.x,t.y,t.z,t.w);
    a1 = 1.f - iou;
    a2 = fabsf(g.x-t.x) + fabsf(g.y-t.y) + fabsf(g.z-t.z) + fabsf(g.w-t.w);
  }
  s1[tid] = a1; s2[tid] = a2; __syncthreads();
  for (int s = 256; s > 0; s >>= 1){
    if (tid < s){ s1[tid] += s1[tid+s]; s2[tid] += s2[tid+s]; }
    __syncthreads();
  }
  if (tid == 0){ sc[3] = s1[0]; sc[4] = s2[0]; }
}

// ---------------- K10: M = tgt_embs @ out_embs^T ----------------
__global__ __launch_bounds__(256) void k_m(
    const float* __restrict__ te, const float* __restrict__ oe,
    float* __restrict__ M){
  int idx = blockIdx.x*256 + threadIdx.x;
  if (idx >= NN*NN) return;
  int i = idx / NN, j = idx % NN;
  const float4* a4 = (const float4*)(te + (size_t)i*DD);
  const float4* b4 = (const float4*)(oe + (size_t)j*DD);
  float s = 0.f;
  #pragma unroll 8
  for (int t = 0; t < DD/4; t++){
    float4 x = a4[t], y = b4[t];
    s += x.x*y.x + x.y*y.y + x.z*y.z + x.w*y.w;
  }
  M[idx] = s;
}

// ---------------- K11: both cross-entropies ----------------
__global__ __launch_bounds__(64) void k_ce(
    const float* __restrict__ M, float* __restrict__ sc){
  int i = blockIdx.x, lane = threadIdx.x;
  float m = -INFINITY;
  for (int j = lane; j < NN; j += 64) m = fmaxf(m, M[(size_t)i*NN + j]);
  for (int o = 32; o > 0; o >>= 1) m = fmaxf(m, __shfl_xor(m, o));
  float s = 0.f;
  for (int j = lane; j < NN; j += 64) s += expf(M[(size_t)i*NN + j] - m);
  for (int o = 32; o > 0; o >>= 1) s += __shfl_xor(s, o);
  float lr = m + logf(s);
  float m2 = -INFINITY;
  for (int j = lane; j < NN; j += 64) m2 = fmaxf(m2, M[(size_t)j*NN + i]);
  for (int o = 32; o > 0; o >>= 1) m2 = fmaxf(m2, __shfl_xor(m2, o));
  float s2 = 0.f;
  for (int j = lane; j < NN; j += 64) s2 += expf(M[(size_t)j*NN + i] - m2);
  for (int o = 32; o > 0; o >>= 1) s2 += __shfl_xor(s2, o);
  float lc = m2 + logf(s2);
  if (lane == 0){
    float d = M[(size_t)i*NN + i];
    atomicAdd(&sc[0], lr - d);
    atomicAdd(&sc[1], lc - d);
  }
}

// ---------------- K12: sel2 ----------------
__global__ __launch_bounds__(256) void k_sel2(
    const float* __restrict__ sims, int* __restrict__ sel2){
  int n = blockIdx.x, tid = threadIdx.x;
  uint32_t gk0, gk1; subkey(2, gk0, gk1);
  float best = -INFINITY; int bi = 0x7fffffff;
  for (int r = tid; r < BQ; r += 256){
    float v = sims[(size_t)r*SIMW + CC + n] + gumbel32(gk0, gk1, (uint32_t)(r*NN + n));
    if (v > best){ best = v; bi = r; }
  }
  __shared__ float sv[256];
  __shared__ int   si[256];
  sv[tid] = best; si[tid] = bi; __syncthreads();
  for (int s = 128; s > 0; s >>= 1){
    if (tid < s){
      float ov = sv[tid+s]; int oi = si[tid+s];
      if (ov > sv[tid] || (ov == sv[tid] && oi < si[tid])){ sv[tid] = ov; si[tid] = oi; }
    }
    __syncthreads();
  }
  if (tid == 0) sel2[n] = si[0];
}

// ---------------- K13: overall_mask_loss + masksum ----------------
__global__ __launch_bounds__(256) void k_om(
    const float* __restrict__ pm, const float* __restrict__ tm,
    const int* __restrict__ sel2, float* __restrict__ msum,
    float* __restrict__ sc){
  int nb = blockIdx.x;
  int n = nb / 9, ch = nb % 9;
  int c0 = ch*1024 + threadIdx.x*4;
  const float4 o4 = *(const float4*)(pm + (size_t)sel2[n]*WHX + c0);
  const float4 t4 = *(const float4*)(tm + (size_t)n*WHX + c0);
  float dx = o4.x-t4.x, dy = o4.y-t4.y, dz = o4.z-t4.z, dw = o4.w-t4.w;
  float d2 = dx*dx + dy*dy + dz*dz + dw*dw;
  float ts = t4.x + t4.y + t4.z + t4.w;
  __shared__ float r1[256], r2[256];
  r1[threadIdx.x] = d2; r2[threadIdx.x] = ts; __syncthreads();
  for (int s = 128; s > 0; s >>= 1){
    if (threadIdx.x < s){ r1[threadIdx.x] += r1[threadIdx.x+s]; r2[threadIdx.x] += r2[threadIdx.x+s]; }
    __syncthreads();
  }
  if (threadIdx.x == 0){ atomicAdd(&sc[2], r1[0]); atomicAdd(&msum[n], r2[0]); }
}

// ---------------- K14: sum_tgt[b] ----------------
__global__ __launch_bounds__(512) void k_sumtgt(
    const int* __restrict__ bidx, const float* __restrict__ rowsum,
    const float* __restrict__ msum, float* __restrict__ stgt){
  int n = threadIdx.x;
  if (n >= NN) return;
  atomicAdd(&stgt[bidx[n]], rowsum[n] * msum[n]);
}

// ---------------- T1: sims f32 -> simTb bf16 [8][304][320] (transpose) ----------------
__global__ __launch_bounds__(256) void t_simT(
    const float* __restrict__ sims, u16* __restrict__ simTb){
  __shared__ float ld[32][65];
  int q0 = blockIdx.x*32, c0 = blockIdx.y*64, b = blockIdx.z;
  int tid = threadIdx.x;
  for (int i = tid; i < 32*64; i += 256){
    int qi = i >> 6, ci = i & 63;
    int q = q0 + qi, c = c0 + ci;
    ld[qi][ci] = (q < QQ && c < CC) ? sims[((size_t)b*QQ + q)*SIMW + c] : 0.f;
  }
  __syncthreads();
  int cloc = tid >> 2, j0 = (tid & 3)*8;
  int c = c0 + cloc;
  if (c < CP){
    u16 tmp[8];
    #pragma unroll
    for (int j = 0; j < 8; j++) tmp[j] = f2bf(ld[j0+j][cloc]);
    *(uint4*)(simTb + ((size_t)b*CP + c)*QP + q0 + j0) = *(const uint4*)tmp;
  }
}

// ---------------- T2: omT bf16 [9216][320] = pm[sel2[q]][wh]/96 (transpose) ----------------
__global__ __launch_bounds__(256) void t_omT(
    const float* __restrict__ pm, const int* __restrict__ sel2,
    u16* __restrict__ omT){
  __shared__ float ld[32][65];
  int q0 = blockIdx.x*32, wh0 = blockIdx.y*64;
  int tid = threadIdx.x;
  for (int i = tid; i < 32*64; i += 256){
    int qi = i >> 6, wi = i & 63;
    int q = q0 + qi;
    ld[qi][wi] = (q < QQ) ? pm[(size_t)sel2[q]*WHX + wh0 + wi] * (1.0f/96.0f) : 0.f;
  }
  __syncthreads();
  int wloc = tid >> 2, j0 = (tid & 3)*8;
  u16 tmp[8];
  #pragma unroll
  for (int j = 0; j < 8; j++) tmp[j] = f2bf(ld[j0+j][wloc]);
  *(uint4*)(omT + (size_t)(wh0+wloc)*QP + q0 + j0) = *(const uint4*)tmp;
}

// ---------------- T3: tmT bf16 [9216][416] (transpose, zero-padded) ----------------
__global__ __launch_bounds__(256) void t_tmT(
    const float* __restrict__ tm, u16* __restrict__ tmT){
  __shared__ float ld[32][65];
  int n0 = blockIdx.x*32, wh0 = blockIdx.y*64;
  int tid = threadIdx.x;
  for (int i = tid; i < 32*64; i += 256){
    int ni = i >> 6, wi = i & 63;
    int n = n0 + ni;
    ld[ni][wi] = (n < NN) ? tm[(size_t)n*WHX + wh0 + wi] : 0.f;
  }
  __syncthreads();
  int wloc = tid >> 2, j0 = (tid & 3)*8;
  u16 tmp[8];
  #pragma unroll
  for (int j = 0; j < 8; j++) tmp[j] = f2bf(ld[j0+j][wloc]);
  *(uint4*)(tmT + (size_t)(wh0+wloc)*NP + n0 + j0) = *(const uint4*)tmp;
}

// ---------------- T4: gtsimP bf16 [8][304][96] (per-batch zero-padded window) ----------------
__global__ __launch_bounds__(256) void t_gtp(
    const float* __restrict__ gtsim, const int* __restrict__ bstart,
    u16* __restrict__ gtp){
  int g = blockIdx.x*256 + threadIdx.x;
  if (g >= BB*CP*(KP/8)) return;
  int b = g / (CP*(KP/8));
  int rem = g - b*CP*(KP/8);
  int c = rem / (KP/8);
  int kg = rem % (KP/8);
  int n0 = bstart[b], n1 = bstart[b+1];
  int kst = n0 & ~7;
  u16 tmp[8];
  #pragma unroll
  for (int j = 0; j < 8; j++){
    int n = kst + kg*8 + j;
    float v = (n >= n0 && n < n1 && c < CC) ? gtsim[(size_t)n*CC + c] : 0.f;
    tmp[j] = f2bf(v);
  }
  *(uint4*)(gtp + ((size_t)b*CP + c)*KP + kg*8) = *(const uint4*)tmp;
}

// ---------------- K15: MFMA z-GEMM + column softmax + dice (LDS-staged A, XCD-pinned) ----------------
// grid: 1152 1D blocks; b = bid & 7 (XCD-pin), tile = bid >> 3.
// A-chunk [304][32] bf16 staged in LDS (pad stride 34), reg-prefetched one ks ahead.
constexpr int ASTR = 34;  // padded LDS row stride (bf16 units)
__global__ __launch_bounds__(256) void k_zsoft(
    const u16* __restrict__ simTb, const u16* __restrict__ omT,
    const u16* __restrict__ gtp, const u16* __restrict__ tmT,
    const int* __restrict__ bstart, float* __restrict__ sc){
  const int bid = blockIdx.x;
  const int b = bid & 7;
  const int tile = bid >> 3;
  const int tid = threadIdx.x;
  const int w = tid >> 6, l = tid & 63;
  const int lrow = l & 15, lgrp = l >> 4;
  const int col = tile*64 + w*16 + lrow;

  __shared__ u16 As[CP*ASTR];       // 20672 B
  __shared__ float red[256];

  const u16* Ab = simTb + (size_t)b*CP*QP;
  const int sidx[5] = {tid, tid+256, tid+512, tid+768, tid+1024};

  // prefetch chunk 0 into regs
  uint4 pf0, pf1, pf2, pf3, pf4;
  {
    int r, g;
    r = sidx[0] >> 2; g = sidx[0] & 3; pf0 = *(const uint4*)(Ab + (size_t)r*QP + g*8);
    r = sidx[1] >> 2; g = sidx[1] & 3; pf1 = *(const uint4*)(Ab + (size_t)r*QP + g*8);
    r = sidx[2] >> 2; g = sidx[2] & 3; pf2 = *(const uint4*)(Ab + (size_t)r*QP + g*8);
    r = sidx[3] >> 2; g = sidx[3] & 3; pf3 = *(const uint4*)(Ab + (size_t)r*QP + g*8);
    if (sidx[4] < 1216){ r = sidx[4] >> 2; g = sidx[4] & 3; pf4 = *(const uint4*)(Ab + (size_t)r*QP + g*8); }
  }
  const u16* pB = omT + (size_t)col*QP;
  bf16x8 bcur = *(const bf16x8*)(pB);

  f32x4 acc[19];
  #pragma unroll
  for (int t = 0; t < 19; t++) acc[t] = (f32x4){0.f,0.f,0.f,0.f};

  for (int ks = 0; ks < 10; ks++){
    // write staged regs to LDS
    {
      int r, g;
      r = sidx[0] >> 2; g = sidx[0] & 3; *(uint4*)&As[r*ASTR + g*8] = pf0;
      r = sidx[1] >> 2; g = sidx[1] & 3; *(uint4*)&As[r*ASTR + g*8] = pf1;
      r = sidx[2] >> 2; g = sidx[2] & 3; *(uint4*)&As[r*ASTR + g*8] = pf2;
      r = sidx[3] >> 2; g = sidx[3] & 3; *(uint4*)&As[r*ASTR + g*8] = pf3;
      if (sidx[4] < 1216){ r = sidx[4] >> 2; g = sidx[4] & 3; *(uint4*)&As[r*ASTR + g*8] = pf4; }
    }
    __syncthreads();
    // prefetch next chunk + next B column segment (overlaps MFMA below)
    bf16x8 bnext;
    if (ks + 1 < 10){
      const size_t ko = (size_t)(ks + 1) * 32;
      int r, g;
      r = sidx[0] >> 2; g = sidx[0] & 3; pf0 = *(const uint4*)(Ab + (size_t)r*QP + ko + g*8);
      r = sidx[1] >> 2; g = sidx[1] & 3; pf1 = *(const uint4*)(Ab + (size_t)r*QP + ko + g*8);
      r = sidx[2] >> 2; g = sidx[2] & 3; pf2 = *(const uint4*)(Ab + (size_t)r*QP + ko + g*8);
      r = sidx[3] >> 2; g = sidx[3] & 3; pf3 = *(const uint4*)(Ab + (size_t)r*QP + ko + g*8);
      if (sidx[4] < 1216){ r = sidx[4] >> 2; g = sidx[4] & 3; pf4 = *(const uint4*)(Ab + (size_t)r*QP + ko + g*8); }
      bnext = *(const bf16x8*)(pB + ko);
    }
    #pragma unroll
    for (int t = 0; t < 19; t++){
      bf16x8 af = *(const bf16x8*)&As[(t*16 + lrow)*ASTR + lgrp*8];
      acc[t] = __builtin_amdgcn_mfma_f32_16x16x32_bf16(af, bcur, acc[t], 0, 0, 0);
    }
    bcur = bnext;
    __syncthreads();
  }

  // column softmax over c (padding rows 300..303: t==18 && lgrp==3)
  float lmax = -INFINITY;
  #pragma unroll
  for (int t = 0; t < 19; t++){
    if (t == 18 && lgrp == 3) continue;
    lmax = fmaxf(lmax, fmaxf(fmaxf(acc[t][0], acc[t][1]), fmaxf(acc[t][2], acc[t][3])));
  }
  lmax = fmaxf(lmax, __shfl_xor(lmax, 16));
  lmax = fmaxf(lmax, __shfl_xor(lmax, 32));
  float ls = 0.f;
  #pragma unroll
  for (int t = 0; t < 19; t++){
    if (t == 18 && lgrp == 3){
      acc[t] = (f32x4){0.f,0.f,0.f,0.f};
      continue;
    }
    float p0 = __expf(acc[t][0] - lmax);
    float p1 = __expf(acc[t][1] - lmax);
    float p2 = __expf(acc[t][2] - lmax);
    float p3 = __expf(acc[t][3] - lmax);
    acc[t][0] = p0; acc[t][1] = p1; acc[t][2] = p2; acc[t][3] = p3;
    ls += p0 + p1 + p2 + p3;
  }
  float S = ls;
  S += __shfl_xor(S, 16);
  S += __shfl_xor(S, 32);
  float inv = 1.f / S;

  // dice: R[c][wh] = sum_n gtsim[n][c] tm[n][wh] via MFMA in same D-layout
  int n0 = bstart[b];
  int kst = n0 & ~7;
  const u16* tB = tmT + (size_t)col*NP + kst + lgrp*8;
  bf16x8 b2a = *(const bf16x8*)(tB);
  bf16x8 b2b = *(const bf16x8*)(tB + 32);
  bf16x8 b2c = *(const bf16x8*)(tB + 64);
  const u16* A2 = gtp + (size_t)b*CP*KP + lgrp*8;
  float dl = 0.f;
  #pragma unroll
  for (int t = 0; t < 19; t++){
    const u16* ar = A2 + (size_t)(t*16 + lrow)*KP;
    f32x4 rr = (f32x4){0.f,0.f,0.f,0.f};
    rr = __builtin_amdgcn_mfma_f32_16x16x32_bf16(*(const bf16x8*)(ar),      b2a, rr, 0, 0, 0);
    rr = __builtin_amdgcn_mfma_f32_16x16x32_bf16(*(const bf16x8*)(ar + 32), b2b, rr, 0, 0, 0);
    rr = __builtin_amdgcn_mfma_f32_16x16x32_bf16(*(const bf16x8*)(ar + 64), b2c, rr, 0, 0, 0);
    dl += acc[t][0]*rr[0] + acc[t][1]*rr[1] + acc[t][2]*rr[2] + acc[t][3]*rr[3];
  }
  dl *= inv;

  red[tid] = dl; __syncthreads();
  for (int s = 128; s > 0; s >>= 1){
    if (tid < s) red[tid] += red[tid+s];
    __syncthreads();
  }
  if (tid == 0) atomicAdd(&sc[5], red[0]);
}

// ---------------- K16: finalize ----------------
__global__ __launch_bounds__(64) void k_final(
    const float* __restrict__ sc, const float* __restrict__ stgt,
    const int* __restrict__ kint, float* __restrict__ out){
  if (threadIdx.x != 0) return;
  float K = (float)kint[0];
  float cls = sc[0]/300.f + sc[1]/300.f;
  float stot = sc[5];
  float dice = 0.f;
  for (int b = 0; b < 8; b++) dice += stot / (9216.0f + stgt[b] + 1e-6f);
  dice *= (1.0f/8.0f);
  out[0] = cls;
  out[1] = dice;
  out[2] = (sc[2] / 2764800.0f) / K;
  out[3] = sc[3] / K;
  out[4] = sc[4] / K;
}

// ---------------- launch ----------------
extern "C" void kernel_launch(void* const* d_in, const int* in_sizes, int n_in,
                              void* d_out, int out_size, void* d_ws, size_t ws_size,
                              hipStream_t stream) {
  const float* ce  = (const float*)d_in[0];
  const float* pl  = (const float*)d_in[1];
  const float* pb  = (const float*)d_in[2];
  const float* pm  = (const float*)d_in[3];
  const float* tm  = (const float*)d_in[4];
  const float* te  = (const float*)d_in[5];
  const float* tbb = (const float*)d_in[6];
  const int*  tids = (const int*)d_in[8];
  const int*  bidx = (const int*)d_in[9];
  float* out = (float*)d_out;
  float* w = (float*)d_ws;

  if (ws_size < F_TOTAL * sizeof(float)) return;

  float* SIMS   = w + F_SIMS;
  float* GTSIM  = w + F_GTSIM;
  float* MM     = w + F_MM;
  float* SCORE  = w + F_SCORE;
  float* BBOX   = w + F_BBOX;
  float* TBOX   = w + F_TB;
  float* SB     = w + F_SB;
  float* SAREA  = w + F_SAREA;
  float* KB     = w + F_KB;
  float* ROWSUM = w + F_ROWSUM;
  float* OE     = w + F_OE;
  float* GSEL   = w + F_GSEL;
  float* MSUM   = w + F_MSUM;
  float* STGT   = w + F_STGT;
  float* SC     = w + F_SC;
  int*   ORDER  = (int*)(w + F_ORDER);
  int*   NMSIDX = (int*)(w + F_NMSIDX);
  int*   SEL2   = (int*)(w + F_SEL2);
  int*   BSTART = (int*)(w + F_BSTART);
  int*   KINT   = (int*)(w + F_KINT);
  unsigned long long* ADJ  = (unsigned long long*)(w + F_ADJ);
  unsigned long long* SUPW = (unsigned long long*)(w + F_SUPW);
  u16* SIMTB = (u16*)(w + F_SIMTB);
  u16* OMT   = (u16*)(w + F_OMT);
  u16* TMT   = (u16*)(w + F_TMT);
  u16* GTP   = (u16*)(w + F_GTP);

  hipMemsetAsync(w + F_OE, 0, (F_ACCEND - F_OE) * sizeof(float), stream);

  k_gemm_t<<<dim3(22, 5), 256, 0, stream>>>(pl, ce, te, SIMS, GTSIM);
  k_post<<<BQ, 512, 0, stream>>>(SIMS, pb, tbb, tids, bidx, GTSIM, SCORE, BBOX, TBOX, ROWSUM);
  k_rank<<<(BQ + 255)/256, 256, 0, stream>>>(SCORE, ORDER);
  k_gather<<<(BQ + 255)/256, 256, 0, stream>>>(BBOX, ORDER, bidx, SB, SAREA, BSTART);
  k_adj<<<BQ, 256, 0, stream>>>(SB, SAREA, ADJ);
  k_nms<<<1, 256, 0, stream>>>(ADJ, SUPW);
  k_compact<<<1, 256, 0, stream>>>(SUPW, ORDER, SB, NMSIDX, KB, KINT);
  k_gtsel<<<BQ, 512, 0, stream>>>(KB, TBOX, NMSIDX, pl, KINT, GSEL, OE);
  k_gtiou<<<1, 512, 0, stream>>>(GSEL, TBOX, SC);
  k_m<<<(NN*NN + 255)/256, 256, 0, stream>>>(te, OE, MM);
  k_ce<<<NN, 64, 0, stream>>>(MM, SC);
  k_sel2<<<NN, 256, 0, stream>>>(SIMS, SEL2);
  k_om<<<NN*9, 256, 0, stream>>>(pm, tm, SEL2, MSUM, SC);
  k_sumtgt<<<1, 512, 0, stream>>>(bidx, ROWSUM, MSUM, STGT);

  t_simT<<<dim3(QP/32, 5, BB), 256, 0, stream>>>(SIMS, SIMTB);
  t_omT<<<dim3(QP/32, WHX/64), 256, 0, stream>>>(pm, SEL2, OMT);
  t_tmT<<<dim3(NP/32, WHX/64), 256, 0, stream>>>(tm, TMT);
  t_gtp<<<(BB*CP*(KP/8) + 255)/256, 256, 0, stream>>>(GTSIM, BSTART, GTP);

  k_zsoft<<<dim3(WHX/64 * BB), 256, 0, stream>>>(SIMTB, OMT, GTP, TMT, BSTART, SC);
  k_final<<<1, 64, 0, stream>>>(SC, STGT, KINT, out);
}

// Round 6
// 364.949 us; speedup vs baseline: 5.5912x; 1.3463x over previous
//
#include <hip/hip_runtime.h>
#include <stdint.h>

#define DEVFN __device__ __forceinline__

typedef unsigned short u16;
typedef short bf16x8 __attribute__((ext_vector_type(8)));
typedef float f32x4 __attribute__((ext_vector_type(4)));

constexpr int BB = 8, QQ = 300, CC = 300, NN = 300, DD = 256;
constexpr int WHX = 9216, BQ = 2400, SIMW = 600;
constexpr int QP = 320;   // padded Q for MFMA K-dim
constexpr int CP = 304;   // padded C rows
constexpr int KP = 96;    // per-batch n-window
constexpr int NP = 416;   // padded tmT n-dim
constexpr int CELLCAP = 300;

// ---------------- workspace layout (float units) ----------------
constexpr size_t F_SIMS   = 0;                                 // [2400][600]
constexpr size_t F_GTSIM  = F_SIMS   + (size_t)BQ*SIMW;        // [300][300]
constexpr size_t F_MM     = F_GTSIM  + (size_t)NN*CC;          // [300][300]
constexpr size_t F_SCORE  = F_MM     + (size_t)NN*NN;          // [2400]
constexpr size_t F_BBOX   = F_SCORE  + BQ;                     // [2400][4]
constexpr size_t F_TB     = F_BBOX   + (size_t)BQ*4;           // [300][4]
constexpr size_t F_SB     = F_TB     + (size_t)NN*4;           // [2400][4]
constexpr size_t F_SAREA  = F_SB     + (size_t)BQ*4;           // [2400]
constexpr size_t F_KB     = F_SAREA  + BQ;                     // [2400][4]
constexpr size_t F_ROWSUM = F_KB     + (size_t)BQ*4;           // [300]
constexpr size_t F_OE     = F_ROWSUM + NN;                     // ---- zeroed zone
constexpr size_t F_GSEL   = F_OE     + (size_t)NN*DD;          // [300][4]
constexpr size_t F_MSUM   = F_GSEL   + (size_t)NN*4;           // [300]
constexpr size_t F_STGT   = F_MSUM   + NN;                     // [8]
constexpr size_t F_SC     = F_STGT   + 8;                      // scalars
constexpr size_t F_CNT    = F_SC     + 16;                     // int [2400] cell counts (zeroed)
constexpr size_t F_ACCEND = F_CNT    + BQ;                     // ---- end zeroed zone
constexpr size_t F_ORDER  = F_ACCEND;                          // int [2400]
constexpr size_t F_NMSIDX = F_ORDER  + BQ;                     // int [2400]
constexpr size_t F_SEL2   = F_NMSIDX + BQ;                     // int [300]
constexpr size_t F_BSTART = F_SEL2   + NN;                     // int [16]
constexpr size_t F_KINT   = F_BSTART + 16;                     // int [4]
constexpr size_t F_CLS    = F_KINT   + 4;                      // int [2400]
constexpr size_t F_KEEPF  = F_CLS    + BQ;                     // int [2400]
constexpr size_t F_LIST   = F_KEEPF  + BQ;                     // int [2400][300]
// bf16 panels (sizes in floats = ushorts/2), 32B-align starts
constexpr size_t F_SIMTB  = ((F_LIST + (size_t)BQ*CELLCAP + 7) & ~(size_t)7);  // u16[8][304][320]
constexpr size_t F_OMT    = F_SIMTB + (size_t)BB*CP*QP/2;           // u16[9216][320]
constexpr size_t F_TMT    = F_OMT   + (size_t)WHX*QP/2;             // u16[9216][416]
constexpr size_t F_GTP    = F_TMT   + (size_t)WHX*NP/2;             // u16[8][304][96]
constexpr size_t F_TOTAL  = F_GTP   + (size_t)BB*CP*KP/2;

// ---------------- JAX threefry2x32 (partitionable scheme) ----------------
DEVFN uint32_t rotl32(uint32_t v, int r){ return (v << r) | (v >> (32 - r)); }

DEVFN void tf2x32(uint32_t k0, uint32_t k1, uint32_t x0, uint32_t x1,
                  uint32_t& o0, uint32_t& o1){
  uint32_t ks2 = k0 ^ k1 ^ 0x1BD11BDAu;
  x0 += k0; x1 += k1;
#define TFR(r) x0 += x1; x1 = rotl32(x1, r); x1 ^= x0;
  TFR(13) TFR(15) TFR(26) TFR(6)   x0 += k1;  x1 += ks2 + 1u;
  TFR(17) TFR(29) TFR(16) TFR(24)  x0 += ks2; x1 += k0  + 2u;
  TFR(13) TFR(15) TFR(26) TFR(6)   x0 += k0;  x1 += k1  + 3u;
  TFR(17) TFR(29) TFR(16) TFR(24)  x0 += k1;  x1 += ks2 + 4u;
  TFR(13) TFR(15) TFR(26) TFR(6)   x0 += ks2; x1 += k0  + 5u;
#undef TFR
  o0 = x0; o1 = x1;
}

DEVFN void subkey(int i, uint32_t& k0, uint32_t& k1){
  tf2x32(0u, 42u, 0u, (uint32_t)i, k0, k1);
}

DEVFN float gumbel32(uint32_t k0, uint32_t k1, uint32_t idx){
  uint32_t h, l; tf2x32(k0, k1, 0u, idx, h, l);
  uint32_t bits = h ^ l;
  float f = __uint_as_float((bits >> 9) | 0x3F800000u) - 1.0f;
  const float tiny = 1.17549435e-38f;
  float u = fmaxf(tiny, f + tiny);
  return -logf(-logf(u));
}

DEVFN float iou_xyxy(float ax1,float ay1,float ax2,float ay2,
                     float bx1,float by1,float bx2,float by2){
  float aa = (ax2-ax1)*(ay2-ay1);
  float ab = (bx2-bx1)*(by2-by1);
  float lx = fmaxf(ax1,bx1), ly = fmaxf(ay1,by1);
  float rx = fminf(ax2,bx2), ry = fminf(ay2,by2);
  float iw = fmaxf(rx-lx,0.f), ih = fmaxf(ry-ly,0.f);
  float in_ = iw*ih;
  return in_/(aa+ab-in_);
}

DEVFN u16 f2bf(float x){
  uint32_t u = __float_as_uint(x);
  uint32_t r = u + 0x7FFFu + ((u >> 16) & 1u);
  return (u16)(r >> 16);
}

// ---------------- K1: tiled f32 GEMM: [pl;te](2700x256) x [ce;te]^T(256x600) ----------------
__global__ __launch_bounds__(256) void k_gemm_t(
    const float* __restrict__ pl, const float* __restrict__ ce,
    const float* __restrict__ te, float* __restrict__ sims,
    float* __restrict__ gtsim){
  __shared__ float As[16][128];
  __shared__ float Bs[16][128];
  const int row0 = blockIdx.x * 128, col0 = blockIdx.y * 128;
  const int tid = threadIdx.x;
  const int lrow = tid >> 1, lk0 = (tid & 1) * 8;
  const int tr = tid >> 4, tc = tid & 15;

  float acc[8][8];
  #pragma unroll
  for (int i = 0; i < 8; i++)
    #pragma unroll
    for (int j = 0; j < 8; j++) acc[i][j] = 0.f;

  const float4 z4 = {0.f,0.f,0.f,0.f};
  const int grow = row0 + lrow;
  const int gcol = col0 + lrow;
  const float* arow = nullptr;
  if (grow < 2400) arow = pl + (size_t)grow * DD;
  else if (grow < 2700) arow = te + (size_t)(grow - 2400) * DD;
  const float* brow = nullptr;
  if (gcol < 300) brow = ce + (size_t)gcol * DD;
  else if (gcol < 600) brow = te + (size_t)(gcol - 300) * DD;

  float4 av0 = arow ? *(const float4*)(arow + lk0)     : z4;
  float4 av1 = arow ? *(const float4*)(arow + lk0 + 4) : z4;
  float4 bv0 = brow ? *(const float4*)(brow + lk0)     : z4;
  float4 bv1 = brow ? *(const float4*)(brow + lk0 + 4) : z4;

  for (int step = 0; step < 16; step++){
    __syncthreads();
    #pragma unroll
    for (int j = 0; j < 4; j++){
      As[lk0 + j][lrow]     = ((const float*)&av0)[j];
      As[lk0 + 4 + j][lrow] = ((const float*)&av1)[j];
      Bs[lk0 + j][lrow]     = ((const float*)&bv0)[j];
      Bs[lk0 + 4 + j][lrow] = ((const float*)&bv1)[j];
    }
    __syncthreads();
    if (step + 1 < 16){
      const int k0 = (step + 1) * 16;
      av0 = arow ? *(const float4*)(arow + k0 + lk0)     : z4;
      av1 = arow ? *(const float4*)(arow + k0 + lk0 + 4) : z4;
      bv0 = brow ? *(const float4*)(brow + k0 + lk0)     : z4;
      bv1 = brow ? *(const float4*)(brow + k0 + lk0 + 4) : z4;
    }
    #pragma unroll
    for (int kk = 0; kk < 16; kk++){
      float4 a0 = *(const float4*)&As[kk][tr*8];
      float4 a1 = *(const float4*)&As[kk][tr*8 + 4];
      float4 b0 = *(const float4*)&Bs[kk][tc*8];
      float4 b1 = *(const float4*)&Bs[kk][tc*8 + 4];
      float a[8] = {a0.x,a0.y,a0.z,a0.w,a1.x,a1.y,a1.z,a1.w};
      float b[8] = {b0.x,b0.y,b0.z,b0.w,b1.x,b1.y,b1.z,b1.w};
      #pragma unroll
      for (int i = 0; i < 8; i++)
        #pragma unroll
        for (int j = 0; j < 8; j++)
          acc[i][j] = fmaf(a[i], b[j], acc[i][j]);
    }
  }

  #pragma unroll
  for (int i = 0; i < 8; i++){
    const int r = row0 + tr*8 + i;
    const int c0 = col0 + tc*8;
    if (r < 2400){
      if (c0 < 600){
        float4 o0 = {acc[i][0],acc[i][1],acc[i][2],acc[i][3]};
        float4 o1 = {acc[i][4],acc[i][5],acc[i][6],acc[i][7]};
        *(float4*)(sims + (size_t)r*SIMW + c0)     = o0;
        *(float4*)(sims + (size_t)r*SIMW + c0 + 4) = o1;
      }
    } else if (r < 2700){
      const int n = r - 2400;
      #pragma unroll
      for (int j = 0; j < 8; j++){
        int c = c0 + j;
        if (c < 300) gtsim[(size_t)n*CC + c] = acc[i][j];
      }
    }
  }
}

// ---------------- K2: per-bq scores/argmax(g0)/boxes/cls; tb rows; gtsim rowsums ----------------
__global__ __launch_bounds__(512) void k_post(
    const float* __restrict__ sims, const float* __restrict__ pb,
    const float* __restrict__ tbb, const int* __restrict__ tids,
    const int* __restrict__ bidx, const float* __restrict__ gtsim,
    float* __restrict__ score, float* __restrict__ bbox,
    float* __restrict__ tb, float* __restrict__ rowsum,
    int* __restrict__ clsout){
  int bq = blockIdx.x, tid = threadIdx.x;
  __shared__ float sv[512];
  __shared__ int   si[512];
  float v = (tid < CC) ? sims[(size_t)bq*SIMW + tid] : -INFINITY;
  sv[tid] = v; __syncthreads();
  for (int s = 256; s > 0; s >>= 1){ if (tid < s) sv[tid] = fmaxf(sv[tid], sv[tid+s]); __syncthreads(); }
  if (tid == 0) score[bq] = sv[0];
  __syncthreads();
  uint32_t gk0, gk1; subkey(0, gk0, gk1);
  float y = (tid < CC) ? v + gumbel32(gk0, gk1, (uint32_t)(bq*CC + tid)) : -INFINITY;
  sv[tid] = y; si[tid] = tid; __syncthreads();
  for (int s = 256; s > 0; s >>= 1){
    if (tid < s){
      float ov = sv[tid+s]; int oi = si[tid+s];
      if (ov > sv[tid] || (ov == sv[tid] && oi < si[tid])){ sv[tid] = ov; si[tid] = oi; }
    }
    __syncthreads();
  }
  if (tid == 0){
    int cls = si[0];
    clsout[bq] = cls;
    float ox = 224.0f * (float)cls;
    float oy = 224.0f * (float)(bq / QQ);
    float cx = pb[bq*4+0], cy = pb[bq*4+1], ww = pb[bq*4+2], hh = pb[bq*4+3];
    bbox[bq*4+0] = cx - 0.5f*ww + ox;
    bbox[bq*4+1] = cy - 0.5f*hh + oy;
    bbox[bq*4+2] = cx + 0.5f*ww + ox;
    bbox[bq*4+3] = cy + 0.5f*hh + oy;
  }
  if (bq < NN){
    __syncthreads();
    float rs = (tid < CC) ? gtsim[(size_t)bq*CC + tid] : 0.f;
    sv[tid] = rs; __syncthreads();
    for (int s = 256; s > 0; s >>= 1){ if (tid < s) sv[tid] += sv[tid+s]; __syncthreads(); }
    if (tid == 0) rowsum[bq] = sv[0];
    if (tid == 1){
      float gx = 224.0f * (float)tids[bq], gy = 224.0f * (float)bidx[bq];
      float cx = tbb[bq*4+0], cy = tbb[bq*4+1], ww = tbb[bq*4+2], hh = tbb[bq*4+3];
      tb[bq*4+0] = cx - 0.5f*ww + gx;
      tb[bq*4+1] = cy - 0.5f*hh + gy;
      tb[bq*4+2] = cx + 0.5f*ww + gx;
      tb[bq*4+3] = cy + 0.5f*hh + gy;
    }
  }
}

// ---------------- K3: stable descending rank sort ----------------
__global__ __launch_bounds__(256) void k_rank(
    const float* __restrict__ score, int* __restrict__ order){
  __shared__ float s[BQ];
  int tid = threadIdx.x;
  for (int i = tid; i < BQ; i += 256) s[i] = score[i];
  __syncthreads();
  int t = blockIdx.x*256 + tid;
  if (t >= BQ) return;
  float st = s[t];
  int cnt = 0;
  for (int j = 0; j < BQ; j++){
    float sj = s[j];
    cnt += (sj > st) || (sj == st && j < t);
  }
  order[cnt] = t;
}

// ---------------- K4: gather sorted boxes/areas + batch starts + cell bucketing ----------------
__global__ __launch_bounds__(256) void k_gather(
    const float* __restrict__ bbox, const int* __restrict__ order,
    const int* __restrict__ bidx, const int* __restrict__ cls,
    float* __restrict__ sb, float* __restrict__ sarea,
    int* __restrict__ bstart, int* __restrict__ cnt,
    int* __restrict__ list){
  int t = blockIdx.x*256 + threadIdx.x;
  if (t < BQ){
    int o = order[t];
    float x1 = bbox[o*4+0], y1 = bbox[o*4+1], x2 = bbox[o*4+2], y2 = bbox[o*4+3];
    sb[t*4+0] = x1; sb[t*4+1] = y1; sb[t*4+2] = x2; sb[t*4+3] = y2;
    sarea[t] = (x2-x1)*(y2-y1);
    // bucket by (batch, argmax class) cell — cross-cell IoU is identically 0 (offsets >= 224)
    int key = (o / QQ) * CC + cls[o];
    int slot = atomicAdd(&cnt[key], 1);
    list[(size_t)key*CELLCAP + slot] = t;
  }
  if (blockIdx.x == 0 && threadIdx.x < 9){
    int b = threadIdx.x, c = 0;
    for (int n = 0; n < NN; n++) c += (bidx[n] < b);
    bstart[b] = c;
  }
}

// ---------------- K6': per-cell greedy NMS (one thread per (batch,class) cell) ----------------
__global__ __launch_bounds__(256) void k_cellnms(
    const float* __restrict__ sb, const int* __restrict__ cnt,
    const int* __restrict__ list, int* __restrict__ keepf){
  int key = blockIdx.x*256 + threadIdx.x;
  if (key >= BB*CC) return;
  int m = cnt[key];
  if (m <= 0) return;
  const int* lst = list + (size_t)key*CELLCAP;
  unsigned long long keptmask = 0ull;   // kept flags by cell-rank (m<=64 fast path)
  int prevp = -1;
  for (int a = 0; a < m; a++){
    // a-th smallest sorted-position in this cell
    int pa = 0x7fffffff;
    for (int j = 0; j < m; j++){
      int pj = lst[j];
      if (pj > prevp && pj < pa) pa = pj;
    }
    prevp = pa;
    float4 A = ((const float4*)sb)[pa];
    float areaA = (A.z-A.x)*(A.w-A.y);
    bool kept = true;
    int pbprev = -1;
    for (int b2 = 0; b2 < a; b2++){
      int pb = 0x7fffffff;
      for (int j = 0; j < m; j++){
        int pj = lst[j];
        if (pj > pbprev && pj < pb) pb = pj;
      }
      pbprev = pb;
      bool keptb = (m <= 64) ? (((keptmask >> b2) & 1ull) != 0ull) : (keepf[pb] != 0);
      if (!keptb) continue;
      float4 B = ((const float4*)sb)[pb];
      float areaB = (B.z-B.x)*(B.w-B.y);
      float lx = fmaxf(A.x,B.x), ly = fmaxf(A.y,B.y);
      float rx = fminf(A.z,B.z), ry = fminf(A.w,B.w);
      float iw = fmaxf(rx-lx,0.f), ih = fmaxf(ry-ly,0.f);
      float inter = iw*ih;
      if (inter/(areaA + areaB - inter) > 0.5f){ kept = false; break; }
    }
    if (m <= 64 && kept) keptmask |= (1ull << a);
    keepf[pa] = kept ? 1 : 0;
  }
}

// ---------------- K7: compact ----------------
__global__ __launch_bounds__(256) void k_compact(
    const int* __restrict__ keepflag, const int* __restrict__ order,
    const float* __restrict__ sb, int* __restrict__ nmsidx,
    float* __restrict__ kb, int* __restrict__ kint){
  __shared__ int csum[256];
  int tid = threadIdx.x;
  int p0 = tid*10;
  int keepf[10];
  int cnt = 0;
  #pragma unroll
  for (int d = 0; d < 10; d++){
    int p = p0 + d;
    int k = 0;
    if (p < BQ) k = keepflag[p];
    keepf[d] = k; cnt += k;
  }
  csum[tid] = cnt; __syncthreads();
  for (int s = 1; s < 256; s <<= 1){
    int add = (tid >= s) ? csum[tid - s] : 0;
    __syncthreads();
    csum[tid] += add;
    __syncthreads();
  }
  int pos = csum[tid] - cnt;
  #pragma unroll
  for (int d = 0; d < 10; d++){
    if (keepf[d]){
      int p = p0 + d;
      nmsidx[pos] = order[p];
      ((float4*)kb)[pos] = ((const float4*)sb)[p];
      pos++;
    }
  }
  if (tid == 255) kint[0] = csum[255];
}

// ---------------- K8: per-kept-box scatter ----------------
__global__ __launch_bounds__(512) void k_gtsel(
    const float* __restrict__ kb, const float* __restrict__ tb,
    const int* __restrict__ nmsidx, const float* __restrict__ pl,
    const int* __restrict__ kint, float* __restrict__ gsel,
    float* __restrict__ oe){
  int k = blockIdx.x;
  if (k >= kint[0]) return;
  int tid = threadIdx.x;
  __shared__ float sv[512];
  __shared__ int   si[512];
  float4 a = ((const float4*)kb)[k];
  float iou = -INFINITY;
  if (tid < NN){
    float4 t = ((const float4*)tb)[tid];
    iou = iou_xyxy(a.x,a.y,a.z,a.w, t.x,t.y,t.z,t.w);
    if (iou != iou) iou = 0.f;
  }
  sv[tid] = iou; __syncthreads();
  for (int s = 256; s > 0; s >>= 1){ if (tid < s) sv[tid] = fmaxf(sv[tid], sv[tid+s]); __syncthreads(); }
  float m = sv[0]; __syncthreads();
  float e = (tid < NN) ? expf(iou - m) : 0.f;
  sv[tid] = e; __syncthreads();
  for (int s = 256; s > 0; s >>= 1){ if (tid < s) sv[tid] += sv[tid+s]; __syncthreads(); }
  float S = sv[0]; __syncthreads();
  uint32_t gk0, gk1; subkey(1, gk0, gk1);
  float y = (tid < NN) ? (e / S + gumbel32(gk0, gk1, (uint32_t)(k*NN + tid))) : -INFINITY;
  sv[tid] = y; si[tid] = tid; __syncthreads();
  for (int s = 256; s > 0; s >>= 1){
    if (tid < s){
      float ov = sv[tid+s]; int oi = si[tid+s];
      if (ov > sv[tid] || (ov == sv[tid] && oi < si[tid])){ sv[tid] = ov; si[tid] = oi; }
    }
    __syncthreads();
  }
  int sel = si[0];
  if (tid < 4) atomicAdd(&gsel[sel*4 + tid], ((const float*)&a)[tid]);
  if (tid < DD) atomicAdd(&oe[(size_t)sel*DD + tid], pl[(size_t)nmsidx[k]*DD + tid]);
}

// ---------------- K9: gt_ious + l1 ----------------
__global__ __launch_bounds__(512) void k_gtiou(
    const float* __restrict__ gsel, const float* __restrict__ tb,
    float* __restrict__ sc){
  int tid = threadIdx.x;
  __shared__ float s1[512], s2[512];
  float a1 = 0.f, a2 = 0.f;
  if (tid < NN){
    float4 g = ((const float4*)gsel)[tid];
    float4 t = ((const float4*)tb)[tid];
    float iou = iou_xyxy(g.x,g.y,g.z,g.w, t.x,t.y,t.z,t.w);
    a1 = 1.f - iou;
    a2 = fabsf(g.x-t.x) + fabsf(g.y-t.y) + fabsf(g.z-t.z) + fabsf(g.w-t.w);
  }
  s1[tid] = a1; s2[tid] = a2; __syncthreads();
  for (int s = 256; s > 0; s >>= 1){
    if (tid < s){ s1[tid] += s1[tid+s]; s2[tid] += s2[tid+s]; }
    __syncthreads();
  }
  if (tid == 0){ sc[3] = s1[0]; sc[4] = s2[0]; }
}

// ---------------- K10: M = tgt_embs @ out_embs^T ----------------
__global__ __launch_bounds__(256) void k_m(
    const float* __restrict__ te, const float* __restrict__ oe,
    float* __restrict__ M){
  int idx = blockIdx.x*256 + threadIdx.x;
  if (idx >= NN*NN) return;
  int i = idx / NN, j = idx % NN;
  const float4* a4 = (const float4*)(te + (size_t)i*DD);
  const float4* b4 = (const float4*)(oe + (size_t)j*DD);
  float s = 0.f;
  #pragma unroll 8
  for (int t = 0; t < DD/4; t++){
    float4 x = a4[t], y = b4[t];
    s += x.x*y.x + x.y*y.y + x.z*y.z + x.w*y.w;
  }
  M[idx] = s;
}

// ---------------- K11: both cross-entropies ----------------
__global__ __launch_bounds__(64) void k_ce(
    const float* __restrict__ M, float* __restrict__ sc){
  int i = blockIdx.x, lane = threadIdx.x;
  float m = -INFINITY;
  for (int j = lane; j < NN; j += 64) m = fmaxf(m, M[(size_t)i*NN + j]);
  for (int o = 32; o > 0; o >>= 1) m = fmaxf(m, __shfl_xor(m, o));
  float s = 0.f;
  for (int j = lane; j < NN; j += 64) s += expf(M[(size_t)i*NN + j] - m);
  for (int o = 32; o > 0; o >>= 1) s += __shfl_xor(s, o);
  float lr = m + logf(s);
  float m2 = -INFINITY;
  for (int j = lane; j < NN; j += 64) m2 = fmaxf(m2, M[(size_t)j*NN + i]);
  for (int o = 32; o > 0; o >>= 1) m2 = fmaxf(m2, __shfl_xor(m2, o));
  float s2 = 0.f;
  for (int j = lane; j < NN; j += 64) s2 += expf(M[(size_t)j*NN + i] - m2);
  for (int o = 32; o > 0; o >>= 1) s2 += __shfl_xor(s2, o);
  float lc = m2 + logf(s2);
  if (lane == 0){
    float d = M[(size_t)i*NN + i];
    atomicAdd(&sc[0], lr - d);
    atomicAdd(&sc[1], lc - d);
  }
}

// ---------------- K12: sel2 ----------------
__global__ __launch_bounds__(256) void k_sel2(
    const float* __restrict__ sims, int* __restrict__ sel2){
  int n = blockIdx.x, tid = threadIdx.x;
  uint32_t gk0, gk1; subkey(2, gk0, gk1);
  float best = -INFINITY; int bi = 0x7fffffff;
  for (int r = tid; r < BQ; r += 256){
    float v = sims[(size_t)r*SIMW + CC + n] + gumbel32(gk0, gk1, (uint32_t)(r*NN + n));
    if (v > best){ best = v; bi = r; }
  }
  __shared__ float sv[256];
  __shared__ int   si[256];
  sv[tid] = best; si[tid] = bi; __syncthreads();
  for (int s = 128; s > 0; s >>= 1){
    if (tid < s){
      float ov = sv[tid+s]; int oi = si[tid+s];
      if (ov > sv[tid] || (ov == sv[tid] && oi < si[tid])){ sv[tid] = ov; si[tid] = oi; }
    }
    __syncthreads();
  }
  if (tid == 0) sel2[n] = si[0];
}

// ---------------- K13: overall_mask_loss + masksum ----------------
__global__ __launch_bounds__(256) void k_om(
    const float* __restrict__ pm, const float* __restrict__ tm,
    const int* __restrict__ sel2, float* __restrict__ msum,
    float* __restrict__ sc){
  int nb = blockIdx.x;
  int n = nb / 9, ch = nb % 9;
  int c0 = ch*1024 + threadIdx.x*4;
  const float4 o4 = *(const float4*)(pm + (size_t)sel2[n]*WHX + c0);
  const float4 t4 = *(const float4*)(tm + (size_t)n*WHX + c0);
  float dx = o4.x-t4.x, dy = o4.y-t4.y, dz = o4.z-t4.z, dw = o4.w-t4.w;
  float d2 = dx*dx + dy*dy + dz*dz + dw*dw;
  float ts = t4.x + t4.y + t4.z + t4.w;
  __shared__ float r1[256], r2[256];
  r1[threadIdx.x] = d2; r2[threadIdx.x] = ts; __syncthreads();
  for (int s = 128; s > 0; s >>= 1){
    if (threadIdx.x < s){ r1[threadIdx.x] += r1[threadIdx.x+s]; r2[threadIdx.x] += r2[threadIdx.x+s]; }
    __syncthreads();
  }
  if (threadIdx.x == 0){ atomicAdd(&sc[2], r1[0]); atomicAdd(&msum[n], r2[0]); }
}

// ---------------- K14: sum_tgt[b] ----------------
__global__ __launch_bounds__(512) void k_sumtgt(
    const int* __restrict__ bidx, const float* __restrict__ rowsum,
    const float* __restrict__ msum, float* __restrict__ stgt){
  int n = threadIdx.x;
  if (n >= NN) return;
  atomicAdd(&stgt[bidx[n]], rowsum[n] * msum[n]);
}

// ---------------- T1: sims f32 -> simTb bf16 [8][304][320] (transpose) ----------------
__global__ __launch_bounds__(256) void t_simT(
    const float* __restrict__ sims, u16* __restrict__ simTb){
  __shared__ float ld[32][65];
  int q0 = blockIdx.x*32, c0 = blockIdx.y*64, b = blockIdx.z;
  int tid = threadIdx.x;
  for (int i = tid; i < 32*64; i += 256){
    int qi = i >> 6, ci = i & 63;
    int q = q0 + qi, c = c0 + ci;
    ld[qi][ci] = (q < QQ && c < CC) ? sims[((size_t)b*QQ + q)*SIMW + c] : 0.f;
  }
  __syncthreads();
  int cloc = tid >> 2, j0 = (tid & 3)*8;
  int c = c0 + cloc;
  if (c < CP){
    u16 tmp[8];
    #pragma unroll
    for (int j = 0; j < 8; j++) tmp[j] = f2bf(ld[j0+j][cloc]);
    *(uint4*)(simTb + ((size_t)b*CP + c)*QP + q0 + j0) = *(const uint4*)tmp;
  }
}

// ---------------- T2: omT bf16 [9216][320] = pm[sel2[q]][wh]/96 (transpose) ----------------
__global__ __launch_bounds__(256) void t_omT(
    const float* __restrict__ pm, const int* __restrict__ sel2,
    u16* __restrict__ omT){
  __shared__ float ld[32][65];
  int q0 = blockIdx.x*32, wh0 = blockIdx.y*64;
  int tid = threadIdx.x;
  for (int i = tid; i < 32*64; i += 256){
    int qi = i >> 6, wi = i & 63;
    int q = q0 + qi;
    ld[qi][wi] = (q < QQ) ? pm[(size_t)sel2[q]*WHX + wh0 + wi] * (1.0f/96.0f) : 0.f;
  }
  __syncthreads();
  int wloc = tid >> 2, j0 = (tid & 3)*8;
  u16 tmp[8];
  #pragma unroll
  for (int j = 0; j < 8; j++) tmp[j] = f2bf(ld[j0+j][wloc]);
  *(uint4*)(omT + (size_t)(wh0+wloc)*QP + q0 + j0) = *(const uint4*)tmp;
}

// ---------------- T3: tmT bf16 [9216][416] (transpose, zero-padded) ----------------
__global__ __launch_bounds__(256) void t_tmT(
    const float* __restrict__ tm, u16* __restrict__ tmT){
  __shared__ float ld[32][65];
  int n0 = blockIdx.x*32, wh0 = blockIdx.y*64;
  int tid = threadIdx.x;
  for (int i = tid; i < 32*64; i += 256){
    int ni = i >> 6, wi = i & 63;
    int n = n0 + ni;
    ld[ni][wi] = (n < NN) ? tm[(size_t)n*WHX + wh0 + wi] : 0.f;
  }
  __syncthreads();
  int wloc = tid >> 2, j0 = (tid & 3)*8;
  u16 tmp[8];
  #pragma unroll
  for (int j = 0; j < 8; j++) tmp[j] = f2bf(ld[j0+j][wloc]);
  *(uint4*)(tmT + (size_t)(wh0+wloc)*NP + n0 + j0) = *(const uint4*)tmp;
}

// ---------------- T4: gtsimP bf16 [8][304][96] (per-batch zero-padded window) ----------------
__global__ __launch_bounds__(256) void t_gtp(
    const float* __restrict__ gtsim, const int* __restrict__ bstart,
    u16* __restrict__ gtp){
  int g = blockIdx.x*256 + threadIdx.x;
  if (g >= BB*CP*(KP/8)) return;
  int b = g / (CP*(KP/8));
  int rem = g - b*CP*(KP/8);
  int c = rem / (KP/8);
  int kg = rem % (KP/8);
  int n0 = bstart[b], n1 = bstart[b+1];
  int kst = n0 & ~7;
  u16 tmp[8];
  #pragma unroll
  for (int j = 0; j < 8; j++){
    int n = kst + kg*8 + j;
    float v = (n >= n0 && n < n1 && c < CC) ? gtsim[(size_t)n*CC + c] : 0.f;
    tmp[j] = f2bf(v);
  }
  *(uint4*)(gtp + ((size_t)b*CP + c)*KP + kg*8) = *(const uint4*)tmp;
}

// ---------------- K15: MFMA z-GEMM + column softmax + dice (LDS-staged A, XCD-pinned) ----------------
constexpr int ASTR = 34;  // padded LDS row stride (bf16 units)
__global__ __launch_bounds__(256) void k_zsoft(
    const u16* __restrict__ simTb, const u16* __restrict__ omT,
    const u16* __restrict__ gtp, const u16* __restrict__ tmT,
    const int* __restrict__ bstart, float* __restrict__ sc){
  const int bid = blockIdx.x;
  const int b = bid & 7;
  const int tile = bid >> 3;
  const int tid = threadIdx.x;
  const int w = tid >> 6, l = tid & 63;
  const int lrow = l & 15, lgrp = l >> 4;
  const int col = tile*64 + w*16 + lrow;

  __shared__ u16 As[CP*ASTR];
  __shared__ float red[256];

  const u16* Ab = simTb + (size_t)b*CP*QP;
  const int sidx[5] = {tid, tid+256, tid+512, tid+768, tid+1024};

  uint4 pf0, pf1, pf2, pf3, pf4;
  {
    int r, g;
    r = sidx[0] >> 2; g = sidx[0] & 3; pf0 = *(const uint4*)(Ab + (size_t)r*QP + g*8);
    r = sidx[1] >> 2; g = sidx[1] & 3; pf1 = *(const uint4*)(Ab + (size_t)r*QP + g*8);
    r = sidx[2] >> 2; g = sidx[2] & 3; pf2 = *(const uint4*)(Ab + (size_t)r*QP + g*8);
    r = sidx[3] >> 2; g = sidx[3] & 3; pf3 = *(const uint4*)(Ab + (size_t)r*QP + g*8);
    if (sidx[4] < 1216){ r = sidx[4] >> 2; g = sidx[4] & 3; pf4 = *(const uint4*)(Ab + (size_t)r*QP + g*8); }
  }
  const u16* pB = omT + (size_t)col*QP;
  bf16x8 bcur = *(const bf16x8*)(pB);

  f32x4 acc[19];
  #pragma unroll
  for (int t = 0; t < 19; t++) acc[t] = (f32x4){0.f,0.f,0.f,0.f};

  for (int ks = 0; ks < 10; ks++){
    {
      int r, g;
      r = sidx[0] >> 2; g = sidx[0] & 3; *(uint4*)&As[r*ASTR + g*8] = pf0;
      r = sidx[1] >> 2; g = sidx[1] & 3; *(uint4*)&As[r*ASTR + g*8] = pf1;
      r = sidx[2] >> 2; g = sidx[2] & 3; *(uint4*)&As[r*ASTR + g*8] = pf2;
      r = sidx[3] >> 2; g = sidx[3] & 3; *(uint4*)&As[r*ASTR + g*8] = pf3;
      if (sidx[4] < 1216){ r = sidx[4] >> 2; g = sidx[4] & 3; *(uint4*)&As[r*ASTR + g*8] = pf4; }
    }
    __syncthreads();
    bf16x8 bnext;
    if (ks + 1 < 10){
      const size_t ko = (size_t)(ks + 1) * 32;
      int r, g;
      r = sidx[0] >> 2; g = sidx[0] & 3; pf0 = *(const uint4*)(Ab + (size_t)r*QP + ko + g*8);
      r = sidx[1] >> 2; g = sidx[1] & 3; pf1 = *(const uint4*)(Ab + (size_t)r*QP + ko + g*8);
      r = sidx[2] >> 2; g = sidx[2] & 3; pf2 = *(const uint4*)(Ab + (size_t)r*QP + ko + g*8);
      r = sidx[3] >> 2; g = sidx[3] & 3; pf3 = *(const uint4*)(Ab + (size_t)r*QP + ko + g*8);
      if (sidx[4] < 1216){ r = sidx[4] >> 2; g = sidx[4] & 3; pf4 = *(const uint4*)(Ab + (size_t)r*QP + ko + g*8); }
      bnext = *(const bf16x8*)(pB + ko);
    }
    #pragma unroll
    for (int t = 0; t < 19; t++){
      bf16x8 af = *(const bf16x8*)&As[(t*16 + lrow)*ASTR + lgrp*8];
      acc[t] = __builtin_amdgcn_mfma_f32_16x16x32_bf16(af, bcur, acc[t], 0, 0, 0);
    }
    bcur = bnext;
    __syncthreads();
  }

  float lmax = -INFINITY;
  #pragma unroll
  for (int t = 0; t < 19; t++){
    if (t == 18 && lgrp == 3) continue;
    lmax = fmaxf(lmax, fmaxf(fmaxf(acc[t][0], acc[t][1]), fmaxf(acc[t][2], acc[t][3])));
  }
  lmax = fmaxf(lmax, __shfl_xor(lmax, 16));
  lmax = fmaxf(lmax, __shfl_xor(lmax, 32));
  float ls = 0.f;
  #pragma unroll
  for (int t = 0; t < 19; t++){
    if (t == 18 && lgrp == 3){
      acc[t] = (f32x4){0.f,0.f,0.f,0.f};
      continue;
    }
    float p0 = __expf(acc[t][0] - lmax);
    float p1 = __expf(acc[t][1] - lmax);
    float p2 = __expf(acc[t][2] - lmax);
    float p3 = __expf(acc[t][3] - lmax);
    acc[t][0] = p0; acc[t][1] = p1; acc[t][2] = p2; acc[t][3] = p3;
    ls += p0 + p1 + p2 + p3;
  }
  float S = ls;
  S += __shfl_xor(S, 16);
  S += __shfl_xor(S, 32);
  float inv = 1.f / S;

  int n0 = bstart[b];
  int kst = n0 & ~7;
  const u16* tB = tmT + (size_t)col*NP + kst + lgrp*8;
  bf16x8 b2a = *(const bf16x8*)(tB);
  bf16x8 b2b = *(const bf16x8*)(tB + 32);
  bf16x8 b2c = *(const bf16x8*)(tB + 64);
  const u16* A2 = gtp + (size_t)b*CP*KP + lgrp*8;
  float dl = 0.f;
  #pragma unroll
  for (int t = 0; t < 19; t++){
    const u16* ar = A2 + (size_t)(t*16 + lrow)*KP;
    f32x4 rr = (f32x4){0.f,0.f,0.f,0.f};
    rr = __builtin_amdgcn_mfma_f32_16x16x32_bf16(*(const bf16x8*)(ar),      b2a, rr, 0, 0, 0);
    rr = __builtin_amdgcn_mfma_f32_16x16x32_bf16(*(const bf16x8*)(ar + 32), b2b, rr, 0, 0, 0);
    rr = __builtin_amdgcn_mfma_f32_16x16x32_bf16(*(const bf16x8*)(ar + 64), b2c, rr, 0, 0, 0);
    dl += acc[t][0]*rr[0] + acc[t][1]*rr[1] + acc[t][2]*rr[2] + acc[t][3]*rr[3];
  }
  dl *= inv;

  red[tid] = dl; __syncthreads();
  for (int s = 128; s > 0; s >>= 1){
    if (tid < s) red[tid] += red[tid+s];
    __syncthreads();
  }
  if (tid == 0) atomicAdd(&sc[5], red[0]);
}

// ---------------- K16: finalize ----------------
__global__ __launch_bounds__(64) void k_final(
    const float* __restrict__ sc, const float* __restrict__ stgt,
    const int* __restrict__ kint, float* __restrict__ out){
  if (threadIdx.x != 0) return;
  float K = (float)kint[0];
  float cls = sc[0]/300.f + sc[1]/300.f;
  float stot = sc[5];
  float dice = 0.f;
  for (int b = 0; b < 8; b++) dice += stot / (9216.0f + stgt[b] + 1e-6f);
  dice *= (1.0f/8.0f);
  out[0] = cls;
  out[1] = dice;
  out[2] = (sc[2] / 2764800.0f) / K;
  out[3] = sc[3] / K;
  out[4] = sc[4] / K;
}

// ---------------- launch ----------------
extern "C" void kernel_launch(void* const* d_in, const int* in_sizes, int n_in,
                              void* d_out, int out_size, void* d_ws, size_t ws_size,
                              hipStream_t stream) {
  const float* ce  = (const float*)d_in[0];
  const float* pl  = (const float*)d_in[1];
  const float* pb  = (const float*)d_in[2];
  const float* pm  = (const float*)d_in[3];
  const float* tm  = (const float*)d_in[4];
  const float* te  = (const float*)d_in[5];
  const float* tbb = (const float*)d_in[6];
  const int*  tids = (const int*)d_in[8];
  const int*  bidx = (const int*)d_in[9];
  float* out = (float*)d_out;
  float* w = (float*)d_ws;

  if (ws_size < F_TOTAL * sizeof(float)) return;

  float* SIMS   = w + F_SIMS;
  float* GTSIM  = w + F_GTSIM;
  float* MM     = w + F_MM;
  float* SCORE  = w + F_SCORE;
  float* BBOX   = w + F_BBOX;
  float* TBOX   = w + F_TB;
  float* SB     = w + F_SB;
  float* SAREA  = w + F_SAREA;
  float* KB     = w + F_KB;
  float* ROWSUM = w + F_ROWSUM;
  float* OE     = w + F_OE;
  float* GSEL   = w + F_GSEL;
  float* MSUM   = w + F_MSUM;
  float* STGT   = w + F_STGT;
  float* SC     = w + F_SC;
  int*   CNT    = (int*)(w + F_CNT);
  int*   ORDER  = (int*)(w + F_ORDER);
  int*   NMSIDX = (int*)(w + F_NMSIDX);
  int*   SEL2   = (int*)(w + F_SEL2);
  int*   BSTART = (int*)(w + F_BSTART);
  int*   KINT   = (int*)(w + F_KINT);
  int*   CLS    = (int*)(w + F_CLS);
  int*   KEEPF  = (int*)(w + F_KEEPF);
  int*   LIST   = (int*)(w + F_LIST);
  u16* SIMTB = (u16*)(w + F_SIMTB);
  u16* OMT   = (u16*)(w + F_OMT);
  u16* TMT   = (u16*)(w + F_TMT);
  u16* GTP   = (u16*)(w + F_GTP);

  // zero accumulators + cell counts
  hipMemsetAsync(w + F_OE, 0, (F_ACCEND - F_OE) * sizeof(float), stream);

  k_gemm_t<<<dim3(22, 5), 256, 0, stream>>>(pl, ce, te, SIMS, GTSIM);
  k_post<<<BQ, 512, 0, stream>>>(SIMS, pb, tbb, tids, bidx, GTSIM, SCORE, BBOX, TBOX, ROWSUM, CLS);
  k_rank<<<(BQ + 255)/256, 256, 0, stream>>>(SCORE, ORDER);
  k_gather<<<(BQ + 255)/256, 256, 0, stream>>>(BBOX, ORDER, bidx, CLS, SB, SAREA, BSTART, CNT, LIST);
  k_cellnms<<<(BB*CC + 255)/256, 256, 0, stream>>>(SB, CNT, LIST, KEEPF);
  k_compact<<<1, 256, 0, stream>>>(KEEPF, ORDER, SB, NMSIDX, KB, KINT);
  k_gtsel<<<BQ, 512, 0, stream>>>(KB, TBOX, NMSIDX, pl, KINT, GSEL, OE);
  k_gtiou<<<1, 512, 0, stream>>>(GSEL, TBOX, SC);
  k_m<<<(NN*NN + 255)/256, 256, 0, stream>>>(te, OE, MM);
  k_ce<<<NN, 64, 0, stream>>>(MM, SC);
  k_sel2<<<NN, 256, 0, stream>>>(SIMS, SEL2);
  k_om<<<NN*9, 256, 0, stream>>>(pm, tm, SEL2, MSUM, SC);
  k_sumtgt<<<1, 512, 0, stream>>>(bidx, ROWSUM, MSUM, STGT);

  t_simT<<<dim3(QP/32, 5, BB), 256, 0, stream>>>(SIMS, SIMTB);
  t_omT<<<dim3(QP/32, WHX/64), 256, 0, stream>>>(pm, SEL2, OMT);
  t_tmT<<<dim3(NP/32, WHX/64), 256, 0, stream>>>(tm, TMT);
  t_gtp<<<(BB*CP*(KP/8) + 255)/256, 256, 0, stream>>>(GTSIM, BSTART, GTP);

  k_zsoft<<<dim3(WHX/64 * BB), 256, 0, stream>>>(SIMTB, OMT, GTP, TMT, BSTART, SC);
  k_final<<<1, 64, 0, stream>>>(SC, STGT, KINT, out);
}

// Round 7
// 355.678 us; speedup vs baseline: 5.7370x; 1.0261x over previous
//
#include <hip/hip_runtime.h>
#include <stdint.h>

#define DEVFN __device__ __forceinline__

typedef unsigned short u16;
typedef short bf16x8 __attribute__((ext_vector_type(8)));
typedef float f32x4 __attribute__((ext_vector_type(4)));

constexpr int BB = 8, QQ = 300, CC = 300, NN = 300, DD = 256;
constexpr int WHX = 9216, BQ = 2400, SIMW = 600;
constexpr int QP = 320;   // padded Q for MFMA K-dim
constexpr int CP = 304;   // padded C rows
constexpr int KP = 96;    // per-batch n-window
constexpr int NP = 416;   // padded tmT n-dim
constexpr int CELLCAP = 300;

// ---------------- workspace layout (float units) ----------------
constexpr size_t F_SIMS   = 0;                                 // [2400][600]
constexpr size_t F_GTSIM  = F_SIMS   + (size_t)BQ*SIMW;        // [300][300]
constexpr size_t F_MM     = F_GTSIM  + (size_t)NN*CC;          // [300][300]
constexpr size_t F_SCORE  = F_MM     + (size_t)NN*NN;          // [2400]
constexpr size_t F_BBOX   = F_SCORE  + BQ;                     // [2400][4]
constexpr size_t F_TB     = F_BBOX   + (size_t)BQ*4;           // [300][4]
constexpr size_t F_SB     = F_TB     + (size_t)NN*4;           // [2400][4]
constexpr size_t F_SAREA  = F_SB     + (size_t)BQ*4;           // [2400]
constexpr size_t F_KB     = F_SAREA  + BQ;                     // [2400][4]
constexpr size_t F_ROWSUM = F_KB     + (size_t)BQ*4;           // [300]
constexpr size_t F_OE     = F_ROWSUM + NN;                     // ---- zeroed zone
constexpr size_t F_GSEL   = F_OE     + (size_t)NN*DD;          // [300][4]
constexpr size_t F_MSUM   = F_GSEL   + (size_t)NN*4;           // [300]
constexpr size_t F_STGT   = F_MSUM   + NN;                     // [8]
constexpr size_t F_SC     = F_STGT   + 8;                      // scalars
constexpr size_t F_CNT    = F_SC     + 16;                     // int [2400] cell counts (zeroed)
constexpr size_t F_ACCEND = F_CNT    + BQ;                     // ---- end zeroed zone
constexpr size_t F_ORDER  = F_ACCEND;                          // int [2400]
constexpr size_t F_NMSIDX = F_ORDER  + BQ;                     // int [2400]
constexpr size_t F_SEL2   = F_NMSIDX + BQ;                     // int [300]
constexpr size_t F_BSTART = F_SEL2   + NN;                     // int [16]
constexpr size_t F_KINT   = F_BSTART + 16;                     // int [4]
constexpr size_t F_CLS    = F_KINT   + 4;                      // int [2400]
constexpr size_t F_KEEPF  = F_CLS    + BQ;                     // int [2400]
constexpr size_t F_LIST   = F_KEEPF  + BQ;                     // int [2400][300]
// bf16 panels (sizes in floats = ushorts/2), 32B-align starts
constexpr size_t F_SIMTB  = ((F_LIST + (size_t)BQ*CELLCAP + 7) & ~(size_t)7);  // u16[8][304][320]
constexpr size_t F_OMT    = F_SIMTB + (size_t)BB*CP*QP/2;           // u16[9216][320]
constexpr size_t F_TMT    = F_OMT   + (size_t)WHX*QP/2;             // u16[9216][416]
constexpr size_t F_GTP    = F_TMT   + (size_t)WHX*NP/2;             // u16[8][304][96]
constexpr size_t F_TOTAL  = F_GTP   + (size_t)BB*CP*KP/2;

// ---------------- JAX threefry2x32 (partitionable scheme) ----------------
DEVFN uint32_t rotl32(uint32_t v, int r){ return (v << r) | (v >> (32 - r)); }

DEVFN void tf2x32(uint32_t k0, uint32_t k1, uint32_t x0, uint32_t x1,
                  uint32_t& o0, uint32_t& o1){
  uint32_t ks2 = k0 ^ k1 ^ 0x1BD11BDAu;
  x0 += k0; x1 += k1;
#define TFR(r) x0 += x1; x1 = rotl32(x1, r); x1 ^= x0;
  TFR(13) TFR(15) TFR(26) TFR(6)   x0 += k1;  x1 += ks2 + 1u;
  TFR(17) TFR(29) TFR(16) TFR(24)  x0 += ks2; x1 += k0  + 2u;
  TFR(13) TFR(15) TFR(26) TFR(6)   x0 += k0;  x1 += k1  + 3u;
  TFR(17) TFR(29) TFR(16) TFR(24)  x0 += k1;  x1 += ks2 + 4u;
  TFR(13) TFR(15) TFR(26) TFR(6)   x0 += ks2; x1 += k0  + 5u;
#undef TFR
  o0 = x0; o1 = x1;
}

DEVFN void subkey(int i, uint32_t& k0, uint32_t& k1){
  tf2x32(0u, 42u, 0u, (uint32_t)i, k0, k1);
}

DEVFN float gumbel32(uint32_t k0, uint32_t k1, uint32_t idx){
  uint32_t h, l; tf2x32(k0, k1, 0u, idx, h, l);
  uint32_t bits = h ^ l;
  float f = __uint_as_float((bits >> 9) | 0x3F800000u) - 1.0f;
  const float tiny = 1.17549435e-38f;
  float u = fmaxf(tiny, f + tiny);
  return -logf(-logf(u));
}

DEVFN float iou_xyxy(float ax1,float ay1,float ax2,float ay2,
                     float bx1,float by1,float bx2,float by2){
  float aa = (ax2-ax1)*(ay2-ay1);
  float ab = (bx2-bx1)*(by2-by1);
  float lx = fmaxf(ax1,bx1), ly = fmaxf(ay1,by1);
  float rx = fminf(ax2,bx2), ry = fminf(ay2,by2);
  float iw = fmaxf(rx-lx,0.f), ih = fmaxf(ry-ly,0.f);
  float in_ = iw*ih;
  return in_/(aa+ab-in_);
}

DEVFN u16 f2bf(float x){
  uint32_t u = __float_as_uint(x);
  uint32_t r = u + 0x7FFFu + ((u >> 16) & 1u);
  return (u16)(r >> 16);
}

// ---------------- K1: tiled f32 GEMM: [pl;te](2700x256) x [ce;te]^T(256x600) ----------------
__global__ __launch_bounds__(256) void k_gemm_t(
    const float* __restrict__ pl, const float* __restrict__ ce,
    const float* __restrict__ te, float* __restrict__ sims,
    float* __restrict__ gtsim){
  __shared__ float As[16][128];
  __shared__ float Bs[16][128];
  const int row0 = blockIdx.x * 128, col0 = blockIdx.y * 128;
  const int tid = threadIdx.x;
  const int lrow = tid >> 1, lk0 = (tid & 1) * 8;
  const int tr = tid >> 4, tc = tid & 15;

  float acc[8][8];
  #pragma unroll
  for (int i = 0; i < 8; i++)
    #pragma unroll
    for (int j = 0; j < 8; j++) acc[i][j] = 0.f;

  const float4 z4 = {0.f,0.f,0.f,0.f};
  const int grow = row0 + lrow;
  const int gcol = col0 + lrow;
  const float* arow = nullptr;
  if (grow < 2400) arow = pl + (size_t)grow * DD;
  else if (grow < 2700) arow = te + (size_t)(grow - 2400) * DD;
  const float* brow = nullptr;
  if (gcol < 300) brow = ce + (size_t)gcol * DD;
  else if (gcol < 600) brow = te + (size_t)(gcol - 300) * DD;

  float4 av0 = arow ? *(const float4*)(arow + lk0)     : z4;
  float4 av1 = arow ? *(const float4*)(arow + lk0 + 4) : z4;
  float4 bv0 = brow ? *(const float4*)(brow + lk0)     : z4;
  float4 bv1 = brow ? *(const float4*)(brow + lk0 + 4) : z4;

  for (int step = 0; step < 16; step++){
    __syncthreads();
    #pragma unroll
    for (int j = 0; j < 4; j++){
      As[lk0 + j][lrow]     = ((const float*)&av0)[j];
      As[lk0 + 4 + j][lrow] = ((const float*)&av1)[j];
      Bs[lk0 + j][lrow]     = ((const float*)&bv0)[j];
      Bs[lk0 + 4 + j][lrow] = ((const float*)&bv1)[j];
    }
    __syncthreads();
    if (step + 1 < 16){
      const int k0 = (step + 1) * 16;
      av0 = arow ? *(const float4*)(arow + k0 + lk0)     : z4;
      av1 = arow ? *(const float4*)(arow + k0 + lk0 + 4) : z4;
      bv0 = brow ? *(const float4*)(brow + k0 + lk0)     : z4;
      bv1 = brow ? *(const float4*)(brow + k0 + lk0 + 4) : z4;
    }
    #pragma unroll
    for (int kk = 0; kk < 16; kk++){
      float4 a0 = *(const float4*)&As[kk][tr*8];
      float4 a1 = *(const float4*)&As[kk][tr*8 + 4];
      float4 b0 = *(const float4*)&Bs[kk][tc*8];
      float4 b1 = *(const float4*)&Bs[kk][tc*8 + 4];
      float a[8] = {a0.x,a0.y,a0.z,a0.w,a1.x,a1.y,a1.z,a1.w};
      float b[8] = {b0.x,b0.y,b0.z,b0.w,b1.x,b1.y,b1.z,b1.w};
      #pragma unroll
      for (int i = 0; i < 8; i++)
        #pragma unroll
        for (int j = 0; j < 8; j++)
          acc[i][j] = fmaf(a[i], b[j], acc[i][j]);
    }
  }

  #pragma unroll
  for (int i = 0; i < 8; i++){
    const int r = row0 + tr*8 + i;
    const int c0 = col0 + tc*8;
    if (r < 2400){
      if (c0 < 600){
        float4 o0 = {acc[i][0],acc[i][1],acc[i][2],acc[i][3]};
        float4 o1 = {acc[i][4],acc[i][5],acc[i][6],acc[i][7]};
        *(float4*)(sims + (size_t)r*SIMW + c0)     = o0;
        *(float4*)(sims + (size_t)r*SIMW + c0 + 4) = o1;
      }
    } else if (r < 2700){
      const int n = r - 2400;
      #pragma unroll
      for (int j = 0; j < 8; j++){
        int c = c0 + j;
        if (c < 300) gtsim[(size_t)n*CC + c] = acc[i][j];
      }
    }
  }
}

// ---------------- K2: per-bq scores/argmax(g0)/boxes/cls; tb rows; gtsim rowsums ----------------
__global__ __launch_bounds__(512) void k_post(
    const float* __restrict__ sims, const float* __restrict__ pb,
    const float* __restrict__ tbb, const int* __restrict__ tids,
    const int* __restrict__ bidx, const float* __restrict__ gtsim,
    float* __restrict__ score, float* __restrict__ bbox,
    float* __restrict__ tb, float* __restrict__ rowsum,
    int* __restrict__ clsout){
  int bq = blockIdx.x, tid = threadIdx.x;
  __shared__ float sv[512];
  __shared__ int   si[512];
  float v = (tid < CC) ? sims[(size_t)bq*SIMW + tid] : -INFINITY;
  sv[tid] = v; __syncthreads();
  for (int s = 256; s > 0; s >>= 1){ if (tid < s) sv[tid] = fmaxf(sv[tid], sv[tid+s]); __syncthreads(); }
  if (tid == 0) score[bq] = sv[0];
  __syncthreads();
  uint32_t gk0, gk1; subkey(0, gk0, gk1);
  float y = (tid < CC) ? v + gumbel32(gk0, gk1, (uint32_t)(bq*CC + tid)) : -INFINITY;
  sv[tid] = y; si[tid] = tid; __syncthreads();
  for (int s = 256; s > 0; s >>= 1){
    if (tid < s){
      float ov = sv[tid+s]; int oi = si[tid+s];
      if (ov > sv[tid] || (ov == sv[tid] && oi < si[tid])){ sv[tid] = ov; si[tid] = oi; }
    }
    __syncthreads();
  }
  if (tid == 0){
    int cls = si[0];
    clsout[bq] = cls;
    float ox = 224.0f * (float)cls;
    float oy = 224.0f * (float)(bq / QQ);
    float cx = pb[bq*4+0], cy = pb[bq*4+1], ww = pb[bq*4+2], hh = pb[bq*4+3];
    bbox[bq*4+0] = cx - 0.5f*ww + ox;
    bbox[bq*4+1] = cy - 0.5f*hh + oy;
    bbox[bq*4+2] = cx + 0.5f*ww + ox;
    bbox[bq*4+3] = cy + 0.5f*hh + oy;
  }
  if (bq < NN){
    __syncthreads();
    float rs = (tid < CC) ? gtsim[(size_t)bq*CC + tid] : 0.f;
    sv[tid] = rs; __syncthreads();
    for (int s = 256; s > 0; s >>= 1){ if (tid < s) sv[tid] += sv[tid+s]; __syncthreads(); }
    if (tid == 0) rowsum[bq] = sv[0];
    if (tid == 1){
      float gx = 224.0f * (float)tids[bq], gy = 224.0f * (float)bidx[bq];
      float cx = tbb[bq*4+0], cy = tbb[bq*4+1], ww = tbb[bq*4+2], hh = tbb[bq*4+3];
      tb[bq*4+0] = cx - 0.5f*ww + gx;
      tb[bq*4+1] = cy - 0.5f*hh + gy;
      tb[bq*4+2] = cx + 0.5f*ww + gx;
      tb[bq*4+3] = cy + 0.5f*hh + gy;
    }
  }
}

// ---------------- K3: stable descending rank sort ----------------
__global__ __launch_bounds__(256) void k_rank(
    const float* __restrict__ score, int* __restrict__ order){
  __shared__ float s[BQ];
  int tid = threadIdx.x;
  for (int i = tid; i < BQ; i += 256) s[i] = score[i];
  __syncthreads();
  int t = blockIdx.x*256 + tid;
  if (t >= BQ) return;
  float st = s[t];
  int cnt = 0;
  for (int j = 0; j < BQ; j++){
    float sj = s[j];
    cnt += (sj > st) || (sj == st && j < t);
  }
  order[cnt] = t;
}

// ---------------- K4: gather sorted boxes/areas + batch starts + cell bucketing ----------------
__global__ __launch_bounds__(256) void k_gather(
    const float* __restrict__ bbox, const int* __restrict__ order,
    const int* __restrict__ bidx, const int* __restrict__ cls,
    float* __restrict__ sb, float* __restrict__ sarea,
    int* __restrict__ bstart, int* __restrict__ cnt,
    int* __restrict__ list){
  int t = blockIdx.x*256 + threadIdx.x;
  if (t < BQ){
    int o = order[t];
    float x1 = bbox[o*4+0], y1 = bbox[o*4+1], x2 = bbox[o*4+2], y2 = bbox[o*4+3];
    sb[t*4+0] = x1; sb[t*4+1] = y1; sb[t*4+2] = x2; sb[t*4+3] = y2;
    sarea[t] = (x2-x1)*(y2-y1);
    // bucket by (batch, argmax class) cell — cross-cell IoU is identically 0 (offsets >= 224)
    int key = (o / QQ) * CC + cls[o];
    int slot = atomicAdd(&cnt[key], 1);
    list[(size_t)key*CELLCAP + slot] = t;
  }
  if (blockIdx.x == 0 && threadIdx.x < 9){
    int b = threadIdx.x, c = 0;
    for (int n = 0; n < NN; n++) c += (bidx[n] < b);
    bstart[b] = c;
  }
}

// ---------------- K6': per-cell greedy NMS (one thread per (batch,class) cell) ----------------
__global__ __launch_bounds__(256) void k_cellnms(
    const float* __restrict__ sb, const int* __restrict__ cnt,
    const int* __restrict__ list, int* __restrict__ keepf){
  int key = blockIdx.x*256 + threadIdx.x;
  if (key >= BB*CC) return;
  int m = cnt[key];
  if (m <= 0) return;
  const int* lst = list + (size_t)key*CELLCAP;
  unsigned long long keptmask = 0ull;   // kept flags by cell-rank (m<=64 fast path)
  int prevp = -1;
  for (int a = 0; a < m; a++){
    // a-th smallest sorted-position in this cell
    int pa = 0x7fffffff;
    for (int j = 0; j < m; j++){
      int pj = lst[j];
      if (pj > prevp && pj < pa) pa = pj;
    }
    prevp = pa;
    float4 A = ((const float4*)sb)[pa];
    float areaA = (A.z-A.x)*(A.w-A.y);
    bool kept = true;
    int pbprev = -1;
    for (int b2 = 0; b2 < a; b2++){
      int pb = 0x7fffffff;
      for (int j = 0; j < m; j++){
        int pj = lst[j];
        if (pj > pbprev && pj < pb) pb = pj;
      }
      pbprev = pb;
      bool keptb = (m <= 64) ? (((keptmask >> b2) & 1ull) != 0ull) : (keepf[pb] != 0);
      if (!keptb) continue;
      float4 B = ((const float4*)sb)[pb];
      float areaB = (B.z-B.x)*(B.w-B.y);
      float lx = fmaxf(A.x,B.x), ly = fmaxf(A.y,B.y);
      float rx = fminf(A.z,B.z), ry = fminf(A.w,B.w);
      float iw = fmaxf(rx-lx,0.f), ih = fmaxf(ry-ly,0.f);
      float inter = iw*ih;
      if (inter/(areaA + areaB - inter) > 0.5f){ kept = false; break; }
    }
    if (m <= 64 && kept) keptmask |= (1ull << a);
    keepf[pa] = kept ? 1 : 0;
  }
}

// ---------------- K7: compact ----------------
__global__ __launch_bounds__(256) void k_compact(
    const int* __restrict__ keepflag, const int* __restrict__ order,
    const float* __restrict__ sb, int* __restrict__ nmsidx,
    float* __restrict__ kb, int* __restrict__ kint){
  __shared__ int csum[256];
  int tid = threadIdx.x;
  int p0 = tid*10;
  int keepf[10];
  int cnt = 0;
  #pragma unroll
  for (int d = 0; d < 10; d++){
    int p = p0 + d;
    int k = 0;
    if (p < BQ) k = keepflag[p];
    keepf[d] = k; cnt += k;
  }
  csum[tid] = cnt; __syncthreads();
  for (int s = 1; s < 256; s <<= 1){
    int add = (tid >= s) ? csum[tid - s] : 0;
    __syncthreads();
    csum[tid] += add;
    __syncthreads();
  }
  int pos = csum[tid] - cnt;
  #pragma unroll
  for (int d = 0; d < 10; d++){
    if (keepf[d]){
      int p = p0 + d;
      nmsidx[pos] = order[p];
      ((float4*)kb)[pos] = ((const float4*)sb)[p];
      pos++;
    }
  }
  if (tid == 255) kint[0] = csum[255];
}

// ---------------- K8: per-kept-box scatter ----------------
__global__ __launch_bounds__(512) void k_gtsel(
    const float* __restrict__ kb, const float* __restrict__ tb,
    const int* __restrict__ nmsidx, const float* __restrict__ pl,
    const int* __restrict__ kint, float* __restrict__ gsel,
    float* __restrict__ oe){
  int k = blockIdx.x;
  if (k >= kint[0]) return;
  int tid = threadIdx.x;
  __shared__ float sv[512];
  __shared__ int   si[512];
  float4 a = ((const float4*)kb)[k];
  float iou = -INFINITY;
  if (tid < NN){
    float4 t = ((const float4*)tb)[tid];
    iou = iou_xyxy(a.x,a.y,a.z,a.w, t.x,t.y,t.z,t.w);
    if (iou != iou) iou = 0.f;
  }
  sv[tid] = iou; __syncthreads();
  for (int s = 256; s > 0; s >>= 1){ if (tid < s) sv[tid] = fmaxf(sv[tid], sv[tid+s]); __syncthreads(); }
  float m = sv[0]; __syncthreads();
  float e = (tid < NN) ? expf(iou - m) : 0.f;
  sv[tid] = e; __syncthreads();
  for (int s = 256; s > 0; s >>= 1){ if (tid < s) sv[tid] += sv[tid+s]; __syncthreads(); }
  float S = sv[0]; __syncthreads();
  uint32_t gk0, gk1; subkey(1, gk0, gk1);
  float y = (tid < NN) ? (e / S + gumbel32(gk0, gk1, (uint32_t)(k*NN + tid))) : -INFINITY;
  sv[tid] = y; si[tid] = tid; __syncthreads();
  for (int s = 256; s > 0; s >>= 1){
    if (tid < s){
      float ov = sv[tid+s]; int oi = si[tid+s];
      if (ov > sv[tid] || (ov == sv[tid] && oi < si[tid])){ sv[tid] = ov; si[tid] = oi; }
    }
    __syncthreads();
  }
  int sel = si[0];
  if (tid < 4) atomicAdd(&gsel[sel*4 + tid], ((const float*)&a)[tid]);
  if (tid < DD) atomicAdd(&oe[(size_t)sel*DD + tid], pl[(size_t)nmsidx[k]*DD + tid]);
}

// ---------------- K9: gt_ious + l1 ----------------
__global__ __launch_bounds__(512) void k_gtiou(
    const float* __restrict__ gsel, const float* __restrict__ tb,
    float* __restrict__ sc){
  int tid = threadIdx.x;
  __shared__ float s1[512], s2[512];
  float a1 = 0.f, a2 = 0.f;
  if (tid < NN){
    float4 g = ((const float4*)gsel)[tid];
    float4 t = ((const float4*)tb)[tid];
    float iou = iou_xyxy(g.x,g.y,g.z,g.w, t.x,t.y,t.z,t.w);
    a1 = 1.f - iou;
    a2 = fabsf(g.x-t.x) + fabsf(g.y-t.y) + fabsf(g.z-t.z) + fabsf(g.w-t.w);
  }
  s1[tid] = a1; s2[tid] = a2; __syncthreads();
  for (int s = 256; s > 0; s >>= 1){
    if (tid < s){ s1[tid] += s1[tid+s]; s2[tid] += s2[tid+s]; }
    __syncthreads();
  }
  if (tid == 0){ sc[3] = s1[0]; sc[4] = s2[0]; }
}

// ---------------- K10: M = tgt_embs @ out_embs^T ----------------
__global__ __launch_bounds__(256) void k_m(
    const float* __restrict__ te, const float* __restrict__ oe,
    float* __restrict__ M){
  int idx = blockIdx.x*256 + threadIdx.x;
  if (idx >= NN*NN) return;
  int i = idx / NN, j = idx % NN;
  const float4* a4 = (const float4*)(te + (size_t)i*DD);
  const float4* b4 = (const float4*)(oe + (size_t)j*DD);
  float s = 0.f;
  #pragma unroll 8
  for (int t = 0; t < DD/4; t++){
    float4 x = a4[t], y = b4[t];
    s += x.x*y.x + x.y*y.y + x.z*y.z + x.w*y.w;
  }
  M[idx] = s;
}

// ---------------- K11: both cross-entropies ----------------
__global__ __launch_bounds__(64) void k_ce(
    const float* __restrict__ M, float* __restrict__ sc){
  int i = blockIdx.x, lane = threadIdx.x;
  float m = -INFINITY;
  for (int j = lane; j < NN; j += 64) m = fmaxf(m, M[(size_t)i*NN + j]);
  for (int o = 32; o > 0; o >>= 1) m = fmaxf(m, __shfl_xor(m, o));
  float s = 0.f;
  for (int j = lane; j < NN; j += 64) s += expf(M[(size_t)i*NN + j] - m);
  for (int o = 32; o > 0; o >>= 1) s += __shfl_xor(s, o);
  float lr = m + logf(s);
  float m2 = -INFINITY;
  for (int j = lane; j < NN; j += 64) m2 = fmaxf(m2, M[(size_t)j*NN + i]);
  for (int o = 32; o > 0; o >>= 1) m2 = fmaxf(m2, __shfl_xor(m2, o));
  float s2 = 0.f;
  for (int j = lane; j < NN; j += 64) s2 += expf(M[(size_t)j*NN + i] - m2);
  for (int o = 32; o > 0; o >>= 1) s2 += __shfl_xor(s2, o);
  float lc = m2 + logf(s2);
  if (lane == 0){
    float d = M[(size_t)i*NN + i];
    atomicAdd(&sc[0], lr - d);
    atomicAdd(&sc[1], lc - d);
  }
}

// ---------------- K12: sel2 ----------------
__global__ __launch_bounds__(256) void k_sel2(
    const float* __restrict__ sims, int* __restrict__ sel2){
  int n = blockIdx.x, tid = threadIdx.x;
  uint32_t gk0, gk1; subkey(2, gk0, gk1);
  float best = -INFINITY; int bi = 0x7fffffff;
  for (int r = tid; r < BQ; r += 256){
    float v = sims[(size_t)r*SIMW + CC + n] + gumbel32(gk0, gk1, (uint32_t)(r*NN + n));
    if (v > best){ best = v; bi = r; }
  }
  __shared__ float sv[256];
  __shared__ int   si[256];
  sv[tid] = best; si[tid] = bi; __syncthreads();
  for (int s = 128; s > 0; s >>= 1){
    if (tid < s){
      float ov = sv[tid+s]; int oi = si[tid+s];
      if (ov > sv[tid] || (ov == sv[tid] && oi < si[tid])){ sv[tid] = ov; si[tid] = oi; }
    }
    __syncthreads();
  }
  if (tid == 0) sel2[n] = si[0];
}

// ---------------- K13: overall_mask_loss + masksum ----------------
__global__ __launch_bounds__(256) void k_om(
    const float* __restrict__ pm, const float* __restrict__ tm,
    const int* __restrict__ sel2, float* __restrict__ msum,
    float* __restrict__ sc){
  int nb = blockIdx.x;
  int n = nb / 9, ch = nb % 9;
  int c0 = ch*1024 + threadIdx.x*4;
  const float4 o4 = *(const float4*)(pm + (size_t)sel2[n]*WHX + c0);
  const float4 t4 = *(const float4*)(tm + (size_t)n*WHX + c0);
  float dx = o4.x-t4.x, dy = o4.y-t4.y, dz = o4.z-t4.z, dw = o4.w-t4.w;
  float d2 = dx*dx + dy*dy + dz*dz + dw*dw;
  float ts = t4.x + t4.y + t4.z + t4.w;
  __shared__ float r1[256], r2[256];
  r1[threadIdx.x] = d2; r2[threadIdx.x] = ts; __syncthreads();
  for (int s = 128; s > 0; s >>= 1){
    if (threadIdx.x < s){ r1[threadIdx.x] += r1[threadIdx.x+s]; r2[threadIdx.x] += r2[threadIdx.x+s]; }
    __syncthreads();
  }
  if (threadIdx.x == 0){ atomicAdd(&sc[2], r1[0]); atomicAdd(&msum[n], r2[0]); }
}

// ---------------- K14: sum_tgt[b] ----------------
__global__ __launch_bounds__(512) void k_sumtgt(
    const int* __restrict__ bidx, const float* __restrict__ rowsum,
    const float* __restrict__ msum, float* __restrict__ stgt){
  int n = threadIdx.x;
  if (n >= NN) return;
  atomicAdd(&stgt[bidx[n]], rowsum[n] * msum[n]);
}

// ---------------- T1: sims f32 -> simTb bf16 [8][304][320] (transpose) ----------------
__global__ __launch_bounds__(256) void t_simT(
    const float* __restrict__ sims, u16* __restrict__ simTb){
  __shared__ float ld[32][65];
  int q0 = blockIdx.x*32, c0 = blockIdx.y*64, b = blockIdx.z;
  int tid = threadIdx.x;
  for (int i = tid; i < 32*64; i += 256){
    int qi = i >> 6, ci = i & 63;
    int q = q0 + qi, c = c0 + ci;
    ld[qi][ci] = (q < QQ && c < CC) ? sims[((size_t)b*QQ + q)*SIMW + c] : 0.f;
  }
  __syncthreads();
  int cloc = tid >> 2, j0 = (tid & 3)*8;
  int c = c0 + cloc;
  if (c < CP){
    u16 tmp[8];
    #pragma unroll
    for (int j = 0; j < 8; j++) tmp[j] = f2bf(ld[j0+j][cloc]);
    *(uint4*)(simTb + ((size_t)b*CP + c)*QP + q0 + j0) = *(const uint4*)tmp;
  }
}

// ---------------- T2: omT bf16 [9216][320] = pm[sel2[q]][wh]/96 (transpose) ----------------
__global__ __launch_bounds__(256) void t_omT(
    const float* __restrict__ pm, const int* __restrict__ sel2,
    u16* __restrict__ omT){
  __shared__ float ld[32][65];
  int q0 = blockIdx.x*32, wh0 = blockIdx.y*64;
  int tid = threadIdx.x;
  for (int i = tid; i < 32*64; i += 256){
    int qi = i >> 6, wi = i & 63;
    int q = q0 + qi;
    ld[qi][wi] = (q < QQ) ? pm[(size_t)sel2[q]*WHX + wh0 + wi] * (1.0f/96.0f) : 0.f;
  }
  __syncthreads();
  int wloc = tid >> 2, j0 = (tid & 3)*8;
  u16 tmp[8];
  #pragma unroll
  for (int j = 0; j < 8; j++) tmp[j] = f2bf(ld[j0+j][wloc]);
  *(uint4*)(omT + (size_t)(wh0+wloc)*QP + q0 + j0) = *(const uint4*)tmp;
}

// ---------------- T3: tmT bf16 [9216][416] (transpose, zero-padded) ----------------
__global__ __launch_bounds__(256) void t_tmT(
    const float* __restrict__ tm, u16* __restrict__ tmT){
  __shared__ float ld[32][65];
  int n0 = blockIdx.x*32, wh0 = blockIdx.y*64;
  int tid = threadIdx.x;
  for (int i = tid; i < 32*64; i += 256){
    int ni = i >> 6, wi = i & 63;
    int n = n0 + ni;
    ld[ni][wi] = (n < NN) ? tm[(size_t)n*WHX + wh0 + wi] : 0.f;
  }
  __syncthreads();
  int wloc = tid >> 2, j0 = (tid & 3)*8;
  u16 tmp[8];
  #pragma unroll
  for (int j = 0; j < 8; j++) tmp[j] = f2bf(ld[j0+j][wloc]);
  *(uint4*)(tmT + (size_t)(wh0+wloc)*NP + n0 + j0) = *(const uint4*)tmp;
}

// ---------------- T4: gtsimP bf16 [8][304][96] (per-batch zero-padded window) ----------------
__global__ __launch_bounds__(256) void t_gtp(
    const float* __restrict__ gtsim, const int* __restrict__ bstart,
    u16* __restrict__ gtp){
  int g = blockIdx.x*256 + threadIdx.x;
  if (g >= BB*CP*(KP/8)) return;
  int b = g / (CP*(KP/8));
  int rem = g - b*(CP*(KP/8));
  int c = rem / (KP/8);
  int kg = rem % (KP/8);
  int n0 = bstart[b], n1 = bstart[b+1];
  int kst = n0 & ~7;
  u16 tmp[8];
  #pragma unroll
  for (int j = 0; j < 8; j++){
    int n = kst + kg*8 + j;
    float v = (n >= n0 && n < n1 && c < CC) ? gtsim[(size_t)n*CC + c] : 0.f;
    tmp[j] = f2bf(v);
  }
  *(uint4*)(gtp + ((size_t)b*CP + c)*KP + kg*8) = *(const uint4*)tmp;
}

// ---------------- K15: MFMA z-GEMM + column softmax + dice (swizzled LDS A, XCD-pinned) ----------------
// LDS A-chunk [304][32] bf16, row stride 32 u16 (64B). 16B-chunk swizzle:
//   chunk' = chunk ^ ((row>>1)&3)  -> every 16-lane phase covers 8 bank-groups
//   with exactly 2 lanes each (2 lanes/bank = free, m136). Read side uses
//   row = t*16+lrow => ((row>>1)&3) == ((lrow>>1)&3) (t*8 == 0 mod 4), so the
//   per-t read address is base + t*1024B (ds offset-foldable).
constexpr int ALDS = 32;  // LDS row stride in u16 (64 B, power of 2)
__global__ __launch_bounds__(256) void k_zsoft(
    const u16* __restrict__ simTb, const u16* __restrict__ omT,
    const u16* __restrict__ gtp, const u16* __restrict__ tmT,
    const int* __restrict__ bstart, float* __restrict__ sc){
  const int bid = blockIdx.x;
  const int b = bid & 7;
  const int tile = bid >> 3;
  const int tid = threadIdx.x;
  const int w = tid >> 6, l = tid & 63;
  const int lrow = l & 15, lgrp = l >> 4;
  const int col = tile*64 + w*16 + lrow;

  __shared__ u16 As[CP*ALDS];   // 19456 B
  __shared__ float red[256];

  const u16* Ab = simTb + (size_t)b*CP*QP;
  const int sidx[5] = {tid, tid+256, tid+512, tid+768, tid+1024};
  // precomputed swizzled LDS write offsets (u16 units)
  int woff[5];
  #pragma unroll
  for (int i = 0; i < 5; i++){
    int r = sidx[i] >> 2, g = sidx[i] & 3;
    woff[i] = r*ALDS + ((g ^ ((r >> 1) & 3)) << 3);
  }
  // swizzled read offset within row (u16 units), t-independent
  const int roff = (lgrp ^ ((lrow >> 1) & 3)) << 3;

  uint4 pf0, pf1, pf2, pf3, pf4;
  {
    int r, g;
    r = sidx[0] >> 2; g = sidx[0] & 3; pf0 = *(const uint4*)(Ab + (size_t)r*QP + g*8);
    r = sidx[1] >> 2; g = sidx[1] & 3; pf1 = *(const uint4*)(Ab + (size_t)r*QP + g*8);
    r = sidx[2] >> 2; g = sidx[2] & 3; pf2 = *(const uint4*)(Ab + (size_t)r*QP + g*8);
    r = sidx[3] >> 2; g = sidx[3] & 3; pf3 = *(const uint4*)(Ab + (size_t)r*QP + g*8);
    if (sidx[4] < 1216){ r = sidx[4] >> 2; g = sidx[4] & 3; pf4 = *(const uint4*)(Ab + (size_t)r*QP + g*8); }
  }
  const u16* pB = omT + (size_t)col*QP;
  bf16x8 bcur = *(const bf16x8*)(pB);

  f32x4 acc[19];
  #pragma unroll
  for (int t = 0; t < 19; t++) acc[t] = (f32x4){0.f,0.f,0.f,0.f};

  for (int ks = 0; ks < 10; ks++){
    *(uint4*)&As[woff[0]] = pf0;
    *(uint4*)&As[woff[1]] = pf1;
    *(uint4*)&As[woff[2]] = pf2;
    *(uint4*)&As[woff[3]] = pf3;
    if (sidx[4] < 1216) *(uint4*)&As[woff[4]] = pf4;
    __syncthreads();
    bf16x8 bnext;
    if (ks + 1 < 10){
      const size_t ko = (size_t)(ks + 1) * 32;
      int r, g;
      r = sidx[0] >> 2; g = sidx[0] & 3; pf0 = *(const uint4*)(Ab + (size_t)r*QP + ko + g*8);
      r = sidx[1] >> 2; g = sidx[1] & 3; pf1 = *(const uint4*)(Ab + (size_t)r*QP + ko + g*8);
      r = sidx[2] >> 2; g = sidx[2] & 3; pf2 = *(const uint4*)(Ab + (size_t)r*QP + ko + g*8);
      r = sidx[3] >> 2; g = sidx[3] & 3; pf3 = *(const uint4*)(Ab + (size_t)r*QP + ko + g*8);
      if (sidx[4] < 1216){ r = sidx[4] >> 2; g = sidx[4] & 3; pf4 = *(const uint4*)(Ab + (size_t)r*QP + ko + g*8); }
      bnext = *(const bf16x8*)(pB + ko);
    }
    #pragma unroll
    for (int t = 0; t < 19; t++){
      bf16x8 af = *(const bf16x8*)&As[t*16*ALDS + lrow*ALDS + roff];
      acc[t] = __builtin_amdgcn_mfma_f32_16x16x32_bf16(af, bcur, acc[t], 0, 0, 0);
    }
    bcur = bnext;
    __syncthreads();
  }

  float lmax = -INFINITY;
  #pragma unroll
  for (int t = 0; t < 19; t++){
    if (t == 18 && lgrp == 3) continue;
    lmax = fmaxf(lmax, fmaxf(fmaxf(acc[t][0], acc[t][1]), fmaxf(acc[t][2], acc[t][3])));
  }
  lmax = fmaxf(lmax, __shfl_xor(lmax, 16));
  lmax = fmaxf(lmax, __shfl_xor(lmax, 32));
  float ls = 0.f;
  #pragma unroll
  for (int t = 0; t < 19; t++){
    if (t == 18 && lgrp == 3){
      acc[t] = (f32x4){0.f,0.f,0.f,0.f};
      continue;
    }
    float p0 = __expf(acc[t][0] - lmax);
    float p1 = __expf(acc[t][1] - lmax);
    float p2 = __expf(acc[t][2] - lmax);
    float p3 = __expf(acc[t][3] - lmax);
    acc[t][0] = p0; acc[t][1] = p1; acc[t][2] = p2; acc[t][3] = p3;
    ls += p0 + p1 + p2 + p3;
  }
  float S = ls;
  S += __shfl_xor(S, 16);
  S += __shfl_xor(S, 32);
  float inv = 1.f / S;

  int n0 = bstart[b];
  int kst = n0 & ~7;
  const u16* tB = tmT + (size_t)col*NP + kst + lgrp*8;
  bf16x8 b2a = *(const bf16x8*)(tB);
  bf16x8 b2b = *(const bf16x8*)(tB + 32);
  bf16x8 b2c = *(const bf16x8*)(tB + 64);
  const u16* A2 = gtp + (size_t)b*CP*KP + lgrp*8;
  float dl = 0.f;
  #pragma unroll
  for (int t = 0; t < 19; t++){
    const u16* ar = A2 + (size_t)(t*16 + lrow)*KP;
    f32x4 rr = (f32x4){0.f,0.f,0.f,0.f};
    rr = __builtin_amdgcn_mfma_f32_16x16x32_bf16(*(const bf16x8*)(ar),      b2a, rr, 0, 0, 0);
    rr = __builtin_amdgcn_mfma_f32_16x16x32_bf16(*(const bf16x8*)(ar + 32), b2b, rr, 0, 0, 0);
    rr = __builtin_amdgcn_mfma_f32_16x16x32_bf16(*(const bf16x8*)(ar + 64), b2c, rr, 0, 0, 0);
    dl += acc[t][0]*rr[0] + acc[t][1]*rr[1] + acc[t][2]*rr[2] + acc[t][3]*rr[3];
  }
  dl *= inv;

  red[tid] = dl; __syncthreads();
  for (int s = 128; s > 0; s >>= 1){
    if (tid < s) red[tid] += red[tid+s];
    __syncthreads();
  }
  if (tid == 0) atomicAdd(&sc[5], red[0]);
}

// ---------------- K16: finalize ----------------
__global__ __launch_bounds__(64) void k_final(
    const float* __restrict__ sc, const float* __restrict__ stgt,
    const int* __restrict__ kint, float* __restrict__ out){
  if (threadIdx.x != 0) return;
  float K = (float)kint[0];
  float cls = sc[0]/300.f + sc[1]/300.f;
  float stot = sc[5];
  float dice = 0.f;
  for (int b = 0; b < 8; b++) dice += stot / (9216.0f + stgt[b] + 1e-6f);
  dice *= (1.0f/8.0f);
  out[0] = cls;
  out[1] = dice;
  out[2] = (sc[2] / 2764800.0f) / K;
  out[3] = sc[3] / K;
  out[4] = sc[4] / K;
}

// ---------------- launch ----------------
extern "C" void kernel_launch(void* const* d_in, const int* in_sizes, int n_in,
                              void* d_out, int out_size, void* d_ws, size_t ws_size,
                              hipStream_t stream) {
  const float* ce  = (const float*)d_in[0];
  const float* pl  = (const float*)d_in[1];
  const float* pb  = (const float*)d_in[2];
  const float* pm  = (const float*)d_in[3];
  const float* tm  = (const float*)d_in[4];
  const float* te  = (const float*)d_in[5];
  const float* tbb = (const float*)d_in[6];
  const int*  tids = (const int*)d_in[8];
  const int*  bidx = (const int*)d_in[9];
  float* out = (float*)d_out;
  float* w = (float*)d_ws;

  if (ws_size < F_TOTAL * sizeof(float)) return;

  float* SIMS   = w + F_SIMS;
  float* GTSIM  = w + F_GTSIM;
  float* MM     = w + F_MM;
  float* SCORE  = w + F_SCORE;
  float* BBOX   = w + F_BBOX;
  float* TBOX   = w + F_TB;
  float* SB     = w + F_SB;
  float* SAREA  = w + F_SAREA;
  float* KB     = w + F_KB;
  float* ROWSUM = w + F_ROWSUM;
  float* OE     = w + F_OE;
  float* GSEL   = w + F_GSEL;
  float* MSUM   = w + F_MSUM;
  float* STGT   = w + F_STGT;
  float* SC     = w + F_SC;
  int*   CNT    = (int*)(w + F_CNT);
  int*   ORDER  = (int*)(w + F_ORDER);
  int*   NMSIDX = (int*)(w + F_NMSIDX);
  int*   SEL2   = (int*)(w + F_SEL2);
  int*   BSTART = (int*)(w + F_BSTART);
  int*   KINT   = (int*)(w + F_KINT);
  int*   CLS    = (int*)(w + F_CLS);
  int*   KEEPF  = (int*)(w + F_KEEPF);
  int*   LIST   = (int*)(w + F_LIST);
  u16* SIMTB = (u16*)(w + F_SIMTB);
  u16* OMT   = (u16*)(w + F_OMT);
  u16* TMT   = (u16*)(w + F_TMT);
  u16* GTP   = (u16*)(w + F_GTP);

  // zero accumulators + cell counts
  hipMemsetAsync(w + F_OE, 0, (F_ACCEND - F_OE) * sizeof(float), stream);

  k_gemm_t<<<dim3(22, 5), 256, 0, stream>>>(pl, ce, te, SIMS, GTSIM);
  k_post<<<BQ, 512, 0, stream>>>(SIMS, pb, tbb, tids, bidx, GTSIM, SCORE, BBOX, TBOX, ROWSUM, CLS);
  k_rank<<<(BQ + 255)/256, 256, 0, stream>>>(SCORE, ORDER);
  k_gather<<<(BQ + 255)/256, 256, 0, stream>>>(BBOX, ORDER, bidx, CLS, SB, SAREA, BSTART, CNT, LIST);
  k_cellnms<<<(BB*CC + 255)/256, 256, 0, stream>>>(SB, CNT, LIST, KEEPF);
  k_compact<<<1, 256, 0, stream>>>(KEEPF, ORDER, SB, NMSIDX, KB, KINT);
  k_gtsel<<<BQ, 512, 0, stream>>>(KB, TBOX, NMSIDX, pl, KINT, GSEL, OE);
  k_gtiou<<<1, 512, 0, stream>>>(GSEL, TBOX, SC);
  k_m<<<(NN*NN + 255)/256, 256, 0, stream>>>(te, OE, MM);
  k_ce<<<NN, 64, 0, stream>>>(MM, SC);
  k_sel2<<<NN, 256, 0, stream>>>(SIMS, SEL2);
  k_om<<<NN*9, 256, 0, stream>>>(pm, tm, SEL2, MSUM, SC);
  k_sumtgt<<<1, 512, 0, stream>>>(bidx, ROWSUM, MSUM, STGT);

  t_simT<<<dim3(QP/32, 5, BB), 256, 0, stream>>>(SIMS, SIMTB);
  t_omT<<<dim3(QP/32, WHX/64), 256, 0, stream>>>(pm, SEL2, OMT);
  t_tmT<<<dim3(NP/32, WHX/64), 256, 0, stream>>>(tm, TMT);
  t_gtp<<<(BB*CP*(KP/8) + 255)/256, 256, 0, stream>>>(GTSIM, BSTART, GTP);

  k_zsoft<<<dim3(WHX/64 * BB), 256, 0, stream>>>(SIMTB, OMT, GTP, TMT, BSTART, SC);
  k_final<<<1, 64, 0, stream>>>(SC, STGT, KINT, out);
}

// Round 8
// 302.021 us; speedup vs baseline: 6.7562x; 1.1777x over previous
//
#include <hip/hip_runtime.h>
#include <stdint.h>

#define DEVFN __device__ __forceinline__

typedef unsigned short u16;
typedef short bf16x8 __attribute__((ext_vector_type(8)));
typedef float f32x4 __attribute__((ext_vector_type(4)));

constexpr int BB = 8, QQ = 300, CC = 300, NN = 300, DD = 256;
constexpr int WHX = 9216, BQ = 2400, SIMW = 600;
constexpr int QP = 320;   // padded Q for MFMA K-dim
constexpr int CP = 304;   // padded C rows
constexpr int KP = 96;    // per-batch n-window
constexpr int NP = 416;   // padded tmT n-dim
constexpr int CELLCAP = 300;

// ---------------- workspace layout (float units) ----------------
constexpr size_t F_SIMS   = 0;                                 // [2400][600]
constexpr size_t F_GTSIM  = F_SIMS   + (size_t)BQ*SIMW;        // [300][300]
constexpr size_t F_MM     = F_GTSIM  + (size_t)NN*CC;          // [300][300]
constexpr size_t F_SCORE  = F_MM     + (size_t)NN*NN;          // [2400]
constexpr size_t F_BBOX   = F_SCORE  + BQ;                     // [2400][4]
constexpr size_t F_TB     = F_BBOX   + (size_t)BQ*4;           // [300][4]
constexpr size_t F_SB     = F_TB     + (size_t)NN*4;           // [2400][4]
constexpr size_t F_SAREA  = F_SB     + (size_t)BQ*4;           // [2400]
constexpr size_t F_KB     = F_SAREA  + BQ;                     // [2400][4]
constexpr size_t F_ROWSUM = F_KB     + (size_t)BQ*4;           // [300]
constexpr size_t F_OE     = F_ROWSUM + NN;                     // ---- zeroed zone
constexpr size_t F_GSEL   = F_OE     + (size_t)NN*DD;          // [300][4]
constexpr size_t F_MSUM   = F_GSEL   + (size_t)NN*4;           // [300]
constexpr size_t F_STGT   = F_MSUM   + NN;                     // [8]
constexpr size_t F_SC     = F_STGT   + 8;                      // scalars
constexpr size_t F_CNT    = F_SC     + 16;                     // int [2400] cell counts (zeroed)
constexpr size_t F_ACCEND = F_CNT    + BQ;                     // ---- end zeroed zone
constexpr size_t F_ORDER  = F_ACCEND;                          // int [2400]
constexpr size_t F_NMSIDX = F_ORDER  + BQ;                     // int [2400]
constexpr size_t F_SEL2   = F_NMSIDX + BQ;                     // int [300]
constexpr size_t F_BSTART = F_SEL2   + NN;                     // int [16]
constexpr size_t F_KINT   = F_BSTART + 16;                     // int [4]
constexpr size_t F_CLS    = F_KINT   + 4;                      // int [2400]
constexpr size_t F_KEEPF  = F_CLS    + BQ;                     // int [2400]
constexpr size_t F_LIST   = F_KEEPF  + BQ;                     // int [2400][300]
// bf16 panels (sizes in floats = ushorts/2), 32B-align starts
constexpr size_t F_SIMTB  = ((F_LIST + (size_t)BQ*CELLCAP + 7) & ~(size_t)7);  // u16[8][304][320]
constexpr size_t F_OMT    = F_SIMTB + (size_t)BB*CP*QP/2;           // u16[9216][320]
constexpr size_t F_TMT    = F_OMT   + (size_t)WHX*QP/2;             // u16[9216][416]
constexpr size_t F_GTP    = F_TMT   + (size_t)WHX*NP/2;             // u16[8][304][96]
constexpr size_t F_TOTAL  = F_GTP   + (size_t)BB*CP*KP/2;

// ---------------- JAX threefry2x32 (partitionable scheme) ----------------
DEVFN uint32_t rotl32(uint32_t v, int r){ return (v << r) | (v >> (32 - r)); }

DEVFN void tf2x32(uint32_t k0, uint32_t k1, uint32_t x0, uint32_t x1,
                  uint32_t& o0, uint32_t& o1){
  uint32_t ks2 = k0 ^ k1 ^ 0x1BD11BDAu;
  x0 += k0; x1 += k1;
#define TFR(r) x0 += x1; x1 = rotl32(x1, r); x1 ^= x0;
  TFR(13) TFR(15) TFR(26) TFR(6)   x0 += k1;  x1 += ks2 + 1u;
  TFR(17) TFR(29) TFR(16) TFR(24)  x0 += ks2; x1 += k0  + 2u;
  TFR(13) TFR(15) TFR(26) TFR(6)   x0 += k0;  x1 += k1  + 3u;
  TFR(17) TFR(29) TFR(16) TFR(24)  x0 += k1;  x1 += ks2 + 4u;
  TFR(13) TFR(15) TFR(26) TFR(6)   x0 += ks2; x1 += k0  + 5u;
#undef TFR
  o0 = x0; o1 = x1;
}

DEVFN void subkey(int i, uint32_t& k0, uint32_t& k1){
  tf2x32(0u, 42u, 0u, (uint32_t)i, k0, k1);
}

DEVFN float gumbel32(uint32_t k0, uint32_t k1, uint32_t idx){
  uint32_t h, l; tf2x32(k0, k1, 0u, idx, h, l);
  uint32_t bits = h ^ l;
  float f = __uint_as_float((bits >> 9) | 0x3F800000u) - 1.0f;
  const float tiny = 1.17549435e-38f;
  float u = fmaxf(tiny, f + tiny);
  return -logf(-logf(u));
}

DEVFN float iou_xyxy(float ax1,float ay1,float ax2,float ay2,
                     float bx1,float by1,float bx2,float by2){
  float aa = (ax2-ax1)*(ay2-ay1);
  float ab = (bx2-bx1)*(by2-by1);
  float lx = fmaxf(ax1,bx1), ly = fmaxf(ay1,by1);
  float rx = fminf(ax2,bx2), ry = fminf(ay2,by2);
  float iw = fmaxf(rx-lx,0.f), ih = fmaxf(ry-ly,0.f);
  float in_ = iw*ih;
  return in_/(aa+ab-in_);
}

DEVFN u16 f2bf(float x){
  uint32_t u = __float_as_uint(x);
  uint32_t r = u + 0x7FFFu + ((u >> 16) & 1u);
  return (u16)(r >> 16);
}

// ---------------- K1: tiled f32 GEMM: [pl;te](2700x256) x [ce;te]^T(256x600) ----------------
__global__ __launch_bounds__(256) void k_gemm_t(
    const float* __restrict__ pl, const float* __restrict__ ce,
    const float* __restrict__ te, float* __restrict__ sims,
    float* __restrict__ gtsim){
  __shared__ float As[16][128];
  __shared__ float Bs[16][128];
  const int row0 = blockIdx.x * 128, col0 = blockIdx.y * 128;
  const int tid = threadIdx.x;
  const int lrow = tid >> 1, lk0 = (tid & 1) * 8;
  const int tr = tid >> 4, tc = tid & 15;

  float acc[8][8];
  #pragma unroll
  for (int i = 0; i < 8; i++)
    #pragma unroll
    for (int j = 0; j < 8; j++) acc[i][j] = 0.f;

  const float4 z4 = {0.f,0.f,0.f,0.f};
  const int grow = row0 + lrow;
  const int gcol = col0 + lrow;
  const float* arow = nullptr;
  if (grow < 2400) arow = pl + (size_t)grow * DD;
  else if (grow < 2700) arow = te + (size_t)(grow - 2400) * DD;
  const float* brow = nullptr;
  if (gcol < 300) brow = ce + (size_t)gcol * DD;
  else if (gcol < 600) brow = te + (size_t)(gcol - 300) * DD;

  float4 av0 = arow ? *(const float4*)(arow + lk0)     : z4;
  float4 av1 = arow ? *(const float4*)(arow + lk0 + 4) : z4;
  float4 bv0 = brow ? *(const float4*)(brow + lk0)     : z4;
  float4 bv1 = brow ? *(const float4*)(brow + lk0 + 4) : z4;

  for (int step = 0; step < 16; step++){
    __syncthreads();
    #pragma unroll
    for (int j = 0; j < 4; j++){
      As[lk0 + j][lrow]     = ((const float*)&av0)[j];
      As[lk0 + 4 + j][lrow] = ((const float*)&av1)[j];
      Bs[lk0 + j][lrow]     = ((const float*)&bv0)[j];
      Bs[lk0 + 4 + j][lrow] = ((const float*)&bv1)[j];
    }
    __syncthreads();
    if (step + 1 < 16){
      const int k0 = (step + 1) * 16;
      av0 = arow ? *(const float4*)(arow + k0 + lk0)     : z4;
      av1 = arow ? *(const float4*)(arow + k0 + lk0 + 4) : z4;
      bv0 = brow ? *(const float4*)(brow + k0 + lk0)     : z4;
      bv1 = brow ? *(const float4*)(brow + k0 + lk0 + 4) : z4;
    }
    #pragma unroll
    for (int kk = 0; kk < 16; kk++){
      float4 a0 = *(const float4*)&As[kk][tr*8];
      float4 a1 = *(const float4*)&As[kk][tr*8 + 4];
      float4 b0 = *(const float4*)&Bs[kk][tc*8];
      float4 b1 = *(const float4*)&Bs[kk][tc*8 + 4];
      float a[8] = {a0.x,a0.y,a0.z,a0.w,a1.x,a1.y,a1.z,a1.w};
      float b[8] = {b0.x,b0.y,b0.z,b0.w,b1.x,b1.y,b1.z,b1.w};
      #pragma unroll
      for (int i = 0; i < 8; i++)
        #pragma unroll
        for (int j = 0; j < 8; j++)
          acc[i][j] = fmaf(a[i], b[j], acc[i][j]);
    }
  }

  #pragma unroll
  for (int i = 0; i < 8; i++){
    const int r = row0 + tr*8 + i;
    const int c0 = col0 + tc*8;
    if (r < 2400){
      if (c0 < 600){
        float4 o0 = {acc[i][0],acc[i][1],acc[i][2],acc[i][3]};
        float4 o1 = {acc[i][4],acc[i][5],acc[i][6],acc[i][7]};
        *(float4*)(sims + (size_t)r*SIMW + c0)     = o0;
        *(float4*)(sims + (size_t)r*SIMW + c0 + 4) = o1;
      }
    } else if (r < 2700){
      const int n = r - 2400;
      #pragma unroll
      for (int j = 0; j < 8; j++){
        int c = c0 + j;
        if (c < 300) gtsim[(size_t)n*CC + c] = acc[i][j];
      }
    }
  }
}

// ---------------- K2: per-bq scores/argmax(g0)/boxes/cls; tb rows; gtsim rowsums ----------------
__global__ __launch_bounds__(512) void k_post(
    const float* __restrict__ sims, const float* __restrict__ pb,
    const float* __restrict__ tbb, const int* __restrict__ tids,
    const int* __restrict__ bidx, const float* __restrict__ gtsim,
    float* __restrict__ score, float* __restrict__ bbox,
    float* __restrict__ tb, float* __restrict__ rowsum,
    int* __restrict__ clsout){
  int bq = blockIdx.x, tid = threadIdx.x;
  __shared__ float sv[512];
  __shared__ int   si[512];
  float v = (tid < CC) ? sims[(size_t)bq*SIMW + tid] : -INFINITY;
  sv[tid] = v; __syncthreads();
  for (int s = 256; s > 0; s >>= 1){ if (tid < s) sv[tid] = fmaxf(sv[tid], sv[tid+s]); __syncthreads(); }
  if (tid == 0) score[bq] = sv[0];
  __syncthreads();
  uint32_t gk0, gk1; subkey(0, gk0, gk1);
  float y = (tid < CC) ? v + gumbel32(gk0, gk1, (uint32_t)(bq*CC + tid)) : -INFINITY;
  sv[tid] = y; si[tid] = tid; __syncthreads();
  for (int s = 256; s > 0; s >>= 1){
    if (tid < s){
      float ov = sv[tid+s]; int oi = si[tid+s];
      if (ov > sv[tid] || (ov == sv[tid] && oi < si[tid])){ sv[tid] = ov; si[tid] = oi; }
    }
    __syncthreads();
  }
  if (tid == 0){
    int cls = si[0];
    clsout[bq] = cls;
    float ox = 224.0f * (float)cls;
    float oy = 224.0f * (float)(bq / QQ);
    float cx = pb[bq*4+0], cy = pb[bq*4+1], ww = pb[bq*4+2], hh = pb[bq*4+3];
    bbox[bq*4+0] = cx - 0.5f*ww + ox;
    bbox[bq*4+1] = cy - 0.5f*hh + oy;
    bbox[bq*4+2] = cx + 0.5f*ww + ox;
    bbox[bq*4+3] = cy + 0.5f*hh + oy;
  }
  if (bq < NN){
    __syncthreads();
    float rs = (tid < CC) ? gtsim[(size_t)bq*CC + tid] : 0.f;
    sv[tid] = rs; __syncthreads();
    for (int s = 256; s > 0; s >>= 1){ if (tid < s) sv[tid] += sv[tid+s]; __syncthreads(); }
    if (tid == 0) rowsum[bq] = sv[0];
    if (tid == 1){
      float gx = 224.0f * (float)tids[bq], gy = 224.0f * (float)bidx[bq];
      float cx = tbb[bq*4+0], cy = tbb[bq*4+1], ww = tbb[bq*4+2], hh = tbb[bq*4+3];
      tb[bq*4+0] = cx - 0.5f*ww + gx;
      tb[bq*4+1] = cy - 0.5f*hh + gy;
      tb[bq*4+2] = cx + 0.5f*ww + gx;
      tb[bq*4+3] = cy + 0.5f*hh + gy;
    }
  }
}

// ---------------- K3: rank sort — one block per element, block-parallel count ----------------
__global__ __launch_bounds__(256) void k_rank(
    const float* __restrict__ score, int* __restrict__ order){
  const int t = blockIdx.x;
  const int tid = threadIdx.x;
  const float st = score[t];
  int cnt = 0;
  for (int j = tid; j < BQ; j += 256){
    float sj = score[j];
    cnt += (sj > st) || (sj == st && j < t);
  }
  __shared__ int red[256];
  red[tid] = cnt; __syncthreads();
  for (int s = 128; s > 0; s >>= 1){
    if (tid < s) red[tid] += red[tid+s];
    __syncthreads();
  }
  if (tid == 0) order[red[0]] = t;
}

// ---------------- K4: gather sorted boxes/areas + batch starts + cell bucketing ----------------
__global__ __launch_bounds__(256) void k_gather(
    const float* __restrict__ bbox, const int* __restrict__ order,
    const int* __restrict__ bidx, const int* __restrict__ cls,
    float* __restrict__ sb, float* __restrict__ sarea,
    int* __restrict__ bstart, int* __restrict__ cnt,
    int* __restrict__ list){
  int t = blockIdx.x*256 + threadIdx.x;
  if (t < BQ){
    int o = order[t];
    float x1 = bbox[o*4+0], y1 = bbox[o*4+1], x2 = bbox[o*4+2], y2 = bbox[o*4+3];
    sb[t*4+0] = x1; sb[t*4+1] = y1; sb[t*4+2] = x2; sb[t*4+3] = y2;
    sarea[t] = (x2-x1)*(y2-y1);
    // bucket by (batch, argmax class) cell — cross-cell IoU is identically 0 (offsets >= 224)
    int key = (o / QQ) * CC + cls[o];
    int slot = atomicAdd(&cnt[key], 1);
    list[(size_t)key*CELLCAP + slot] = t;
  }
  if (blockIdx.x == 0 && threadIdx.x < 9){
    int b = threadIdx.x, c = 0;
    for (int n = 0; n < NN; n++) c += (bidx[n] < b);
    bstart[b] = c;
  }
}

// ---------------- K6': per-cell greedy NMS (one thread per (batch,class) cell) ----------------
__global__ __launch_bounds__(256) void k_cellnms(
    const float* __restrict__ sb, const int* __restrict__ cnt,
    const int* __restrict__ list, int* __restrict__ keepf){
  int key = blockIdx.x*256 + threadIdx.x;
  if (key >= BB*CC) return;
  int m = cnt[key];
  if (m <= 0) return;
  const int* lst = list + (size_t)key*CELLCAP;
  unsigned long long keptmask = 0ull;   // kept flags by cell-rank (m<=64 fast path)
  int prevp = -1;
  for (int a = 0; a < m; a++){
    // a-th smallest sorted-position in this cell
    int pa = 0x7fffffff;
    for (int j = 0; j < m; j++){
      int pj = lst[j];
      if (pj > prevp && pj < pa) pa = pj;
    }
    prevp = pa;
    float4 A = ((const float4*)sb)[pa];
    float areaA = (A.z-A.x)*(A.w-A.y);
    bool kept = true;
    int pbprev = -1;
    for (int b2 = 0; b2 < a; b2++){
      int pb = 0x7fffffff;
      for (int j = 0; j < m; j++){
        int pj = lst[j];
        if (pj > pbprev && pj < pb) pb = pj;
      }
      pbprev = pb;
      bool keptb = (m <= 64) ? (((keptmask >> b2) & 1ull) != 0ull) : (keepf[pb] != 0);
      if (!keptb) continue;
      float4 B = ((const float4*)sb)[pb];
      float areaB = (B.z-B.x)*(B.w-B.y);
      float lx = fmaxf(A.x,B.x), ly = fmaxf(A.y,B.y);
      float rx = fminf(A.z,B.z), ry = fminf(A.w,B.w);
      float iw = fmaxf(rx-lx,0.f), ih = fmaxf(ry-ly,0.f);
      float inter = iw*ih;
      if (inter/(areaA + areaB - inter) > 0.5f){ kept = false; break; }
    }
    if (m <= 64 && kept) keptmask |= (1ull << a);
    keepf[pa] = kept ? 1 : 0;
  }
}

// ---------------- K7: compact ----------------
__global__ __launch_bounds__(256) void k_compact(
    const int* __restrict__ keepflag, const int* __restrict__ order,
    const float* __restrict__ sb, int* __restrict__ nmsidx,
    float* __restrict__ kb, int* __restrict__ kint){
  __shared__ int csum[256];
  int tid = threadIdx.x;
  int p0 = tid*10;
  int keepf[10];
  int cnt = 0;
  #pragma unroll
  for (int d = 0; d < 10; d++){
    int p = p0 + d;
    int k = 0;
    if (p < BQ) k = keepflag[p];
    keepf[d] = k; cnt += k;
  }
  csum[tid] = cnt; __syncthreads();
  for (int s = 1; s < 256; s <<= 1){
    int add = (tid >= s) ? csum[tid - s] : 0;
    __syncthreads();
    csum[tid] += add;
    __syncthreads();
  }
  int pos = csum[tid] - cnt;
  #pragma unroll
  for (int d = 0; d < 10; d++){
    if (keepf[d]){
      int p = p0 + d;
      nmsidx[pos] = order[p];
      ((float4*)kb)[pos] = ((const float4*)sb)[p];
      pos++;
    }
  }
  if (tid == 255) kint[0] = csum[255];
}

// ---------------- K8: per-kept-box scatter ----------------
__global__ __launch_bounds__(512) void k_gtsel(
    const float* __restrict__ kb, const float* __restrict__ tb,
    const int* __restrict__ nmsidx, const float* __restrict__ pl,
    const int* __restrict__ kint, float* __restrict__ gsel,
    float* __restrict__ oe){
  int k = blockIdx.x;
  if (k >= kint[0]) return;
  int tid = threadIdx.x;
  __shared__ float sv[512];
  __shared__ int   si[512];
  float4 a = ((const float4*)kb)[k];
  float iou = -INFINITY;
  if (tid < NN){
    float4 t = ((const float4*)tb)[tid];
    iou = iou_xyxy(a.x,a.y,a.z,a.w, t.x,t.y,t.z,t.w);
    if (iou != iou) iou = 0.f;
  }
  sv[tid] = iou; __syncthreads();
  for (int s = 256; s > 0; s >>= 1){ if (tid < s) sv[tid] = fmaxf(sv[tid], sv[tid+s]); __syncthreads(); }
  float m = sv[0]; __syncthreads();
  float e = (tid < NN) ? expf(iou - m) : 0.f;
  sv[tid] = e; __syncthreads();
  for (int s = 256; s > 0; s >>= 1){ if (tid < s) sv[tid] += sv[tid+s]; __syncthreads(); }
  float S = sv[0]; __syncthreads();
  uint32_t gk0, gk1; subkey(1, gk0, gk1);
  float y = (tid < NN) ? (e / S + gumbel32(gk0, gk1, (uint32_t)(k*NN + tid))) : -INFINITY;
  sv[tid] = y; si[tid] = tid; __syncthreads();
  for (int s = 256; s > 0; s >>= 1){
    if (tid < s){
      float ov = sv[tid+s]; int oi = si[tid+s];
      if (ov > sv[tid] || (ov == sv[tid] && oi < si[tid])){ sv[tid] = ov; si[tid] = oi; }
    }
    __syncthreads();
  }
  int sel = si[0];
  if (tid < 4) atomicAdd(&gsel[sel*4 + tid], ((const float*)&a)[tid]);
  if (tid < DD) atomicAdd(&oe[(size_t)sel*DD + tid], pl[(size_t)nmsidx[k]*DD + tid]);
}

// ---------------- K9: gt_ious + l1 ----------------
__global__ __launch_bounds__(512) void k_gtiou(
    const float* __restrict__ gsel, const float* __restrict__ tb,
    float* __restrict__ sc){
  int tid = threadIdx.x;
  __shared__ float s1[512], s2[512];
  float a1 = 0.f, a2 = 0.f;
  if (tid < NN){
    float4 g = ((const float4*)gsel)[tid];
    float4 t = ((const float4*)tb)[tid];
    float iou = iou_xyxy(g.x,g.y,g.z,g.w, t.x,t.y,t.z,t.w);
    a1 = 1.f - iou;
    a2 = fabsf(g.x-t.x) + fabsf(g.y-t.y) + fabsf(g.z-t.z) + fabsf(g.w-t.w);
  }
  s1[tid] = a1; s2[tid] = a2; __syncthreads();
  for (int s = 256; s > 0; s >>= 1){
    if (tid < s){ s1[tid] += s1[tid+s]; s2[tid] += s2[tid+s]; }
    __syncthreads();
  }
  if (tid == 0){ sc[3] = s1[0]; sc[4] = s2[0]; }
}

// ---------------- K10: M = tgt_embs @ out_embs^T ----------------
__global__ __launch_bounds__(256) void k_m(
    const float* __restrict__ te, const float* __restrict__ oe,
    float* __restrict__ M){
  int idx = blockIdx.x*256 + threadIdx.x;
  if (idx >= NN*NN) return;
  int i = idx / NN, j = idx % NN;
  const float4* a4 = (const float4*)(te + (size_t)i*DD);
  const float4* b4 = (const float4*)(oe + (size_t)j*DD);
  float s = 0.f;
  #pragma unroll 8
  for (int t = 0; t < DD/4; t++){
    float4 x = a4[t], y = b4[t];
    s += x.x*y.x + x.y*y.y + x.z*y.z + x.w*y.w;
  }
  M[idx] = s;
}

// ---------------- K11: both cross-entropies ----------------
__global__ __launch_bounds__(64) void k_ce(
    const float* __restrict__ M, float* __restrict__ sc){
  int i = blockIdx.x, lane = threadIdx.x;
  float m = -INFINITY;
  for (int j = lane; j < NN; j += 64) m = fmaxf(m, M[(size_t)i*NN + j]);
  for (int o = 32; o > 0; o >>= 1) m = fmaxf(m, __shfl_xor(m, o));
  float s = 0.f;
  for (int j = lane; j < NN; j += 64) s += expf(M[(size_t)i*NN + j] - m);
  for (int o = 32; o > 0; o >>= 1) s += __shfl_xor(s, o);
  float lr = m + logf(s);
  float m2 = -INFINITY;
  for (int j = lane; j < NN; j += 64) m2 = fmaxf(m2, M[(size_t)j*NN + i]);
  for (int o = 32; o > 0; o >>= 1) m2 = fmaxf(m2, __shfl_xor(m2, o));
  float s2 = 0.f;
  for (int j = lane; j < NN; j += 64) s2 += expf(M[(size_t)j*NN + i] - m2);
  for (int o = 32; o > 0; o >>= 1) s2 += __shfl_xor(s2, o);
  float lc = m2 + logf(s2);
  if (lane == 0){
    float d = M[(size_t)i*NN + i];
    atomicAdd(&sc[0], lr - d);
    atomicAdd(&sc[1], lc - d);
  }
}

// ---------------- K12: sel2 ----------------
__global__ __launch_bounds__(256) void k_sel2(
    const float* __restrict__ sims, int* __restrict__ sel2){
  int n = blockIdx.x, tid = threadIdx.x;
  uint32_t gk0, gk1; subkey(2, gk0, gk1);
  float best = -INFINITY; int bi = 0x7fffffff;
  for (int r = tid; r < BQ; r += 256){
    float v = sims[(size_t)r*SIMW + CC + n] + gumbel32(gk0, gk1, (uint32_t)(r*NN + n));
    if (v > best){ best = v; bi = r; }
  }
  __shared__ float sv[256];
  __shared__ int   si[256];
  sv[tid] = best; si[tid] = bi; __syncthreads();
  for (int s = 128; s > 0; s >>= 1){
    if (tid < s){
      float ov = sv[tid+s]; int oi = si[tid+s];
      if (ov > sv[tid] || (ov == sv[tid] && oi < si[tid])){ sv[tid] = ov; si[tid] = oi; }
    }
    __syncthreads();
  }
  if (tid == 0) sel2[n] = si[0];
}

// ---------------- K13: overall_mask_loss + masksum ----------------
__global__ __launch_bounds__(256) void k_om(
    const float* __restrict__ pm, const float* __restrict__ tm,
    const int* __restrict__ sel2, float* __restrict__ msum,
    float* __restrict__ sc){
  int nb = blockIdx.x;
  int n = nb / 9, ch = nb % 9;
  int c0 = ch*1024 + threadIdx.x*4;
  const float4 o4 = *(const float4*)(pm + (size_t)sel2[n]*WHX + c0);
  const float4 t4 = *(const float4*)(tm + (size_t)n*WHX + c0);
  float dx = o4.x-t4.x, dy = o4.y-t4.y, dz = o4.z-t4.z, dw = o4.w-t4.w;
  float d2 = dx*dx + dy*dy + dz*dz + dw*dw;
  float ts = t4.x + t4.y + t4.z + t4.w;
  __shared__ float r1[256], r2[256];
  r1[threadIdx.x] = d2; r2[threadIdx.x] = ts; __syncthreads();
  for (int s = 128; s > 0; s >>= 1){
    if (threadIdx.x < s){ r1[threadIdx.x] += r1[threadIdx.x+s]; r2[threadIdx.x] += r2[threadIdx.x+s]; }
    __syncthreads();
  }
  if (threadIdx.x == 0){ atomicAdd(&sc[2], r1[0]); atomicAdd(&msum[n], r2[0]); }
}

// ---------------- K14: sum_tgt[b] ----------------
__global__ __launch_bounds__(512) void k_sumtgt(
    const int* __restrict__ bidx, const float* __restrict__ rowsum,
    const float* __restrict__ msum, float* __restrict__ stgt){
  int n = threadIdx.x;
  if (n >= NN) return;
  atomicAdd(&stgt[bidx[n]], rowsum[n] * msum[n]);
}

// ---------------- T1: sims f32 -> simTb bf16 [8][304][320] (transpose) ----------------
__global__ __launch_bounds__(256) void t_simT(
    const float* __restrict__ sims, u16* __restrict__ simTb){
  __shared__ float ld[32][65];
  int q0 = blockIdx.x*32, c0 = blockIdx.y*64, b = blockIdx.z;
  int tid = threadIdx.x;
  for (int i = tid; i < 32*64; i += 256){
    int qi = i >> 6, ci = i & 63;
    int q = q0 + qi, c = c0 + ci;
    ld[qi][ci] = (q < QQ && c < CC) ? sims[((size_t)b*QQ + q)*SIMW + c] : 0.f;
  }
  __syncthreads();
  int cloc = tid >> 2, j0 = (tid & 3)*8;
  int c = c0 + cloc;
  if (c < CP){
    u16 tmp[8];
    #pragma unroll
    for (int j = 0; j < 8; j++) tmp[j] = f2bf(ld[j0+j][cloc]);
    *(uint4*)(simTb + ((size_t)b*CP + c)*QP + q0 + j0) = *(const uint4*)tmp;
  }
}

// ---------------- T2: omT bf16 [9216][320] = pm[sel2[q]][wh]/96 (transpose) ----------------
__global__ __launch_bounds__(256) void t_omT(
    const float* __restrict__ pm, const int* __restrict__ sel2,
    u16* __restrict__ omT){
  __shared__ float ld[32][65];
  int q0 = blockIdx.x*32, wh0 = blockIdx.y*64;
  int tid = threadIdx.x;
  for (int i = tid; i < 32*64; i += 256){
    int qi = i >> 6, wi = i & 63;
    int q = q0 + qi;
    ld[qi][wi] = (q < QQ) ? pm[(size_t)sel2[q]*WHX + wh0 + wi] * (1.0f/96.0f) : 0.f;
  }
  __syncthreads();
  int wloc = tid >> 2, j0 = (tid & 3)*8;
  u16 tmp[8];
  #pragma unroll
  for (int j = 0; j < 8; j++) tmp[j] = f2bf(ld[j0+j][wloc]);
  *(uint4*)(omT + (size_t)(wh0+wloc)*QP + q0 + j0) = *(const uint4*)tmp;
}

// ---------------- T3: tmT bf16 [9216][416] (transpose, zero-padded) ----------------
__global__ __launch_bounds__(256) void t_tmT(
    const float* __restrict__ tm, u16* __restrict__ tmT){
  __shared__ float ld[32][65];
  int n0 = blockIdx.x*32, wh0 = blockIdx.y*64;
  int tid = threadIdx.x;
  for (int i = tid; i < 32*64; i += 256){
    int ni = i >> 6, wi = i & 63;
    int n = n0 + ni;
    ld[ni][wi] = (n < NN) ? tm[(size_t)n*WHX + wh0 + wi] : 0.f;
  }
  __syncthreads();
  int wloc = tid >> 2, j0 = (tid & 3)*8;
  u16 tmp[8];
  #pragma unroll
  for (int j = 0; j < 8; j++) tmp[j] = f2bf(ld[j0+j][wloc]);
  *(uint4*)(tmT + (size_t)(wh0+wloc)*NP + n0 + j0) = *(const uint4*)tmp;
}

// ---------------- T4: gtsimP bf16 [8][304][96] (per-batch zero-padded window) ----------------
__global__ __launch_bounds__(256) void t_gtp(
    const float* __restrict__ gtsim, const int* __restrict__ bstart,
    u16* __restrict__ gtp){
  int g = blockIdx.x*256 + threadIdx.x;
  if (g >= BB*CP*(KP/8)) return;
  int b = g / (CP*(KP/8));
  int rem = g - b*(CP*(KP/8));
  int c = rem / (KP/8);
  int kg = rem % (KP/8);
  int n0 = bstart[b], n1 = bstart[b+1];
  int kst = n0 & ~7;
  u16 tmp[8];
  #pragma unroll
  for (int j = 0; j < 8; j++){
    int n = kst + kg*8 + j;
    float v = (n >= n0 && n < n1 && c < CC) ? gtsim[(size_t)n*CC + c] : 0.f;
    tmp[j] = f2bf(v);
  }
  *(uint4*)(gtp + ((size_t)b*CP + c)*KP + kg*8) = *(const uint4*)tmp;
}

// ---------------- K15: MFMA z-GEMM + column softmax + dice (swizzled LDS A, XCD-pinned) ----------------
constexpr int ALDS = 32;  // LDS row stride in u16 (64 B, power of 2)
__global__ __launch_bounds__(256) void k_zsoft(
    const u16* __restrict__ simTb, const u16* __restrict__ omT,
    const u16* __restrict__ gtp, const u16* __restrict__ tmT,
    const int* __restrict__ bstart, float* __restrict__ sc){
  const int bid = blockIdx.x;
  const int b = bid & 7;
  const int tile = bid >> 3;
  const int tid = threadIdx.x;
  const int w = tid >> 6, l = tid & 63;
  const int lrow = l & 15, lgrp = l >> 4;
  const int col = tile*64 + w*16 + lrow;

  __shared__ u16 As[CP*ALDS];   // 19456 B
  __shared__ float red[256];

  const u16* Ab = simTb + (size_t)b*CP*QP;
  const int sidx[5] = {tid, tid+256, tid+512, tid+768, tid+1024};
  int woff[5];
  #pragma unroll
  for (int i = 0; i < 5; i++){
    int r = sidx[i] >> 2, g = sidx[i] & 3;
    woff[i] = r*ALDS + ((g ^ ((r >> 1) & 3)) << 3);
  }
  const int roff = (lgrp ^ ((lrow >> 1) & 3)) << 3;

  uint4 pf0, pf1, pf2, pf3, pf4;
  {
    int r, g;
    r = sidx[0] >> 2; g = sidx[0] & 3; pf0 = *(const uint4*)(Ab + (size_t)r*QP + g*8);
    r = sidx[1] >> 2; g = sidx[1] & 3; pf1 = *(const uint4*)(Ab + (size_t)r*QP + g*8);
    r = sidx[2] >> 2; g = sidx[2] & 3; pf2 = *(const uint4*)(Ab + (size_t)r*QP + g*8);
    r = sidx[3] >> 2; g = sidx[3] & 3; pf3 = *(const uint4*)(Ab + (size_t)r*QP + g*8);
    if (sidx[4] < 1216){ r = sidx[4] >> 2; g = sidx[4] & 3; pf4 = *(const uint4*)(Ab + (size_t)r*QP + g*8); }
  }
  const u16* pB = omT + (size_t)col*QP;
  bf16x8 bcur = *(const bf16x8*)(pB);

  f32x4 acc[19];
  #pragma unroll
  for (int t = 0; t < 19; t++) acc[t] = (f32x4){0.f,0.f,0.f,0.f};

  for (int ks = 0; ks < 10; ks++){
    *(uint4*)&As[woff[0]] = pf0;
    *(uint4*)&As[woff[1]] = pf1;
    *(uint4*)&As[woff[2]] = pf2;
    *(uint4*)&As[woff[3]] = pf3;
    if (sidx[4] < 1216) *(uint4*)&As[woff[4]] = pf4;
    __syncthreads();
    bf16x8 bnext;
    if (ks + 1 < 10){
      const size_t ko = (size_t)(ks + 1) * 32;
      int r, g;
      r = sidx[0] >> 2; g = sidx[0] & 3; pf0 = *(const uint4*)(Ab + (size_t)r*QP + ko + g*8);
      r = sidx[1] >> 2; g = sidx[1] & 3; pf1 = *(const uint4*)(Ab + (size_t)r*QP + ko + g*8);
      r = sidx[2] >> 2; g = sidx[2] & 3; pf2 = *(const uint4*)(Ab + (size_t)r*QP + ko + g*8);
      r = sidx[3] >> 2; g = sidx[3] & 3; pf3 = *(const uint4*)(Ab + (size_t)r*QP + ko + g*8);
      if (sidx[4] < 1216){ r = sidx[4] >> 2; g = sidx[4] & 3; pf4 = *(const uint4*)(Ab + (size_t)r*QP + ko + g*8); }
      bnext = *(const bf16x8*)(pB + ko);
    }
    #pragma unroll
    for (int t = 0; t < 19; t++){
      bf16x8 af = *(const bf16x8*)&As[t*16*ALDS + lrow*ALDS + roff];
      acc[t] = __builtin_amdgcn_mfma_f32_16x16x32_bf16(af, bcur, acc[t], 0, 0, 0);
    }
    bcur = bnext;
    __syncthreads();
  }

  float lmax = -INFINITY;
  #pragma unroll
  for (int t = 0; t < 19; t++){
    if (t == 18 && lgrp == 3) continue;
    lmax = fmaxf(lmax, fmaxf(fmaxf(acc[t][0], acc[t][1]), fmaxf(acc[t][2], acc[t][3])));
  }
  lmax = fmaxf(lmax, __shfl_xor(lmax, 16));
  lmax = fmaxf(lmax, __shfl_xor(lmax, 32));
  float ls = 0.f;
  #pragma unroll
  for (int t = 0; t < 19; t++){
    if (t == 18 && lgrp == 3){
      acc[t] = (f32x4){0.f,0.f,0.f,0.f};
      continue;
    }
    float p0 = __expf(acc[t][0] - lmax);
    float p1 = __expf(acc[t][1] - lmax);
    float p2 = __expf(acc[t][2] - lmax);
    float p3 = __expf(acc[t][3] - lmax);
    acc[t][0] = p0; acc[t][1] = p1; acc[t][2] = p2; acc[t][3] = p3;
    ls += p0 + p1 + p2 + p3;
  }
  float S = ls;
  S += __shfl_xor(S, 16);
  S += __shfl_xor(S, 32);
  float inv = 1.f / S;

  int n0 = bstart[b];
  int kst = n0 & ~7;
  const u16* tB = tmT + (size_t)col*NP + kst + lgrp*8;
  bf16x8 b2a = *(const bf16x8*)(tB);
  bf16x8 b2b = *(const bf16x8*)(tB + 32);
  bf16x8 b2c = *(const bf16x8*)(tB + 64);
  const u16* A2 = gtp + (size_t)b*CP*KP + lgrp*8;
  float dl = 0.f;
  #pragma unroll
  for (int t = 0; t < 19; t++){
    const u16* ar = A2 + (size_t)(t*16 + lrow)*KP;
    f32x4 rr = (f32x4){0.f,0.f,0.f,0.f};
    rr = __builtin_amdgcn_mfma_f32_16x16x32_bf16(*(const bf16x8*)(ar),      b2a, rr, 0, 0, 0);
    rr = __builtin_amdgcn_mfma_f32_16x16x32_bf16(*(const bf16x8*)(ar + 32), b2b, rr, 0, 0, 0);
    rr = __builtin_amdgcn_mfma_f32_16x16x32_bf16(*(const bf16x8*)(ar + 64), b2c, rr, 0, 0, 0);
    dl += acc[t][0]*rr[0] + acc[t][1]*rr[1] + acc[t][2]*rr[2] + acc[t][3]*rr[3];
  }
  dl *= inv;

  red[tid] = dl; __syncthreads();
  for (int s = 128; s > 0; s >>= 1){
    if (tid < s) red[tid] += red[tid+s];
    __syncthreads();
  }
  if (tid == 0) atomicAdd(&sc[5], red[0]);
}

// ---------------- K16: finalize ----------------
__global__ __launch_bounds__(64) void k_final(
    const float* __restrict__ sc, const float* __restrict__ stgt,
    const int* __restrict__ kint, float* __restrict__ out){
  if (threadIdx.x != 0) return;
  float K = (float)kint[0];
  float cls = sc[0]/300.f + sc[1]/300.f;
  float stot = sc[5];
  float dice = 0.f;
  for (int b = 0; b < 8; b++) dice += stot / (9216.0f + stgt[b] + 1e-6f);
  dice *= (1.0f/8.0f);
  out[0] = cls;
  out[1] = dice;
  out[2] = (sc[2] / 2764800.0f) / K;
  out[3] = sc[3] / K;
  out[4] = sc[4] / K;
}

// ---------------- launch ----------------
extern "C" void kernel_launch(void* const* d_in, const int* in_sizes, int n_in,
                              void* d_out, int out_size, void* d_ws, size_t ws_size,
                              hipStream_t stream) {
  const float* ce  = (const float*)d_in[0];
  const float* pl  = (const float*)d_in[1];
  const float* pb  = (const float*)d_in[2];
  const float* pm  = (const float*)d_in[3];
  const float* tm  = (const float*)d_in[4];
  const float* te  = (const float*)d_in[5];
  const float* tbb = (const float*)d_in[6];
  const int*  tids = (const int*)d_in[8];
  const int*  bidx = (const int*)d_in[9];
  float* out = (float*)d_out;
  float* w = (float*)d_ws;

  if (ws_size < F_TOTAL * sizeof(float)) return;

  float* SIMS   = w + F_SIMS;
  float* GTSIM  = w + F_GTSIM;
  float* MM     = w + F_MM;
  float* SCORE  = w + F_SCORE;
  float* BBOX   = w + F_BBOX;
  float* TBOX   = w + F_TB;
  float* SB     = w + F_SB;
  float* SAREA  = w + F_SAREA;
  float* KB     = w + F_KB;
  float* ROWSUM = w + F_ROWSUM;
  float* OE     = w + F_OE;
  float* GSEL   = w + F_GSEL;
  float* MSUM   = w + F_MSUM;
  float* STGT   = w + F_STGT;
  float* SC     = w + F_SC;
  int*   CNT    = (int*)(w + F_CNT);
  int*   ORDER  = (int*)(w + F_ORDER);
  int*   NMSIDX = (int*)(w + F_NMSIDX);
  int*   SEL2   = (int*)(w + F_SEL2);
  int*   BSTART = (int*)(w + F_BSTART);
  int*   KINT   = (int*)(w + F_KINT);
  int*   CLS    = (int*)(w + F_CLS);
  int*   KEEPF  = (int*)(w + F_KEEPF);
  int*   LIST   = (int*)(w + F_LIST);
  u16* SIMTB = (u16*)(w + F_SIMTB);
  u16* OMT   = (u16*)(w + F_OMT);
  u16* TMT   = (u16*)(w + F_TMT);
  u16* GTP   = (u16*)(w + F_GTP);

  // zero accumulators + cell counts
  hipMemsetAsync(w + F_OE, 0, (F_ACCEND - F_OE) * sizeof(float), stream);

  k_gemm_t<<<dim3(22, 5), 256, 0, stream>>>(pl, ce, te, SIMS, GTSIM);
  k_post<<<BQ, 512, 0, stream>>>(SIMS, pb, tbb, tids, bidx, GTSIM, SCORE, BBOX, TBOX, ROWSUM, CLS);
  k_rank<<<BQ, 256, 0, stream>>>(SCORE, ORDER);
  k_gather<<<(BQ + 255)/256, 256, 0, stream>>>(BBOX, ORDER, bidx, CLS, SB, SAREA, BSTART, CNT, LIST);
  k_cellnms<<<(BB*CC + 255)/256, 256, 0, stream>>>(SB, CNT, LIST, KEEPF);
  k_compact<<<1, 256, 0, stream>>>(KEEPF, ORDER, SB, NMSIDX, KB, KINT);
  k_gtsel<<<BQ, 512, 0, stream>>>(KB, TBOX, NMSIDX, pl, KINT, GSEL, OE);
  k_gtiou<<<1, 512, 0, stream>>>(GSEL, TBOX, SC);
  k_m<<<(NN*NN + 255)/256, 256, 0, stream>>>(te, OE, MM);
  k_ce<<<NN, 64, 0, stream>>>(MM, SC);
  k_sel2<<<NN, 256, 0, stream>>>(SIMS, SEL2);
  k_om<<<NN*9, 256, 0, stream>>>(pm, tm, SEL2, MSUM, SC);
  k_sumtgt<<<1, 512, 0, stream>>>(bidx, ROWSUM, MSUM, STGT);

  t_simT<<<dim3(QP/32, 5, BB), 256, 0, stream>>>(SIMS, SIMTB);
  t_omT<<<dim3(QP/32, WHX/64), 256, 0, stream>>>(pm, SEL2, OMT);
  t_tmT<<<dim3(NP/32, WHX/64), 256, 0, stream>>>(tm, TMT);
  t_gtp<<<(BB*CP*(KP/8) + 255)/256, 256, 0, stream>>>(GTSIM, BSTART, GTP);

  k_zsoft<<<dim3(WHX/64 * BB), 256, 0, stream>>>(SIMTB, OMT, GTP, TMT, BSTART, SC);
  k_final<<<1, 64, 0, stream>>>(SC, STGT, KINT, out);
}

// Round 9
// 290.307 us; speedup vs baseline: 7.0288x; 1.0404x over previous
//
#include <hip/hip_runtime.h>
#include <stdint.h>

#define DEVFN __device__ __forceinline__

typedef unsigned short u16;
typedef short bf16x8 __attribute__((ext_vector_type(8)));
typedef float f32x4 __attribute__((ext_vector_type(4)));

constexpr int BB = 8, QQ = 300, CC = 300, NN = 300, DD = 256;
constexpr int WHX = 9216, BQ = 2400, SIMW = 600;
constexpr int QP = 320;   // padded Q for MFMA K-dim
constexpr int CP = 304;   // padded C rows
constexpr int KP = 96;    // per-batch n-window
constexpr int NP = 416;   // padded tmT n-dim
constexpr int CELLCAP = 300;

// ---------------- workspace layout (float units) ----------------
constexpr size_t F_SIMS   = 0;                                 // [2400][600]
constexpr size_t F_GTSIM  = F_SIMS   + (size_t)BQ*SIMW;        // [300][300]
constexpr size_t F_MM     = F_GTSIM  + (size_t)NN*CC;          // [300][300]
constexpr size_t F_SCORE  = F_MM     + (size_t)NN*NN;          // [2400]
constexpr size_t F_BBOX   = F_SCORE  + BQ;                     // [2400][4]
constexpr size_t F_TB     = F_BBOX   + (size_t)BQ*4;           // [300][4]
constexpr size_t F_SB     = F_TB     + (size_t)NN*4;           // [2400][4]
constexpr size_t F_SAREA  = F_SB     + (size_t)BQ*4;           // [2400]
constexpr size_t F_KB     = F_SAREA  + BQ;                     // [2400][4]
constexpr size_t F_ROWSUM = F_KB     + (size_t)BQ*4;           // [300]
constexpr size_t F_OE     = F_ROWSUM + NN;                     // ---- zeroed zone
constexpr size_t F_GSEL   = F_OE     + (size_t)NN*DD;          // [300][4]
constexpr size_t F_MSUM   = F_GSEL   + (size_t)NN*4;           // [300]
constexpr size_t F_STGT   = F_MSUM   + NN;                     // [8]
constexpr size_t F_SC     = F_STGT   + 8;                      // scalars
constexpr size_t F_CNT    = F_SC     + 16;                     // int [2400] cell counts (zeroed)
constexpr size_t F_ACCEND = F_CNT    + BQ;                     // ---- end zeroed zone
constexpr size_t F_ORDER  = F_ACCEND;                          // int [2400]
constexpr size_t F_NMSIDX = F_ORDER  + BQ;                     // int [2400]
constexpr size_t F_SEL2   = F_NMSIDX + BQ;                     // int [300]
constexpr size_t F_BSTART = F_SEL2   + NN;                     // int [16]
constexpr size_t F_KINT   = F_BSTART + 16;                     // int [4]
constexpr size_t F_CLS    = F_KINT   + 4;                      // int [2400]
constexpr size_t F_KEEPF  = F_CLS    + BQ;                     // int [2400]
constexpr size_t F_LIST   = F_KEEPF  + BQ;                     // int [2400][300]
// bf16 panels (sizes in floats = ushorts/2), 32B-align starts
constexpr size_t F_SIMTB  = ((F_LIST + (size_t)BQ*CELLCAP + 7) & ~(size_t)7);  // u16[8][304][320]
constexpr size_t F_OMT    = F_SIMTB + (size_t)BB*CP*QP/2;           // u16[9216][320]
constexpr size_t F_TMT    = F_OMT   + (size_t)WHX*QP/2;             // u16[9216][416]
constexpr size_t F_GTP    = F_TMT   + (size_t)WHX*NP/2;             // u16[8][304][96]
constexpr size_t F_TOTAL  = F_GTP   + (size_t)BB*CP*KP/2;

// ---------------- JAX threefry2x32 (partitionable scheme) ----------------
DEVFN uint32_t rotl32(uint32_t v, int r){ return (v << r) | (v >> (32 - r)); }

DEVFN void tf2x32(uint32_t k0, uint32_t k1, uint32_t x0, uint32_t x1,
                  uint32_t& o0, uint32_t& o1){
  uint32_t ks2 = k0 ^ k1 ^ 0x1BD11BDAu;
  x0 += k0; x1 += k1;
#define TFR(r) x0 += x1; x1 = rotl32(x1, r); x1 ^= x0;
  TFR(13) TFR(15) TFR(26) TFR(6)   x0 += k1;  x1 += ks2 + 1u;
  TFR(17) TFR(29) TFR(16) TFR(24)  x0 += ks2; x1 += k0  + 2u;
  TFR(13) TFR(15) TFR(26) TFR(6)   x0 += k0;  x1 += k1  + 3u;
  TFR(17) TFR(29) TFR(16) TFR(24)  x0 += k1;  x1 += ks2 + 4u;
  TFR(13) TFR(15) TFR(26) TFR(6)   x0 += ks2; x1 += k0  + 5u;
#undef TFR
  o0 = x0; o1 = x1;
}

DEVFN void subkey(int i, uint32_t& k0, uint32_t& k1){
  tf2x32(0u, 42u, 0u, (uint32_t)i, k0, k1);
}

DEVFN float gumbel32(uint32_t k0, uint32_t k1, uint32_t idx){
  uint32_t h, l; tf2x32(k0, k1, 0u, idx, h, l);
  uint32_t bits = h ^ l;
  float f = __uint_as_float((bits >> 9) | 0x3F800000u) - 1.0f;
  const float tiny = 1.17549435e-38f;
  float u = fmaxf(tiny, f + tiny);
  return -logf(-logf(u));
}

DEVFN float iou_xyxy(float ax1,float ay1,float ax2,float ay2,
                     float bx1,float by1,float bx2,float by2){
  float aa = (ax2-ax1)*(ay2-ay1);
  float ab = (bx2-bx1)*(by2-by1);
  float lx = fmaxf(ax1,bx1), ly = fmaxf(ay1,by1);
  float rx = fminf(ax2,bx2), ry = fminf(ay2,by2);
  float iw = fmaxf(rx-lx,0.f), ih = fmaxf(ry-ly,0.f);
  float in_ = iw*ih;
  return in_/(aa+ab-in_);
}

DEVFN u16 f2bf(float x){
  uint32_t u = __float_as_uint(x);
  uint32_t r = u + 0x7FFFu + ((u >> 16) & 1u);
  return (u16)(r >> 16);
}

// ---------------- K1: tiled f32 GEMM 64x64: [pl;te](2700x256) x [ce;te]^T(256x600) ----------------
// 430 blocks (43x10) to fill all 256 CUs. fmaf chain per output k-ascending (bit-identical).
__global__ __launch_bounds__(256) void k_gemm_t(
    const float* __restrict__ pl, const float* __restrict__ ce,
    const float* __restrict__ te, float* __restrict__ sims,
    float* __restrict__ gtsim){
  __shared__ float As[16][64];
  __shared__ float Bs[16][64];
  const int row0 = blockIdx.x * 64, col0 = blockIdx.y * 64;
  const int tid = threadIdx.x;
  const int lrow = tid >> 2, lk0 = (tid & 3) * 4;   // load map: 64 rows x 16 k
  const int tr = tid >> 4, tc = tid & 15;           // compute map: 16x16 threads

  float acc[4][4];
  #pragma unroll
  for (int i = 0; i < 4; i++)
    #pragma unroll
    for (int j = 0; j < 4; j++) acc[i][j] = 0.f;

  const float4 z4 = {0.f,0.f,0.f,0.f};
  const int grow = row0 + lrow;
  const int gcol = col0 + lrow;
  const float* arow = nullptr;
  if (grow < 2400) arow = pl + (size_t)grow * DD;
  else if (grow < 2700) arow = te + (size_t)(grow - 2400) * DD;
  const float* brow = nullptr;
  if (gcol < 300) brow = ce + (size_t)gcol * DD;
  else if (gcol < 600) brow = te + (size_t)(gcol - 300) * DD;

  float4 av = arow ? *(const float4*)(arow + lk0) : z4;
  float4 bv = brow ? *(const float4*)(brow + lk0) : z4;

  for (int step = 0; step < 16; step++){
    __syncthreads();
    #pragma unroll
    for (int j = 0; j < 4; j++){
      As[lk0 + j][lrow] = ((const float*)&av)[j];
      Bs[lk0 + j][lrow] = ((const float*)&bv)[j];
    }
    __syncthreads();
    if (step + 1 < 16){
      const int k0 = (step + 1) * 16;
      av = arow ? *(const float4*)(arow + k0 + lk0) : z4;
      bv = brow ? *(const float4*)(brow + k0 + lk0) : z4;
    }
    #pragma unroll
    for (int kk = 0; kk < 16; kk++){
      float4 a4 = *(const float4*)&As[kk][tr*4];
      float4 b4 = *(const float4*)&Bs[kk][tc*4];
      float a[4] = {a4.x,a4.y,a4.z,a4.w};
      float b[4] = {b4.x,b4.y,b4.z,b4.w};
      #pragma unroll
      for (int i = 0; i < 4; i++)
        #pragma unroll
        for (int j = 0; j < 4; j++)
          acc[i][j] = fmaf(a[i], b[j], acc[i][j]);
    }
  }

  #pragma unroll
  for (int i = 0; i < 4; i++){
    const int r = row0 + tr*4 + i;
    const int c0 = col0 + tc*4;
    if (r < 2400){
      if (c0 < 600){
        float4 o0 = {acc[i][0],acc[i][1],acc[i][2],acc[i][3]};
        *(float4*)(sims + (size_t)r*SIMW + c0) = o0;
      }
    } else if (r < 2700){
      const int n = r - 2400;
      #pragma unroll
      for (int j = 0; j < 4; j++){
        int c = c0 + j;
        if (c < 300) gtsim[(size_t)n*CC + c] = acc[i][j];
      }
    }
  }
}

// ---------------- K2: per-bq scores/argmax(g0)/boxes/cls; tb rows; gtsim rowsums ----------------
__global__ __launch_bounds__(512) void k_post(
    const float* __restrict__ sims, const float* __restrict__ pb,
    const float* __restrict__ tbb, const int* __restrict__ tids,
    const int* __restrict__ bidx, const float* __restrict__ gtsim,
    float* __restrict__ score, float* __restrict__ bbox,
    float* __restrict__ tb, float* __restrict__ rowsum,
    int* __restrict__ clsout){
  int bq = blockIdx.x, tid = threadIdx.x;
  __shared__ float sv[512];
  __shared__ int   si[512];
  float v = (tid < CC) ? sims[(size_t)bq*SIMW + tid] : -INFINITY;
  sv[tid] = v; __syncthreads();
  for (int s = 256; s > 0; s >>= 1){ if (tid < s) sv[tid] = fmaxf(sv[tid], sv[tid+s]); __syncthreads(); }
  if (tid == 0) score[bq] = sv[0];
  __syncthreads();
  uint32_t gk0, gk1; subkey(0, gk0, gk1);
  float y = (tid < CC) ? v + gumbel32(gk0, gk1, (uint32_t)(bq*CC + tid)) : -INFINITY;
  sv[tid] = y; si[tid] = tid; __syncthreads();
  for (int s = 256; s > 0; s >>= 1){
    if (tid < s){
      float ov = sv[tid+s]; int oi = si[tid+s];
      if (ov > sv[tid] || (ov == sv[tid] && oi < si[tid])){ sv[tid] = ov; si[tid] = oi; }
    }
    __syncthreads();
  }
  if (tid == 0){
    int cls = si[0];
    clsout[bq] = cls;
    float ox = 224.0f * (float)cls;
    float oy = 224.0f * (float)(bq / QQ);
    float cx = pb[bq*4+0], cy = pb[bq*4+1], ww = pb[bq*4+2], hh = pb[bq*4+3];
    bbox[bq*4+0] = cx - 0.5f*ww + ox;
    bbox[bq*4+1] = cy - 0.5f*hh + oy;
    bbox[bq*4+2] = cx + 0.5f*ww + ox;
    bbox[bq*4+3] = cy + 0.5f*hh + oy;
  }
  if (bq < NN){
    __syncthreads();
    float rs = (tid < CC) ? gtsim[(size_t)bq*CC + tid] : 0.f;
    sv[tid] = rs; __syncthreads();
    for (int s = 256; s > 0; s >>= 1){ if (tid < s) sv[tid] += sv[tid+s]; __syncthreads(); }
    if (tid == 0) rowsum[bq] = sv[0];
    if (tid == 1){
      float gx = 224.0f * (float)tids[bq], gy = 224.0f * (float)bidx[bq];
      float cx = tbb[bq*4+0], cy = tbb[bq*4+1], ww = tbb[bq*4+2], hh = tbb[bq*4+3];
      tb[bq*4+0] = cx - 0.5f*ww + gx;
      tb[bq*4+1] = cy - 0.5f*hh + gy;
      tb[bq*4+2] = cx + 0.5f*ww + gx;
      tb[bq*4+3] = cy + 0.5f*hh + gy;
    }
  }
}

// ---------------- K3: rank sort — one block per element, block-parallel count ----------------
__global__ __launch_bounds__(256) void k_rank(
    const float* __restrict__ score, int* __restrict__ order){
  const int t = blockIdx.x;
  const int tid = threadIdx.x;
  const float st = score[t];
  int cnt = 0;
  for (int j = tid; j < BQ; j += 256){
    float sj = score[j];
    cnt += (sj > st) || (sj == st && j < t);
  }
  __shared__ int red[256];
  red[tid] = cnt; __syncthreads();
  for (int s = 128; s > 0; s >>= 1){
    if (tid < s) red[tid] += red[tid+s];
    __syncthreads();
  }
  if (tid == 0) order[red[0]] = t;
}

// ---------------- K4: gather sorted boxes/areas + batch starts + cell bucketing ----------------
__global__ __launch_bounds__(256) void k_gather(
    const float* __restrict__ bbox, const int* __restrict__ order,
    const int* __restrict__ bidx, const int* __restrict__ cls,
    float* __restrict__ sb, float* __restrict__ sarea,
    int* __restrict__ bstart, int* __restrict__ cnt,
    int* __restrict__ list){
  int t = blockIdx.x*256 + threadIdx.x;
  if (t < BQ){
    int o = order[t];
    float x1 = bbox[o*4+0], y1 = bbox[o*4+1], x2 = bbox[o*4+2], y2 = bbox[o*4+3];
    sb[t*4+0] = x1; sb[t*4+1] = y1; sb[t*4+2] = x2; sb[t*4+3] = y2;
    sarea[t] = (x2-x1)*(y2-y1);
    // bucket by (batch, argmax class) cell — cross-cell IoU is identically 0 (offsets >= 224)
    int key = (o / QQ) * CC + cls[o];
    int slot = atomicAdd(&cnt[key], 1);
    list[(size_t)key*CELLCAP + slot] = t;
  }
  if (blockIdx.x == 0 && threadIdx.x < 9){
    int b = threadIdx.x, c = 0;
    for (int n = 0; n < NN; n++) c += (bidx[n] < b);
    bstart[b] = c;
  }
}

// ---------------- K6': per-cell greedy NMS (one thread per (batch,class) cell) ----------------
__global__ __launch_bounds__(256) void k_cellnms(
    const float* __restrict__ sb, const int* __restrict__ cnt,
    const int* __restrict__ list, int* __restrict__ keepf){
  int key = blockIdx.x*256 + threadIdx.x;
  if (key >= BB*CC) return;
  int m = cnt[key];
  if (m <= 0) return;
  const int* lst = list + (size_t)key*CELLCAP;
  unsigned long long keptmask = 0ull;   // kept flags by cell-rank (m<=64 fast path)
  int prevp = -1;
  for (int a = 0; a < m; a++){
    int pa = 0x7fffffff;
    for (int j = 0; j < m; j++){
      int pj = lst[j];
      if (pj > prevp && pj < pa) pa = pj;
    }
    prevp = pa;
    float4 A = ((const float4*)sb)[pa];
    float areaA = (A.z-A.x)*(A.w-A.y);
    bool kept = true;
    int pbprev = -1;
    for (int b2 = 0; b2 < a; b2++){
      int pb = 0x7fffffff;
      for (int j = 0; j < m; j++){
        int pj = lst[j];
        if (pj > pbprev && pj < pb) pb = pj;
      }
      pbprev = pb;
      bool keptb = (m <= 64) ? (((keptmask >> b2) & 1ull) != 0ull) : (keepf[pb] != 0);
      if (!keptb) continue;
      float4 B = ((const float4*)sb)[pb];
      float areaB = (B.z-B.x)*(B.w-B.y);
      float lx = fmaxf(A.x,B.x), ly = fmaxf(A.y,B.y);
      float rx = fminf(A.z,B.z), ry = fminf(A.w,B.w);
      float iw = fmaxf(rx-lx,0.f), ih = fmaxf(ry-ly,0.f);
      float inter = iw*ih;
      if (inter/(areaA + areaB - inter) > 0.5f){ kept = false; break; }
    }
    if (m <= 64 && kept) keptmask |= (1ull << a);
    keepf[pa] = kept ? 1 : 0;
  }
}

// ---------------- K7: compact ----------------
__global__ __launch_bounds__(256) void k_compact(
    const int* __restrict__ keepflag, const int* __restrict__ order,
    const float* __restrict__ sb, int* __restrict__ nmsidx,
    float* __restrict__ kb, int* __restrict__ kint){
  __shared__ int csum[256];
  int tid = threadIdx.x;
  int p0 = tid*10;
  int keepf[10];
  int cnt = 0;
  #pragma unroll
  for (int d = 0; d < 10; d++){
    int p = p0 + d;
    int k = 0;
    if (p < BQ) k = keepflag[p];
    keepf[d] = k; cnt += k;
  }
  csum[tid] = cnt; __syncthreads();
  for (int s = 1; s < 256; s <<= 1){
    int add = (tid >= s) ? csum[tid - s] : 0;
    __syncthreads();
    csum[tid] += add;
    __syncthreads();
  }
  int pos = csum[tid] - cnt;
  #pragma unroll
  for (int d = 0; d < 10; d++){
    if (keepf[d]){
      int p = p0 + d;
      nmsidx[pos] = order[p];
      ((float4*)kb)[pos] = ((const float4*)sb)[p];
      pos++;
    }
  }
  if (tid == 255) kint[0] = csum[255];
}

// ---------------- K8: per-kept-box scatter ----------------
__global__ __launch_bounds__(512) void k_gtsel(
    const float* __restrict__ kb, const float* __restrict__ tb,
    const int* __restrict__ nmsidx, const float* __restrict__ pl,
    const int* __restrict__ kint, float* __restrict__ gsel,
    float* __restrict__ oe){
  int k = blockIdx.x;
  if (k >= kint[0]) return;
  int tid = threadIdx.x;
  __shared__ float sv[512];
  __shared__ int   si[512];
  float4 a = ((const float4*)kb)[k];
  float iou = -INFINITY;
  if (tid < NN){
    float4 t = ((const float4*)tb)[tid];
    iou = iou_xyxy(a.x,a.y,a.z,a.w, t.x,t.y,t.z,t.w);
    if (iou != iou) iou = 0.f;
  }
  sv[tid] = iou; __syncthreads();
  for (int s = 256; s > 0; s >>= 1){ if (tid < s) sv[tid] = fmaxf(sv[tid], sv[tid+s]); __syncthreads(); }
  float m = sv[0]; __syncthreads();
  float e = (tid < NN) ? expf(iou - m) : 0.f;
  sv[tid] = e; __syncthreads();
  for (int s = 256; s > 0; s >>= 1){ if (tid < s) sv[tid] += sv[tid+s]; __syncthreads(); }
  float S = sv[0]; __syncthreads();
  uint32_t gk0, gk1; subkey(1, gk0, gk1);
  float y = (tid < NN) ? (e / S + gumbel32(gk0, gk1, (uint32_t)(k*NN + tid))) : -INFINITY;
  sv[tid] = y; si[tid] = tid; __syncthreads();
  for (int s = 256; s > 0; s >>= 1){
    if (tid < s){
      float ov = sv[tid+s]; int oi = si[tid+s];
      if (ov > sv[tid] || (ov == sv[tid] && oi < si[tid])){ sv[tid] = ov; si[tid] = oi; }
    }
    __syncthreads();
  }
  int sel = si[0];
  if (tid < 4) atomicAdd(&gsel[sel*4 + tid], ((const float*)&a)[tid]);
  if (tid < DD) atomicAdd(&oe[(size_t)sel*DD + tid], pl[(size_t)nmsidx[k]*DD + tid]);
}

// ---------------- K9: gt_ious + l1 ----------------
__global__ __launch_bounds__(512) void k_gtiou(
    const float* __restrict__ gsel, const float* __restrict__ tb,
    float* __restrict__ sc){
  int tid = threadIdx.x;
  __shared__ float s1[512], s2[512];
  float a1 = 0.f, a2 = 0.f;
  if (tid < NN){
    float4 g = ((const float4*)gsel)[tid];
    float4 t = ((const float4*)tb)[tid];
    float iou = iou_xyxy(g.x,g.y,g.z,g.w, t.x,t.y,t.z,t.w);
    a1 = 1.f - iou;
    a2 = fabsf(g.x-t.x) + fabsf(g.y-t.y) + fabsf(g.z-t.z) + fabsf(g.w-t.w);
  }
  s1[tid] = a1; s2[tid] = a2; __syncthreads();
  for (int s = 256; s > 0; s >>= 1){
    if (tid < s){ s1[tid] += s1[tid+s]; s2[tid] += s2[tid+s]; }
    __syncthreads();
  }
  if (tid == 0){ sc[3] = s1[0]; sc[4] = s2[0]; }
}

// ---------------- K10: M = tgt_embs @ out_embs^T ----------------
__global__ __launch_bounds__(256) void k_m(
    const float* __restrict__ te, const float* __restrict__ oe,
    float* __restrict__ M){
  int idx = blockIdx.x*256 + threadIdx.x;
  if (idx >= NN*NN) return;
  int i = idx / NN, j = idx % NN;
  const float4* a4 = (const float4*)(te + (size_t)i*DD);
  const float4* b4 = (const float4*)(oe + (size_t)j*DD);
  float s = 0.f;
  #pragma unroll 8
  for (int t = 0; t < DD/4; t++){
    float4 x = a4[t], y = b4[t];
    s += x.x*y.x + x.y*y.y + x.z*y.z + x.w*y.w;
  }
  M[idx] = s;
}

// ---------------- K11: both cross-entropies ----------------
__global__ __launch_bounds__(64) void k_ce(
    const float* __restrict__ M, float* __restrict__ sc){
  int i = blockIdx.x, lane = threadIdx.x;
  float m = -INFINITY;
  for (int j = lane; j < NN; j += 64) m = fmaxf(m, M[(size_t)i*NN + j]);
  for (int o = 32; o > 0; o >>= 1) m = fmaxf(m, __shfl_xor(m, o));
  float s = 0.f;
  for (int j = lane; j < NN; j += 64) s += expf(M[(size_t)i*NN + j] - m);
  for (int o = 32; o > 0; o >>= 1) s += __shfl_xor(s, o);
  float lr = m + logf(s);
  float m2 = -INFINITY;
  for (int j = lane; j < NN; j += 64) m2 = fmaxf(m2, M[(size_t)j*NN + i]);
  for (int o = 32; o > 0; o >>= 1) m2 = fmaxf(m2, __shfl_xor(m2, o));
  float s2 = 0.f;
  for (int j = lane; j < NN; j += 64) s2 += expf(M[(size_t)j*NN + i] - m2);
  for (int o = 32; o > 0; o >>= 1) s2 += __shfl_xor(s2, o);
  float lc = m2 + logf(s2);
  if (lane == 0){
    float d = M[(size_t)i*NN + i];
    atomicAdd(&sc[0], lr - d);
    atomicAdd(&sc[1], lc - d);
  }
}

// ---------------- K12: sel2 ----------------
__global__ __launch_bounds__(256) void k_sel2(
    const float* __restrict__ sims, int* __restrict__ sel2){
  int n = blockIdx.x, tid = threadIdx.x;
  uint32_t gk0, gk1; subkey(2, gk0, gk1);
  float best = -INFINITY; int bi = 0x7fffffff;
  for (int r = tid; r < BQ; r += 256){
    float v = sims[(size_t)r*SIMW + CC + n] + gumbel32(gk0, gk1, (uint32_t)(r*NN + n));
    if (v > best){ best = v; bi = r; }
  }
  __shared__ float sv[256];
  __shared__ int   si[256];
  sv[tid] = best; si[tid] = bi; __syncthreads();
  for (int s = 128; s > 0; s >>= 1){
    if (tid < s){
      float ov = sv[tid+s]; int oi = si[tid+s];
      if (ov > sv[tid] || (ov == sv[tid] && oi < si[tid])){ sv[tid] = ov; si[tid] = oi; }
    }
    __syncthreads();
  }
  if (tid == 0) sel2[n] = si[0];
}

// ---------------- K13: overall_mask_loss + masksum ----------------
__global__ __launch_bounds__(256) void k_om(
    const float* __restrict__ pm, const float* __restrict__ tm,
    const int* __restrict__ sel2, float* __restrict__ msum,
    float* __restrict__ sc){
  int nb = blockIdx.x;
  int n = nb / 9, ch = nb % 9;
  int c0 = ch*1024 + threadIdx.x*4;
  const float4 o4 = *(const float4*)(pm + (size_t)sel2[n]*WHX + c0);
  const float4 t4 = *(const float4*)(tm + (size_t)n*WHX + c0);
  float dx = o4.x-t4.x, dy = o4.y-t4.y, dz = o4.z-t4.z, dw = o4.w-t4.w;
  float d2 = dx*dx + dy*dy + dz*dz + dw*dw;
  float ts = t4.x + t4.y + t4.z + t4.w;
  __shared__ float r1[256], r2[256];
  r1[threadIdx.x] = d2; r2[threadIdx.x] = ts; __syncthreads();
  for (int s = 128; s > 0; s >>= 1){
    if (threadIdx.x < s){ r1[threadIdx.x] += r1[threadIdx.x+s]; r2[threadIdx.x] += r2[threadIdx.x+s]; }
    __syncthreads();
  }
  if (threadIdx.x == 0){ atomicAdd(&sc[2], r1[0]); atomicAdd(&msum[n], r2[0]); }
}

// ---------------- K14: sum_tgt[b] ----------------
__global__ __launch_bounds__(512) void k_sumtgt(
    const int* __restrict__ bidx, const float* __restrict__ rowsum,
    const float* __restrict__ msum, float* __restrict__ stgt){
  int n = threadIdx.x;
  if (n >= NN) return;
  atomicAdd(&stgt[bidx[n]], rowsum[n] * msum[n]);
}

// ---------------- T1: sims f32 -> simTb bf16 [8][304][320] (transpose) ----------------
__global__ __launch_bounds__(256) void t_simT(
    const float* __restrict__ sims, u16* __restrict__ simTb){
  __shared__ float ld[32][65];
  int q0 = blockIdx.x*32, c0 = blockIdx.y*64, b = blockIdx.z;
  int tid = threadIdx.x;
  for (int i = tid; i < 32*64; i += 256){
    int qi = i >> 6, ci = i & 63;
    int q = q0 + qi, c = c0 + ci;
    ld[qi][ci] = (q < QQ && c < CC) ? sims[((size_t)b*QQ + q)*SIMW + c] : 0.f;
  }
  __syncthreads();
  int cloc = tid >> 2, j0 = (tid & 3)*8;
  int c = c0 + cloc;
  if (c < CP){
    u16 tmp[8];
    #pragma unroll
    for (int j = 0; j < 8; j++) tmp[j] = f2bf(ld[j0+j][cloc]);
    *(uint4*)(simTb + ((size_t)b*CP + c)*QP + q0 + j0) = *(const uint4*)tmp;
  }
}

// ---------------- T2: omT bf16 [9216][320] = pm[sel2[q]][wh]/96 (transpose) ----------------
__global__ __launch_bounds__(256) void t_omT(
    const float* __restrict__ pm, const int* __restrict__ sel2,
    u16* __restrict__ omT){
  __shared__ float ld[32][65];
  int q0 = blockIdx.x*32, wh0 = blockIdx.y*64;
  int tid = threadIdx.x;
  for (int i = tid; i < 32*64; i += 256){
    int qi = i >> 6, wi = i & 63;
    int q = q0 + qi;
    ld[qi][wi] = (q < QQ) ? pm[(size_t)sel2[q]*WHX + wh0 + wi] * (1.0f/96.0f) : 0.f;
  }
  __syncthreads();
  int wloc = tid >> 2, j0 = (tid & 3)*8;
  u16 tmp[8];
  #pragma unroll
  for (int j = 0; j < 8; j++) tmp[j] = f2bf(ld[j0+j][wloc]);
  *(uint4*)(omT + (size_t)(wh0+wloc)*QP + q0 + j0) = *(const uint4*)tmp;
}

// ---------------- T3: tmT bf16 [9216][416] (transpose, zero-padded) ----------------
__global__ __launch_bounds__(256) void t_tmT(
    const float* __restrict__ tm, u16* __restrict__ tmT){
  __shared__ float ld[32][65];
  int n0 = blockIdx.x*32, wh0 = blockIdx.y*64;
  int tid = threadIdx.x;
  for (int i = tid; i < 32*64; i += 256){
    int ni = i >> 6, wi = i & 63;
    int n = n0 + ni;
    ld[ni][wi] = (n < NN) ? tm[(size_t)n*WHX + wh0 + wi] : 0.f;
  }
  __syncthreads();
  int wloc = tid >> 2, j0 = (tid & 3)*8;
  u16 tmp[8];
  #pragma unroll
  for (int j = 0; j < 8; j++) tmp[j] = f2bf(ld[j0+j][wloc]);
  *(uint4*)(tmT + (size_t)(wh0+wloc)*NP + n0 + j0) = *(const uint4*)tmp;
}

// ---------------- T4: gtsimP bf16 [8][304][96] (per-batch zero-padded window) ----------------
__global__ __launch_bounds__(256) void t_gtp(
    const float* __restrict__ gtsim, const int* __restrict__ bstart,
    u16* __restrict__ gtp){
  int g = blockIdx.x*256 + threadIdx.x;
  if (g >= BB*CP*(KP/8)) return;
  int b = g / (CP*(KP/8));
  int rem = g - b*(CP*(KP/8));
  int c = rem / (KP/8);
  int kg = rem % (KP/8);
  int n0 = bstart[b], n1 = bstart[b+1];
  int kst = n0 & ~7;
  u16 tmp[8];
  #pragma unroll
  for (int j = 0; j < 8; j++){
    int n = kst + kg*8 + j;
    float v = (n >= n0 && n < n1 && c < CC) ? gtsim[(size_t)n*CC + c] : 0.f;
    tmp[j] = f2bf(v);
  }
  *(uint4*)(gtp + ((size_t)b*CP + c)*KP + kg*8) = *(const uint4*)tmp;
}

// ---------------- K15: MFMA z-GEMM + column softmax + dice ----------------
// 2 col-groups per wave: one A-fragment ds_read feeds 2 MFMAs (halves LDS read pressure).
// Block covers 128 wh cols; grid 72*8, b = bid&7 (XCD pin). Per-output math unchanged (bit-exact).
constexpr int ALDS = 32;  // LDS row stride in u16 (64 B, power of 2)
__global__ __launch_bounds__(256) void k_zsoft(
    const u16* __restrict__ simTb, const u16* __restrict__ omT,
    const u16* __restrict__ gtp, const u16* __restrict__ tmT,
    const int* __restrict__ bstart, float* __restrict__ sc){
  const int bid = blockIdx.x;
  const int b = bid & 7;
  const int tile = bid >> 3;
  const int tid = threadIdx.x;
  const int w = tid >> 6, l = tid & 63;
  const int lrow = l & 15, lgrp = l >> 4;
  const int col0 = tile*128 + w*32 + lrow;   // group 0 col; group 1 = col0+16

  __shared__ u16 As[CP*ALDS];   // 19456 B
  __shared__ float red[256];

  const u16* Ab = simTb + (size_t)b*CP*QP;
  const int sidx[5] = {tid, tid+256, tid+512, tid+768, tid+1024};
  int woff[5];
  #pragma unroll
  for (int i = 0; i < 5; i++){
    int r = sidx[i] >> 2, g = sidx[i] & 3;
    woff[i] = r*ALDS + ((g ^ ((r >> 1) & 3)) << 3);
  }
  const int roff = (lgrp ^ ((lrow >> 1) & 3)) << 3;

  uint4 pf0, pf1, pf2, pf3, pf4;
  {
    int r, g;
    r = sidx[0] >> 2; g = sidx[0] & 3; pf0 = *(const uint4*)(Ab + (size_t)r*QP + g*8);
    r = sidx[1] >> 2; g = sidx[1] & 3; pf1 = *(const uint4*)(Ab + (size_t)r*QP + g*8);
    r = sidx[2] >> 2; g = sidx[2] & 3; pf2 = *(const uint4*)(Ab + (size_t)r*QP + g*8);
    r = sidx[3] >> 2; g = sidx[3] & 3; pf3 = *(const uint4*)(Ab + (size_t)r*QP + g*8);
    if (sidx[4] < 1216){ r = sidx[4] >> 2; g = sidx[4] & 3; pf4 = *(const uint4*)(Ab + (size_t)r*QP + g*8); }
  }
  const u16* pB0 = omT + (size_t)col0*QP;
  const u16* pB1 = omT + (size_t)(col0+16)*QP;
  bf16x8 bcur0 = *(const bf16x8*)(pB0);
  bf16x8 bcur1 = *(const bf16x8*)(pB1);

  f32x4 acc0[19], acc1[19];
  #pragma unroll
  for (int t = 0; t < 19; t++){
    acc0[t] = (f32x4){0.f,0.f,0.f,0.f};
    acc1[t] = (f32x4){0.f,0.f,0.f,0.f};
  }

  for (int ks = 0; ks < 10; ks++){
    *(uint4*)&As[woff[0]] = pf0;
    *(uint4*)&As[woff[1]] = pf1;
    *(uint4*)&As[woff[2]] = pf2;
    *(uint4*)&As[woff[3]] = pf3;
    if (sidx[4] < 1216) *(uint4*)&As[woff[4]] = pf4;
    __syncthreads();
    bf16x8 bnext0, bnext1;
    if (ks + 1 < 10){
      const size_t ko = (size_t)(ks + 1) * 32;
      int r, g;
      r = sidx[0] >> 2; g = sidx[0] & 3; pf0 = *(const uint4*)(Ab + (size_t)r*QP + ko + g*8);
      r = sidx[1] >> 2; g = sidx[1] & 3; pf1 = *(const uint4*)(Ab + (size_t)r*QP + ko + g*8);
      r = sidx[2] >> 2; g = sidx[2] & 3; pf2 = *(const uint4*)(Ab + (size_t)r*QP + ko + g*8);
      r = sidx[3] >> 2; g = sidx[3] & 3; pf3 = *(const uint4*)(Ab + (size_t)r*QP + ko + g*8);
      if (sidx[4] < 1216){ r = sidx[4] >> 2; g = sidx[4] & 3; pf4 = *(const uint4*)(Ab + (size_t)r*QP + ko + g*8); }
      bnext0 = *(const bf16x8*)(pB0 + ko);
      bnext1 = *(const bf16x8*)(pB1 + ko);
    }
    #pragma unroll
    for (int t = 0; t < 19; t++){
      bf16x8 af = *(const bf16x8*)&As[t*16*ALDS + lrow*ALDS + roff];
      acc0[t] = __builtin_amdgcn_mfma_f32_16x16x32_bf16(af, bcur0, acc0[t], 0, 0, 0);
      acc1[t] = __builtin_amdgcn_mfma_f32_16x16x32_bf16(af, bcur1, acc1[t], 0, 0, 0);
    }
    bcur0 = bnext0; bcur1 = bnext1;
    __syncthreads();
  }

  // column softmax per group (padding rows 300..303: t==18 && lgrp==3)
  float lmax0 = -INFINITY, lmax1 = -INFINITY;
  #pragma unroll
  for (int t = 0; t < 19; t++){
    if (t == 18 && lgrp == 3) continue;
    lmax0 = fmaxf(lmax0, fmaxf(fmaxf(acc0[t][0], acc0[t][1]), fmaxf(acc0[t][2], acc0[t][3])));
    lmax1 = fmaxf(lmax1, fmaxf(fmaxf(acc1[t][0], acc1[t][1]), fmaxf(acc1[t][2], acc1[t][3])));
  }
  lmax0 = fmaxf(lmax0, __shfl_xor(lmax0, 16));
  lmax0 = fmaxf(lmax0, __shfl_xor(lmax0, 32));
  lmax1 = fmaxf(lmax1, __shfl_xor(lmax1, 16));
  lmax1 = fmaxf(lmax1, __shfl_xor(lmax1, 32));
  float ls0 = 0.f, ls1 = 0.f;
  #pragma unroll
  for (int t = 0; t < 19; t++){
    if (t == 18 && lgrp == 3){
      acc0[t] = (f32x4){0.f,0.f,0.f,0.f};
      acc1[t] = (f32x4){0.f,0.f,0.f,0.f};
      continue;
    }
    #pragma unroll
    for (int q = 0; q < 4; q++){
      float p0 = __expf(acc0[t][q] - lmax0);
      float p1 = __expf(acc1[t][q] - lmax1);
      acc0[t][q] = p0; acc1[t][q] = p1;
      ls0 += p0; ls1 += p1;
    }
  }
  float S0 = ls0, S1 = ls1;
  S0 += __shfl_xor(S0, 16); S0 += __shfl_xor(S0, 32);
  S1 += __shfl_xor(S1, 16); S1 += __shfl_xor(S1, 32);
  float inv0 = 1.f / S0, inv1 = 1.f / S1;

  // dice: R[c][wh] = sum_n gtsim[n][c] tm[n][wh] via MFMA in same D-layout
  int n0 = bstart[b];
  int kst = n0 & ~7;
  const u16* tB0 = tmT + (size_t)col0*NP + kst + lgrp*8;
  const u16* tB1 = tmT + (size_t)(col0+16)*NP + kst + lgrp*8;
  bf16x8 b2a0 = *(const bf16x8*)(tB0);
  bf16x8 b2b0 = *(const bf16x8*)(tB0 + 32);
  bf16x8 b2c0 = *(const bf16x8*)(tB0 + 64);
  bf16x8 b2a1 = *(const bf16x8*)(tB1);
  bf16x8 b2b1 = *(const bf16x8*)(tB1 + 32);
  bf16x8 b2c1 = *(const bf16x8*)(tB1 + 64);
  const u16* A2 = gtp + (size_t)b*CP*KP + lgrp*8;
  float dl0 = 0.f, dl1 = 0.f;
  #pragma unroll
  for (int t = 0; t < 19; t++){
    const u16* ar = A2 + (size_t)(t*16 + lrow)*KP;
    bf16x8 a0 = *(const bf16x8*)(ar);
    bf16x8 a1 = *(const bf16x8*)(ar + 32);
    bf16x8 a2 = *(const bf16x8*)(ar + 64);
    f32x4 r0 = (f32x4){0.f,0.f,0.f,0.f};
    r0 = __builtin_amdgcn_mfma_f32_16x16x32_bf16(a0, b2a0, r0, 0, 0, 0);
    r0 = __builtin_amdgcn_mfma_f32_16x16x32_bf16(a1, b2b0, r0, 0, 0, 0);
    r0 = __builtin_amdgcn_mfma_f32_16x16x32_bf16(a2, b2c0, r0, 0, 0, 0);
    f32x4 r1 = (f32x4){0.f,0.f,0.f,0.f};
    r1 = __builtin_amdgcn_mfma_f32_16x16x32_bf16(a0, b2a1, r1, 0, 0, 0);
    r1 = __builtin_amdgcn_mfma_f32_16x16x32_bf16(a1, b2b1, r1, 0, 0, 0);
    r1 = __builtin_amdgcn_mfma_f32_16x16x32_bf16(a2, b2c1, r1, 0, 0, 0);
    dl0 += acc0[t][0]*r0[0] + acc0[t][1]*r0[1] + acc0[t][2]*r0[2] + acc0[t][3]*r0[3];
    dl1 += acc1[t][0]*r1[0] + acc1[t][1]*r1[1] + acc1[t][2]*r1[2] + acc1[t][3]*r1[3];
  }
  float dl = dl0*inv0 + dl1*inv1;

  red[tid] = dl; __syncthreads();
  for (int s = 128; s > 0; s >>= 1){
    if (tid < s) red[tid] += red[tid+s];
    __syncthreads();
  }
  if (tid == 0) atomicAdd(&sc[5], red[0]);
}

// ---------------- K16: finalize ----------------
__global__ __launch_bounds__(64) void k_final(
    const float* __restrict__ sc, const float* __restrict__ stgt,
    const int* __restrict__ kint, float* __restrict__ out){
  if (threadIdx.x != 0) return;
  float K = (float)kint[0];
  float cls = sc[0]/300.f + sc[1]/300.f;
  float stot = sc[5];
  float dice = 0.f;
  for (int b = 0; b < 8; b++) dice += stot / (9216.0f + stgt[b] + 1e-6f);
  dice *= (1.0f/8.0f);
  out[0] = cls;
  out[1] = dice;
  out[2] = (sc[2] / 2764800.0f) / K;
  out[3] = sc[3] / K;
  out[4] = sc[4] / K;
}

// ---------------- launch ----------------
extern "C" void kernel_launch(void* const* d_in, const int* in_sizes, int n_in,
                              void* d_out, int out_size, void* d_ws, size_t ws_size,
                              hipStream_t stream) {
  const float* ce  = (const float*)d_in[0];
  const float* pl  = (const float*)d_in[1];
  const float* pb  = (const float*)d_in[2];
  const float* pm  = (const float*)d_in[3];
  const float* tm  = (const float*)d_in[4];
  const float* te  = (const float*)d_in[5];
  const float* tbb = (const float*)d_in[6];
  const int*  tids = (const int*)d_in[8];
  const int*  bidx = (const int*)d_in[9];
  float* out = (float*)d_out;
  float* w = (float*)d_ws;

  if (ws_size < F_TOTAL * sizeof(float)) return;

  float* SIMS   = w + F_SIMS;
  float* GTSIM  = w + F_GTSIM;
  float* MM     = w + F_MM;
  float* SCORE  = w + F_SCORE;
  float* BBOX   = w + F_BBOX;
  float* TBOX   = w + F_TB;
  float* SB     = w + F_SB;
  float* SAREA  = w + F_SAREA;
  float* KB     = w + F_KB;
  float* ROWSUM = w + F_ROWSUM;
  float* OE     = w + F_OE;
  float* GSEL   = w + F_GSEL;
  float* MSUM   = w + F_MSUM;
  float* STGT   = w + F_STGT;
  float* SC     = w + F_SC;
  int*   CNT    = (int*)(w + F_CNT);
  int*   ORDER  = (int*)(w + F_ORDER);
  int*   NMSIDX = (int*)(w + F_NMSIDX);
  int*   SEL2   = (int*)(w + F_SEL2);
  int*   BSTART = (int*)(w + F_BSTART);
  int*   KINT   = (int*)(w + F_KINT);
  int*   CLS    = (int*)(w + F_CLS);
  int*   KEEPF  = (int*)(w + F_KEEPF);
  int*   LIST   = (int*)(w + F_LIST);
  u16* SIMTB = (u16*)(w + F_SIMTB);
  u16* OMT   = (u16*)(w + F_OMT);
  u16* TMT   = (u16*)(w + F_TMT);
  u16* GTP   = (u16*)(w + F_GTP);

  // zero accumulators + cell counts
  hipMemsetAsync(w + F_OE, 0, (F_ACCEND - F_OE) * sizeof(float), stream);

  k_gemm_t<<<dim3(43, 10), 256, 0, stream>>>(pl, ce, te, SIMS, GTSIM);
  k_post<<<BQ, 512, 0, stream>>>(SIMS, pb, tbb, tids, bidx, GTSIM, SCORE, BBOX, TBOX, ROWSUM, CLS);
  k_rank<<<BQ, 256, 0, stream>>>(SCORE, ORDER);
  k_gather<<<(BQ + 255)/256, 256, 0, stream>>>(BBOX, ORDER, bidx, CLS, SB, SAREA, BSTART, CNT, LIST);
  k_cellnms<<<(BB*CC + 255)/256, 256, 0, stream>>>(SB, CNT, LIST, KEEPF);
  k_compact<<<1, 256, 0, stream>>>(KEEPF, ORDER, SB, NMSIDX, KB, KINT);
  k_gtsel<<<BQ, 512, 0, stream>>>(KB, TBOX, NMSIDX, pl, KINT, GSEL, OE);
  k_gtiou<<<1, 512, 0, stream>>>(GSEL, TBOX, SC);
  k_m<<<(NN*NN + 255)/256, 256, 0, stream>>>(te, OE, MM);
  k_ce<<<NN, 64, 0, stream>>>(MM, SC);
  k_sel2<<<NN, 256, 0, stream>>>(SIMS, SEL2);
  k_om<<<NN*9, 256, 0, stream>>>(pm, tm, SEL2, MSUM, SC);
  k_sumtgt<<<1, 512, 0, stream>>>(bidx, ROWSUM, MSUM, STGT);

  t_simT<<<dim3(QP/32, 5, BB), 256, 0, stream>>>(SIMS, SIMTB);
  t_omT<<<dim3(QP/32, WHX/64), 256, 0, stream>>>(pm, SEL2, OMT);
  t_tmT<<<dim3(NP/32, WHX/64), 256, 0, stream>>>(tm, TMT);
  t_gtp<<<(BB*CP*(KP/8) + 255)/256, 256, 0, stream>>>(GTSIM, BSTART, GTP);

  k_zsoft<<<dim3((WHX/128) * BB), 256, 0, stream>>>(SIMTB, OMT, GTP, TMT, BSTART, SC);
  k_final<<<1, 64, 0, stream>>>(SC, STGT, KINT, out);
}

// Round 10
// 280.579 us; speedup vs baseline: 7.2725x; 1.0347x over previous
//
#include <hip/hip_runtime.h>
#include <stdint.h>

#define DEVFN __device__ __forceinline__

typedef unsigned short u16;
typedef short bf16x8 __attribute__((ext_vector_type(8)));
typedef float f32x4 __attribute__((ext_vector_type(4)));

constexpr int BB = 8, QQ = 300, CC = 300, NN = 300, DD = 256;
constexpr int WHX = 9216, BQ = 2400, SIMW = 600;
constexpr int QP = 320;   // padded Q for MFMA K-dim
constexpr int CP = 304;   // padded C rows
constexpr int KP = 96;    // per-batch n-window
constexpr int NP = 416;   // padded tmT n-dim
constexpr int CELLCAP = 300;

// ---------------- workspace layout (float units) ----------------
constexpr size_t F_SIMS   = 0;                                 // [2400][600]
constexpr size_t F_GTSIM  = F_SIMS   + (size_t)BQ*SIMW;        // [300][300]
constexpr size_t F_MM     = F_GTSIM  + (size_t)NN*CC;          // [300][300]
constexpr size_t F_SCORE  = F_MM     + (size_t)NN*NN;          // [2400]
constexpr size_t F_BBOX   = F_SCORE  + BQ;                     // [2400][4]
constexpr size_t F_TB     = F_BBOX   + (size_t)BQ*4;           // [300][4]
constexpr size_t F_SB     = F_TB     + (size_t)NN*4;           // [2400][4]
constexpr size_t F_SAREA  = F_SB     + (size_t)BQ*4;           // [2400]
constexpr size_t F_KB     = F_SAREA  + BQ;                     // [2400][4]
constexpr size_t F_ROWSUM = F_KB     + (size_t)BQ*4;           // [300]
constexpr size_t F_OE     = F_ROWSUM + NN;                     // ---- zeroed zone
constexpr size_t F_GSEL   = F_OE     + (size_t)NN*DD;          // [300][4]
constexpr size_t F_MSUM   = F_GSEL   + (size_t)NN*4;           // [300]
constexpr size_t F_STGT   = F_MSUM   + NN;                     // [8]
constexpr size_t F_SC     = F_STGT   + 8;                      // scalars
constexpr size_t F_CNT    = F_SC     + 16;                     // int [2400] cell counts (zeroed)
constexpr size_t F_ACCEND = F_CNT    + BQ;                     // ---- end zeroed zone
constexpr size_t F_ORDER  = F_ACCEND;                          // int [2400]
constexpr size_t F_NMSIDX = F_ORDER  + BQ;                     // int [2400]
constexpr size_t F_SEL2   = F_NMSIDX + BQ;                     // int [300]
constexpr size_t F_BSTART = F_SEL2   + NN;                     // int [16]
constexpr size_t F_KINT   = F_BSTART + 16;                     // int [4]
constexpr size_t F_CLS    = F_KINT   + 4;                      // int [2400]
constexpr size_t F_KEEPF  = F_CLS    + BQ;                     // int [2400]
constexpr size_t F_LIST   = F_KEEPF  + BQ;                     // int [2400][300]
// bf16 panels (sizes in floats = ushorts/2), 32B-align starts
constexpr size_t F_SIMTB  = ((F_LIST + (size_t)BQ*CELLCAP + 7) & ~(size_t)7);  // u16[8][304][320]
constexpr size_t F_OMT    = F_SIMTB + (size_t)BB*CP*QP/2;           // u16[9216][320]
constexpr size_t F_TMT    = F_OMT   + (size_t)WHX*QP/2;             // u16[9216][416]
constexpr size_t F_GTP    = F_TMT   + (size_t)WHX*NP/2;             // u16[8][304][96]
constexpr size_t F_TOTAL  = F_GTP   + (size_t)BB*CP*KP/2;

// ---------------- JAX threefry2x32 (partitionable scheme) ----------------
DEVFN uint32_t rotl32(uint32_t v, int r){ return (v << r) | (v >> (32 - r)); }

DEVFN void tf2x32(uint32_t k0, uint32_t k1, uint32_t x0, uint32_t x1,
                  uint32_t& o0, uint32_t& o1){
  uint32_t ks2 = k0 ^ k1 ^ 0x1BD11BDAu;
  x0 += k0; x1 += k1;
#define TFR(r) x0 += x1; x1 = rotl32(x1, r); x1 ^= x0;
  TFR(13) TFR(15) TFR(26) TFR(6)   x0 += k1;  x1 += ks2 + 1u;
  TFR(17) TFR(29) TFR(16) TFR(24)  x0 += ks2; x1 += k0  + 2u;
  TFR(13) TFR(15) TFR(26) TFR(6)   x0 += k0;  x1 += k1  + 3u;
  TFR(17) TFR(29) TFR(16) TFR(24)  x0 += k1;  x1 += ks2 + 4u;
  TFR(13) TFR(15) TFR(26) TFR(6)   x0 += ks2; x1 += k0  + 5u;
#undef TFR
  o0 = x0; o1 = x1;
}

DEVFN void subkey(int i, uint32_t& k0, uint32_t& k1){
  tf2x32(0u, 42u, 0u, (uint32_t)i, k0, k1);
}

DEVFN float gumbel32(uint32_t k0, uint32_t k1, uint32_t idx){
  uint32_t h, l; tf2x32(k0, k1, 0u, idx, h, l);
  uint32_t bits = h ^ l;
  float f = __uint_as_float((bits >> 9) | 0x3F800000u) - 1.0f;
  const float tiny = 1.17549435e-38f;
  float u = fmaxf(tiny, f + tiny);
  return -logf(-logf(u));
}

DEVFN float iou_xyxy(float ax1,float ay1,float ax2,float ay2,
                     float bx1,float by1,float bx2,float by2){
  float aa = (ax2-ax1)*(ay2-ay1);
  float ab = (bx2-bx1)*(by2-by1);
  float lx = fmaxf(ax1,bx1), ly = fmaxf(ay1,by1);
  float rx = fminf(ax2,bx2), ry = fminf(ay2,by2);
  float iw = fmaxf(rx-lx,0.f), ih = fmaxf(ry-ly,0.f);
  float in_ = iw*ih;
  return in_/(aa+ab-in_);
}

DEVFN u16 f2bf(float x){
  uint32_t u = __float_as_uint(x);
  uint32_t r = u + 0x7FFFu + ((u >> 16) & 1u);
  return (u16)(r >> 16);
}

// ---------------- K1: tiled f32 GEMM 64x64: [pl;te](2700x256) x [ce;te]^T(256x600) ----------------
__global__ __launch_bounds__(256) void k_gemm_t(
    const float* __restrict__ pl, const float* __restrict__ ce,
    const float* __restrict__ te, float* __restrict__ sims,
    float* __restrict__ gtsim){
  __shared__ float As[16][64];
  __shared__ float Bs[16][64];
  const int row0 = blockIdx.x * 64, col0 = blockIdx.y * 64;
  const int tid = threadIdx.x;
  const int lrow = tid >> 2, lk0 = (tid & 3) * 4;
  const int tr = tid >> 4, tc = tid & 15;

  float acc[4][4];
  #pragma unroll
  for (int i = 0; i < 4; i++)
    #pragma unroll
    for (int j = 0; j < 4; j++) acc[i][j] = 0.f;

  const float4 z4 = {0.f,0.f,0.f,0.f};
  const int grow = row0 + lrow;
  const int gcol = col0 + lrow;
  const float* arow = nullptr;
  if (grow < 2400) arow = pl + (size_t)grow * DD;
  else if (grow < 2700) arow = te + (size_t)(grow - 2400) * DD;
  const float* brow = nullptr;
  if (gcol < 300) brow = ce + (size_t)gcol * DD;
  else if (gcol < 600) brow = te + (size_t)(gcol - 300) * DD;

  float4 av = arow ? *(const float4*)(arow + lk0) : z4;
  float4 bv = brow ? *(const float4*)(brow + lk0) : z4;

  for (int step = 0; step < 16; step++){
    __syncthreads();
    #pragma unroll
    for (int j = 0; j < 4; j++){
      As[lk0 + j][lrow] = ((const float*)&av)[j];
      Bs[lk0 + j][lrow] = ((const float*)&bv)[j];
    }
    __syncthreads();
    if (step + 1 < 16){
      const int k0 = (step + 1) * 16;
      av = arow ? *(const float4*)(arow + k0 + lk0) : z4;
      bv = brow ? *(const float4*)(brow + k0 + lk0) : z4;
    }
    #pragma unroll
    for (int kk = 0; kk < 16; kk++){
      float4 a4 = *(const float4*)&As[kk][tr*4];
      float4 b4 = *(const float4*)&Bs[kk][tc*4];
      float a[4] = {a4.x,a4.y,a4.z,a4.w};
      float b[4] = {b4.x,b4.y,b4.z,b4.w};
      #pragma unroll
      for (int i = 0; i < 4; i++)
        #pragma unroll
        for (int j = 0; j < 4; j++)
          acc[i][j] = fmaf(a[i], b[j], acc[i][j]);
    }
  }

  #pragma unroll
  for (int i = 0; i < 4; i++){
    const int r = row0 + tr*4 + i;
    const int c0 = col0 + tc*4;
    if (r < 2400){
      if (c0 < 600){
        float4 o0 = {acc[i][0],acc[i][1],acc[i][2],acc[i][3]};
        *(float4*)(sims + (size_t)r*SIMW + c0) = o0;
      }
    } else if (r < 2700){
      const int n = r - 2400;
      #pragma unroll
      for (int j = 0; j < 4; j++){
        int c = c0 + j;
        if (c < 300) gtsim[(size_t)n*CC + c] = acc[i][j];
      }
    }
  }
}

// ---------------- K2: per-bq scores/argmax(g0)/boxes/cls; tb rows; gtsim rowsums ----------------
__global__ __launch_bounds__(512) void k_post(
    const float* __restrict__ sims, const float* __restrict__ pb,
    const float* __restrict__ tbb, const int* __restrict__ tids,
    const int* __restrict__ bidx, const float* __restrict__ gtsim,
    float* __restrict__ score, float* __restrict__ bbox,
    float* __restrict__ tb, float* __restrict__ rowsum,
    int* __restrict__ clsout){
  int bq = blockIdx.x, tid = threadIdx.x;
  __shared__ float sv[512];
  __shared__ int   si[512];
  float v = (tid < CC) ? sims[(size_t)bq*SIMW + tid] : -INFINITY;
  sv[tid] = v; __syncthreads();
  for (int s = 256; s > 0; s >>= 1){ if (tid < s) sv[tid] = fmaxf(sv[tid], sv[tid+s]); __syncthreads(); }
  if (tid == 0) score[bq] = sv[0];
  __syncthreads();
  uint32_t gk0, gk1; subkey(0, gk0, gk1);
  float y = (tid < CC) ? v + gumbel32(gk0, gk1, (uint32_t)(bq*CC + tid)) : -INFINITY;
  sv[tid] = y; si[tid] = tid; __syncthreads();
  for (int s = 256; s > 0; s >>= 1){
    if (tid < s){
      float ov = sv[tid+s]; int oi = si[tid+s];
      if (ov > sv[tid] || (ov == sv[tid] && oi < si[tid])){ sv[tid] = ov; si[tid] = oi; }
    }
    __syncthreads();
  }
  if (tid == 0){
    int cls = si[0];
    clsout[bq] = cls;
    float ox = 224.0f * (float)cls;
    float oy = 224.0f * (float)(bq / QQ);
    float cx = pb[bq*4+0], cy = pb[bq*4+1], ww = pb[bq*4+2], hh = pb[bq*4+3];
    bbox[bq*4+0] = cx - 0.5f*ww + ox;
    bbox[bq*4+1] = cy - 0.5f*hh + oy;
    bbox[bq*4+2] = cx + 0.5f*ww + ox;
    bbox[bq*4+3] = cy + 0.5f*hh + oy;
  }
  if (bq < NN){
    __syncthreads();
    float rs = (tid < CC) ? gtsim[(size_t)bq*CC + tid] : 0.f;
    sv[tid] = rs; __syncthreads();
    for (int s = 256; s > 0; s >>= 1){ if (tid < s) sv[tid] += sv[tid+s]; __syncthreads(); }
    if (tid == 0) rowsum[bq] = sv[0];
    if (tid == 1){
      float gx = 224.0f * (float)tids[bq], gy = 224.0f * (float)bidx[bq];
      float cx = tbb[bq*4+0], cy = tbb[bq*4+1], ww = tbb[bq*4+2], hh = tbb[bq*4+3];
      tb[bq*4+0] = cx - 0.5f*ww + gx;
      tb[bq*4+1] = cy - 0.5f*hh + gy;
      tb[bq*4+2] = cx + 0.5f*ww + gx;
      tb[bq*4+3] = cy + 0.5f*hh + gy;
    }
  }
}

// ---------------- K3: rank sort — one block per element, block-parallel count ----------------
__global__ __launch_bounds__(256) void k_rank(
    const float* __restrict__ score, int* __restrict__ order){
  const int t = blockIdx.x;
  const int tid = threadIdx.x;
  const float st = score[t];
  int cnt = 0;
  for (int j = tid; j < BQ; j += 256){
    float sj = score[j];
    cnt += (sj > st) || (sj == st && j < t);
  }
  __shared__ int red[256];
  red[tid] = cnt; __syncthreads();
  for (int s = 128; s > 0; s >>= 1){
    if (tid < s) red[tid] += red[tid+s];
    __syncthreads();
  }
  if (tid == 0) order[red[0]] = t;
}

// ---------------- K4: gather sorted boxes/areas + batch starts + cell bucketing ----------------
__global__ __launch_bounds__(256) void k_gather(
    const float* __restrict__ bbox, const int* __restrict__ order,
    const int* __restrict__ bidx, const int* __restrict__ cls,
    float* __restrict__ sb, float* __restrict__ sarea,
    int* __restrict__ bstart, int* __restrict__ cnt,
    int* __restrict__ list){
  int t = blockIdx.x*256 + threadIdx.x;
  if (t < BQ){
    int o = order[t];
    float x1 = bbox[o*4+0], y1 = bbox[o*4+1], x2 = bbox[o*4+2], y2 = bbox[o*4+3];
    sb[t*4+0] = x1; sb[t*4+1] = y1; sb[t*4+2] = x2; sb[t*4+3] = y2;
    sarea[t] = (x2-x1)*(y2-y1);
    int key = (o / QQ) * CC + cls[o];
    int slot = atomicAdd(&cnt[key], 1);
    list[(size_t)key*CELLCAP + slot] = t;
  }
  if (blockIdx.x == 0 && threadIdx.x < 9){
    int b = threadIdx.x, c = 0;
    for (int n = 0; n < NN; n++) c += (bidx[n] < b);
    bstart[b] = c;
  }
}

// ---------------- K6': per-cell greedy NMS ----------------
__global__ __launch_bounds__(256) void k_cellnms(
    const float* __restrict__ sb, const int* __restrict__ cnt,
    const int* __restrict__ list, int* __restrict__ keepf){
  int key = blockIdx.x*256 + threadIdx.x;
  if (key >= BB*CC) return;
  int m = cnt[key];
  if (m <= 0) return;
  const int* lst = list + (size_t)key*CELLCAP;
  unsigned long long keptmask = 0ull;
  int prevp = -1;
  for (int a = 0; a < m; a++){
    int pa = 0x7fffffff;
    for (int j = 0; j < m; j++){
      int pj = lst[j];
      if (pj > prevp && pj < pa) pa = pj;
    }
    prevp = pa;
    float4 A = ((const float4*)sb)[pa];
    float areaA = (A.z-A.x)*(A.w-A.y);
    bool kept = true;
    int pbprev = -1;
    for (int b2 = 0; b2 < a; b2++){
      int pb = 0x7fffffff;
      for (int j = 0; j < m; j++){
        int pj = lst[j];
        if (pj > pbprev && pj < pb) pb = pj;
      }
      pbprev = pb;
      bool keptb = (m <= 64) ? (((keptmask >> b2) & 1ull) != 0ull) : (keepf[pb] != 0);
      if (!keptb) continue;
      float4 B = ((const float4*)sb)[pb];
      float areaB = (B.z-B.x)*(B.w-B.y);
      float lx = fmaxf(A.x,B.x), ly = fmaxf(A.y,B.y);
      float rx = fminf(A.z,B.z), ry = fminf(A.w,B.w);
      float iw = fmaxf(rx-lx,0.f), ih = fmaxf(ry-ly,0.f);
      float inter = iw*ih;
      if (inter/(areaA + areaB - inter) > 0.5f){ kept = false; break; }
    }
    if (m <= 64 && kept) keptmask |= (1ull << a);
    keepf[pa] = kept ? 1 : 0;
  }
}

// ---------------- K7: compact ----------------
__global__ __launch_bounds__(256) void k_compact(
    const int* __restrict__ keepflag, const int* __restrict__ order,
    const float* __restrict__ sb, int* __restrict__ nmsidx,
    float* __restrict__ kb, int* __restrict__ kint){
  __shared__ int csum[256];
  int tid = threadIdx.x;
  int p0 = tid*10;
  int keepf[10];
  int cnt = 0;
  #pragma unroll
  for (int d = 0; d < 10; d++){
    int p = p0 + d;
    int k = 0;
    if (p < BQ) k = keepflag[p];
    keepf[d] = k; cnt += k;
  }
  csum[tid] = cnt; __syncthreads();
  for (int s = 1; s < 256; s <<= 1){
    int add = (tid >= s) ? csum[tid - s] : 0;
    __syncthreads();
    csum[tid] += add;
    __syncthreads();
  }
  int pos = csum[tid] - cnt;
  #pragma unroll
  for (int d = 0; d < 10; d++){
    if (keepf[d]){
      int p = p0 + d;
      nmsidx[pos] = order[p];
      ((float4*)kb)[pos] = ((const float4*)sb)[p];
      pos++;
    }
  }
  if (tid == 255) kint[0] = csum[255];
}

// ---------------- K8: per-kept-box scatter ----------------
__global__ __launch_bounds__(512) void k_gtsel(
    const float* __restrict__ kb, const float* __restrict__ tb,
    const int* __restrict__ nmsidx, const float* __restrict__ pl,
    const int* __restrict__ kint, float* __restrict__ gsel,
    float* __restrict__ oe){
  int k = blockIdx.x;
  if (k >= kint[0]) return;
  int tid = threadIdx.x;
  __shared__ float sv[512];
  __shared__ int   si[512];
  float4 a = ((const float4*)kb)[k];
  float iou = -INFINITY;
  if (tid < NN){
    float4 t = ((const float4*)tb)[tid];
    iou = iou_xyxy(a.x,a.y,a.z,a.w, t.x,t.y,t.z,t.w);
    if (iou != iou) iou = 0.f;
  }
  sv[tid] = iou; __syncthreads();
  for (int s = 256; s > 0; s >>= 1){ if (tid < s) sv[tid] = fmaxf(sv[tid], sv[tid+s]); __syncthreads(); }
  float m = sv[0]; __syncthreads();
  float e = (tid < NN) ? expf(iou - m) : 0.f;
  sv[tid] = e; __syncthreads();
  for (int s = 256; s > 0; s >>= 1){ if (tid < s) sv[tid] += sv[tid+s]; __syncthreads(); }
  float S = sv[0]; __syncthreads();
  uint32_t gk0, gk1; subkey(1, gk0, gk1);
  float y = (tid < NN) ? (e / S + gumbel32(gk0, gk1, (uint32_t)(k*NN + tid))) : -INFINITY;
  sv[tid] = y; si[tid] = tid; __syncthreads();
  for (int s = 256; s > 0; s >>= 1){
    if (tid < s){
      float ov = sv[tid+s]; int oi = si[tid+s];
      if (ov > sv[tid] || (ov == sv[tid] && oi < si[tid])){ sv[tid] = ov; si[tid] = oi; }
    }
    __syncthreads();
  }
  int sel = si[0];
  if (tid < 4) atomicAdd(&gsel[sel*4 + tid], ((const float*)&a)[tid]);
  if (tid < DD) atomicAdd(&oe[(size_t)sel*DD + tid], pl[(size_t)nmsidx[k]*DD + tid]);
}

// ---------------- K9: gt_ious + l1 ----------------
__global__ __launch_bounds__(512) void k_gtiou(
    const float* __restrict__ gsel, const float* __restrict__ tb,
    float* __restrict__ sc){
  int tid = threadIdx.x;
  __shared__ float s1[512], s2[512];
  float a1 = 0.f, a2 = 0.f;
  if (tid < NN){
    float4 g = ((const float4*)gsel)[tid];
    float4 t = ((const float4*)tb)[tid];
    float iou = iou_xyxy(g.x,g.y,g.z,g.w, t.x,t.y,t.z,t.w);
    a1 = 1.f - iou;
    a2 = fabsf(g.x-t.x) + fabsf(g.y-t.y) + fabsf(g.z-t.z) + fabsf(g.w-t.w);
  }
  s1[tid] = a1; s2[tid] = a2; __syncthreads();
  for (int s = 256; s > 0; s >>= 1){
    if (tid < s){ s1[tid] += s1[tid+s]; s2[tid] += s2[tid+s]; }
    __syncthreads();
  }
  if (tid == 0){ sc[3] = s1[0]; sc[4] = s2[0]; }
}

// ---------------- K10: M = tgt_embs @ out_embs^T ----------------
__global__ __launch_bounds__(256) void k_m(
    const float* __restrict__ te, const float* __restrict__ oe,
    float* __restrict__ M){
  int idx = blockIdx.x*256 + threadIdx.x;
  if (idx >= NN*NN) return;
  int i = idx / NN, j = idx % NN;
  const float4* a4 = (const float4*)(te + (size_t)i*DD);
  const float4* b4 = (const float4*)(oe + (size_t)j*DD);
  float s = 0.f;
  #pragma unroll 8
  for (int t = 0; t < DD/4; t++){
    float4 x = a4[t], y = b4[t];
    s += x.x*y.x + x.y*y.y + x.z*y.z + x.w*y.w;
  }
  M[idx] = s;
}

// ---------------- K11: both cross-entropies ----------------
__global__ __launch_bounds__(64) void k_ce(
    const float* __restrict__ M, float* __restrict__ sc){
  int i = blockIdx.x, lane = threadIdx.x;
  float m = -INFINITY;
  for (int j = lane; j < NN; j += 64) m = fmaxf(m, M[(size_t)i*NN + j]);
  for (int o = 32; o > 0; o >>= 1) m = fmaxf(m, __shfl_xor(m, o));
  float s = 0.f;
  for (int j = lane; j < NN; j += 64) s += expf(M[(size_t)i*NN + j] - m);
  for (int o = 32; o > 0; o >>= 1) s += __shfl_xor(s, o);
  float lr = m + logf(s);
  float m2 = -INFINITY;
  for (int j = lane; j < NN; j += 64) m2 = fmaxf(m2, M[(size_t)j*NN + i]);
  for (int o = 32; o > 0; o >>= 1) m2 = fmaxf(m2, __shfl_xor(m2, o));
  float s2 = 0.f;
  for (int j = lane; j < NN; j += 64) s2 += expf(M[(size_t)j*NN + i] - m2);
  for (int o = 32; o > 0; o >>= 1) s2 += __shfl_xor(s2, o);
  float lc = m2 + logf(s2);
  if (lane == 0){
    float d = M[(size_t)i*NN + i];
    atomicAdd(&sc[0], lr - d);
    atomicAdd(&sc[1], lc - d);
  }
}

// ---------------- K12: sel2 ----------------
__global__ __launch_bounds__(256) void k_sel2(
    const float* __restrict__ sims, int* __restrict__ sel2){
  int n = blockIdx.x, tid = threadIdx.x;
  uint32_t gk0, gk1; subkey(2, gk0, gk1);
  float best = -INFINITY; int bi = 0x7fffffff;
  for (int r = tid; r < BQ; r += 256){
    float v = sims[(size_t)r*SIMW + CC + n] + gumbel32(gk0, gk1, (uint32_t)(r*NN + n));
    if (v > best){ best = v; bi = r; }
  }
  __shared__ float sv[256];
  __shared__ int   si[256];
  sv[tid] = best; si[tid] = bi; __syncthreads();
  for (int s = 128; s > 0; s >>= 1){
    if (tid < s){
      float ov = sv[tid+s]; int oi = si[tid+s];
      if (ov > sv[tid] || (ov == sv[tid] && oi < si[tid])){ sv[tid] = ov; si[tid] = oi; }
    }
    __syncthreads();
  }
  if (tid == 0) sel2[n] = si[0];
}

// ---------------- K13: overall_mask_loss + masksum ----------------
__global__ __launch_bounds__(256) void k_om(
    const float* __restrict__ pm, const float* __restrict__ tm,
    const int* __restrict__ sel2, float* __restrict__ msum,
    float* __restrict__ sc){
  int nb = blockIdx.x;
  int n = nb / 9, ch = nb % 9;
  int c0 = ch*1024 + threadIdx.x*4;
  const float4 o4 = *(const float4*)(pm + (size_t)sel2[n]*WHX + c0);
  const float4 t4 = *(const float4*)(tm + (size_t)n*WHX + c0);
  float dx = o4.x-t4.x, dy = o4.y-t4.y, dz = o4.z-t4.z, dw = o4.w-t4.w;
  float d2 = dx*dx + dy*dy + dz*dz + dw*dw;
  float ts = t4.x + t4.y + t4.z + t4.w;
  __shared__ float r1[256], r2[256];
  r1[threadIdx.x] = d2; r2[threadIdx.x] = ts; __syncthreads();
  for (int s = 128; s > 0; s >>= 1){
    if (threadIdx.x < s){ r1[threadIdx.x] += r1[threadIdx.x+s]; r2[threadIdx.x] += r2[threadIdx.x+s]; }
    __syncthreads();
  }
  if (threadIdx.x == 0){ atomicAdd(&sc[2], r1[0]); atomicAdd(&msum[n], r2[0]); }
}

// ---------------- K14: sum_tgt[b] ----------------
__global__ __launch_bounds__(512) void k_sumtgt(
    const int* __restrict__ bidx, const float* __restrict__ rowsum,
    const float* __restrict__ msum, float* __restrict__ stgt){
  int n = threadIdx.x;
  if (n >= NN) return;
  atomicAdd(&stgt[bidx[n]], rowsum[n] * msum[n]);
}

// ---------------- T1: sims f32 -> simTb bf16 [8][304][320] (transpose) ----------------
__global__ __launch_bounds__(256) void t_simT(
    const float* __restrict__ sims, u16* __restrict__ simTb){
  __shared__ float ld[32][65];
  int q0 = blockIdx.x*32, c0 = blockIdx.y*64, b = blockIdx.z;
  int tid = threadIdx.x;
  for (int i = tid; i < 32*64; i += 256){
    int qi = i >> 6, ci = i & 63;
    int q = q0 + qi, c = c0 + ci;
    ld[qi][ci] = (q < QQ && c < CC) ? sims[((size_t)b*QQ + q)*SIMW + c] : 0.f;
  }
  __syncthreads();
  int cloc = tid >> 2, j0 = (tid & 3)*8;
  int c = c0 + cloc;
  if (c < CP){
    u16 tmp[8];
    #pragma unroll
    for (int j = 0; j < 8; j++) tmp[j] = f2bf(ld[j0+j][cloc]);
    *(uint4*)(simTb + ((size_t)b*CP + c)*QP + q0 + j0) = *(const uint4*)tmp;
  }
}

// ---------------- T2: omT bf16 [9216][320] = pm[sel2[q]][wh]/96 (transpose) ----------------
__global__ __launch_bounds__(256) void t_omT(
    const float* __restrict__ pm, const int* __restrict__ sel2,
    u16* __restrict__ omT){
  __shared__ float ld[32][65];
  int q0 = blockIdx.x*32, wh0 = blockIdx.y*64;
  int tid = threadIdx.x;
  for (int i = tid; i < 32*64; i += 256){
    int qi = i >> 6, wi = i & 63;
    int q = q0 + qi;
    ld[qi][wi] = (q < QQ) ? pm[(size_t)sel2[q]*WHX + wh0 + wi] * (1.0f/96.0f) : 0.f;
  }
  __syncthreads();
  int wloc = tid >> 2, j0 = (tid & 3)*8;
  u16 tmp[8];
  #pragma unroll
  for (int j = 0; j < 8; j++) tmp[j] = f2bf(ld[j0+j][wloc]);
  *(uint4*)(omT + (size_t)(wh0+wloc)*QP + q0 + j0) = *(const uint4*)tmp;
}

// ---------------- T3: tmT bf16 [9216][416] (transpose, zero-padded) ----------------
__global__ __launch_bounds__(256) void t_tmT(
    const float* __restrict__ tm, u16* __restrict__ tmT){
  __shared__ float ld[32][65];
  int n0 = blockIdx.x*32, wh0 = blockIdx.y*64;
  int tid = threadIdx.x;
  for (int i = tid; i < 32*64; i += 256){
    int ni = i >> 6, wi = i & 63;
    int n = n0 + ni;
    ld[ni][wi] = (n < NN) ? tm[(size_t)n*WHX + wh0 + wi] : 0.f;
  }
  __syncthreads();
  int wloc = tid >> 2, j0 = (tid & 3)*8;
  u16 tmp[8];
  #pragma unroll
  for (int j = 0; j < 8; j++) tmp[j] = f2bf(ld[j0+j][wloc]);
  *(uint4*)(tmT + (size_t)(wh0+wloc)*NP + n0 + j0) = *(const uint4*)tmp;
}

// ---------------- T4: gtsimP bf16 [8][304][96] (per-batch zero-padded window) ----------------
__global__ __launch_bounds__(256) void t_gtp(
    const float* __restrict__ gtsim, const int* __restrict__ bstart,
    u16* __restrict__ gtp){
  int g = blockIdx.x*256 + threadIdx.x;
  if (g >= BB*CP*(KP/8)) return;
  int b = g / (CP*(KP/8));
  int rem = g - b*(CP*(KP/8));
  int c = rem / (KP/8);
  int kg = rem % (KP/8);
  int n0 = bstart[b], n1 = bstart[b+1];
  int kst = n0 & ~7;
  u16 tmp[8];
  #pragma unroll
  for (int j = 0; j < 8; j++){
    int n = kst + kg*8 + j;
    float v = (n >= n0 && n < n1 && c < CC) ? gtsim[(size_t)n*CC + c] : 0.f;
    tmp[j] = f2bf(v);
  }
  *(uint4*)(gtp + ((size_t)b*CP + c)*KP + kg*8) = *(const uint4*)tmp;
}

// ---------------- K15: MFMA z-GEMM + column softmax + dice (swizzled LDS A) ----------------
// XCD pinned by TILE RANGE (not batch): xcd = bid&7 owns tiles [18*xcd, 18*xcd+18)
// for all 8 batches -> per-XCD working set = omT slice (0.74MB) + tmT slice (0.22MB)
// + all simTb panels (1.56MB) = 2.5MB, fully L2-resident.
constexpr int ALDS = 32;  // LDS row stride in u16 (64 B, power of 2)
__global__ __launch_bounds__(256) void k_zsoft(
    const u16* __restrict__ simTb, const u16* __restrict__ omT,
    const u16* __restrict__ gtp, const u16* __restrict__ tmT,
    const int* __restrict__ bstart, float* __restrict__ sc){
  const int bid = blockIdx.x;
  const int xcd = bid & 7;
  const int r9  = bid >> 3;            // 0..143
  const int tile = xcd * 18 + (r9 % 18);
  const int b    = r9 / 18;
  const int tid = threadIdx.x;
  const int w = tid >> 6, l = tid & 63;
  const int lrow = l & 15, lgrp = l >> 4;
  const int col = tile*64 + w*16 + lrow;

  __shared__ u16 As[CP*ALDS];   // 19456 B
  __shared__ float red[256];

  const u16* Ab = simTb + (size_t)b*CP*QP;
  const int sidx[5] = {tid, tid+256, tid+512, tid+768, tid+1024};
  int woff[5];
  #pragma unroll
  for (int i = 0; i < 5; i++){
    int rr = sidx[i] >> 2, g = sidx[i] & 3;
    woff[i] = rr*ALDS + ((g ^ ((rr >> 1) & 3)) << 3);
  }
  const int roff = (lgrp ^ ((lrow >> 1) & 3)) << 3;

  uint4 pf0, pf1, pf2, pf3, pf4;
  {
    int rr, g;
    rr = sidx[0] >> 2; g = sidx[0] & 3; pf0 = *(const uint4*)(Ab + (size_t)rr*QP + g*8);
    rr = sidx[1] >> 2; g = sidx[1] & 3; pf1 = *(const uint4*)(Ab + (size_t)rr*QP + g*8);
    rr = sidx[2] >> 2; g = sidx[2] & 3; pf2 = *(const uint4*)(Ab + (size_t)rr*QP + g*8);
    rr = sidx[3] >> 2; g = sidx[3] & 3; pf3 = *(const uint4*)(Ab + (size_t)rr*QP + g*8);
    if (sidx[4] < 1216){ rr = sidx[4] >> 2; g = sidx[4] & 3; pf4 = *(const uint4*)(Ab + (size_t)rr*QP + g*8); }
  }
  const u16* pB = omT + (size_t)col*QP;
  bf16x8 bcur = *(const bf16x8*)(pB);

  f32x4 acc[19];
  #pragma unroll
  for (int t = 0; t < 19; t++) acc[t] = (f32x4){0.f,0.f,0.f,0.f};

  for (int ks = 0; ks < 10; ks++){
    *(uint4*)&As[woff[0]] = pf0;
    *(uint4*)&As[woff[1]] = pf1;
    *(uint4*)&As[woff[2]] = pf2;
    *(uint4*)&As[woff[3]] = pf3;
    if (sidx[4] < 1216) *(uint4*)&As[woff[4]] = pf4;
    __syncthreads();
    bf16x8 bnext;
    if (ks + 1 < 10){
      const size_t ko = (size_t)(ks + 1) * 32;
      int rr, g;
      rr = sidx[0] >> 2; g = sidx[0] & 3; pf0 = *(const uint4*)(Ab + (size_t)rr*QP + ko + g*8);
      rr = sidx[1] >> 2; g = sidx[1] & 3; pf1 = *(const uint4*)(Ab + (size_t)rr*QP + ko + g*8);
      rr = sidx[2] >> 2; g = sidx[2] & 3; pf2 = *(const uint4*)(Ab + (size_t)rr*QP + ko + g*8);
      rr = sidx[3] >> 2; g = sidx[3] & 3; pf3 = *(const uint4*)(Ab + (size_t)rr*QP + ko + g*8);
      if (sidx[4] < 1216){ rr = sidx[4] >> 2; g = sidx[4] & 3; pf4 = *(const uint4*)(Ab + (size_t)rr*QP + ko + g*8); }
      bnext = *(const bf16x8*)(pB + ko);
    }
    #pragma unroll
    for (int t = 0; t < 19; t++){
      bf16x8 af = *(const bf16x8*)&As[t*16*ALDS + lrow*ALDS + roff];
      acc[t] = __builtin_amdgcn_mfma_f32_16x16x32_bf16(af, bcur, acc[t], 0, 0, 0);
    }
    bcur = bnext;
    __syncthreads();
  }

  float lmax = -INFINITY;
  #pragma unroll
  for (int t = 0; t < 19; t++){
    if (t == 18 && lgrp == 3) continue;
    lmax = fmaxf(lmax, fmaxf(fmaxf(acc[t][0], acc[t][1]), fmaxf(acc[t][2], acc[t][3])));
  }
  lmax = fmaxf(lmax, __shfl_xor(lmax, 16));
  lmax = fmaxf(lmax, __shfl_xor(lmax, 32));
  float ls = 0.f;
  #pragma unroll
  for (int t = 0; t < 19; t++){
    if (t == 18 && lgrp == 3){
      acc[t] = (f32x4){0.f,0.f,0.f,0.f};
      continue;
    }
    float p0 = __expf(acc[t][0] - lmax);
    float p1 = __expf(acc[t][1] - lmax);
    float p2 = __expf(acc[t][2] - lmax);
    float p3 = __expf(acc[t][3] - lmax);
    acc[t][0] = p0; acc[t][1] = p1; acc[t][2] = p2; acc[t][3] = p3;
    ls += p0 + p1 + p2 + p3;
  }
  float S = ls;
  S += __shfl_xor(S, 16);
  S += __shfl_xor(S, 32);
  float inv = 1.f / S;

  int n0 = bstart[b];
  int kst = n0 & ~7;
  const u16* tB = tmT + (size_t)col*NP + kst + lgrp*8;
  bf16x8 b2a = *(const bf16x8*)(tB);
  bf16x8 b2b = *(const bf16x8*)(tB + 32);
  bf16x8 b2c = *(const bf16x8*)(tB + 64);
  const u16* A2 = gtp + (size_t)b*CP*KP + lgrp*8;
  float dl = 0.f;
  #pragma unroll
  for (int t = 0; t < 19; t++){
    const u16* ar = A2 + (size_t)(t*16 + lrow)*KP;
    f32x4 rr = (f32x4){0.f,0.f,0.f,0.f};
    rr = __builtin_amdgcn_mfma_f32_16x16x32_bf16(*(const bf16x8*)(ar),      b2a, rr, 0, 0, 0);
    rr = __builtin_amdgcn_mfma_f32_16x16x32_bf16(*(const bf16x8*)(ar + 32), b2b, rr, 0, 0, 0);
    rr = __builtin_amdgcn_mfma_f32_16x16x32_bf16(*(const bf16x8*)(ar + 64), b2c, rr, 0, 0, 0);
    dl += acc[t][0]*rr[0] + acc[t][1]*rr[1] + acc[t][2]*rr[2] + acc[t][3]*rr[3];
  }
  dl *= inv;

  red[tid] = dl; __syncthreads();
  for (int s = 128; s > 0; s >>= 1){
    if (tid < s) red[tid] += red[tid+s];
    __syncthreads();
  }
  if (tid == 0) atomicAdd(&sc[5], red[0]);
}

// ---------------- K16: finalize ----------------
__global__ __launch_bounds__(64) void k_final(
    const float* __restrict__ sc, const float* __restrict__ stgt,
    const int* __restrict__ kint, float* __restrict__ out){
  if (threadIdx.x != 0) return;
  float K = (float)kint[0];
  float cls = sc[0]/300.f + sc[1]/300.f;
  float stot = sc[5];
  float dice = 0.f;
  for (int b = 0; b < 8; b++) dice += stot / (9216.0f + stgt[b] + 1e-6f);
  dice *= (1.0f/8.0f);
  out[0] = cls;
  out[1] = dice;
  out[2] = (sc[2] / 2764800.0f) / K;
  out[3] = sc[3] / K;
  out[4] = sc[4] / K;
}

// ---------------- launch ----------------
extern "C" void kernel_launch(void* const* d_in, const int* in_sizes, int n_in,
                              void* d_out, int out_size, void* d_ws, size_t ws_size,
                              hipStream_t stream) {
  const float* ce  = (const float*)d_in[0];
  const float* pl  = (const float*)d_in[1];
  const float* pb  = (const float*)d_in[2];
  const float* pm  = (const float*)d_in[3];
  const float* tm  = (const float*)d_in[4];
  const float* te  = (const float*)d_in[5];
  const float* tbb = (const float*)d_in[6];
  const int*  tids = (const int*)d_in[8];
  const int*  bidx = (const int*)d_in[9];
  float* out = (float*)d_out;
  float* w = (float*)d_ws;

  if (ws_size < F_TOTAL * sizeof(float)) return;

  float* SIMS   = w + F_SIMS;
  float* GTSIM  = w + F_GTSIM;
  float* MM     = w + F_MM;
  float* SCORE  = w + F_SCORE;
  float* BBOX   = w + F_BBOX;
  float* TBOX   = w + F_TB;
  float* SB     = w + F_SB;
  float* SAREA  = w + F_SAREA;
  float* KB     = w + F_KB;
  float* ROWSUM = w + F_ROWSUM;
  float* OE     = w + F_OE;
  float* GSEL   = w + F_GSEL;
  float* MSUM   = w + F_MSUM;
  float* STGT   = w + F_STGT;
  float* SC     = w + F_SC;
  int*   CNT    = (int*)(w + F_CNT);
  int*   ORDER  = (int*)(w + F_ORDER);
  int*   NMSIDX = (int*)(w + F_NMSIDX);
  int*   SEL2   = (int*)(w + F_SEL2);
  int*   BSTART = (int*)(w + F_BSTART);
  int*   KINT   = (int*)(w + F_KINT);
  int*   CLS    = (int*)(w + F_CLS);
  int*   KEEPF  = (int*)(w + F_KEEPF);
  int*   LIST   = (int*)(w + F_LIST);
  u16* SIMTB = (u16*)(w + F_SIMTB);
  u16* OMT   = (u16*)(w + F_OMT);
  u16* TMT   = (u16*)(w + F_TMT);
  u16* GTP   = (u16*)(w + F_GTP);

  // zero accumulators + cell counts
  hipMemsetAsync(w + F_OE, 0, (F_ACCEND - F_OE) * sizeof(float), stream);

  k_gemm_t<<<dim3(43, 10), 256, 0, stream>>>(pl, ce, te, SIMS, GTSIM);
  k_post<<<BQ, 512, 0, stream>>>(SIMS, pb, tbb, tids, bidx, GTSIM, SCORE, BBOX, TBOX, ROWSUM, CLS);
  k_rank<<<BQ, 256, 0, stream>>>(SCORE, ORDER);
  k_gather<<<(BQ + 255)/256, 256, 0, stream>>>(BBOX, ORDER, bidx, CLS, SB, SAREA, BSTART, CNT, LIST);
  k_cellnms<<<(BB*CC + 255)/256, 256, 0, stream>>>(SB, CNT, LIST, KEEPF);
  k_compact<<<1, 256, 0, stream>>>(KEEPF, ORDER, SB, NMSIDX, KB, KINT);
  k_gtsel<<<BQ, 512, 0, stream>>>(KB, TBOX, NMSIDX, pl, KINT, GSEL, OE);
  k_gtiou<<<1, 512, 0, stream>>>(GSEL, TBOX, SC);
  k_m<<<(NN*NN + 255)/256, 256, 0, stream>>>(te, OE, MM);
  k_ce<<<NN, 64, 0, stream>>>(MM, SC);
  k_sel2<<<NN, 256, 0, stream>>>(SIMS, SEL2);
  k_om<<<NN*9, 256, 0, stream>>>(pm, tm, SEL2, MSUM, SC);
  k_sumtgt<<<1, 512, 0, stream>>>(bidx, ROWSUM, MSUM, STGT);

  t_simT<<<dim3(QP/32, 5, BB), 256, 0, stream>>>(SIMS, SIMTB);
  t_omT<<<dim3(QP/32, WHX/64), 256, 0, stream>>>(pm, SEL2, OMT);
  t_tmT<<<dim3(NP/32, WHX/64), 256, 0, stream>>>(tm, TMT);
  t_gtp<<<(BB*CP*(KP/8) + 255)/256, 256, 0, stream>>>(GTSIM, BSTART, GTP);

  k_zsoft<<<dim3((WHX/64) * BB), 256, 0, stream>>>(SIMTB, OMT, GTP, TMT, BSTART, SC);
  k_final<<<1, 64, 0, stream>>>(SC, STGT, KINT, out);
}

// Round 11
// 274.114 us; speedup vs baseline: 7.4440x; 1.0236x over previous
//
#include <hip/hip_runtime.h>
#include <stdint.h>

#define DEVFN __device__ __forceinline__

typedef unsigned short u16;
typedef short bf16x8 __attribute__((ext_vector_type(8)));
typedef float f32x4 __attribute__((ext_vector_type(4)));

constexpr int BB = 8, QQ = 300, CC = 300, NN = 300, DD = 256;
constexpr int WHX = 9216, BQ = 2400, SIMW = 600;
constexpr int QP = 320;   // padded Q for MFMA K-dim
constexpr int CP = 304;   // padded C rows
constexpr int KP = 96;    // per-batch n-window
constexpr int NP = 416;   // padded tmT n-dim
constexpr int CELLCAP = 300;

// ---------------- workspace layout (float units) ----------------
constexpr size_t F_SIMS   = 0;                                 // [2400][600]
constexpr size_t F_GTSIM  = F_SIMS   + (size_t)BQ*SIMW;        // [300][300]
constexpr size_t F_MM     = F_GTSIM  + (size_t)NN*CC;          // [300][300]
constexpr size_t F_SCORE  = F_MM     + (size_t)NN*NN;          // [2400]
constexpr size_t F_BBOX   = F_SCORE  + BQ;                     // [2400][4]
constexpr size_t F_TB     = F_BBOX   + (size_t)BQ*4;           // [300][4]
constexpr size_t F_SB     = F_TB     + (size_t)NN*4;           // [2400][4]
constexpr size_t F_SAREA  = F_SB     + (size_t)BQ*4;           // [2400] (unused slot)
constexpr size_t F_KB     = F_SAREA  + BQ;                     // [2400][4]
constexpr size_t F_ROWSUM = F_KB     + (size_t)BQ*4;           // [300]
constexpr size_t F_OE     = F_ROWSUM + NN;                     // ---- zeroed zone
constexpr size_t F_GSEL   = F_OE     + (size_t)NN*DD;          // [300][4]
constexpr size_t F_MSUM   = F_GSEL   + (size_t)NN*4;           // [300]
constexpr size_t F_STGT   = F_MSUM   + NN;                     // [8] (unused slot)
constexpr size_t F_SC     = F_STGT   + 8;                      // scalars
constexpr size_t F_CNT    = F_SC     + 16;                     // int [2400] cell counts (zeroed)
constexpr size_t F_ACCEND = F_CNT    + BQ;                     // ---- end zeroed zone
constexpr size_t F_ORDER  = F_ACCEND;                          // int [2400]
constexpr size_t F_NMSIDX = F_ORDER  + BQ;                     // int [2400]
constexpr size_t F_SEL2   = F_NMSIDX + BQ;                     // int [300]
constexpr size_t F_BSTART = F_SEL2   + NN;                     // int [16]
constexpr size_t F_KINT   = F_BSTART + 16;                     // int [4]
constexpr size_t F_CLS    = F_KINT   + 4;                      // int [2400]
constexpr size_t F_KEEPF  = F_CLS    + BQ;                     // int [2400]
constexpr size_t F_LIST   = F_KEEPF  + BQ;                     // int [2400][300]
// bf16 panels (sizes in floats = ushorts/2), 32B-align starts
constexpr size_t F_SIMTB  = ((F_LIST + (size_t)BQ*CELLCAP + 7) & ~(size_t)7);  // u16[8][304][320]
constexpr size_t F_OMT    = F_SIMTB + (size_t)BB*CP*QP/2;           // u16[9216][320]
constexpr size_t F_TMT    = F_OMT   + (size_t)WHX*QP/2;             // u16[9216][416]
constexpr size_t F_GTP    = F_TMT   + (size_t)WHX*NP/2;             // u16[8][304][96]
constexpr size_t F_TOTAL  = F_GTP   + (size_t)BB*CP*KP/2;

// ---------------- JAX threefry2x32 (partitionable scheme) ----------------
DEVFN uint32_t rotl32(uint32_t v, int r){ return (v << r) | (v >> (32 - r)); }

DEVFN void tf2x32(uint32_t k0, uint32_t k1, uint32_t x0, uint32_t x1,
                  uint32_t& o0, uint32_t& o1){
  uint32_t ks2 = k0 ^ k1 ^ 0x1BD11BDAu;
  x0 += k0; x1 += k1;
#define TFR(r) x0 += x1; x1 = rotl32(x1, r); x1 ^= x0;
  TFR(13) TFR(15) TFR(26) TFR(6)   x0 += k1;  x1 += ks2 + 1u;
  TFR(17) TFR(29) TFR(16) TFR(24)  x0 += ks2; x1 += k0  + 2u;
  TFR(13) TFR(15) TFR(26) TFR(6)   x0 += k0;  x1 += k1  + 3u;
  TFR(17) TFR(29) TFR(16) TFR(24)  x0 += k1;  x1 += ks2 + 4u;
  TFR(13) TFR(15) TFR(26) TFR(6)   x0 += ks2; x1 += k0  + 5u;
#undef TFR
  o0 = x0; o1 = x1;
}

DEVFN void subkey(int i, uint32_t& k0, uint32_t& k1){
  tf2x32(0u, 42u, 0u, (uint32_t)i, k0, k1);
}

DEVFN float gumbel32(uint32_t k0, uint32_t k1, uint32_t idx){
  uint32_t h, l; tf2x32(k0, k1, 0u, idx, h, l);
  uint32_t bits = h ^ l;
  float f = __uint_as_float((bits >> 9) | 0x3F800000u) - 1.0f;
  const float tiny = 1.17549435e-38f;
  float u = fmaxf(tiny, f + tiny);
  return -logf(-logf(u));
}

DEVFN float iou_xyxy(float ax1,float ay1,float ax2,float ay2,
                     float bx1,float by1,float bx2,float by2){
  float aa = (ax2-ax1)*(ay2-ay1);
  float ab = (bx2-bx1)*(by2-by1);
  float lx = fmaxf(ax1,bx1), ly = fmaxf(ay1,by1);
  float rx = fminf(ax2,bx2), ry = fminf(ay2,by2);
  float iw = fmaxf(rx-lx,0.f), ih = fmaxf(ry-ly,0.f);
  float in_ = iw*ih;
  return in_/(aa+ab-in_);
}

DEVFN u16 f2bf(float x){
  uint32_t u = __float_as_uint(x);
  uint32_t r = u + 0x7FFFu + ((u >> 16) & 1u);
  return (u16)(r >> 16);
}

DEVFN void gload_lds16(const u16* g, u16* l){
  __builtin_amdgcn_global_load_lds(
      (const __attribute__((address_space(1))) unsigned int*)g,
      (__attribute__((address_space(3))) unsigned int*)l,
      16, 0, 0);
}

// ---------------- K1: tiled f32 GEMM 64x64: [pl;te](2700x256) x [ce;te]^T(256x600) ----------------
__global__ __launch_bounds__(256) void k_gemm_t(
    const float* __restrict__ pl, const float* __restrict__ ce,
    const float* __restrict__ te, float* __restrict__ sims,
    float* __restrict__ gtsim){
  __shared__ float As[16][64];
  __shared__ float Bs[16][64];
  const int row0 = blockIdx.x * 64, col0 = blockIdx.y * 64;
  const int tid = threadIdx.x;
  const int lrow = tid >> 2, lk0 = (tid & 3) * 4;
  const int tr = tid >> 4, tc = tid & 15;

  float acc[4][4];
  #pragma unroll
  for (int i = 0; i < 4; i++)
    #pragma unroll
    for (int j = 0; j < 4; j++) acc[i][j] = 0.f;

  const float4 z4 = {0.f,0.f,0.f,0.f};
  const int grow = row0 + lrow;
  const int gcol = col0 + lrow;
  const float* arow = nullptr;
  if (grow < 2400) arow = pl + (size_t)grow * DD;
  else if (grow < 2700) arow = te + (size_t)(grow - 2400) * DD;
  const float* brow = nullptr;
  if (gcol < 300) brow = ce + (size_t)gcol * DD;
  else if (gcol < 600) brow = te + (size_t)(gcol - 300) * DD;

  float4 av = arow ? *(const float4*)(arow + lk0) : z4;
  float4 bv = brow ? *(const float4*)(brow + lk0) : z4;

  for (int step = 0; step < 16; step++){
    __syncthreads();
    #pragma unroll
    for (int j = 0; j < 4; j++){
      As[lk0 + j][lrow] = ((const float*)&av)[j];
      Bs[lk0 + j][lrow] = ((const float*)&bv)[j];
    }
    __syncthreads();
    if (step + 1 < 16){
      const int k0 = (step + 1) * 16;
      av = arow ? *(const float4*)(arow + k0 + lk0) : z4;
      bv = brow ? *(const float4*)(brow + k0 + lk0) : z4;
    }
    #pragma unroll
    for (int kk = 0; kk < 16; kk++){
      float4 a4 = *(const float4*)&As[kk][tr*4];
      float4 b4 = *(const float4*)&Bs[kk][tc*4];
      float a[4] = {a4.x,a4.y,a4.z,a4.w};
      float b[4] = {b4.x,b4.y,b4.z,b4.w};
      #pragma unroll
      for (int i = 0; i < 4; i++)
        #pragma unroll
        for (int j = 0; j < 4; j++)
          acc[i][j] = fmaf(a[i], b[j], acc[i][j]);
    }
  }

  #pragma unroll
  for (int i = 0; i < 4; i++){
    const int r = row0 + tr*4 + i;
    const int c0 = col0 + tc*4;
    if (r < 2400){
      if (c0 < 600){
        float4 o0 = {acc[i][0],acc[i][1],acc[i][2],acc[i][3]};
        *(float4*)(sims + (size_t)r*SIMW + c0) = o0;
      }
    } else if (r < 2700){
      const int n = r - 2400;
      #pragma unroll
      for (int j = 0; j < 4; j++){
        int c = c0 + j;
        if (c < 300) gtsim[(size_t)n*CC + c] = acc[i][j];
      }
    }
  }
}

// ---------------- K2: per-bq scores/argmax(g0)/boxes/cls; tb rows; gtsim rowsums ----------------
__global__ __launch_bounds__(512) void k_post(
    const float* __restrict__ sims, const float* __restrict__ pb,
    const float* __restrict__ tbb, const int* __restrict__ tids,
    const int* __restrict__ bidx, const float* __restrict__ gtsim,
    float* __restrict__ score, float* __restrict__ bbox,
    float* __restrict__ tb, float* __restrict__ rowsum,
    int* __restrict__ clsout){
  int bq = blockIdx.x, tid = threadIdx.x;
  __shared__ float sv[512];
  __shared__ int   si[512];
  float v = (tid < CC) ? sims[(size_t)bq*SIMW + tid] : -INFINITY;
  sv[tid] = v; __syncthreads();
  for (int s = 256; s > 0; s >>= 1){ if (tid < s) sv[tid] = fmaxf(sv[tid], sv[tid+s]); __syncthreads(); }
  if (tid == 0) score[bq] = sv[0];
  __syncthreads();
  uint32_t gk0, gk1; subkey(0, gk0, gk1);
  float y = (tid < CC) ? v + gumbel32(gk0, gk1, (uint32_t)(bq*CC + tid)) : -INFINITY;
  sv[tid] = y; si[tid] = tid; __syncthreads();
  for (int s = 256; s > 0; s >>= 1){
    if (tid < s){
      float ov = sv[tid+s]; int oi = si[tid+s];
      if (ov > sv[tid] || (ov == sv[tid] && oi < si[tid])){ sv[tid] = ov; si[tid] = oi; }
    }
    __syncthreads();
  }
  if (tid == 0){
    int cls = si[0];
    clsout[bq] = cls;
    float ox = 224.0f * (float)cls;
    float oy = 224.0f * (float)(bq / QQ);
    float cx = pb[bq*4+0], cy = pb[bq*4+1], ww = pb[bq*4+2], hh = pb[bq*4+3];
    bbox[bq*4+0] = cx - 0.5f*ww + ox;
    bbox[bq*4+1] = cy - 0.5f*hh + oy;
    bbox[bq*4+2] = cx + 0.5f*ww + ox;
    bbox[bq*4+3] = cy + 0.5f*hh + oy;
  }
  if (bq < NN){
    __syncthreads();
    float rs = (tid < CC) ? gtsim[(size_t)bq*CC + tid] : 0.f;
    sv[tid] = rs; __syncthreads();
    for (int s = 256; s > 0; s >>= 1){ if (tid < s) sv[tid] += sv[tid+s]; __syncthreads(); }
    if (tid == 0) rowsum[bq] = sv[0];
    if (tid == 1){
      float gx = 224.0f * (float)tids[bq], gy = 224.0f * (float)bidx[bq];
      float cx = tbb[bq*4+0], cy = tbb[bq*4+1], ww = tbb[bq*4+2], hh = tbb[bq*4+3];
      tb[bq*4+0] = cx - 0.5f*ww + gx;
      tb[bq*4+1] = cy - 0.5f*hh + gy;
      tb[bq*4+2] = cx + 0.5f*ww + gx;
      tb[bq*4+3] = cy + 0.5f*hh + gy;
    }
  }
}

// ---------------- K3: fused rank + gather + bucket (one block per element) ----------------
__global__ __launch_bounds__(256) void k_rankgather(
    const float* __restrict__ score, const float* __restrict__ bbox,
    const int* __restrict__ cls, const int* __restrict__ bidx,
    int* __restrict__ order, float* __restrict__ sb,
    int* __restrict__ bstart, int* __restrict__ cnt,
    int* __restrict__ list){
  const int t = blockIdx.x;
  const int tid = threadIdx.x;
  const float st = score[t];
  int c = 0;
  for (int j = tid; j < BQ; j += 256){
    float sj = score[j];
    c += (sj > st) || (sj == st && j < t);
  }
  __shared__ int red[256];
  red[tid] = c; __syncthreads();
  for (int s = 128; s > 0; s >>= 1){
    if (tid < s) red[tid] += red[tid+s];
    __syncthreads();
  }
  if (tid == 0){
    int r = red[0];
    order[r] = t;
    float x1 = bbox[t*4+0], y1 = bbox[t*4+1], x2 = bbox[t*4+2], y2 = bbox[t*4+3];
    sb[r*4+0] = x1; sb[r*4+1] = y1; sb[r*4+2] = x2; sb[r*4+3] = y2;
    int key = (t / QQ) * CC + cls[t];
    int slot = atomicAdd(&cnt[key], 1);
    list[(size_t)key*CELLCAP + slot] = r;     // cellnms orders by position itself
  }
  if (t == 0 && tid >= 32 && tid < 41){
    int b = tid - 32, cb = 0;
    for (int n = 0; n < NN; n++) cb += (bidx[n] < b);
    bstart[b] = cb;
  }
}

// ---------------- K6': per-cell greedy NMS ----------------
__global__ __launch_bounds__(256) void k_cellnms(
    const float* __restrict__ sb, const int* __restrict__ cnt,
    const int* __restrict__ list, int* __restrict__ keepf){
  int key = blockIdx.x*256 + threadIdx.x;
  if (key >= BB*CC) return;
  int m = cnt[key];
  if (m <= 0) return;
  const int* lst = list + (size_t)key*CELLCAP;
  unsigned long long keptmask = 0ull;
  int prevp = -1;
  for (int a = 0; a < m; a++){
    int pa = 0x7fffffff;
    for (int j = 0; j < m; j++){
      int pj = lst[j];
      if (pj > prevp && pj < pa) pa = pj;
    }
    prevp = pa;
    float4 A = ((const float4*)sb)[pa];
    float areaA = (A.z-A.x)*(A.w-A.y);
    bool kept = true;
    int pbprev = -1;
    for (int b2 = 0; b2 < a; b2++){
      int pb = 0x7fffffff;
      for (int j = 0; j < m; j++){
        int pj = lst[j];
        if (pj > pbprev && pj < pb) pb = pj;
      }
      pbprev = pb;
      bool keptb = (m <= 64) ? (((keptmask >> b2) & 1ull) != 0ull) : (keepf[pb] != 0);
      if (!keptb) continue;
      float4 B = ((const float4*)sb)[pb];
      float areaB = (B.z-B.x)*(B.w-B.y);
      float lx = fmaxf(A.x,B.x), ly = fmaxf(A.y,B.y);
      float rx = fminf(A.z,B.z), ry = fminf(A.w,B.w);
      float iw = fmaxf(rx-lx,0.f), ih = fmaxf(ry-ly,0.f);
      float inter = iw*ih;
      if (inter/(areaA + areaB - inter) > 0.5f){ kept = false; break; }
    }
    if (m <= 64 && kept) keptmask |= (1ull << a);
    keepf[pa] = kept ? 1 : 0;
  }
}

// ---------------- K7: compact ----------------
__global__ __launch_bounds__(256) void k_compact(
    const int* __restrict__ keepflag, const int* __restrict__ order,
    const float* __restrict__ sb, int* __restrict__ nmsidx,
    float* __restrict__ kb, int* __restrict__ kint){
  __shared__ int csum[256];
  int tid = threadIdx.x;
  int p0 = tid*10;
  int keepf[10];
  int cnt = 0;
  #pragma unroll
  for (int d = 0; d < 10; d++){
    int p = p0 + d;
    int k = 0;
    if (p < BQ) k = keepflag[p];
    keepf[d] = k; cnt += k;
  }
  csum[tid] = cnt; __syncthreads();
  for (int s = 1; s < 256; s <<= 1){
    int add = (tid >= s) ? csum[tid - s] : 0;
    __syncthreads();
    csum[tid] += add;
    __syncthreads();
  }
  int pos = csum[tid] - cnt;
  #pragma unroll
  for (int d = 0; d < 10; d++){
    if (keepf[d]){
      int p = p0 + d;
      nmsidx[pos] = order[p];
      ((float4*)kb)[pos] = ((const float4*)sb)[p];
      pos++;
    }
  }
  if (tid == 255) kint[0] = csum[255];
}

// ---------------- K8: per-kept-box scatter ----------------
__global__ __launch_bounds__(512) void k_gtsel(
    const float* __restrict__ kb, const float* __restrict__ tb,
    const int* __restrict__ nmsidx, const float* __restrict__ pl,
    const int* __restrict__ kint, float* __restrict__ gsel,
    float* __restrict__ oe){
  int k = blockIdx.x;
  if (k >= kint[0]) return;
  int tid = threadIdx.x;
  __shared__ float sv[512];
  __shared__ int   si[512];
  float4 a = ((const float4*)kb)[k];
  float iou = -INFINITY;
  if (tid < NN){
    float4 t = ((const float4*)tb)[tid];
    iou = iou_xyxy(a.x,a.y,a.z,a.w, t.x,t.y,t.z,t.w);
    if (iou != iou) iou = 0.f;
  }
  sv[tid] = iou; __syncthreads();
  for (int s = 256; s > 0; s >>= 1){ if (tid < s) sv[tid] = fmaxf(sv[tid], sv[tid+s]); __syncthreads(); }
  float m = sv[0]; __syncthreads();
  float e = (tid < NN) ? expf(iou - m) : 0.f;
  sv[tid] = e; __syncthreads();
  for (int s = 256; s > 0; s >>= 1){ if (tid < s) sv[tid] += sv[tid+s]; __syncthreads(); }
  float S = sv[0]; __syncthreads();
  uint32_t gk0, gk1; subkey(1, gk0, gk1);
  float y = (tid < NN) ? (e / S + gumbel32(gk0, gk1, (uint32_t)(k*NN + tid))) : -INFINITY;
  sv[tid] = y; si[tid] = tid; __syncthreads();
  for (int s = 256; s > 0; s >>= 1){
    if (tid < s){
      float ov = sv[tid+s]; int oi = si[tid+s];
      if (ov > sv[tid] || (ov == sv[tid] && oi < si[tid])){ sv[tid] = ov; si[tid] = oi; }
    }
    __syncthreads();
  }
  int sel = si[0];
  if (tid < 4) atomicAdd(&gsel[sel*4 + tid], ((const float*)&a)[tid]);
  if (tid < DD) atomicAdd(&oe[(size_t)sel*DD + tid], pl[(size_t)nmsidx[k]*DD + tid]);
}

// ---------------- K10: M = tgt_embs @ out_embs^T ----------------
__global__ __launch_bounds__(256) void k_m(
    const float* __restrict__ te, const float* __restrict__ oe,
    float* __restrict__ M){
  int idx = blockIdx.x*256 + threadIdx.x;
  if (idx >= NN*NN) return;
  int i = idx / NN, j = idx % NN;
  const float4* a4 = (const float4*)(te + (size_t)i*DD);
  const float4* b4 = (const float4*)(oe + (size_t)j*DD);
  float s = 0.f;
  #pragma unroll 8
  for (int t = 0; t < DD/4; t++){
    float4 x = a4[t], y = b4[t];
    s += x.x*y.x + x.y*y.y + x.z*y.z + x.w*y.w;
  }
  M[idx] = s;
}

// ---------------- K11: both cross-entropies ----------------
__global__ __launch_bounds__(64) void k_ce(
    const float* __restrict__ M, float* __restrict__ sc){
  int i = blockIdx.x, lane = threadIdx.x;
  float m = -INFINITY;
  for (int j = lane; j < NN; j += 64) m = fmaxf(m, M[(size_t)i*NN + j]);
  for (int o = 32; o > 0; o >>= 1) m = fmaxf(m, __shfl_xor(m, o));
  float s = 0.f;
  for (int j = lane; j < NN; j += 64) s += expf(M[(size_t)i*NN + j] - m);
  for (int o = 32; o > 0; o >>= 1) s += __shfl_xor(s, o);
  float lr = m + logf(s);
  float m2 = -INFINITY;
  for (int j = lane; j < NN; j += 64) m2 = fmaxf(m2, M[(size_t)j*NN + i]);
  for (int o = 32; o > 0; o >>= 1) m2 = fmaxf(m2, __shfl_xor(m2, o));
  float s2 = 0.f;
  for (int j = lane; j < NN; j += 64) s2 += expf(M[(size_t)j*NN + i] - m2);
  for (int o = 32; o > 0; o >>= 1) s2 += __shfl_xor(s2, o);
  float lc = m2 + logf(s2);
  if (lane == 0){
    float d = M[(size_t)i*NN + i];
    atomicAdd(&sc[0], lr - d);
    atomicAdd(&sc[1], lc - d);
  }
}

// ---------------- K12: sel2 ----------------
__global__ __launch_bounds__(256) void k_sel2(
    const float* __restrict__ sims, int* __restrict__ sel2){
  int n = blockIdx.x, tid = threadIdx.x;
  uint32_t gk0, gk1; subkey(2, gk0, gk1);
  float best = -INFINITY; int bi = 0x7fffffff;
  for (int r = tid; r < BQ; r += 256){
    float v = sims[(size_t)r*SIMW + CC + n] + gumbel32(gk0, gk1, (uint32_t)(r*NN + n));
    if (v > best){ best = v; bi = r; }
  }
  __shared__ float sv[256];
  __shared__ int   si[256];
  sv[tid] = best; si[tid] = bi; __syncthreads();
  for (int s = 128; s > 0; s >>= 1){
    if (tid < s){
      float ov = sv[tid+s]; int oi = si[tid+s];
      if (ov > sv[tid] || (ov == sv[tid] && oi < si[tid])){ sv[tid] = ov; si[tid] = oi; }
    }
    __syncthreads();
  }
  if (tid == 0) sel2[n] = si[0];
}

// ---------------- K13: overall_mask_loss + masksum ----------------
__global__ __launch_bounds__(256) void k_om(
    const float* __restrict__ pm, const float* __restrict__ tm,
    const int* __restrict__ sel2, float* __restrict__ msum,
    float* __restrict__ sc){
  int nb = blockIdx.x;
  int n = nb / 9, ch = nb % 9;
  int c0 = ch*1024 + threadIdx.x*4;
  const float4 o4 = *(const float4*)(pm + (size_t)sel2[n]*WHX + c0);
  const float4 t4 = *(const float4*)(tm + (size_t)n*WHX + c0);
  float dx = o4.x-t4.x, dy = o4.y-t4.y, dz = o4.z-t4.z, dw = o4.w-t4.w;
  float d2 = dx*dx + dy*dy + dz*dz + dw*dw;
  float ts = t4.x + t4.y + t4.z + t4.w;
  __shared__ float r1[256], r2[256];
  r1[threadIdx.x] = d2; r2[threadIdx.x] = ts; __syncthreads();
  for (int s = 128; s > 0; s >>= 1){
    if (threadIdx.x < s){ r1[threadIdx.x] += r1[threadIdx.x+s]; r2[threadIdx.x] += r2[threadIdx.x+s]; }
    __syncthreads();
  }
  if (threadIdx.x == 0){ atomicAdd(&sc[2], r1[0]); atomicAdd(&msum[n], r2[0]); }
}

// ---------------- T1: sims f32 -> simTb bf16 [8][304][320] (transpose) ----------------
__global__ __launch_bounds__(256) void t_simT(
    const float* __restrict__ sims, u16* __restrict__ simTb){
  __shared__ float ld[32][65];
  int q0 = blockIdx.x*32, c0 = blockIdx.y*64, b = blockIdx.z;
  int tid = threadIdx.x;
  for (int i = tid; i < 32*64; i += 256){
    int qi = i >> 6, ci = i & 63;
    int q = q0 + qi, c = c0 + ci;
    ld[qi][ci] = (q < QQ && c < CC) ? sims[((size_t)b*QQ + q)*SIMW + c] : 0.f;
  }
  __syncthreads();
  int cloc = tid >> 2, j0 = (tid & 3)*8;
  int c = c0 + cloc;
  if (c < CP){
    u16 tmp[8];
    #pragma unroll
    for (int j = 0; j < 8; j++) tmp[j] = f2bf(ld[j0+j][cloc]);
    *(uint4*)(simTb + ((size_t)b*CP + c)*QP + q0 + j0) = *(const uint4*)tmp;
  }
}

// ---------------- T2: omT bf16 [9216][320] = pm[sel2[q]][wh]/96 (transpose) ----------------
__global__ __launch_bounds__(256) void t_omT(
    const float* __restrict__ pm, const int* __restrict__ sel2,
    u16* __restrict__ omT){
  __shared__ float ld[32][65];
  int q0 = blockIdx.x*32, wh0 = blockIdx.y*64;
  int tid = threadIdx.x;
  for (int i = tid; i < 32*64; i += 256){
    int qi = i >> 6, wi = i & 63;
    int q = q0 + qi;
    ld[qi][wi] = (q < QQ) ? pm[(size_t)sel2[q]*WHX + wh0 + wi] * (1.0f/96.0f) : 0.f;
  }
  __syncthreads();
  int wloc = tid >> 2, j0 = (tid & 3)*8;
  u16 tmp[8];
  #pragma unroll
  for (int j = 0; j < 8; j++) tmp[j] = f2bf(ld[j0+j][wloc]);
  *(uint4*)(omT + (size_t)(wh0+wloc)*QP + q0 + j0) = *(const uint4*)tmp;
}

// ---------------- T3: tmT bf16 [9216][416] (transpose, zero-padded) ----------------
__global__ __launch_bounds__(256) void t_tmT(
    const float* __restrict__ tm, u16* __restrict__ tmT){
  __shared__ float ld[32][65];
  int n0 = blockIdx.x*32, wh0 = blockIdx.y*64;
  int tid = threadIdx.x;
  for (int i = tid; i < 32*64; i += 256){
    int ni = i >> 6, wi = i & 63;
    int n = n0 + ni;
    ld[ni][wi] = (n < NN) ? tm[(size_t)n*WHX + wh0 + wi] : 0.f;
  }
  __syncthreads();
  int wloc = tid >> 2, j0 = (tid & 3)*8;
  u16 tmp[8];
  #pragma unroll
  for (int j = 0; j < 8; j++) tmp[j] = f2bf(ld[j0+j][wloc]);
  *(uint4*)(tmT + (size_t)(wh0+wloc)*NP + n0 + j0) = *(const uint4*)tmp;
}

// ---------------- T4: gtsimP bf16 [8][304][96] (per-batch zero-padded window) ----------------
__global__ __launch_bounds__(256) void t_gtp(
    const float* __restrict__ gtsim, const int* __restrict__ bstart,
    u16* __restrict__ gtp){
  int g = blockIdx.x*256 + threadIdx.x;
  if (g >= BB*CP*(KP/8)) return;
  int b = g / (CP*(KP/8));
  int rem = g - b*(CP*(KP/8));
  int c = rem / (KP/8);
  int kg = rem % (KP/8);
  int n0 = bstart[b], n1 = bstart[b+1];
  int kst = n0 & ~7;
  u16 tmp[8];
  #pragma unroll
  for (int j = 0; j < 8; j++){
    int n = kst + kg*8 + j;
    float v = (n >= n0 && n < n1 && c < CC) ? gtsim[(size_t)n*CC + c] : 0.f;
    tmp[j] = f2bf(v);
  }
  *(uint4*)(gtp + ((size_t)b*CP + c)*KP + kg*8) = *(const uint4*)tmp;
}

// ---------------- K15: MFMA z-GEMM + column softmax + dice ----------------
// global_load_lds double-buffered A staging: linear LDS dest, PRE-SWIZZLED per-lane
// global source, swizzled ds_read (content check: slot(row,cs)=chunk cs^((row>>1)&3);
// read cs = lgrp^((lrow>>1)&3); (row>>1)&3 == (lrow>>1)&3 since t*8%4==0 => data = chunk lgrp). Bit-exact.
// One barrier per K-step (writes go to the other buffer). XCD pinned by tile range.
constexpr int ALDS = 32;  // LDS row stride in u16 (64 B, power of 2)
__global__ __launch_bounds__(256) void k_zsoft(
    const u16* __restrict__ simTb, const u16* __restrict__ omT,
    const u16* __restrict__ gtp, const u16* __restrict__ tmT,
    const int* __restrict__ bstart, float* __restrict__ sc){
  const int bid = blockIdx.x;
  const int xcd = bid & 7;
  const int r9  = bid >> 3;            // 0..143
  const int tile = xcd * 18 + (r9 % 18);
  const int b    = r9 / 18;
  const int tid = threadIdx.x;
  const int w = tid >> 6, l = tid & 63;
  const int lrow = l & 15, lgrp = l >> 4;
  const int col = tile*64 + w*16 + lrow;

  __shared__ u16 As[2][CP*ALDS];   // 2 x 19456 B
  __shared__ float red[256];

  const u16* Ab = simTb + (size_t)b*CP*QP;
  // DMA mapping: issue idx q = w*5+i covers LDS chunks q*64+lane (chunk = 16B).
  // q==19 exceeds 1216 chunks entirely -> skipped (CP*4 == 1216 == 19*64).
  int srcoff[5];
  #pragma unroll
  for (int i = 0; i < 5; i++){
    int p = (w*5 + i)*64 + l;
    int row = p >> 2, cs = p & 3;
    int g = cs ^ ((row >> 1) & 3);
    srcoff[i] = row*QP + g*8;
  }
  const int nIss = (w == 3) ? 4 : 5;
  const int roff = (lgrp ^ ((lrow >> 1) & 3)) << 3;
  const u16* pB = omT + (size_t)col*QP;

  // prologue: DMA chunk ks=0 into buf 0
  #pragma unroll
  for (int i = 0; i < 5; i++){
    if (i < nIss) gload_lds16(Ab + srcoff[i], &As[0][(w*5+i)*512]);
  }
  bf16x8 bcur = *(const bf16x8*)(pB);

  f32x4 acc[19];
  #pragma unroll
  for (int t = 0; t < 19; t++) acc[t] = (f32x4){0.f,0.f,0.f,0.f};
  __syncthreads();   // drains vmcnt -> buf0 ready

  for (int ks = 0; ks < 10; ks++){
    const int cur = ks & 1;
    bf16x8 bnext;
    if (ks + 1 < 10){
      const int ko = (ks + 1) * 32;
      #pragma unroll
      for (int i = 0; i < 5; i++){
        if (i < nIss) gload_lds16(Ab + srcoff[i] + ko, &As[cur ^ 1][(w*5+i)*512]);
      }
      bnext = *(const bf16x8*)(pB + ko);
    }
    __builtin_amdgcn_s_setprio(1);
    #pragma unroll
    for (int t = 0; t < 19; t++){
      bf16x8 af = *(const bf16x8*)&As[cur][t*16*ALDS + lrow*ALDS + roff];
      acc[t] = __builtin_amdgcn_mfma_f32_16x16x32_bf16(af, bcur, acc[t], 0, 0, 0);
    }
    __builtin_amdgcn_s_setprio(0);
    bcur = bnext;
    __syncthreads();  // drains vmcnt -> next buffer ready; also protects WAR on cur
  }

  float lmax = -INFINITY;
  #pragma unroll
  for (int t = 0; t < 19; t++){
    if (t == 18 && lgrp == 3) continue;
    lmax = fmaxf(lmax, fmaxf(fmaxf(acc[t][0], acc[t][1]), fmaxf(acc[t][2], acc[t][3])));
  }
  lmax = fmaxf(lmax, __shfl_xor(lmax, 16));
  lmax = fmaxf(lmax, __shfl_xor(lmax, 32));
  float ls = 0.f;
  #pragma unroll
  for (int t = 0; t < 19; t++){
    if (t == 18 && lgrp == 3){
      acc[t] = (f32x4){0.f,0.f,0.f,0.f};
      continue;
    }
    float p0 = __expf(acc[t][0] - lmax);
    float p1 = __expf(acc[t][1] - lmax);
    float p2 = __expf(acc[t][2] - lmax);
    float p3 = __expf(acc[t][3] - lmax);
    acc[t][0] = p0; acc[t][1] = p1; acc[t][2] = p2; acc[t][3] = p3;
    ls += p0 + p1 + p2 + p3;
  }
  float S = ls;
  S += __shfl_xor(S, 16);
  S += __shfl_xor(S, 32);
  float inv = 1.f / S;

  int n0 = bstart[b];
  int kst = n0 & ~7;
  const u16* tB = tmT + (size_t)col*NP + kst + lgrp*8;
  bf16x8 b2a = *(const bf16x8*)(tB);
  bf16x8 b2b = *(const bf16x8*)(tB + 32);
  bf16x8 b2c = *(const bf16x8*)(tB + 64);
  const u16* A2 = gtp + (size_t)b*CP*KP + lgrp*8;
  float dl = 0.f;
  #pragma unroll
  for (int t = 0; t < 19; t++){
    const u16* ar = A2 + (size_t)(t*16 + lrow)*KP;
    f32x4 rr = (f32x4){0.f,0.f,0.f,0.f};
    rr = __builtin_amdgcn_mfma_f32_16x16x32_bf16(*(const bf16x8*)(ar),      b2a, rr, 0, 0, 0);
    rr = __builtin_amdgcn_mfma_f32_16x16x32_bf16(*(const bf16x8*)(ar + 32), b2b, rr, 0, 0, 0);
    rr = __builtin_amdgcn_mfma_f32_16x16x32_bf16(*(const bf16x8*)(ar + 64), b2c, rr, 0, 0, 0);
    dl += acc[t][0]*rr[0] + acc[t][1]*rr[1] + acc[t][2]*rr[2] + acc[t][3]*rr[3];
  }
  dl *= inv;

  red[tid] = dl; __syncthreads();
  for (int s = 128; s > 0; s >>= 1){
    if (tid < s) red[tid] += red[tid+s];
    __syncthreads();
  }
  if (tid == 0) atomicAdd(&sc[5], red[0]);
}

// ---------------- K16: fused gtiou + sumtgt + finalize ----------------
__global__ __launch_bounds__(512) void k_final3(
    const float* __restrict__ gsel, const float* __restrict__ tb,
    const int* __restrict__ bidx, const float* __restrict__ rowsum,
    const float* __restrict__ msum, const float* __restrict__ sc,
    const int* __restrict__ kint, float* __restrict__ out){
  int tid = threadIdx.x;
  __shared__ float s1[512], s2[512];
  __shared__ float stgt[8];
  if (tid < 8) stgt[tid] = 0.f;
  __syncthreads();
  float a1 = 0.f, a2 = 0.f;
  if (tid < NN){
    float4 g = ((const float4*)gsel)[tid];
    float4 t = ((const float4*)tb)[tid];
    float iou = iou_xyxy(g.x,g.y,g.z,g.w, t.x,t.y,t.z,t.w);
    a1 = 1.f - iou;
    a2 = fabsf(g.x-t.x) + fabsf(g.y-t.y) + fabsf(g.z-t.z) + fabsf(g.w-t.w);
    atomicAdd(&stgt[bidx[tid]], rowsum[tid] * msum[tid]);
  }
  s1[tid] = a1; s2[tid] = a2; __syncthreads();
  for (int s = 256; s > 0; s >>= 1){
    if (tid < s){ s1[tid] += s1[tid+s]; s2[tid] += s2[tid+s]; }
    __syncthreads();
  }
  if (tid == 0){
    float K = (float)kint[0];
    float cls = sc[0]/300.f + sc[1]/300.f;
    float stot = sc[5];
    float dice = 0.f;
    for (int b = 0; b < 8; b++) dice += stot / (9216.0f + stgt[b] + 1e-6f);
    dice *= (1.0f/8.0f);
    out[0] = cls;
    out[1] = dice;
    out[2] = (sc[2] / 2764800.0f) / K;
    out[3] = s1[0] / K;
    out[4] = s2[0] / K;
  }
}

// ---------------- launch ----------------
extern "C" void kernel_launch(void* const* d_in, const int* in_sizes, int n_in,
                              void* d_out, int out_size, void* d_ws, size_t ws_size,
                              hipStream_t stream) {
  const float* ce  = (const float*)d_in[0];
  const float* pl  = (const float*)d_in[1];
  const float* pb  = (const float*)d_in[2];
  const float* pm  = (const float*)d_in[3];
  const float* tm  = (const float*)d_in[4];
  const float* te  = (const float*)d_in[5];
  const float* tbb = (const float*)d_in[6];
  const int*  tids = (const int*)d_in[8];
  const int*  bidx = (const int*)d_in[9];
  float* out = (float*)d_out;
  float* w = (float*)d_ws;

  if (ws_size < F_TOTAL * sizeof(float)) return;

  float* SIMS   = w + F_SIMS;
  float* GTSIM  = w + F_GTSIM;
  float* MM     = w + F_MM;
  float* SCORE  = w + F_SCORE;
  float* BBOX   = w + F_BBOX;
  float* TBOX   = w + F_TB;
  float* SB     = w + F_SB;
  float* KB     = w + F_KB;
  float* ROWSUM = w + F_ROWSUM;
  float* OE     = w + F_OE;
  float* GSEL   = w + F_GSEL;
  float* MSUM   = w + F_MSUM;
  float* SC     = w + F_SC;
  int*   CNT    = (int*)(w + F_CNT);
  int*   ORDER  = (int*)(w + F_ORDER);
  int*   NMSIDX = (int*)(w + F_NMSIDX);
  int*   SEL2   = (int*)(w + F_SEL2);
  int*   BSTART = (int*)(w + F_BSTART);
  int*   KINT   = (int*)(w + F_KINT);
  int*   CLS    = (int*)(w + F_CLS);
  int*   KEEPF  = (int*)(w + F_KEEPF);
  int*   LIST   = (int*)(w + F_LIST);
  u16* SIMTB = (u16*)(w + F_SIMTB);
  u16* OMT   = (u16*)(w + F_OMT);
  u16* TMT   = (u16*)(w + F_TMT);
  u16* GTP   = (u16*)(w + F_GTP);

  // zero accumulators + cell counts
  hipMemsetAsync(w + F_OE, 0, (F_ACCEND - F_OE) * sizeof(float), stream);

  k_gemm_t<<<dim3(43, 10), 256, 0, stream>>>(pl, ce, te, SIMS, GTSIM);
  k_post<<<BQ, 512, 0, stream>>>(SIMS, pb, tbb, tids, bidx, GTSIM, SCORE, BBOX, TBOX, ROWSUM, CLS);
  k_rankgather<<<BQ, 256, 0, stream>>>(SCORE, BBOX, CLS, bidx, ORDER, SB, BSTART, CNT, LIST);
  k_cellnms<<<(BB*CC + 255)/256, 256, 0, stream>>>(SB, CNT, LIST, KEEPF);
  k_compact<<<1, 256, 0, stream>>>(KEEPF, ORDER, SB, NMSIDX, KB, KINT);
  k_gtsel<<<BQ, 512, 0, stream>>>(KB, TBOX, NMSIDX, pl, KINT, GSEL, OE);
  k_m<<<(NN*NN + 255)/256, 256, 0, stream>>>(te, OE, MM);
  k_ce<<<NN, 64, 0, stream>>>(MM, SC);
  k_sel2<<<NN, 256, 0, stream>>>(SIMS, SEL2);
  k_om<<<NN*9, 256, 0, stream>>>(pm, tm, SEL2, MSUM, SC);

  t_simT<<<dim3(QP/32, 5, BB), 256, 0, stream>>>(SIMS, SIMTB);
  t_omT<<<dim3(QP/32, WHX/64), 256, 0, stream>>>(pm, SEL2, OMT);
  t_tmT<<<dim3(NP/32, WHX/64), 256, 0, stream>>>(tm, TMT);
  t_gtp<<<(BB*CP*(KP/8) + 255)/256, 256, 0, stream>>>(GTSIM, BSTART, GTP);

  k_zsoft<<<dim3((WHX/64) * BB), 256, 0, stream>>>(SIMTB, OMT, GTP, TMT, BSTART, SC);
  k_final3<<<1, 512, 0, stream>>>(GSEL, TBOX, bidx, ROWSUM, MSUM, SC, KINT, out);
}

// Round 12
// 267.981 us; speedup vs baseline: 7.6144x; 1.0229x over previous
//
#include <hip/hip_runtime.h>
#include <stdint.h>

#define DEVFN __device__ __forceinline__

typedef unsigned short u16;
typedef short bf16x8 __attribute__((ext_vector_type(8)));
typedef float f32x4 __attribute__((ext_vector_type(4)));

constexpr int BB = 8, QQ = 300, CC = 300, NN = 300, DD = 256;
constexpr int WHX = 9216, BQ = 2400, SIMW = 600;
constexpr int QP = 320;
constexpr int CP = 304;
constexpr int KP = 96;
constexpr int NP = 416;
constexpr int CELLCAP = 300;

// ---------------- workspace layout (float units) ----------------
constexpr size_t F_SIMS   = 0;
constexpr size_t F_GTSIM  = F_SIMS   + (size_t)BQ*SIMW;
constexpr size_t F_MM     = F_GTSIM  + (size_t)NN*CC;
constexpr size_t F_SCORE  = F_MM     + (size_t)NN*NN;
constexpr size_t F_BBOX   = F_SCORE  + BQ;
constexpr size_t F_TB     = F_BBOX   + (size_t)BQ*4;
constexpr size_t F_SB     = F_TB     + (size_t)NN*4;
constexpr size_t F_SAREA  = F_SB     + (size_t)BQ*4;
constexpr size_t F_KB     = F_SAREA  + BQ;
constexpr size_t F_ROWSUM = F_KB     + (size_t)BQ*4;
constexpr size_t F_OE     = F_ROWSUM + NN;                     // ---- zeroed zone
constexpr size_t F_GSEL   = F_OE     + (size_t)NN*DD;
constexpr size_t F_MSUM   = F_GSEL   + (size_t)NN*4;
constexpr size_t F_STGT   = F_MSUM   + NN;
constexpr size_t F_SC     = F_STGT   + 8;
constexpr size_t F_CNT    = F_SC     + 16;
constexpr size_t F_ACCEND = F_CNT    + BQ;                     // ---- end zeroed zone
constexpr size_t F_ORDER  = F_ACCEND;
constexpr size_t F_NMSIDX = F_ORDER  + BQ;
constexpr size_t F_SEL2   = F_NMSIDX + BQ;
constexpr size_t F_BSTART = F_SEL2   + NN;
constexpr size_t F_KINT   = F_BSTART + 16;
constexpr size_t F_CLS    = F_KINT   + 4;
constexpr size_t F_KEEPF  = F_CLS    + BQ;
constexpr size_t F_LIST   = F_KEEPF  + BQ;
constexpr size_t F_S2T    = F_LIST   + (size_t)BQ*CELLCAP;     // f32 [300][2400]
constexpr size_t F_SIMTB  = ((F_S2T + (size_t)NN*BQ + 7) & ~(size_t)7);  // u16[8][304][320]
constexpr size_t F_OMT    = F_SIMTB + (size_t)BB*CP*QP/2;
constexpr size_t F_TMT    = F_OMT   + (size_t)WHX*QP/2;
constexpr size_t F_GTP    = F_TMT   + (size_t)WHX*NP/2;
constexpr size_t F_TOTAL  = F_GTP   + (size_t)BB*CP*KP/2;

// ---------------- JAX threefry2x32 (partitionable scheme) ----------------
DEVFN uint32_t rotl32(uint32_t v, int r){ return (v << r) | (v >> (32 - r)); }

DEVFN void tf2x32(uint32_t k0, uint32_t k1, uint32_t x0, uint32_t x1,
                  uint32_t& o0, uint32_t& o1){
  uint32_t ks2 = k0 ^ k1 ^ 0x1BD11BDAu;
  x0 += k0; x1 += k1;
#define TFR(r) x0 += x1; x1 = rotl32(x1, r); x1 ^= x0;
  TFR(13) TFR(15) TFR(26) TFR(6)   x0 += k1;  x1 += ks2 + 1u;
  TFR(17) TFR(29) TFR(16) TFR(24)  x0 += ks2; x1 += k0  + 2u;
  TFR(13) TFR(15) TFR(26) TFR(6)   x0 += k0;  x1 += k1  + 3u;
  TFR(17) TFR(29) TFR(16) TFR(24)  x0 += k1;  x1 += ks2 + 4u;
  TFR(13) TFR(15) TFR(26) TFR(6)   x0 += ks2; x1 += k0  + 5u;
#undef TFR
  o0 = x0; o1 = x1;
}

DEVFN void subkey(int i, uint32_t& k0, uint32_t& k1){
  tf2x32(0u, 42u, 0u, (uint32_t)i, k0, k1);
}

DEVFN float gumbel32(uint32_t k0, uint32_t k1, uint32_t idx){
  uint32_t h, l; tf2x32(k0, k1, 0u, idx, h, l);
  uint32_t bits = h ^ l;
  float f = __uint_as_float((bits >> 9) | 0x3F800000u) - 1.0f;
  const float tiny = 1.17549435e-38f;
  float u = fmaxf(tiny, f + tiny);
  return -logf(-logf(u));
}

DEVFN float iou_xyxy(float ax1,float ay1,float ax2,float ay2,
                     float bx1,float by1,float bx2,float by2){
  float aa = (ax2-ax1)*(ay2-ay1);
  float ab = (bx2-bx1)*(by2-by1);
  float lx = fmaxf(ax1,bx1), ly = fmaxf(ay1,by1);
  float rx = fminf(ax2,bx2), ry = fminf(ay2,by2);
  float iw = fmaxf(rx-lx,0.f), ih = fmaxf(ry-ly,0.f);
  float in_ = iw*ih;
  return in_/(aa+ab-in_);
}

DEVFN u16 f2bf(float x){
  uint32_t u = __float_as_uint(x);
  uint32_t r = u + 0x7FFFu + ((u >> 16) & 1u);
  return (u16)(r >> 16);
}

DEVFN void gload_lds16(const u16* g, u16* l){
  __builtin_amdgcn_global_load_lds(
      (const __attribute__((address_space(1))) unsigned int*)g,
      (__attribute__((address_space(3))) unsigned int*)l,
      16, 0, 0);
}

// ---------------- K1: tiled f32 GEMM 64x64 + s2T side-write ----------------
__global__ __launch_bounds__(256) void k_gemm_t(
    const float* __restrict__ pl, const float* __restrict__ ce,
    const float* __restrict__ te, float* __restrict__ sims,
    float* __restrict__ gtsim, float* __restrict__ s2t){
  __shared__ float As[16][64];
  __shared__ float Bs[16][64];
  const int row0 = blockIdx.x * 64, col0 = blockIdx.y * 64;
  const int tid = threadIdx.x;
  const int lrow = tid >> 2, lk0 = (tid & 3) * 4;
  const int tr = tid >> 4, tc = tid & 15;

  float acc[4][4];
  #pragma unroll
  for (int i = 0; i < 4; i++)
    #pragma unroll
    for (int j = 0; j < 4; j++) acc[i][j] = 0.f;

  const float4 z4 = {0.f,0.f,0.f,0.f};
  const int grow = row0 + lrow;
  const int gcol = col0 + lrow;
  const float* arow = nullptr;
  if (grow < 2400) arow = pl + (size_t)grow * DD;
  else if (grow < 2700) arow = te + (size_t)(grow - 2400) * DD;
  const float* brow = nullptr;
  if (gcol < 300) brow = ce + (size_t)gcol * DD;
  else if (gcol < 600) brow = te + (size_t)(gcol - 300) * DD;

  float4 av = arow ? *(const float4*)(arow + lk0) : z4;
  float4 bv = brow ? *(const float4*)(brow + lk0) : z4;

  for (int step = 0; step < 16; step++){
    __syncthreads();
    #pragma unroll
    for (int j = 0; j < 4; j++){
      As[lk0 + j][lrow] = ((const float*)&av)[j];
      Bs[lk0 + j][lrow] = ((const float*)&bv)[j];
    }
    __syncthreads();
    if (step + 1 < 16){
      const int k0 = (step + 1) * 16;
      av = arow ? *(const float4*)(arow + k0 + lk0) : z4;
      bv = brow ? *(const float4*)(brow + k0 + lk0) : z4;
    }
    #pragma unroll
    for (int kk = 0; kk < 16; kk++){
      float4 a4 = *(const float4*)&As[kk][tr*4];
      float4 b4 = *(const float4*)&Bs[kk][tc*4];
      float a[4] = {a4.x,a4.y,a4.z,a4.w};
      float b[4] = {b4.x,b4.y,b4.z,b4.w};
      #pragma unroll
      for (int i = 0; i < 4; i++)
        #pragma unroll
        for (int j = 0; j < 4; j++)
          acc[i][j] = fmaf(a[i], b[j], acc[i][j]);
    }
  }

  #pragma unroll
  for (int i = 0; i < 4; i++){
    const int r = row0 + tr*4 + i;
    const int c0 = col0 + tc*4;
    if (r < 2400){
      if (c0 < 600){
        float4 o0 = {acc[i][0],acc[i][1],acc[i][2],acc[i][3]};
        *(float4*)(sims + (size_t)r*SIMW + c0) = o0;
        if (c0 >= 300){
          #pragma unroll
          for (int j = 0; j < 4; j++)
            s2t[(size_t)(c0 + j - 300)*BQ + r] = acc[i][j];
        }
      }
    } else if (r < 2700){
      const int n = r - 2400;
      #pragma unroll
      for (int j = 0; j < 4; j++){
        int c = c0 + j;
        if (c < 300) gtsim[(size_t)n*CC + c] = acc[i][j];
      }
    }
  }
}

// ---------------- K2: per-bq scores/argmax(g0)/boxes/cls; tb rows; gtsim rowsums ----------------
// 256 threads, 2 elems/thread pre-reduce == original 512-tree first step (bit-identical).
__global__ __launch_bounds__(256) void k_post(
    const float* __restrict__ sims, const float* __restrict__ pb,
    const float* __restrict__ tbb, const int* __restrict__ tids,
    const int* __restrict__ bidx, const float* __restrict__ gtsim,
    float* __restrict__ score, float* __restrict__ bbox,
    float* __restrict__ tb, float* __restrict__ rowsum,
    int* __restrict__ clsout){
  int bq = blockIdx.x, tid = threadIdx.x;
  __shared__ float sv[256];
  __shared__ int   si[256];
  const int i2 = tid + 256;
  float v1 = (tid < CC) ? sims[(size_t)bq*SIMW + tid] : -INFINITY;
  float v2 = (i2  < CC) ? sims[(size_t)bq*SIMW + i2]  : -INFINITY;
  sv[tid] = fmaxf(v1, v2); __syncthreads();
  for (int s = 128; s > 0; s >>= 1){ if (tid < s) sv[tid] = fmaxf(sv[tid], sv[tid+s]); __syncthreads(); }
  if (tid == 0) score[bq] = sv[0];
  __syncthreads();
  uint32_t gk0, gk1; subkey(0, gk0, gk1);
  float y1 = (tid < CC) ? v1 + gumbel32(gk0, gk1, (uint32_t)(bq*CC + tid)) : -INFINITY;
  float y2 = (i2  < CC) ? v2 + gumbel32(gk0, gk1, (uint32_t)(bq*CC + i2))  : -INFINITY;
  float ym; int yi;
  if (y2 > y1){ ym = y2; yi = i2; } else { ym = y1; yi = tid; }
  sv[tid] = ym; si[tid] = yi; __syncthreads();
  for (int s = 128; s > 0; s >>= 1){
    if (tid < s){
      float ov = sv[tid+s]; int oi = si[tid+s];
      if (ov > sv[tid] || (ov == sv[tid] && oi < si[tid])){ sv[tid] = ov; si[tid] = oi; }
    }
    __syncthreads();
  }
  if (tid == 0){
    int cls = si[0];
    clsout[bq] = cls;
    float ox = 224.0f * (float)cls;
    float oy = 224.0f * (float)(bq / QQ);
    float cx = pb[bq*4+0], cy = pb[bq*4+1], ww = pb[bq*4+2], hh = pb[bq*4+3];
    bbox[bq*4+0] = cx - 0.5f*ww + ox;
    bbox[bq*4+1] = cy - 0.5f*hh + oy;
    bbox[bq*4+2] = cx + 0.5f*ww + ox;
    bbox[bq*4+3] = cy + 0.5f*hh + oy;
  }
  if (bq < NN){
    __syncthreads();
    float r1 = (tid < CC) ? gtsim[(size_t)bq*CC + tid] : 0.f;
    float r2 = (i2  < CC) ? gtsim[(size_t)bq*CC + i2]  : 0.f;
    sv[tid] = r1 + r2; __syncthreads();
    for (int s = 128; s > 0; s >>= 1){ if (tid < s) sv[tid] += sv[tid+s]; __syncthreads(); }
    if (tid == 0) rowsum[bq] = sv[0];
    if (tid == 1){
      float gx = 224.0f * (float)tids[bq], gy = 224.0f * (float)bidx[bq];
      float cx = tbb[bq*4+0], cy = tbb[bq*4+1], ww = tbb[bq*4+2], hh = tbb[bq*4+3];
      tb[bq*4+0] = cx - 0.5f*ww + gx;
      tb[bq*4+1] = cy - 0.5f*hh + gy;
      tb[bq*4+2] = cx + 0.5f*ww + gx;
      tb[bq*4+3] = cy + 0.5f*hh + gy;
    }
  }
}

// ---------------- K3: fused rank + gather + bucket ----------------
__global__ __launch_bounds__(256) void k_rankgather(
    const float* __restrict__ score, const float* __restrict__ bbox,
    const int* __restrict__ cls, const int* __restrict__ bidx,
    int* __restrict__ order, float* __restrict__ sb,
    int* __restrict__ bstart, int* __restrict__ cnt,
    int* __restrict__ list){
  const int t = blockIdx.x;
  const int tid = threadIdx.x;
  const float st = score[t];
  int c = 0;
  for (int j = tid; j < BQ; j += 256){
    float sj = score[j];
    c += (sj > st) || (sj == st && j < t);
  }
  __shared__ int red[256];
  red[tid] = c; __syncthreads();
  for (int s = 128; s > 0; s >>= 1){
    if (tid < s) red[tid] += red[tid+s];
    __syncthreads();
  }
  if (tid == 0){
    int r = red[0];
    order[r] = t;
    float x1 = bbox[t*4+0], y1 = bbox[t*4+1], x2 = bbox[t*4+2], y2 = bbox[t*4+3];
    sb[r*4+0] = x1; sb[r*4+1] = y1; sb[r*4+2] = x2; sb[r*4+3] = y2;
    int key = (t / QQ) * CC + cls[t];
    int slot = atomicAdd(&cnt[key], 1);
    list[(size_t)key*CELLCAP + slot] = r;
  }
  if (t == 0 && tid >= 32 && tid < 41){
    int b = tid - 32, cb = 0;
    for (int n = 0; n < NN; n++) cb += (bidx[n] < b);
    bstart[b] = cb;
  }
}

// ---------------- K6': per-cell greedy NMS ----------------
__global__ __launch_bounds__(256) void k_cellnms(
    const float* __restrict__ sb, const int* __restrict__ cnt,
    const int* __restrict__ list, int* __restrict__ keepf){
  int key = blockIdx.x*256 + threadIdx.x;
  if (key >= BB*CC) return;
  int m = cnt[key];
  if (m <= 0) return;
  const int* lst = list + (size_t)key*CELLCAP;
  unsigned long long keptmask = 0ull;
  int prevp = -1;
  for (int a = 0; a < m; a++){
    int pa = 0x7fffffff;
    for (int j = 0; j < m; j++){
      int pj = lst[j];
      if (pj > prevp && pj < pa) pa = pj;
    }
    prevp = pa;
    float4 A = ((const float4*)sb)[pa];
    float areaA = (A.z-A.x)*(A.w-A.y);
    bool kept = true;
    int pbprev = -1;
    for (int b2 = 0; b2 < a; b2++){
      int pb = 0x7fffffff;
      for (int j = 0; j < m; j++){
        int pj = lst[j];
        if (pj > pbprev && pj < pb) pb = pj;
      }
      pbprev = pb;
      bool keptb = (m <= 64) ? (((keptmask >> b2) & 1ull) != 0ull) : (keepf[pb] != 0);
      if (!keptb) continue;
      float4 B = ((const float4*)sb)[pb];
      float areaB = (B.z-B.x)*(B.w-B.y);
      float lx = fmaxf(A.x,B.x), ly = fmaxf(A.y,B.y);
      float rx = fminf(A.z,B.z), ry = fminf(A.w,B.w);
      float iw = fmaxf(rx-lx,0.f), ih = fmaxf(ry-ly,0.f);
      float inter = iw*ih;
      if (inter/(areaA + areaB - inter) > 0.5f){ kept = false; break; }
    }
    if (m <= 64 && kept) keptmask |= (1ull << a);
    keepf[pa] = kept ? 1 : 0;
  }
}

// ---------------- K7: compact ----------------
__global__ __launch_bounds__(256) void k_compact(
    const int* __restrict__ keepflag, const int* __restrict__ order,
    const float* __restrict__ sb, int* __restrict__ nmsidx,
    float* __restrict__ kb, int* __restrict__ kint){
  __shared__ int csum[256];
  int tid = threadIdx.x;
  int p0 = tid*10;
  int keepf[10];
  int cnt = 0;
  #pragma unroll
  for (int d = 0; d < 10; d++){
    int p = p0 + d;
    int k = 0;
    if (p < BQ) k = keepflag[p];
    keepf[d] = k; cnt += k;
  }
  csum[tid] = cnt; __syncthreads();
  for (int s = 1; s < 256; s <<= 1){
    int add = (tid >= s) ? csum[tid - s] : 0;
    __syncthreads();
    csum[tid] += add;
    __syncthreads();
  }
  int pos = csum[tid] - cnt;
  #pragma unroll
  for (int d = 0; d < 10; d++){
    if (keepf[d]){
      int p = p0 + d;
      nmsidx[pos] = order[p];
      ((float4*)kb)[pos] = ((const float4*)sb)[p];
      pos++;
    }
  }
  if (tid == 255) kint[0] = csum[255];
}

// ---------------- K8: per-kept-box scatter ----------------
__global__ __launch_bounds__(512) void k_gtsel(
    const float* __restrict__ kb, const float* __restrict__ tb,
    const int* __restrict__ nmsidx, const float* __restrict__ pl,
    const int* __restrict__ kint, float* __restrict__ gsel,
    float* __restrict__ oe){
  int k = blockIdx.x;
  if (k >= kint[0]) return;
  int tid = threadIdx.x;
  __shared__ float sv[512];
  __shared__ int   si[512];
  float4 a = ((const float4*)kb)[k];
  float iou = -INFINITY;
  if (tid < NN){
    float4 t = ((const float4*)tb)[tid];
    iou = iou_xyxy(a.x,a.y,a.z,a.w, t.x,t.y,t.z,t.w);
    if (iou != iou) iou = 0.f;
  }
  sv[tid] = iou; __syncthreads();
  for (int s = 256; s > 0; s >>= 1){ if (tid < s) sv[tid] = fmaxf(sv[tid], sv[tid+s]); __syncthreads(); }
  float m = sv[0]; __syncthreads();
  float e = (tid < NN) ? expf(iou - m) : 0.f;
  sv[tid] = e; __syncthreads();
  for (int s = 256; s > 0; s >>= 1){ if (tid < s) sv[tid] += sv[tid+s]; __syncthreads(); }
  float S = sv[0]; __syncthreads();
  uint32_t gk0, gk1; subkey(1, gk0, gk1);
  float y = (tid < NN) ? (e / S + gumbel32(gk0, gk1, (uint32_t)(k*NN + tid))) : -INFINITY;
  sv[tid] = y; si[tid] = tid; __syncthreads();
  for (int s = 256; s > 0; s >>= 1){
    if (tid < s){
      float ov = sv[tid+s]; int oi = si[tid+s];
      if (ov > sv[tid] || (ov == sv[tid] && oi < si[tid])){ sv[tid] = ov; si[tid] = oi; }
    }
    __syncthreads();
  }
  int sel = si[0];
  if (tid < 4) atomicAdd(&gsel[sel*4 + tid], ((const float*)&a)[tid]);
  if (tid < DD) atomicAdd(&oe[(size_t)sel*DD + tid], pl[(size_t)nmsidx[k]*DD + tid]);
}

// ---------------- K10: tiled M = te @ oe^T (32x32 tiles) ----------------
__global__ __launch_bounds__(256) void k_m_t(
    const float* __restrict__ te, const float* __restrict__ oe,
    float* __restrict__ M){
  __shared__ float As[16][32];
  __shared__ float Bs[16][32];
  const int row0 = blockIdx.x * 32, col0 = blockIdx.y * 32;
  const int tid = threadIdx.x;
  const int lr = tid >> 3, lk0 = (tid & 7) * 2;
  const int tr = tid >> 4, tc = tid & 15;
  float acc[2][2] = {{0.f,0.f},{0.f,0.f}};
  const float* arow = (row0 + lr < NN) ? te + (size_t)(row0 + lr)*DD : nullptr;
  const float* brow = (col0 + lr < NN) ? oe + (size_t)(col0 + lr)*DD : nullptr;
  for (int step = 0; step < 16; step++){
    const int k0 = step*16;
    float2 a2 = arow ? *(const float2*)(arow + k0 + lk0) : float2{0.f,0.f};
    float2 b2 = brow ? *(const float2*)(brow + k0 + lk0) : float2{0.f,0.f};
    __syncthreads();
    As[lk0][lr] = a2.x; As[lk0+1][lr] = a2.y;
    Bs[lk0][lr] = b2.x; Bs[lk0+1][lr] = b2.y;
    __syncthreads();
    #pragma unroll
    for (int kk = 0; kk < 16; kk++){
      float a0 = As[kk][tr*2], a1 = As[kk][tr*2+1];
      float b0 = Bs[kk][tc*2], b1 = Bs[kk][tc*2+1];
      acc[0][0] = fmaf(a0,b0,acc[0][0]);
      acc[0][1] = fmaf(a0,b1,acc[0][1]);
      acc[1][0] = fmaf(a1,b0,acc[1][0]);
      acc[1][1] = fmaf(a1,b1,acc[1][1]);
    }
  }
  #pragma unroll
  for (int i = 0; i < 2; i++){
    int r = row0 + tr*2 + i;
    if (r >= NN) continue;
    #pragma unroll
    for (int j = 0; j < 2; j++){
      int c = col0 + tc*2 + j;
      if (c < NN) M[(size_t)r*NN + c] = acc[i][j];
    }
  }
}

// ---------------- K11: both cross-entropies ----------------
__global__ __launch_bounds__(64) void k_ce(
    const float* __restrict__ M, float* __restrict__ sc){
  int i = blockIdx.x, lane = threadIdx.x;
  float m = -INFINITY;
  for (int j = lane; j < NN; j += 64) m = fmaxf(m, M[(size_t)i*NN + j]);
  for (int o = 32; o > 0; o >>= 1) m = fmaxf(m, __shfl_xor(m, o));
  float s = 0.f;
  for (int j = lane; j < NN; j += 64) s += expf(M[(size_t)i*NN + j] - m);
  for (int o = 32; o > 0; o >>= 1) s += __shfl_xor(s, o);
  float lr = m + logf(s);
  float m2 = -INFINITY;
  for (int j = lane; j < NN; j += 64) m2 = fmaxf(m2, M[(size_t)j*NN + i]);
  for (int o = 32; o > 0; o >>= 1) m2 = fmaxf(m2, __shfl_xor(m2, o));
  float s2 = 0.f;
  for (int j = lane; j < NN; j += 64) s2 += expf(M[(size_t)j*NN + i] - m2);
  for (int o = 32; o > 0; o >>= 1) s2 += __shfl_xor(s2, o);
  float lc = m2 + logf(s2);
  if (lane == 0){
    float d = M[(size_t)i*NN + i];
    atomicAdd(&sc[0], lr - d);
    atomicAdd(&sc[1], lc - d);
  }
}

// ---------------- K12: sel2 (coalesced via s2T) ----------------
__global__ __launch_bounds__(256) void k_sel2(
    const float* __restrict__ s2t, int* __restrict__ sel2){
  int n = blockIdx.x, tid = threadIdx.x;
  uint32_t gk0, gk1; subkey(2, gk0, gk1);
  float best = -INFINITY; int bi = 0x7fffffff;
  for (int r = tid; r < BQ; r += 256){
    float v = s2t[(size_t)n*BQ + r] + gumbel32(gk0, gk1, (uint32_t)(r*NN + n));
    if (v > best){ best = v; bi = r; }
  }
  __shared__ float sv[256];
  __shared__ int   si[256];
  sv[tid] = best; si[tid] = bi; __syncthreads();
  for (int s = 128; s > 0; s >>= 1){
    if (tid < s){
      float ov = sv[tid+s]; int oi = si[tid+s];
      if (ov > sv[tid] || (ov == sv[tid] && oi < si[tid])){ sv[tid] = ov; si[tid] = oi; }
    }
    __syncthreads();
  }
  if (tid == 0) sel2[n] = si[0];
}

// ---------------- K_PACK: fused transposes + k_om (5 ranges) ----------------
constexpr int PB_SIMT = 400;                // (10 q) x (5 c) x 8 b
constexpr int PB_OMT  = 1440;               // (10 q) x 144 wh
constexpr int PB_TMT  = 1872;               // (13 n) x 144 wh
constexpr int PB_GTP  = 114;                // 29184 / 256
constexpr int PB_OM   = 2700;               // 300 n x 9 ch
__global__ __launch_bounds__(256) void k_pack(
    const float* __restrict__ sims, const float* __restrict__ pm,
    const float* __restrict__ tm, const float* __restrict__ gtsim,
    const int* __restrict__ sel2, const int* __restrict__ bstart,
    u16* __restrict__ simTb, u16* __restrict__ omT,
    u16* __restrict__ tmT, u16* __restrict__ gtp,
    float* __restrict__ msum, float* __restrict__ sc){
  __shared__ float ld[32][65];
  const int blk = blockIdx.x;
  const int tid = threadIdx.x;

  if (blk < PB_SIMT){
    int bx = blk % 10, by = (blk / 10) % 5, b = blk / 50;
    int q0 = bx*32, c0 = by*64;
    for (int i = tid; i < 32*64; i += 256){
      int qi = i >> 6, ci = i & 63;
      int q = q0 + qi, c = c0 + ci;
      ld[qi][ci] = (q < QQ && c < CC) ? sims[((size_t)b*QQ + q)*SIMW + c] : 0.f;
    }
    __syncthreads();
    int cloc = tid >> 2, j0 = (tid & 3)*8;
    int c = c0 + cloc;
    if (c < CP){
      u16 tmp[8];
      #pragma unroll
      for (int j = 0; j < 8; j++) tmp[j] = f2bf(ld[j0+j][cloc]);
      *(uint4*)(simTb + ((size_t)b*CP + c)*QP + q0 + j0) = *(const uint4*)tmp;
    }
  } else if (blk < PB_SIMT + PB_OMT){
    int r = blk - PB_SIMT;
    int q0 = (r % 10)*32, wh0 = (r / 10)*64;
    for (int i = tid; i < 32*64; i += 256){
      int qi = i >> 6, wi = i & 63;
      int q = q0 + qi;
      ld[qi][wi] = (q < QQ) ? pm[(size_t)sel2[q]*WHX + wh0 + wi] * (1.0f/96.0f) : 0.f;
    }
    __syncthreads();
    int wloc = tid >> 2, j0 = (tid & 3)*8;
    u16 tmp[8];
    #pragma unroll
    for (int j = 0; j < 8; j++) tmp[j] = f2bf(ld[j0+j][wloc]);
    *(uint4*)(omT + (size_t)(wh0+wloc)*QP + q0 + j0) = *(const uint4*)tmp;
  } else if (blk < PB_SIMT + PB_OMT + PB_TMT){
    int r = blk - PB_SIMT - PB_OMT;
    int n0 = (r % 13)*32, wh0 = (r / 13)*64;
    for (int i = tid; i < 32*64; i += 256){
      int ni = i >> 6, wi = i & 63;
      int n = n0 + ni;
      ld[ni][wi] = (n < NN) ? tm[(size_t)n*WHX + wh0 + wi] : 0.f;
    }
    __syncthreads();
    int wloc = tid >> 2, j0 = (tid & 3)*8;
    u16 tmp[8];
    #pragma unroll
    for (int j = 0; j < 8; j++) tmp[j] = f2bf(ld[j0+j][wloc]);
    *(uint4*)(tmT + (size_t)(wh0+wloc)*NP + n0 + j0) = *(const uint4*)tmp;
  } else if (blk < PB_SIMT + PB_OMT + PB_TMT + PB_GTP){
    int g = (blk - PB_SIMT - PB_OMT - PB_TMT)*256 + tid;
    int b = g / (CP*(KP/8));
    int rem = g - b*(CP*(KP/8));
    int c = rem / (KP/8);
    int kg = rem % (KP/8);
    int n0 = bstart[b], n1 = bstart[b+1];
    int kst = n0 & ~7;
    u16 tmp[8];
    #pragma unroll
    for (int j = 0; j < 8; j++){
      int n = kst + kg*8 + j;
      float v = (n >= n0 && n < n1 && c < CC) ? gtsim[(size_t)n*CC + c] : 0.f;
      tmp[j] = f2bf(v);
    }
    *(uint4*)(gtp + ((size_t)b*CP + c)*KP + kg*8) = *(const uint4*)tmp;
  } else {
    int nb = blk - (PB_SIMT + PB_OMT + PB_TMT + PB_GTP);
    int n = nb / 9, ch = nb % 9;
    int c0 = ch*1024 + tid*4;
    const float4 o4 = *(const float4*)(pm + (size_t)sel2[n]*WHX + c0);
    const float4 t4 = *(const float4*)(tm + (size_t)n*WHX + c0);
    float dx = o4.x-t4.x, dy = o4.y-t4.y, dz = o4.z-t4.z, dw = o4.w-t4.w;
    float d2 = dx*dx + dy*dy + dz*dz + dw*dw;
    float ts = t4.x + t4.y + t4.z + t4.w;
    float* r1 = &ld[0][0];
    float* r2 = r1 + 256;
    r1[tid] = d2; r2[tid] = ts; __syncthreads();
    for (int s = 128; s > 0; s >>= 1){
      if (tid < s){ r1[tid] += r1[tid+s]; r2[tid] += r2[tid+s]; }
      __syncthreads();
    }
    if (tid == 0){ atomicAdd(&sc[2], r1[0]); atomicAdd(&msum[n], r2[0]); }
  }
}

// ---------------- K15: MFMA z-GEMM + column softmax + dice ----------------
constexpr int ALDS = 32;
__global__ __launch_bounds__(256) void k_zsoft(
    const u16* __restrict__ simTb, const u16* __restrict__ omT,
    const u16* __restrict__ gtp, const u16* __restrict__ tmT,
    const int* __restrict__ bstart, float* __restrict__ sc){
  const int bid = blockIdx.x;
  const int xcd = bid & 7;
  const int r9  = bid >> 3;
  const int tile = xcd * 18 + (r9 % 18);
  const int b    = r9 / 18;
  const int tid = threadIdx.x;
  const int w = tid >> 6, l = tid & 63;
  const int lrow = l & 15, lgrp = l >> 4;
  const int col = tile*64 + w*16 + lrow;

  __shared__ u16 As[2][CP*ALDS];
  __shared__ float red[256];

  const u16* Ab = simTb + (size_t)b*CP*QP;
  int srcoff[5];
  #pragma unroll
  for (int i = 0; i < 5; i++){
    int p = (w*5 + i)*64 + l;
    int row = p >> 2, cs = p & 3;
    int g = cs ^ ((row >> 1) & 3);
    srcoff[i] = row*QP + g*8;
  }
  const int nIss = (w == 3) ? 4 : 5;
  const int roff = (lgrp ^ ((lrow >> 1) & 3)) << 3;
  const u16* pB = omT + (size_t)col*QP + lgrp*8;   // lgrp*8: correct B k-slice

  #pragma unroll
  for (int i = 0; i < 5; i++){
    if (i < nIss) gload_lds16(Ab + srcoff[i], &As[0][(w*5+i)*512]);
  }
  bf16x8 bcur = *(const bf16x8*)(pB);

  f32x4 acc[19];
  #pragma unroll
  for (int t = 0; t < 19; t++) acc[t] = (f32x4){0.f,0.f,0.f,0.f};
  __syncthreads();

  for (int ks = 0; ks < 10; ks++){
    const int cur = ks & 1;
    bf16x8 bnext;
    if (ks + 1 < 10){
      const int ko = (ks + 1) * 32;
      #pragma unroll
      for (int i = 0; i < 5; i++){
        if (i < nIss) gload_lds16(Ab + srcoff[i] + ko, &As[cur ^ 1][(w*5+i)*512]);
      }
      bnext = *(const bf16x8*)(pB + ko);
    }
    __builtin_amdgcn_s_setprio(1);
    #pragma unroll
    for (int t = 0; t < 19; t++){
      bf16x8 af = *(const bf16x8*)&As[cur][t*16*ALDS + lrow*ALDS + roff];
      acc[t] = __builtin_amdgcn_mfma_f32_16x16x32_bf16(af, bcur, acc[t], 0, 0, 0);
    }
    __builtin_amdgcn_s_setprio(0);
    bcur = bnext;
    __syncthreads();
  }

  // ---- issue dice prefetches early: latency hides under softmax VALU ----
  const int n0 = bstart[b];
  const int kst = n0 & ~7;
  const u16* tB = tmT + (size_t)col*NP + kst + lgrp*8;
  bf16x8 b2a = *(const bf16x8*)(tB);
  bf16x8 b2b = *(const bf16x8*)(tB + 32);
  bf16x8 b2c = *(const bf16x8*)(tB + 64);
  const u16* A2 = gtp + (size_t)b*CP*KP + (size_t)lrow*KP + lgrp*8;
  bf16x8 ca0 = *(const bf16x8*)(A2);
  bf16x8 ca1 = *(const bf16x8*)(A2 + 32);
  bf16x8 ca2 = *(const bf16x8*)(A2 + 64);
  bf16x8 da0 = *(const bf16x8*)(A2 + 16*KP);
  bf16x8 da1 = *(const bf16x8*)(A2 + 16*KP + 32);
  bf16x8 da2 = *(const bf16x8*)(A2 + 16*KP + 64);

  float lmax = -INFINITY;
  #pragma unroll
  for (int t = 0; t < 19; t++){
    if (t == 18 && lgrp == 3) continue;
    lmax = fmaxf(lmax, fmaxf(fmaxf(acc[t][0], acc[t][1]), fmaxf(acc[t][2], acc[t][3])));
  }
  lmax = fmaxf(lmax, __shfl_xor(lmax, 16));
  lmax = fmaxf(lmax, __shfl_xor(lmax, 32));
  float ls = 0.f;
  #pragma unroll
  for (int t = 0; t < 19; t++){
    if (t == 18 && lgrp == 3){
      acc[t] = (f32x4){0.f,0.f,0.f,0.f};
      continue;
    }
    float p0 = __expf(acc[t][0] - lmax);
    float p1 = __expf(acc[t][1] - lmax);
    float p2 = __expf(acc[t][2] - lmax);
    float p3 = __expf(acc[t][3] - lmax);
    acc[t][0] = p0; acc[t][1] = p1; acc[t][2] = p2; acc[t][3] = p3;
    ls += p0 + p1 + p2 + p3;
  }
  float S = ls;
  S += __shfl_xor(S, 16);
  S += __shfl_xor(S, 32);
  float inv = 1.f / S;

  // depth-2 software-pipelined dice loop
  float dl = 0.f;
  #pragma unroll
  for (int t = 0; t < 19; t++){
    f32x4 rr = (f32x4){0.f,0.f,0.f,0.f};
    rr = __builtin_amdgcn_mfma_f32_16x16x32_bf16(ca0, b2a, rr, 0, 0, 0);
    rr = __builtin_amdgcn_mfma_f32_16x16x32_bf16(ca1, b2b, rr, 0, 0, 0);
    rr = __builtin_amdgcn_mfma_f32_16x16x32_bf16(ca2, b2c, rr, 0, 0, 0);
    dl += acc[t][0]*rr[0] + acc[t][1]*rr[1] + acc[t][2]*rr[2] + acc[t][3]*rr[3];
    ca0 = da0; ca1 = da1; ca2 = da2;
    if (t + 2 < 19){
      const u16* ar = A2 + (size_t)(t + 2)*16*KP;
      da0 = *(const bf16x8*)(ar);
      da1 = *(const bf16x8*)(ar + 32);
      da2 = *(const bf16x8*)(ar + 64);
    }
  }
  dl *= inv;

  red[tid] = dl; __syncthreads();
  for (int s = 128; s > 0; s >>= 1){
    if (tid < s) red[tid] += red[tid+s];
    __syncthreads();
  }
  if (tid == 0) atomicAdd(&sc[5], red[0]);
}

// ---------------- K16: fused gtiou + sumtgt + finalize ----------------
__global__ __launch_bounds__(512) void k_final3(
    const float* __restrict__ gsel, const float* __restrict__ tb,
    const int* __restrict__ bidx, const float* __restrict__ rowsum,
    const float* __restrict__ msum, const float* __restrict__ sc,
    const int* __restrict__ kint, float* __restrict__ out){
  int tid = threadIdx.x;
  __shared__ float s1[512], s2[512];
  __shared__ float stgt[8];
  if (tid < 8) stgt[tid] = 0.f;
  __syncthreads();
  float a1 = 0.f, a2 = 0.f;
  if (tid < NN){
    float4 g = ((const float4*)gsel)[tid];
    float4 t = ((const float4*)tb)[tid];
    float iou = iou_xyxy(g.x,g.y,g.z,g.w, t.x,t.y,t.z,t.w);
    a1 = 1.f - iou;
    a2 = fabsf(g.x-t.x) + fabsf(g.y-t.y) + fabsf(g.z-t.z) + fabsf(g.w-t.w);
    atomicAdd(&stgt[bidx[tid]], rowsum[tid] * msum[tid]);
  }
  s1[tid] = a1; s2[tid] = a2; __syncthreads();
  for (int s = 256; s > 0; s >>= 1){
    if (tid < s){ s1[tid] += s1[tid+s]; s2[tid] += s2[tid+s]; }
    __syncthreads();
  }
  if (tid == 0){
    float K = (float)kint[0];
    float cls = sc[0]/300.f + sc[1]/300.f;
    float stot = sc[5];
    float dice = 0.f;
    for (int b = 0; b < 8; b++) dice += stot / (9216.0f + stgt[b] + 1e-6f);
    dice *= (1.0f/8.0f);
    out[0] = cls;
    out[1] = dice;
    out[2] = (sc[2] / 2764800.0f) / K;
    out[3] = s1[0] / K;
    out[4] = s2[0] / K;
  }
}

// ---------------- launch ----------------
extern "C" void kernel_launch(void* const* d_in, const int* in_sizes, int n_in,
                              void* d_out, int out_size, void* d_ws, size_t ws_size,
                              hipStream_t stream) {
  const float* ce  = (const float*)d_in[0];
  const float* pl  = (const float*)d_in[1];
  const float* pb  = (const float*)d_in[2];
  const float* pm  = (const float*)d_in[3];
  const float* tm  = (const float*)d_in[4];
  const float* te  = (const float*)d_in[5];
  const float* tbb = (const float*)d_in[6];
  const int*  tids = (const int*)d_in[8];
  const int*  bidx = (const int*)d_in[9];
  float* out = (float*)d_out;
  float* w = (float*)d_ws;

  if (ws_size < F_TOTAL * sizeof(float)) return;

  float* SIMS   = w + F_SIMS;
  float* GTSIM  = w + F_GTSIM;
  float* MM     = w + F_MM;
  float* SCORE  = w + F_SCORE;
  float* BBOX   = w + F_BBOX;
  float* TBOX   = w + F_TB;
  float* SB     = w + F_SB;
  float* KB     = w + F_KB;
  float* ROWSUM = w + F_ROWSUM;
  float* OE     = w + F_OE;
  float* GSEL   = w + F_GSEL;
  float* MSUM   = w + F_MSUM;
  float* SC     = w + F_SC;
  float* S2T    = w + F_S2T;
  int*   CNT    = (int*)(w + F_CNT);
  int*   ORDER  = (int*)(w + F_ORDER);
  int*   NMSIDX = (int*)(w + F_NMSIDX);
  int*   SEL2   = (int*)(w + F_SEL2);
  int*   BSTART = (int*)(w + F_BSTART);
  int*   KINT   = (int*)(w + F_KINT);
  int*   CLS    = (int*)(w + F_CLS);
  int*   KEEPF  = (int*)(w + F_KEEPF);
  int*   LIST   = (int*)(w + F_LIST);
  u16* SIMTB = (u16*)(w + F_SIMTB);
  u16* OMT   = (u16*)(w + F_OMT);
  u16* TMT   = (u16*)(w + F_TMT);
  u16* GTP   = (u16*)(w + F_GTP);

  hipMemsetAsync(w + F_OE, 0, (F_ACCEND - F_OE) * sizeof(float), stream);

  k_gemm_t<<<dim3(43, 10), 256, 0, stream>>>(pl, ce, te, SIMS, GTSIM, S2T);
  k_post<<<BQ, 256, 0, stream>>>(SIMS, pb, tbb, tids, bidx, GTSIM, SCORE, BBOX, TBOX, ROWSUM, CLS);
  k_rankgather<<<BQ, 256, 0, stream>>>(SCORE, BBOX, CLS, bidx, ORDER, SB, BSTART, CNT, LIST);
  k_sel2<<<NN, 256, 0, stream>>>(S2T, SEL2);
  k_pack<<<PB_SIMT + PB_OMT + PB_TMT + PB_GTP + PB_OM, 256, 0, stream>>>(
      SIMS, pm, tm, GTSIM, SEL2, BSTART, SIMTB, OMT, TMT, GTP, MSUM, SC);
  k_cellnms<<<(BB*CC + 255)/256, 256, 0, stream>>>(SB, CNT, LIST, KEEPF);
  k_compact<<<1, 256, 0, stream>>>(KEEPF, ORDER, SB, NMSIDX, KB, KINT);
  k_gtsel<<<BQ, 512, 0, stream>>>(KB, TBOX, NMSIDX, pl, KINT, GSEL, OE);
  k_m_t<<<dim3(10, 10), 256, 0, stream>>>(te, OE, MM);
  k_ce<<<NN, 64, 0, stream>>>(MM, SC);
  k_zsoft<<<dim3((WHX/64) * BB), 256, 0, stream>>>(SIMTB, OMT, GTP, TMT, BSTART, SC);
  k_final3<<<1, 512, 0, stream>>>(GSEL, TBOX, bidx, ROWSUM, MSUM, SC, KINT, out);
}